// Round 2
// 1893.251 us; speedup vs baseline: 1.0649x; 1.0649x over previous
//
#include <hip/hip_runtime.h>
#include <math.h>

typedef long long i64;
#define NN_ 65536L

typedef __attribute__((ext_vector_type(8))) short bf16x8;
typedef __attribute__((ext_vector_type(4))) float f32x4;

__device__ inline unsigned short f2bf(float f){
  unsigned int u = __float_as_uint(f);
  return (unsigned short)((u + 0x7FFFu + ((u>>16)&1u)) >> 16);
}

// ---------------- elementwise ----------------
__global__ __launch_bounds__(256) void copy_k(float* __restrict__ d, const float* __restrict__ s, long n){
  long i = (long)blockIdx.x*blockDim.x + threadIdx.x;
  if (i < n) d[i] = s[i];
}

// channel-major [128][65536] -> row-major [65536][128]
__global__ __launch_bounds__(256) void chw2hwc_k(const float* __restrict__ in, float* __restrict__ out){
  __shared__ float t[32][33];
  int r0 = blockIdx.x*32, c0 = blockIdx.y*32;
  int tx = threadIdx.x & 31, ty = threadIdx.x >> 5;
  for (int i = ty; i < 32; i += 8) t[i][tx] = in[(i64)(c0+i)*NN_ + r0 + tx];
  __syncthreads();
  for (int i = ty; i < 32; i += 8) out[(i64)(r0+i)*128 + c0 + tx] = t[tx][i];
}

// row-major [65536][128] -> ch-major [128][65536] with per-row mask
__global__ __launch_bounds__(256) void tr_mask_k(const float* __restrict__ in, const float* __restrict__ mask,
                                                 float* __restrict__ out){
  __shared__ float t[32][33];
  int r0 = blockIdx.x*32, c0 = blockIdx.y*32;
  int tx = threadIdx.x & 31, ty = threadIdx.x >> 5;
  for (int i = ty; i < 32; i += 8) t[i][tx] = in[(i64)(r0+i)*128 + c0 + tx];
  __syncthreads();
  for (int i = ty; i < 32; i += 8) out[(i64)(c0+i)*NN_ + r0 + tx] = t[tx][i] * mask[r0+tx];
}

// nb [q,k,h=4] -> nbT [h][k][q]
__global__ __launch_bounds__(256) void nbT_k(const float* __restrict__ in, float* __restrict__ out){
  int kk = blockIdx.x, qq = threadIdx.x;
  float4 vv = *(const float4*)(in + ((i64)qq*256 + kk)*4);
  out[0*65536 + kk*256 + qq] = vv.x;
  out[1*65536 + kk*256 + qq] = vv.y;
  out[2*65536 + kk*256 + qq] = vv.z;
  out[3*65536 + kk*256 + qq] = vv.w;
}

// ---------------- LayerNorm generic (rowwise, C arbitrary) ----------------
__global__ __launch_bounds__(128) void ln_k(const float* __restrict__ in, float* __restrict__ out,
                                            const float* __restrict__ w, int C){
  i64 row = blockIdx.x;
  const float* x = in + row*C;
  float* y = out + row*C;
  int tid = threadIdx.x;
  float s=0.f, s2=0.f;
  for (int c=tid;c<C;c+=128){ float v = x[c]; s += v; s2 += v*v; }
  __shared__ float rs[128], rq[128];
  rs[tid]=s; rq[tid]=s2; __syncthreads();
  for (int off=64;off>0;off>>=1){ if (tid<off){ rs[tid]+=rs[tid+off]; rq[tid]+=rq[tid+off]; } __syncthreads(); }
  float mu = rs[0]/C;
  float var = rq[0]/C - mu*mu;
  float inv = rsqrtf(var + 1e-5f);
  for (int c=tid;c<C;c+=128) y[c] = (x[c]-mu)*inv*w[c] + w[C+c];
}

// ---------------- LayerNorm C=128: one wave per row, shuffle-only reduction ----------------
// T=1: read row rt = transpose-pair index of row (fused pa transpose for per-column attention)
__global__ __launch_bounds__(256) void ln128_k(const float* __restrict__ in, float* __restrict__ out,
                                               const float* __restrict__ w, int T){
  int wv = threadIdx.x >> 6, lane = threadIdx.x & 63;
  i64 row = (i64)blockIdx.x*4 + wv;
  i64 rr = T ? (i64)((((int)row & 255) << 8) | ((int)row >> 8)) : row;
  float2 v = *(const float2*)(in + rr*128 + lane*2);
  float s = v.x + v.y, s2 = v.x*v.x + v.y*v.y;
  #pragma unroll
  for (int off=32; off; off>>=1){ s += __shfl_down(s, off); s2 += __shfl_down(s2, off); }
  s = __shfl(s, 0); s2 = __shfl(s2, 0);
  float mu = s*(1.f/128.f);
  float var = s2*(1.f/128.f) - mu*mu;
  float inv = rsqrtf(var + 1e-5f);
  float2 wl = *(const float2*)(w + lane*2);
  float2 wb = *(const float2*)(w + 128 + lane*2);
  float2 y; y.x = (v.x-mu)*inv*wl.x + wb.x; y.y = (v.y-mu)*inv*wl.y + wb.y;
  *(float2*)(out + row*128 + lane*2) = y;
}

// ---------------- bf16 MFMA GEMM: 128x128 tile, 256 thr (2x2 waves of 64x64) ----------------
// combine: 0 store, 1 +=, 2 *=, 3: C += aux*v, 4: C[transpose-pair(m)] += v (pair tensor only)
template<bool TA, bool TB>
__global__ __launch_bounds__(256) void mgemm_k(
    const float* __restrict__ A, int lda, i64 sA,
    const float* __restrict__ B, int ldb, i64 sB,
    float* __restrict__ C, int ldc, i64 sC,
    int M, int N, int K,
    const float* __restrict__ bias, float scale, int act,
    const float* __restrict__ rowmul, int combine, const float* __restrict__ aux)
{
  A += (i64)blockIdx.z * sA;
  B += (i64)blockIdx.z * sB;
  C += (i64)blockIdx.z * sC;
  int m0 = blockIdx.x * 128, n0 = blockIdx.y * 128;
  int tid = threadIdx.x;
  int wave = tid >> 6, lane = tid & 63;
  int quad = lane >> 4, mr = lane & 15;
  int wm = (wave >> 1) * 64, wn = (wave & 1) * 64;
  __shared__ unsigned short As[128][40];
  __shared__ unsigned short Bs[128][40];
  f32x4 acc[4][4];
  #pragma unroll
  for (int i=0;i<4;i++)
    #pragma unroll
    for (int j=0;j<4;j++) acc[i][j] = (f32x4){0.f,0.f,0.f,0.f};

  for (int k0 = 0; k0 < K; k0 += 32){
    if (!TA){
      #pragma unroll
      for (int it=0; it<4; it++){
        int lin = tid + it*256;
        int r = lin >> 3, c4 = (lin & 7) * 4;
        float4 g = *(const float4*)&A[(i64)(m0+r)*lda + k0 + c4];
        As[r][c4]   = f2bf(g.x); As[r][c4+1] = f2bf(g.y);
        As[r][c4+2] = f2bf(g.z); As[r][c4+3] = f2bf(g.w);
      }
    } else {
      #pragma unroll
      for (int it=0; it<4; it++){
        int lin = tid + it*256;
        int m = lin & 127, kg = (lin >> 7) * 4;
        float v0 = A[(i64)(k0+kg  )*lda + m0 + m];
        float v1 = A[(i64)(k0+kg+1)*lda + m0 + m];
        float v2 = A[(i64)(k0+kg+2)*lda + m0 + m];
        float v3 = A[(i64)(k0+kg+3)*lda + m0 + m];
        As[m][kg] = f2bf(v0); As[m][kg+1] = f2bf(v1);
        As[m][kg+2] = f2bf(v2); As[m][kg+3] = f2bf(v3);
      }
    }
    if (!TB){
      #pragma unroll
      for (int it=0; it<4; it++){
        int lin = tid + it*256;
        int n = lin & 127, kg = (lin >> 7) * 4;
        float v0 = B[(i64)(k0+kg  )*ldb + n0 + n];
        float v1 = B[(i64)(k0+kg+1)*ldb + n0 + n];
        float v2 = B[(i64)(k0+kg+2)*ldb + n0 + n];
        float v3 = B[(i64)(k0+kg+3)*ldb + n0 + n];
        Bs[n][kg] = f2bf(v0); Bs[n][kg+1] = f2bf(v1);
        Bs[n][kg+2] = f2bf(v2); Bs[n][kg+3] = f2bf(v3);
      }
    } else {
      #pragma unroll
      for (int it=0; it<4; it++){
        int lin = tid + it*256;
        int r = lin >> 3, c4 = (lin & 7) * 4;
        float4 g = *(const float4*)&B[(i64)(n0+r)*ldb + k0 + c4];
        Bs[r][c4]   = f2bf(g.x); Bs[r][c4+1] = f2bf(g.y);
        Bs[r][c4+2] = f2bf(g.z); Bs[r][c4+3] = f2bf(g.w);
      }
    }
    __syncthreads();
    bf16x8 af[4], bfr[4];
    #pragma unroll
    for (int i=0;i<4;i++) af[i]  = *(const bf16x8*)&As[wm + i*16 + mr][quad*8];
    #pragma unroll
    for (int j=0;j<4;j++) bfr[j] = *(const bf16x8*)&Bs[wn + j*16 + mr][quad*8];
    #pragma unroll
    for (int i=0;i<4;i++)
      #pragma unroll
      for (int j=0;j<4;j++)
        acc[i][j] = __builtin_amdgcn_mfma_f32_16x16x32_bf16(af[i], bfr[j], acc[i][j], 0, 0, 0);
    __syncthreads();
  }
  #pragma unroll
  for (int i=0;i<4;i++){
    #pragma unroll
    for (int r=0;r<4;r++){
      int m = m0 + wm + i*16 + quad*4 + r;
      float rm = rowmul ? rowmul[m] : 1.f;
      i64 mrow = (combine == 4) ? (i64)(((m & 255) << 8) | (m >> 8)) : (i64)m;
      #pragma unroll
      for (int j=0;j<4;j++){
        int n = n0 + wn + j*16 + mr;
        float v = acc[i][j][r] * scale;
        if (bias) v += bias[n];
        if (act == 1) v = fmaxf(v, 0.f);
        else if (act == 2) v = 1.f/(1.f + __expf(-v));
        v *= rm;
        i64 idx = mrow*ldc + n;
        if (combine == 0) C[idx] = v;
        else if (combine == 1 || combine == 4) C[idx] += v;
        else if (combine == 2) C[idx] *= v;
        else C[idx] += aux[(i64)m*ldc + n] * v;
      }
    }
  }
}

// ---------------- fused dual-MFMA lin*sigmoid(gate) for tri-mult (M=65536, N=128, K=128) ----------------
__global__ __launch_bounds__(256) void mlrgate_k(
    const float* __restrict__ X,
    const float* __restrict__ Wl, const float* __restrict__ bl,
    const float* __restrict__ Wg, const float* __restrict__ bg,
    float* __restrict__ Out)
{
  int m0 = blockIdx.x * 128;
  int tid = threadIdx.x;
  int wave = tid >> 6, lane = tid & 63;
  int quad = lane >> 4, mr = lane & 15;
  int wm = (wave >> 1) * 64, wn = (wave & 1) * 64;
  __shared__ unsigned short As[128][40], B1s[128][40], B2s[128][40];
  f32x4 acc1[4][4], acc2[4][4];
  #pragma unroll
  for (int i=0;i<4;i++)
    #pragma unroll
    for (int j=0;j<4;j++){ acc1[i][j] = (f32x4){0,0,0,0}; acc2[i][j] = (f32x4){0,0,0,0}; }

  for (int k0 = 0; k0 < 128; k0 += 32){
    #pragma unroll
    for (int it=0; it<4; it++){
      int lin = tid + it*256;
      int r = lin >> 3, c4 = (lin & 7) * 4;
      float4 g = *(const float4*)&X[(i64)(m0+r)*128 + k0 + c4];
      As[r][c4]   = f2bf(g.x); As[r][c4+1] = f2bf(g.y);
      As[r][c4+2] = f2bf(g.z); As[r][c4+3] = f2bf(g.w);
    }
    #pragma unroll
    for (int it=0; it<4; it++){
      int lin = tid + it*256;
      int n = lin & 127, kg = (lin >> 7) * 4;
      float a0 = Wl[(i64)(k0+kg  )*128 + n];
      float a1 = Wl[(i64)(k0+kg+1)*128 + n];
      float a2 = Wl[(i64)(k0+kg+2)*128 + n];
      float a3 = Wl[(i64)(k0+kg+3)*128 + n];
      B1s[n][kg] = f2bf(a0); B1s[n][kg+1] = f2bf(a1);
      B1s[n][kg+2] = f2bf(a2); B1s[n][kg+3] = f2bf(a3);
      float g0 = Wg[(i64)(k0+kg  )*128 + n];
      float g1 = Wg[(i64)(k0+kg+1)*128 + n];
      float g2 = Wg[(i64)(k0+kg+2)*128 + n];
      float g3 = Wg[(i64)(k0+kg+3)*128 + n];
      B2s[n][kg] = f2bf(g0); B2s[n][kg+1] = f2bf(g1);
      B2s[n][kg+2] = f2bf(g2); B2s[n][kg+3] = f2bf(g3);
    }
    __syncthreads();
    bf16x8 af[4], b1f[4], b2f[4];
    #pragma unroll
    for (int i=0;i<4;i++) af[i]  = *(const bf16x8*)&As[wm + i*16 + mr][quad*8];
    #pragma unroll
    for (int j=0;j<4;j++){
      b1f[j] = *(const bf16x8*)&B1s[wn + j*16 + mr][quad*8];
      b2f[j] = *(const bf16x8*)&B2s[wn + j*16 + mr][quad*8];
    }
    #pragma unroll
    for (int i=0;i<4;i++)
      #pragma unroll
      for (int j=0;j<4;j++){
        acc1[i][j] = __builtin_amdgcn_mfma_f32_16x16x32_bf16(af[i], b1f[j], acc1[i][j], 0, 0, 0);
        acc2[i][j] = __builtin_amdgcn_mfma_f32_16x16x32_bf16(af[i], b2f[j], acc2[i][j], 0, 0, 0);
      }
    __syncthreads();
  }
  #pragma unroll
  for (int i=0;i<4;i++){
    #pragma unroll
    for (int r=0;r<4;r++){
      int m = m0 + wm + i*16 + quad*4 + r;
      #pragma unroll
      for (int j=0;j<4;j++){
        int n = wn + j*16 + mr;
        float lv = acc1[i][j][r] + bl[n];
        float gv = acc2[i][j][r] + bg[n];
        Out[(i64)m*128 + n] = lv * (1.f/(1.f + __expf(-gv)));
      }
    }
  }
}

// ---------------- generic batched GEMM (fp32, 64x64 tile) ----------------
template<bool TA, bool TB>
__global__ __launch_bounds__(256) void gemm_k(
    const float* __restrict__ A, int lda, i64 sA,
    const float* __restrict__ B, int ldb, i64 sB,
    float* __restrict__ C, int ldc, i64 sC,
    int M, int N, int K,
    const float* __restrict__ bias, float scale, int act,
    const float* __restrict__ rowmul, int combine)
{
  A += (i64)blockIdx.z * sA;
  B += (i64)blockIdx.z * sB;
  C += (i64)blockIdx.z * sC;
  int m0 = blockIdx.x * 64, n0 = blockIdx.y * 64;
  int tid = threadIdx.x, tx = tid & 15, ty = tid >> 4;
  __shared__ float As[16][68], Bs[16][68];
  float acc[4][4] = {};
  for (int k0 = 0; k0 < K; k0 += 16){
    if (TA){
      for (int l = tid; l < 1024; l += 256){
        int kk = l >> 6, mi = l & 63; int m = m0 + mi;
        As[kk][mi] = (m < M) ? A[(i64)(k0+kk)*lda + m] : 0.f;
      }
    } else {
      for (int l = tid; l < 1024; l += 256){
        int mi = l >> 4, kk = l & 15; int m = m0 + mi;
        As[kk][mi] = (m < M) ? A[(i64)m*lda + k0 + kk] : 0.f;
      }
    }
    if (TB){
      for (int l = tid; l < 1024; l += 256){
        int ni = l >> 4, kk = l & 15; int n = n0 + ni;
        Bs[kk][ni] = (n < N) ? B[(i64)n*ldb + k0 + kk] : 0.f;
      }
    } else {
      for (int l = tid; l < 1024; l += 256){
        int kk = l >> 6, ni = l & 63; int n = n0 + ni;
        Bs[kk][ni] = (n < N) ? B[(i64)(k0+kk)*ldb + n] : 0.f;
      }
    }
    __syncthreads();
    #pragma unroll
    for (int kk = 0; kk < 16; ++kk){
      float4 av4 = *(const float4*)&As[kk][ty*4];
      float4 bv4 = *(const float4*)&Bs[kk][tx*4];
      float av[4] = {av4.x, av4.y, av4.z, av4.w};
      float bv[4] = {bv4.x, bv4.y, bv4.z, bv4.w};
      #pragma unroll
      for (int i=0;i<4;i++)
        #pragma unroll
        for (int j=0;j<4;j++) acc[i][j] = fmaf(av[i], bv[j], acc[i][j]);
    }
    __syncthreads();
  }
  #pragma unroll
  for (int i=0;i<4;i++){
    int m = m0 + ty*4 + i;
    if (m >= M) continue;
    float rm = rowmul ? rowmul[m] : 1.f;
    #pragma unroll
    for (int j=0;j<4;j++){
      int n = n0 + tx*4 + j;
      if (n >= N) continue;
      float v = acc[i][j] * scale;
      if (bias) v += bias[n];
      if (act == 1) v = fmaxf(v, 0.f);
      else if (act == 2) v = 1.f/(1.f + expf(-v));
      v *= rm;
      i64 idx = (i64)m*ldc + n;
      if (combine == 0) C[idx] = v;
      else if (combine == 1) C[idx] += v;
      else C[idx] *= v;
    }
  }
}

// ---------------- thin GEMM (small M): split-K two-phase ----------------
__global__ __launch_bounds__(256) void gemm_part_k(
    const float* __restrict__ A, int lda,
    const float* __restrict__ B, int ldb,
    float* __restrict__ Cp, int M, int N, int K, int chunk)
{
  int m0 = blockIdx.x*16, n0 = blockIdx.y*64, z = blockIdx.z;
  int kb = z*chunk, ke = min(K, kb+chunk);
  int tid = threadIdx.x;
  int mi = tid >> 4, ni4 = (tid & 15)*4;
  __shared__ float As[16][17], Bs[16][68];
  float acc[4] = {0.f,0.f,0.f,0.f};
  for (int k0 = kb; k0 < ke; k0 += 16){
    { int r = tid>>4, c = tid&15; int m = m0+r;
      As[c][r] = (m < M) ? A[(i64)m*lda + k0 + c] : 0.f; }
    for (int l = tid; l < 1024; l += 256){
      int kk = l>>6, nn = l&63; int n = n0+nn;
      Bs[kk][nn] = (n < N) ? B[(i64)(k0+kk)*ldb + n] : 0.f;
    }
    __syncthreads();
    #pragma unroll
    for (int kk=0;kk<16;kk++){
      float a = As[kk][mi];
      float4 b = *(const float4*)&Bs[kk][ni4];
      acc[0]=fmaf(a,b.x,acc[0]); acc[1]=fmaf(a,b.y,acc[1]);
      acc[2]=fmaf(a,b.z,acc[2]); acc[3]=fmaf(a,b.w,acc[3]);
    }
    __syncthreads();
  }
  int m = m0+mi, n = n0+ni4;
  if (m < M && n < N) *(float4*)&Cp[((i64)z*M + m)*N + n] = *(float4*)acc;
}

__global__ __launch_bounds__(256) void gemm_reduce_k(
    const float* __restrict__ Cp, float* __restrict__ C, int ldc,
    int M, int N, int S,
    const float* __restrict__ bias, float scale, int act,
    const float* __restrict__ rowmul, int combine)
{
  i64 idx = (i64)blockIdx.x*256 + threadIdx.x;
  if (idx >= (i64)M*N) return;
  int m = (int)(idx / N), n = (int)(idx % N);
  float s = 0.f;
  for (int z=0; z<S; z++) s += Cp[(i64)z*M*N + idx];
  float v = s*scale;
  if (bias) v += bias[n];
  if (act == 1) v = fmaxf(v, 0.f);
  else if (act == 2) v = 1.f/(1.f + expf(-v));
  if (rowmul) v *= rowmul[m];
  i64 o = (i64)m*ldc + n;
  if (combine == 0) C[o] = v;
  else if (combine == 1) C[o] += v;
  else C[o] *= v;
}

// ---------------- OPM ----------------
__global__ __launch_bounds__(128) void opm_wd_k(const float* __restrict__ right, const float* __restrict__ W,
                                                float* __restrict__ Wd){
  int d = blockIdx.x, c = blockIdx.y, f = threadIdx.x;
  float acc = 0.f;
  #pragma unroll
  for (int e=0;e<32;e++) acc = fmaf(right[d*32+e], W[((i64)c*32+e)*128 + f], acc);
  Wd[((i64)d*32+c)*128 + f] = acc;
}

// pa[d,b,f] = pair_act[d,b,f] + (sum_c left[b,c]*Wd[d,c,f] + ob[f]) / (1e-3 + sm[d]*sm[b])
__global__ __launch_bounds__(128) void opm_final_k(const float* __restrict__ left, const float* __restrict__ Wd,
                                                   const float* __restrict__ ob, const float* __restrict__ sm,
                                                   const float* __restrict__ pair_act, float* __restrict__ pa){
  int d = blockIdx.x, b0 = blockIdx.y*16, f = threadIdx.x;
  __shared__ float wd_s[32][128];
  __shared__ float l_s[16][32];
  for (int c=0;c<32;c++) wd_s[c][f] = Wd[((i64)d*32+c)*128 + f];
  for (int l = f; l < 512; l += 128){ int bi=l>>5, c=l&31; l_s[bi][c] = left[(b0+bi)*32 + c]; }
  __syncthreads();
  float md = sm[d], obf = ob[f];
  for (int bi=0;bi<16;bi++){
    float acc = 0.f;
    #pragma unroll
    for (int c=0;c<32;c++) acc = fmaf(l_s[bi][c], wd_s[c][f], acc);
    int b = b0+bi;
    i64 idx = ((i64)d*256 + b)*128 + f;
    pa[idx] = pair_act[idx] + (acc + obf) / (1e-3f + md*sm[b]);
  }
}

// ---------------- row attention core ----------------
__global__ __launch_bounds__(256) void ra_attn_k(const float* __restrict__ q, const float* __restrict__ k,
                                                 const float* __restrict__ v, const float* __restrict__ nb,
                                                 const float* __restrict__ sm, float* __restrict__ wa){
  int qi = blockIdx.x, h = blockIdx.y, tid = threadIdx.x;
  __shared__ float qv[48];
  __shared__ float p[256];
  __shared__ float red[256];
  if (tid < 48) qv[tid] = q[(i64)qi*384 + h*48 + tid];
  __syncthreads();
  float acc = 0.f;
  const float* kr = k + (i64)tid*384 + h*48;
  #pragma unroll
  for (int c=0;c<48;c++) acc = fmaf(qv[c], kr[c], acc);
  acc += 1e9f*(sm[tid]-1.f) + nb[((i64)qi*256 + tid)*8 + h];
  red[tid] = acc; __syncthreads();
  for (int off=128;off>0;off>>=1){ if (tid<off) red[tid] = fmaxf(red[tid], red[tid+off]); __syncthreads(); }
  float mx = red[0]; __syncthreads();
  float e = expf(acc - mx);
  red[tid] = e; __syncthreads();
  for (int off=128;off>0;off>>=1){ if (tid<off) red[tid] += red[tid+off]; __syncthreads(); }
  p[tid] = e / red[0];
  __syncthreads();
  if (tid < 48){
    float a = 0.f;
    for (int kk=0;kk<256;kk++) a = fmaf(p[kk], v[(i64)kk*384 + h*48 + tid], a);
    wa[(i64)qi*384 + h*48 + tid] = a;
  }
}

// ---------------- triangle attention core v6: MFMA 16x16x32 bf16 flash ----------------
// Replaces scalar v4 (180 us, MfmaUtil=0, VALU-bound at the 55 us fp32-FMA floor).
// Block = (b, h, qblk): 4 waves x 16 q-rows = 64 q rows per block; keys processed in
// 32-wide tiles, K/V staged bf16 in LDS in two 128-key halves (25 KB -> 6 blocks/CU).
// Fragment mapping identical to mgemm_k (verified): A-frag row = lane&15, k = quad*8;
// C/D row = quad*4+reg, col = lane&15.
//  - QK^T: A = Q[16q x 32c] (regs), B = K[key][c] from Ks (pad 40 -> 2-way-free banks).
//  - online softmax: per-row butterfly shfl_xor over the 16 'mr' lanes (cols).
//  - P (bf16) round-trips a PER-WAVE LDS tile Pl[16][40] (no barrier; same-wave DS order).
//  - PV: A = P from Pl, B = V^T from Vt[32][136] (contiguous 16B reads).
__global__ __launch_bounds__(256) void ta_mfma_k(
    const float* __restrict__ q, const float* __restrict__ k, const float* __restrict__ v,
    const float* __restrict__ nbT, const float* __restrict__ mask, int maskT,
    float* __restrict__ wa)
{
  int b = blockIdx.x, h = blockIdx.y, qblk = blockIdx.z;
  int tid = threadIdx.x;
  int wave = tid >> 6, lane = tid & 63;
  int quad = lane >> 4, mr = lane & 15;
  const i64 base = ((i64)b*256)*128 + h*32;
  const float* nbh = nbT + (i64)h*65536;

  __shared__ unsigned short Ks[128][40];   // [key_local][c], row 80B (16B-aligned, 2-way banks)
  __shared__ unsigned short Vt[32][136];   // [c][key_local], row 272B
  __shared__ float mask_s[256];
  __shared__ unsigned short Pl[4][16][40]; // per-wave P tile [q][key_local]

  mask_s[tid] = 1e9f * ((maskT ? mask[(i64)tid*256 + b] : mask[(i64)b*256 + tid]) - 1.f);

  // Q fragment: rows q0w+mr, cols quad*8..+8 (reads complete before the in-place O write)
  int q0w = qblk*64 + wave*16;
  bf16x8 qf;
  {
    const float* qp = q + base + (i64)(q0w + mr)*128 + quad*8;
    float4 a = *(const float4*)qp;
    float4 c = *(const float4*)(qp+4);
    qf[0]=(short)f2bf(a.x); qf[1]=(short)f2bf(a.y); qf[2]=(short)f2bf(a.z); qf[3]=(short)f2bf(a.w);
    qf[4]=(short)f2bf(c.x); qf[5]=(short)f2bf(c.y); qf[6]=(short)f2bf(c.z); qf[7]=(short)f2bf(c.w);
  }

  f32x4 o0 = (f32x4){0,0,0,0}, o1 = (f32x4){0,0,0,0};
  float mm[4], ll[4];
  #pragma unroll
  for (int r=0;r<4;r++){ mm[r] = -1e30f; ll[r] = 0.f; }

  for (int half = 0; half < 2; half++){
    __syncthreads();   // waves done with previous half's Ks/Vt (and mask_s staged, first pass)
    #pragma unroll
    for (int it=0; it<4; it++){
      int idx = it*256 + tid;              // 0..1023 -> 128 keys x 32 c
      int kl = idx >> 3, c4 = (idx & 7)*4;
      i64 roff = base + (i64)(half*128 + kl)*128 + c4;
      float4 g  = *(const float4*)(k + roff);
      unsigned short* d = &Ks[kl][c4];
      d[0]=f2bf(g.x); d[1]=f2bf(g.y); d[2]=f2bf(g.z); d[3]=f2bf(g.w);
      float4 gv = *(const float4*)(v + roff);
      Vt[c4  ][kl] = f2bf(gv.x);
      Vt[c4+1][kl] = f2bf(gv.y);
      Vt[c4+2][kl] = f2bf(gv.z);
      Vt[c4+3][kl] = f2bf(gv.w);
    }
    __syncthreads();

    #pragma unroll
    for (int it=0; it<4; it++){
      int kc = it*32;                 // key base within half
      int kg = half*128 + kc;         // global key base
      int k0g = kg + mr, k1g = kg + 16 + mr;
      // bias loads issued early to overlap MFMA
      float nb0[4], nb1[4];
      #pragma unroll
      for (int r=0;r<4;r++){
        int qg = q0w + quad*4 + r;
        nb0[r] = nbh[(i64)k0g*256 + qg];
        nb1[r] = nbh[(i64)k1g*256 + qg];
      }
      bf16x8 kf0 = *(const bf16x8*)&Ks[kc + mr][quad*8];
      bf16x8 kf1 = *(const bf16x8*)&Ks[kc + 16 + mr][quad*8];
      f32x4 s0 = __builtin_amdgcn_mfma_f32_16x16x32_bf16(qf, kf0, (f32x4){0,0,0,0}, 0, 0, 0);
      f32x4 s1 = __builtin_amdgcn_mfma_f32_16x16x32_bf16(qf, kf1, (f32x4){0,0,0,0}, 0, 0, 0);
      float mb0 = mask_s[k0g], mb1 = mask_s[k1g];
      #pragma unroll
      for (int r=0;r<4;r++){ s0[r] += mb0 + nb0[r]; s1[r] += mb1 + nb1[r]; }

      // online softmax, rows = quad*4+r; reduce over 16 'mr' lanes (2 keys each)
      #pragma unroll
      for (int r=0;r<4;r++){
        float nm = fmaxf(s0[r], s1[r]);
        nm = fmaxf(nm, __shfl_xor(nm, 1));
        nm = fmaxf(nm, __shfl_xor(nm, 2));
        nm = fmaxf(nm, __shfl_xor(nm, 4));
        nm = fmaxf(nm, __shfl_xor(nm, 8));
        nm = fmaxf(nm, mm[r]);
        float alpha = __expf(mm[r] - nm);
        mm[r] = nm;
        float e0 = __expf(s0[r] - nm), e1 = __expf(s1[r] - nm);
        float ps = e0 + e1;
        ps += __shfl_xor(ps, 1);
        ps += __shfl_xor(ps, 2);
        ps += __shfl_xor(ps, 4);
        ps += __shfl_xor(ps, 8);
        ll[r] = ll[r]*alpha + ps;
        o0[r] *= alpha; o1[r] *= alpha;
        Pl[wave][quad*4+r][mr]      = f2bf(e0);
        Pl[wave][quad*4+r][mr + 16] = f2bf(e1);
      }
      // PV: A = P[q=mr][key_local = quad*8+j], B = V^T
      bf16x8 pf  = *(const bf16x8*)&Pl[wave][mr][quad*8];
      bf16x8 vf0 = *(const bf16x8*)&Vt[mr     ][kc + quad*8];
      bf16x8 vf1 = *(const bf16x8*)&Vt[16 + mr][kc + quad*8];
      o0 = __builtin_amdgcn_mfma_f32_16x16x32_bf16(pf, vf0, o0, 0, 0, 0);
      o1 = __builtin_amdgcn_mfma_f32_16x16x32_bf16(pf, vf1, o1, 0, 0, 0);
    }
  }

  #pragma unroll
  for (int r=0;r<4;r++){
    float inv = 1.f/ll[r];
    float* wp = wa + base + (i64)(q0w + quad*4 + r)*128;
    wp[mr]      = o0[r]*inv;
    wp[16 + mr] = o1[r]*inv;
  }
}

// ---------------- host dispatch ----------------
static void gemm(hipStream_t st, bool TA, bool TB,
                 const float* A, int lda, i64 sA,
                 const float* B, int ldb, i64 sB,
                 float* C, int ldc, i64 sC,
                 int M, int N, int K, int batch,
                 const float* bias, float scale, int act,
                 const float* rowmul, int combine)
{
  dim3 g((M+63)/64, (N+63)/64, batch), bl(256);
  if (!TA && !TB)      gemm_k<false,false><<<g,bl,0,st>>>(A,lda,sA,B,ldb,sB,C,ldc,sC,M,N,K,bias,scale,act,rowmul,combine);
  else if (!TA &&  TB) gemm_k<false,true ><<<g,bl,0,st>>>(A,lda,sA,B,ldb,sB,C,ldc,sC,M,N,K,bias,scale,act,rowmul,combine);
  else                 gemm_k<true ,false><<<g,bl,0,st>>>(A,lda,sA,B,ldb,sB,C,ldc,sC,M,N,K,bias,scale,act,rowmul,combine);
}

static void mgemm(hipStream_t st, bool TA, bool TB,
                  const float* A, int lda, i64 sA,
                  const float* B, int ldb, i64 sB,
                  float* C, int ldc, i64 sC,
                  int M, int N, int K, int batch,
                  const float* bias, float scale, int act,
                  const float* rowmul, int combine, const float* aux = nullptr)
{
  dim3 g(M/128, N/128, batch), bl(256);
  if (!TA && !TB)      mgemm_k<false,false><<<g,bl,0,st>>>(A,lda,sA,B,ldb,sB,C,ldc,sC,M,N,K,bias,scale,act,rowmul,combine,aux);
  else if (!TA &&  TB) mgemm_k<false,true ><<<g,bl,0,st>>>(A,lda,sA,B,ldb,sB,C,ldc,sC,M,N,K,bias,scale,act,rowmul,combine,aux);
  else                 mgemm_k<true ,false><<<g,bl,0,st>>>(A,lda,sA,B,ldb,sB,C,ldc,sC,M,N,K,bias,scale,act,rowmul,combine,aux);
}

static void gemm_thin(hipStream_t st,
                      const float* A, int lda, const float* B, int ldb,
                      float* C, int ldc, int M, int N, int K,
                      const float* bias, float scale, int act,
                      const float* rowmul, int combine, float* part)
{
  const int S = 8;
  int chunk = ((K/S + 15)/16)*16; if (chunk < 16) chunk = 16;
  dim3 g((M+15)/16, (N+63)/64, S);
  gemm_part_k<<<g,256,0,st>>>(A,lda,B,ldb,part,M,N,K,chunk);
  i64 t = (i64)M*N;
  gemm_reduce_k<<<(int)((t+255)/256),256,0,st>>>(part,C,ldc,M,N,S,bias,scale,act,rowmul,combine);
}

extern "C" void kernel_launch(void* const* d_in, const int* in_sizes, int n_in,
                              void* d_out, int out_size, void* d_ws, size_t ws_size,
                              hipStream_t stream)
{
  const float* IN[64];
  for (int i=0;i<n_in && i<64;i++) IN[i] = (const float*)d_in[i];

  const float* single_act = IN[0];
  const float* pair_act   = IN[1];
  const float* sm         = IN[2];
  const float* pm         = IN[3];
  const float* opm_ln     = IN[4];
  const float* opm_lr_w   = IN[5];
  const float* opm_lr_b   = IN[6];
  const float* opm_out_w  = IN[7];
  const float* opm_out_b  = IN[8];
  const float* ra_ln      = IN[9];
  const float* ra_pair_ln = IN[10];
  const float* ra_feat_w  = IN[11];
  const float* ra_qkv_w   = IN[12];
  const float* ra_gate_w  = IN[13];
  const float* ra_gate_b  = IN[14];
  const float* ra_o_w     = IN[15];
  const float* ra_o_b     = IN[16];
  const float* st_ln      = IN[17];
  const float* st_w1      = IN[18];
  const float* st_b1      = IN[19];
  const float* st_w2      = IN[20];
  const float* st_b2      = IN[21];
  const float* pt_ln      = IN[56];
  const float* pt_w1      = IN[57];
  const float* pt_b1      = IN[58];
  const float* pt_w2      = IN[59];
  const float* pt_b2      = IN[60];

  float* sa = (float*)d_out;           // [256,384]
  float* pa = (float*)d_out + 98304;   // [256,256,128]

  float* W  = (float*)d_ws;
  float* B0 = W;
  float* B1 = W + 8388608L;
  float* B2 = W + 16777216L;
  float* B3 = W + 25165824L;
  float* SMA = W + 33554432L;
  float* xs   = SMA;
  float* qb   = SMA +  98304;
  float* kb   = SMA + 196608;
  float* vb   = SMA + 294912;
  float* wab  = SMA + 393216;
  float* hst  = SMA + 491520;   // 393216
  float* nbra = SMA + 884736;   // 524288 (reused as nbT in tri-attn phase)
  float* lbuf = SMA + 1409024;  // 8192
  float* rbuf = SMA + 1417216;  // 8192
  float* Wd   = SMA + 1425408;  // 1048576
  float* nbt  = SMA + 2473984;  // 262144

  // init sa with residual base (pa is initialized by opm_final_k's fused write)
  copy_k<<<384, 256, 0, stream>>>(sa, single_act, 98304L);

  // ---- 1) OPM -> pair residual (writes pa = pair_act + update) ----
  ln_k<<<256,128,0,stream>>>(single_act, xs, opm_ln, 384);
  gemm_thin(stream, xs,384, opm_lr_w,32,       lbuf,32, 256,32,384, opm_lr_b,    1.f,0, sm,0, B1);
  gemm_thin(stream, xs,384, opm_lr_w+12288,32, rbuf,32, 256,32,384, opm_lr_b+32, 1.f,0, sm,0, B1);
  opm_wd_k<<<dim3(256,32),128,0,stream>>>(rbuf, opm_out_w, Wd);
  opm_final_k<<<dim3(256,16),128,0,stream>>>(lbuf, Wd, opm_out_b, sm, pair_act, pa);

  // ---- 2) row attention with pair bias ----
  ln_k<<<256,128,0,stream>>>(sa, xs, ra_ln, 384);
  ln128_k<<<16384,256,0,stream>>>(pa, B0, ra_pair_ln, 0);
  gemm(stream,false,false, B0,128,0, ra_feat_w,8,0, nbra,8,0, 65536,8,128,1, nullptr,1.f,0,nullptr,0);
  const float qs_ra = 0.14433756729740643f; // 1/sqrt(48)
  gemm_thin(stream, xs,384, ra_qkv_w,384,        qb,384, 256,384,384, nullptr,qs_ra,0,nullptr,0, B1);
  gemm_thin(stream, xs,384, ra_qkv_w+147456,384, kb,384, 256,384,384, nullptr,1.f,0,nullptr,0, B1);
  gemm_thin(stream, xs,384, ra_qkv_w+294912,384, vb,384, 256,384,384, nullptr,1.f,0,nullptr,0, B1);
  ra_attn_k<<<dim3(256,8),256,0,stream>>>(qb, kb, vb, nbra, sm, wab);
  gemm_thin(stream, xs,384,  ra_gate_w,384, wab,384, 256,384,384, ra_gate_b,1.f,2,nullptr,2, B1);
  gemm_thin(stream, wab,384, ra_o_w,384,    sa,384,  256,384,384, ra_o_b,   1.f,0,nullptr,1, B1);

  // ---- 3) single transition ----
  ln_k<<<256,128,0,stream>>>(sa, xs, st_ln, 384);
  gemm_thin(stream, xs,384,   st_w1,1536, hst,1536, 256,1536,384, st_b1,1.f,1,nullptr,0, B1);
  gemm_thin(stream, hst,1536, st_w2,384,  sa,384,   256,384,1536, st_b2,1.f,0,nullptr,1, B1);

  // ---- 4/5) triangle multiplications ----
  auto tri_mult = [&](int base, bool outgoing){
    const float* ln_w = IN[base+0];
    const float* lr_w = IN[base+1];
    const float* lr_b = IN[base+2];
    const float* gw   = IN[base+3];
    const float* gb   = IN[base+4];
    const float* cln  = IN[base+5];
    const float* ow   = IN[base+6];
    const float* ob   = IN[base+7];
    const float* ogw  = IN[base+8];
    const float* ogb  = IN[base+9];
    ln128_k<<<16384,256,0,stream>>>(pa, B0, ln_w, 0);
    // left = mask * (X@Wl+bl) * sigmoid(X@Wg+bg): fused dual-MFMA, then transpose+mask -> B1 (ch-major)
    mlrgate_k<<<512,256,0,stream>>>(B0, lr_w, lr_b, gw, gb, B3);
    tr_mask_k<<<dim3(2048,4),256,0,stream>>>(B3, pm, B1);
    // right -> B2 (ch-major)
    mlrgate_k<<<512,256,0,stream>>>(B0, lr_w+16384, lr_b+128, gw+16384, gb+128, B3);
    tr_mask_k<<<dim3(2048,4),256,0,stream>>>(B3, pm, B2);
    if (outgoing) // out[i,j,c] = sum_k L_c[i,k] * R_c[j,k]
      mgemm(stream,false,true, B1,256,65536, B2,256,65536, B3,256,65536, 256,256,256,128, nullptr,1.f,0,nullptr,0);
    else          // out[i,j,c] = sum_k R_c[k,i] * L_c[k,j]
      mgemm(stream,true,false, B2,256,65536, B1,256,65536, B3,256,65536, 256,256,256,128, nullptr,1.f,0,nullptr,0);
    chw2hwc_k<<<dim3(2048,4),256,0,stream>>>(B3, B1);
    ln128_k<<<16384,256,0,stream>>>(B1, B3, cln, 0);
    mgemm(stream,false,false, B3,128,0, ow,128,0,  B1,128,0, 65536,128,128,1, ob,  1.f,0,nullptr,0);
    // fused: pa += B1 * sigmoid(B0@ogw + ogb)
    mgemm(stream,false,false, B0,128,0, ogw,128,0, pa,128,0, 65536,128,128,1, ogb, 1.f,2,nullptr,3, B1);
  };
  tri_mult(22, true);   // tmo
  tri_mult(32, false);  // tmi

  // ---- 6/7) triangle attentions ----
  auto tri_attn = [&](int base, bool percol){
    const float* ln_w   = IN[base+0];
    const float* feat_w = IN[base+1];
    const float* qkv_w  = IN[base+2];
    const float* gw     = IN[base+3];
    const float* gb     = IN[base+4];
    const float* ow     = IN[base+5];
    const float* ob     = IN[base+6];
    // LN with fused pair-transpose read for per-column attention
    ln128_k<<<16384,256,0,stream>>>(pa, B0, ln_w, percol?1:0);
    gemm(stream,false,false, B0,128,0, feat_w,4,0, nbt,4,0, 65536,4,128,1, nullptr,1.f,0,nullptr,0);
    nbT_k<<<256,256,0,stream>>>(nbt, nbra);  // nbT[h][k][q]
    const float qs = 0.17677669529663687f; // 1/sqrt(32)
    mgemm(stream,false,false, B0,128,0, qkv_w,128,0,       B1,128,0, 65536,128,128,1, nullptr,qs, 0,nullptr,0);
    mgemm(stream,false,false, B0,128,0, qkv_w+16384,128,0, B2,128,0, 65536,128,128,1, nullptr,1.f,0,nullptr,0);
    mgemm(stream,false,false, B0,128,0, qkv_w+32768,128,0, B3,128,0, 65536,128,128,1, nullptr,1.f,0,nullptr,0);
    ta_mfma_k<<<dim3(256,4,4),256,0,stream>>>(B1, B2, B3, nbra, pm, percol?1:0, B1);
    mgemm(stream,false,false, B0,128,0, gw,128,0, B1,128,0, 65536,128,128,1, gb,1.f,2,nullptr,2); // wa *= sigmoid(gate)
    // out-projection fused with residual add (4 = transpose-pair write for per-column)
    mgemm(stream,false,false, B1,128,0, ow,128,0, pa,128,0, 65536,128,128,1, ob,1.f,0,nullptr, percol?4:1);
  };
  tri_attn(42, false);  // tas (per-row)
  tri_attn(49, true);   // tae (per-column)

  // ---- 8) pair transition ----
  ln128_k<<<16384,256,0,stream>>>(pa, B0, pt_ln, 0);
  for (int half = 0; half < 2; half++){
    const float* xh = B0 + (i64)half*4194304;
    float* ph = pa + (i64)half*4194304;
    mgemm(stream,false,false, xh,128,0, pt_w1,512,0, B1,512,0, 32768,512,128,1, pt_b1,1.f,1,nullptr,0);
    mgemm(stream,false,false, B1,512,0, pt_w2,128,0, ph,128,0, 32768,128,512,1, pt_b2,1.f,0,nullptr,1);
  }
}

// Round 3
// 1852.472 us; speedup vs baseline: 1.0883x; 1.0220x over previous
//
#include <hip/hip_runtime.h>
#include <math.h>

typedef long long i64;
#define NN_ 65536L

typedef __attribute__((ext_vector_type(8))) short bf16x8;
typedef __attribute__((ext_vector_type(4))) float f32x4;

__device__ inline unsigned short f2bf(float f){
  unsigned int u = __float_as_uint(f);
  return (unsigned short)((u + 0x7FFFu + ((u>>16)&1u)) >> 16);
}

// ---------------- elementwise ----------------
__global__ __launch_bounds__(256) void copy_k(float* __restrict__ d, const float* __restrict__ s, long n){
  long i = (long)blockIdx.x*blockDim.x + threadIdx.x;
  if (i < n) d[i] = s[i];
}

// channel-major [128][65536] -> row-major [65536][128]
__global__ __launch_bounds__(256) void chw2hwc_k(const float* __restrict__ in, float* __restrict__ out){
  __shared__ float t[32][33];
  int r0 = blockIdx.x*32, c0 = blockIdx.y*32;
  int tx = threadIdx.x & 31, ty = threadIdx.x >> 5;
  for (int i = ty; i < 32; i += 8) t[i][tx] = in[(i64)(c0+i)*NN_ + r0 + tx];
  __syncthreads();
  for (int i = ty; i < 32; i += 8) out[(i64)(r0+i)*128 + c0 + tx] = t[tx][i];
}

// row-major [65536][128] -> ch-major [128][65536] with per-row mask
__global__ __launch_bounds__(256) void tr_mask_k(const float* __restrict__ in, const float* __restrict__ mask,
                                                 float* __restrict__ out){
  __shared__ float t[32][33];
  int r0 = blockIdx.x*32, c0 = blockIdx.y*32;
  int tx = threadIdx.x & 31, ty = threadIdx.x >> 5;
  for (int i = ty; i < 32; i += 8) t[i][tx] = in[(i64)(r0+i)*128 + c0 + tx];
  __syncthreads();
  for (int i = ty; i < 32; i += 8) out[(i64)(c0+i)*NN_ + r0 + tx] = t[tx][i] * mask[r0+tx];
}

// nb [q,k,h=4] -> nbQ [h][q][k]  (block = q row, thread = k: coalesced read AND write)
__global__ __launch_bounds__(256) void nbQ_k(const float* __restrict__ in, float* __restrict__ out){
  int qq = blockIdx.x, kk = threadIdx.x;
  float4 vv = *(const float4*)(in + ((i64)qq*256 + kk)*4);
  out[0*65536 + qq*256 + kk] = vv.x;
  out[1*65536 + qq*256 + kk] = vv.y;
  out[2*65536 + qq*256 + kk] = vv.z;
  out[3*65536 + qq*256 + kk] = vv.w;
}

// ---------------- LayerNorm generic (rowwise, C arbitrary) ----------------
__global__ __launch_bounds__(128) void ln_k(const float* __restrict__ in, float* __restrict__ out,
                                            const float* __restrict__ w, int C){
  i64 row = blockIdx.x;
  const float* x = in + row*C;
  float* y = out + row*C;
  int tid = threadIdx.x;
  float s=0.f, s2=0.f;
  for (int c=tid;c<C;c+=128){ float v = x[c]; s += v; s2 += v*v; }
  __shared__ float rs[128], rq[128];
  rs[tid]=s; rq[tid]=s2; __syncthreads();
  for (int off=64;off>0;off>>=1){ if (tid<off){ rs[tid]+=rs[tid+off]; rq[tid]+=rq[tid+off]; } __syncthreads(); }
  float mu = rs[0]/C;
  float var = rq[0]/C - mu*mu;
  float inv = rsqrtf(var + 1e-5f);
  for (int c=tid;c<C;c+=128) y[c] = (x[c]-mu)*inv*w[c] + w[C+c];
}

// ---------------- LayerNorm C=128: one wave per row, shuffle-only reduction ----------------
// T=1: read row rt = transpose-pair index of row (fused pa transpose for per-column attention)
__global__ __launch_bounds__(256) void ln128_k(const float* __restrict__ in, float* __restrict__ out,
                                               const float* __restrict__ w, int T){
  int wv = threadIdx.x >> 6, lane = threadIdx.x & 63;
  i64 row = (i64)blockIdx.x*4 + wv;
  i64 rr = T ? (i64)((((int)row & 255) << 8) | ((int)row >> 8)) : row;
  float2 v = *(const float2*)(in + rr*128 + lane*2);
  float s = v.x + v.y, s2 = v.x*v.x + v.y*v.y;
  #pragma unroll
  for (int off=32; off; off>>=1){ s += __shfl_down(s, off); s2 += __shfl_down(s2, off); }
  s = __shfl(s, 0); s2 = __shfl(s2, 0);
  float mu = s*(1.f/128.f);
  float var = s2*(1.f/128.f) - mu*mu;
  float inv = rsqrtf(var + 1e-5f);
  float2 wl = *(const float2*)(w + lane*2);
  float2 wb = *(const float2*)(w + 128 + lane*2);
  float2 y; y.x = (v.x-mu)*inv*wl.x + wb.x; y.y = (v.y-mu)*inv*wl.y + wb.y;
  *(float2*)(out + row*128 + lane*2) = y;
}

// ---------------- bf16 MFMA GEMM: 128x128 tile, 256 thr (2x2 waves of 64x64) ----------------
// combine: 0 store, 1 +=, 2 *=, 3: C += aux*v, 4: C[transpose-pair(m)] += v (pair tensor only)
template<bool TA, bool TB>
__global__ __launch_bounds__(256) void mgemm_k(
    const float* __restrict__ A, int lda, i64 sA,
    const float* __restrict__ B, int ldb, i64 sB,
    float* __restrict__ C, int ldc, i64 sC,
    int M, int N, int K,
    const float* __restrict__ bias, float scale, int act,
    const float* __restrict__ rowmul, int combine, const float* __restrict__ aux)
{
  A += (i64)blockIdx.z * sA;
  B += (i64)blockIdx.z * sB;
  C += (i64)blockIdx.z * sC;
  int m0 = blockIdx.x * 128, n0 = blockIdx.y * 128;
  int tid = threadIdx.x;
  int wave = tid >> 6, lane = tid & 63;
  int quad = lane >> 4, mr = lane & 15;
  int wm = (wave >> 1) * 64, wn = (wave & 1) * 64;
  __shared__ unsigned short As[128][40];
  __shared__ unsigned short Bs[128][40];
  f32x4 acc[4][4];
  #pragma unroll
  for (int i=0;i<4;i++)
    #pragma unroll
    for (int j=0;j<4;j++) acc[i][j] = (f32x4){0.f,0.f,0.f,0.f};

  for (int k0 = 0; k0 < K; k0 += 32){
    if (!TA){
      #pragma unroll
      for (int it=0; it<4; it++){
        int lin = tid + it*256;
        int r = lin >> 3, c4 = (lin & 7) * 4;
        float4 g = *(const float4*)&A[(i64)(m0+r)*lda + k0 + c4];
        As[r][c4]   = f2bf(g.x); As[r][c4+1] = f2bf(g.y);
        As[r][c4+2] = f2bf(g.z); As[r][c4+3] = f2bf(g.w);
      }
    } else {
      #pragma unroll
      for (int it=0; it<4; it++){
        int lin = tid + it*256;
        int m = lin & 127, kg = (lin >> 7) * 4;
        float v0 = A[(i64)(k0+kg  )*lda + m0 + m];
        float v1 = A[(i64)(k0+kg+1)*lda + m0 + m];
        float v2 = A[(i64)(k0+kg+2)*lda + m0 + m];
        float v3 = A[(i64)(k0+kg+3)*lda + m0 + m];
        As[m][kg] = f2bf(v0); As[m][kg+1] = f2bf(v1);
        As[m][kg+2] = f2bf(v2); As[m][kg+3] = f2bf(v3);
      }
    }
    if (!TB){
      #pragma unroll
      for (int it=0; it<4; it++){
        int lin = tid + it*256;
        int n = lin & 127, kg = (lin >> 7) * 4;
        float v0 = B[(i64)(k0+kg  )*ldb + n0 + n];
        float v1 = B[(i64)(k0+kg+1)*ldb + n0 + n];
        float v2 = B[(i64)(k0+kg+2)*ldb + n0 + n];
        float v3 = B[(i64)(k0+kg+3)*ldb + n0 + n];
        Bs[n][kg] = f2bf(v0); Bs[n][kg+1] = f2bf(v1);
        Bs[n][kg+2] = f2bf(v2); Bs[n][kg+3] = f2bf(v3);
      }
    } else {
      #pragma unroll
      for (int it=0; it<4; it++){
        int lin = tid + it*256;
        int r = lin >> 3, c4 = (lin & 7) * 4;
        float4 g = *(const float4*)&B[(i64)(n0+r)*ldb + k0 + c4];
        Bs[r][c4]   = f2bf(g.x); Bs[r][c4+1] = f2bf(g.y);
        Bs[r][c4+2] = f2bf(g.z); Bs[r][c4+3] = f2bf(g.w);
      }
    }
    __syncthreads();
    bf16x8 af[4], bfr[4];
    #pragma unroll
    for (int i=0;i<4;i++) af[i]  = *(const bf16x8*)&As[wm + i*16 + mr][quad*8];
    #pragma unroll
    for (int j=0;j<4;j++) bfr[j] = *(const bf16x8*)&Bs[wn + j*16 + mr][quad*8];
    #pragma unroll
    for (int i=0;i<4;i++)
      #pragma unroll
      for (int j=0;j<4;j++)
        acc[i][j] = __builtin_amdgcn_mfma_f32_16x16x32_bf16(af[i], bfr[j], acc[i][j], 0, 0, 0);
    __syncthreads();
  }
  #pragma unroll
  for (int i=0;i<4;i++){
    #pragma unroll
    for (int r=0;r<4;r++){
      int m = m0 + wm + i*16 + quad*4 + r;
      float rm = rowmul ? rowmul[m] : 1.f;
      i64 mrow = (combine == 4) ? (i64)(((m & 255) << 8) | (m >> 8)) : (i64)m;
      #pragma unroll
      for (int j=0;j<4;j++){
        int n = n0 + wn + j*16 + mr;
        float v = acc[i][j][r] * scale;
        if (bias) v += bias[n];
        if (act == 1) v = fmaxf(v, 0.f);
        else if (act == 2) v = 1.f/(1.f + __expf(-v));
        v *= rm;
        i64 idx = mrow*ldc + n;
        if (combine == 0) C[idx] = v;
        else if (combine == 1 || combine == 4) C[idx] += v;
        else if (combine == 2) C[idx] *= v;
        else C[idx] += aux[(i64)m*ldc + n] * v;
      }
    }
  }
}

// ---------------- fused dual-MFMA lin*sigmoid(gate) for tri-mult (M=65536, N=128, K=128) ----------------
__global__ __launch_bounds__(256) void mlrgate_k(
    const float* __restrict__ X,
    const float* __restrict__ Wl, const float* __restrict__ bl,
    const float* __restrict__ Wg, const float* __restrict__ bg,
    float* __restrict__ Out)
{
  int m0 = blockIdx.x * 128;
  int tid = threadIdx.x;
  int wave = tid >> 6, lane = tid & 63;
  int quad = lane >> 4, mr = lane & 15;
  int wm = (wave >> 1) * 64, wn = (wave & 1) * 64;
  __shared__ unsigned short As[128][40], B1s[128][40], B2s[128][40];
  f32x4 acc1[4][4], acc2[4][4];
  #pragma unroll
  for (int i=0;i<4;i++)
    #pragma unroll
    for (int j=0;j<4;j++){ acc1[i][j] = (f32x4){0,0,0,0}; acc2[i][j] = (f32x4){0,0,0,0}; }

  for (int k0 = 0; k0 < 128; k0 += 32){
    #pragma unroll
    for (int it=0; it<4; it++){
      int lin = tid + it*256;
      int r = lin >> 3, c4 = (lin & 7) * 4;
      float4 g = *(const float4*)&X[(i64)(m0+r)*128 + k0 + c4];
      As[r][c4]   = f2bf(g.x); As[r][c4+1] = f2bf(g.y);
      As[r][c4+2] = f2bf(g.z); As[r][c4+3] = f2bf(g.w);
    }
    #pragma unroll
    for (int it=0; it<4; it++){
      int lin = tid + it*256;
      int n = lin & 127, kg = (lin >> 7) * 4;
      float a0 = Wl[(i64)(k0+kg  )*128 + n];
      float a1 = Wl[(i64)(k0+kg+1)*128 + n];
      float a2 = Wl[(i64)(k0+kg+2)*128 + n];
      float a3 = Wl[(i64)(k0+kg+3)*128 + n];
      B1s[n][kg] = f2bf(a0); B1s[n][kg+1] = f2bf(a1);
      B1s[n][kg+2] = f2bf(a2); B1s[n][kg+3] = f2bf(a3);
      float g0 = Wg[(i64)(k0+kg  )*128 + n];
      float g1 = Wg[(i64)(k0+kg+1)*128 + n];
      float g2 = Wg[(i64)(k0+kg+2)*128 + n];
      float g3 = Wg[(i64)(k0+kg+3)*128 + n];
      B2s[n][kg] = f2bf(g0); B2s[n][kg+1] = f2bf(g1);
      B2s[n][kg+2] = f2bf(g2); B2s[n][kg+3] = f2bf(g3);
    }
    __syncthreads();
    bf16x8 af[4], b1f[4], b2f[4];
    #pragma unroll
    for (int i=0;i<4;i++) af[i]  = *(const bf16x8*)&As[wm + i*16 + mr][quad*8];
    #pragma unroll
    for (int j=0;j<4;j++){
      b1f[j] = *(const bf16x8*)&B1s[wn + j*16 + mr][quad*8];
      b2f[j] = *(const bf16x8*)&B2s[wn + j*16 + mr][quad*8];
    }
    #pragma unroll
    for (int i=0;i<4;i++)
      #pragma unroll
      for (int j=0;j<4;j++){
        acc1[i][j] = __builtin_amdgcn_mfma_f32_16x16x32_bf16(af[i], b1f[j], acc1[i][j], 0, 0, 0);
        acc2[i][j] = __builtin_amdgcn_mfma_f32_16x16x32_bf16(af[i], b2f[j], acc2[i][j], 0, 0, 0);
      }
    __syncthreads();
  }
  #pragma unroll
  for (int i=0;i<4;i++){
    #pragma unroll
    for (int r=0;r<4;r++){
      int m = m0 + wm + i*16 + quad*4 + r;
      #pragma unroll
      for (int j=0;j<4;j++){
        int n = wn + j*16 + mr;
        float lv = acc1[i][j][r] + bl[n];
        float gv = acc2[i][j][r] + bg[n];
        Out[(i64)m*128 + n] = lv * (1.f/(1.f + __expf(-gv)));
      }
    }
  }
}

// ---------------- generic batched GEMM (fp32, 64x64 tile) ----------------
template<bool TA, bool TB>
__global__ __launch_bounds__(256) void gemm_k(
    const float* __restrict__ A, int lda, i64 sA,
    const float* __restrict__ B, int ldb, i64 sB,
    float* __restrict__ C, int ldc, i64 sC,
    int M, int N, int K,
    const float* __restrict__ bias, float scale, int act,
    const float* __restrict__ rowmul, int combine)
{
  A += (i64)blockIdx.z * sA;
  B += (i64)blockIdx.z * sB;
  C += (i64)blockIdx.z * sC;
  int m0 = blockIdx.x * 64, n0 = blockIdx.y * 64;
  int tid = threadIdx.x, tx = tid & 15, ty = tid >> 4;
  __shared__ float As[16][68], Bs[16][68];
  float acc[4][4] = {};
  for (int k0 = 0; k0 < K; k0 += 16){
    if (TA){
      for (int l = tid; l < 1024; l += 256){
        int kk = l >> 6, mi = l & 63; int m = m0 + mi;
        As[kk][mi] = (m < M) ? A[(i64)(k0+kk)*lda + m] : 0.f;
      }
    } else {
      for (int l = tid; l < 1024; l += 256){
        int mi = l >> 4, kk = l & 15; int m = m0 + mi;
        As[kk][mi] = (m < M) ? A[(i64)m*lda + k0 + kk] : 0.f;
      }
    }
    if (TB){
      for (int l = tid; l < 1024; l += 256){
        int ni = l >> 4, kk = l & 15; int n = n0 + ni;
        Bs[kk][ni] = (n < N) ? B[(i64)n*ldb + k0 + kk] : 0.f;
      }
    } else {
      for (int l = tid; l < 1024; l += 256){
        int kk = l >> 6, ni = l & 63; int n = n0 + ni;
        Bs[kk][ni] = (n < N) ? B[(i64)(k0+kk)*ldb + n] : 0.f;
      }
    }
    __syncthreads();
    #pragma unroll
    for (int kk = 0; kk < 16; ++kk){
      float4 av4 = *(const float4*)&As[kk][ty*4];
      float4 bv4 = *(const float4*)&Bs[kk][tx*4];
      float av[4] = {av4.x, av4.y, av4.z, av4.w};
      float bv[4] = {bv4.x, bv4.y, bv4.z, bv4.w};
      #pragma unroll
      for (int i=0;i<4;i++)
        #pragma unroll
        for (int j=0;j<4;j++) acc[i][j] = fmaf(av[i], bv[j], acc[i][j]);
    }
    __syncthreads();
  }
  #pragma unroll
  for (int i=0;i<4;i++){
    int m = m0 + ty*4 + i;
    if (m >= M) continue;
    float rm = rowmul ? rowmul[m] : 1.f;
    #pragma unroll
    for (int j=0;j<4;j++){
      int n = n0 + tx*4 + j;
      if (n >= N) continue;
      float v = acc[i][j] * scale;
      if (bias) v += bias[n];
      if (act == 1) v = fmaxf(v, 0.f);
      else if (act == 2) v = 1.f/(1.f + expf(-v));
      v *= rm;
      i64 idx = (i64)m*ldc + n;
      if (combine == 0) C[idx] = v;
      else if (combine == 1) C[idx] += v;
      else C[idx] *= v;
    }
  }
}

// ---------------- thin GEMM (small M): split-K two-phase ----------------
__global__ __launch_bounds__(256) void gemm_part_k(
    const float* __restrict__ A, int lda,
    const float* __restrict__ B, int ldb,
    float* __restrict__ Cp, int M, int N, int K, int chunk)
{
  int m0 = blockIdx.x*16, n0 = blockIdx.y*64, z = blockIdx.z;
  int kb = z*chunk, ke = min(K, kb+chunk);
  int tid = threadIdx.x;
  int mi = tid >> 4, ni4 = (tid & 15)*4;
  __shared__ float As[16][17], Bs[16][68];
  float acc[4] = {0.f,0.f,0.f,0.f};
  for (int k0 = kb; k0 < ke; k0 += 16){
    { int r = tid>>4, c = tid&15; int m = m0+r;
      As[c][r] = (m < M) ? A[(i64)m*lda + k0 + c] : 0.f; }
    for (int l = tid; l < 1024; l += 256){
      int kk = l>>6, nn = l&63; int n = n0+nn;
      Bs[kk][nn] = (n < N) ? B[(i64)(k0+kk)*ldb + n] : 0.f;
    }
    __syncthreads();
    #pragma unroll
    for (int kk=0;kk<16;kk++){
      float a = As[kk][mi];
      float4 b = *(const float4*)&Bs[kk][ni4];
      acc[0]=fmaf(a,b.x,acc[0]); acc[1]=fmaf(a,b.y,acc[1]);
      acc[2]=fmaf(a,b.z,acc[2]); acc[3]=fmaf(a,b.w,acc[3]);
    }
    __syncthreads();
  }
  int m = m0+mi, n = n0+ni4;
  if (m < M && n < N) *(float4*)&Cp[((i64)z*M + m)*N + n] = *(float4*)acc;
}

__global__ __launch_bounds__(256) void gemm_reduce_k(
    const float* __restrict__ Cp, float* __restrict__ C, int ldc,
    int M, int N, int S,
    const float* __restrict__ bias, float scale, int act,
    const float* __restrict__ rowmul, int combine)
{
  i64 idx = (i64)blockIdx.x*256 + threadIdx.x;
  if (idx >= (i64)M*N) return;
  int m = (int)(idx / N), n = (int)(idx % N);
  float s = 0.f;
  for (int z=0; z<S; z++) s += Cp[(i64)z*M*N + idx];
  float v = s*scale;
  if (bias) v += bias[n];
  if (act == 1) v = fmaxf(v, 0.f);
  else if (act == 2) v = 1.f/(1.f + expf(-v));
  if (rowmul) v *= rowmul[m];
  i64 o = (i64)m*ldc + n;
  if (combine == 0) C[o] = v;
  else if (combine == 1) C[o] += v;
  else C[o] *= v;
}

// ---------------- OPM ----------------
__global__ __launch_bounds__(128) void opm_wd_k(const float* __restrict__ right, const float* __restrict__ W,
                                                float* __restrict__ Wd){
  int d = blockIdx.x, c = blockIdx.y, f = threadIdx.x;
  float acc = 0.f;
  #pragma unroll
  for (int e=0;e<32;e++) acc = fmaf(right[d*32+e], W[((i64)c*32+e)*128 + f], acc);
  Wd[((i64)d*32+c)*128 + f] = acc;
}

// pa[d,b,f] = pair_act[d,b,f] + (sum_c left[b,c]*Wd[d,c,f] + ob[f]) / (1e-3 + sm[d]*sm[b])
__global__ __launch_bounds__(128) void opm_final_k(const float* __restrict__ left, const float* __restrict__ Wd,
                                                   const float* __restrict__ ob, const float* __restrict__ sm,
                                                   const float* __restrict__ pair_act, float* __restrict__ pa){
  int d = blockIdx.x, b0 = blockIdx.y*16, f = threadIdx.x;
  __shared__ float wd_s[32][128];
  __shared__ float l_s[16][32];
  for (int c=0;c<32;c++) wd_s[c][f] = Wd[((i64)d*32+c)*128 + f];
  for (int l = f; l < 512; l += 128){ int bi=l>>5, c=l&31; l_s[bi][c] = left[(b0+bi)*32 + c]; }
  __syncthreads();
  float md = sm[d], obf = ob[f];
  for (int bi=0;bi<16;bi++){
    float acc = 0.f;
    #pragma unroll
    for (int c=0;c<32;c++) acc = fmaf(l_s[bi][c], wd_s[c][f], acc);
    int b = b0+bi;
    i64 idx = ((i64)d*256 + b)*128 + f;
    pa[idx] = pair_act[idx] + (acc + obf) / (1e-3f + md*sm[b]);
  }
}

// ---------------- row attention core ----------------
__global__ __launch_bounds__(256) void ra_attn_k(const float* __restrict__ q, const float* __restrict__ k,
                                                 const float* __restrict__ v, const float* __restrict__ nb,
                                                 const float* __restrict__ sm, float* __restrict__ wa){
  int qi = blockIdx.x, h = blockIdx.y, tid = threadIdx.x;
  __shared__ float qv[48];
  __shared__ float p[256];
  __shared__ float red[256];
  if (tid < 48) qv[tid] = q[(i64)qi*384 + h*48 + tid];
  __syncthreads();
  float acc = 0.f;
  const float* kr = k + (i64)tid*384 + h*48;
  #pragma unroll
  for (int c=0;c<48;c++) acc = fmaf(qv[c], kr[c], acc);
  acc += 1e9f*(sm[tid]-1.f) + nb[((i64)qi*256 + tid)*8 + h];
  red[tid] = acc; __syncthreads();
  for (int off=128;off>0;off>>=1){ if (tid<off) red[tid] = fmaxf(red[tid], red[tid+off]); __syncthreads(); }
  float mx = red[0]; __syncthreads();
  float e = expf(acc - mx);
  red[tid] = e; __syncthreads();
  for (int off=128;off>0;off>>=1){ if (tid<off) red[tid] += red[tid+off]; __syncthreads(); }
  p[tid] = e / red[0];
  __syncthreads();
  if (tid < 48){
    float a = 0.f;
    for (int kk=0;kk<256;kk++) a = fmaf(p[kk], v[(i64)kk*384 + h*48 + tid], a);
    wa[(i64)qi*384 + h*48 + tid] = a;
  }
}

// ---------------- triangle attention core v7: swapped-operand MFMA flash ----------------
// v6 (104 us) was latency-bound: 16x16 C-layout spread each q-row over 16 lanes -> 32 serial
// shfl_xor per 32-key tile, 4x per-r serialization (MfmaUtil 3.3, VALUBusy 46, occ 46).
// v7 swaps BOTH mfma operand orders (T12 mechanism: reduction axis lane-local):
//   S = mfma(K, Q): lane (quad,mr) holds S[key = kc+{quad*4+r, 16+quad*4+r}][q = q0w+mr]
//     -> softmax per lane: 7 in-lane fmax + 2 shfl_xor(16,32) + 8 exp + adds + 2 shfl_xor.
//   O^T = mfma(V^T, P): O[c = quad*4+r (+16)][q = mr] -> alpha/1/l are per-lane SCALARS,
//     output store = 2 coalesced float4.
// P round-trips per-wave LDS tile (2x b64 packed writes + 1 b128 read, same-wave, no barrier).
// nb is consumed as nbQ[h][q][k] -> 2 float4 loads per tile. Grid (qblk,h,b): qblk fastest
// so the 4 blocks sharing (b,h) K/V are dispatch-adjacent -> L2 reuse (FETCH 147->~105 MB).
__global__ __launch_bounds__(256, 6) void ta_mfma_k(
    const float* __restrict__ q, const float* __restrict__ k, const float* __restrict__ v,
    const float* __restrict__ nbQ, const float* __restrict__ mask, int maskT,
    float* __restrict__ wa)
{
  int qblk = blockIdx.x, h = blockIdx.y, b = blockIdx.z;
  int tid = threadIdx.x;
  int wave = tid >> 6, lane = tid & 63;
  int quad = lane >> 4, mr = lane & 15;
  const i64 base = ((i64)b*256)*128 + h*32;

  __shared__ __align__(16) unsigned short Ks[128][40];   // [key][c], row 80B
  __shared__ __align__(16) unsigned short Vt[32][136];   // [c][key], row 272B
  __shared__ __align__(16) float mask_s[256];
  __shared__ __align__(16) unsigned short Pl[4][16][40]; // per-wave P [q][key]

  mask_s[tid] = 1e9f * ((maskT ? mask[(i64)tid*256 + b] : mask[(i64)b*256 + tid]) - 1.f);

  int q0w = qblk*64 + wave*16;
  int qg = q0w + mr;                      // this lane's q row (fixed for whole kernel)
  const float* nbq = nbQ + (i64)h*65536 + (i64)qg*256;

  // Q as B-operand fragment: [n=q=mr][k-ch quad*8..+7] — same addresses as v6's A-frag
  bf16x8 qf;
  {
    const float* qp = q + base + (i64)qg*128 + quad*8;
    float4 a = *(const float4*)qp;
    float4 c = *(const float4*)(qp+4);
    qf[0]=(short)f2bf(a.x); qf[1]=(short)f2bf(a.y); qf[2]=(short)f2bf(a.z); qf[3]=(short)f2bf(a.w);
    qf[4]=(short)f2bf(c.x); qf[5]=(short)f2bf(c.y); qf[6]=(short)f2bf(c.z); qf[7]=(short)f2bf(c.w);
  }

  f32x4 o0 = (f32x4){0,0,0,0}, o1 = (f32x4){0,0,0,0}; // O^T[c=quad*4+r(+16)][q=mr]
  float mm = -1e30f, ll = 0.f;                         // per-lane softmax state (q = qg)

  for (int half = 0; half < 2; half++){
    __syncthreads();
    #pragma unroll
    for (int it=0; it<4; it++){
      int idx = it*256 + tid;              // 128 keys x 32 ch
      int kl = idx >> 3, c4 = (idx & 7)*4;
      i64 roff = base + (i64)(half*128 + kl)*128 + c4;
      float4 g  = *(const float4*)(k + roff);
      unsigned int w0 = (unsigned int)f2bf(g.x) | ((unsigned int)f2bf(g.y)<<16);
      unsigned int w1 = (unsigned int)f2bf(g.z) | ((unsigned int)f2bf(g.w)<<16);
      *(uint2*)&Ks[kl][c4] = make_uint2(w0, w1);
      float4 gv = *(const float4*)(v + roff);
      Vt[c4  ][kl] = f2bf(gv.x);
      Vt[c4+1][kl] = f2bf(gv.y);
      Vt[c4+2][kl] = f2bf(gv.z);
      Vt[c4+3][kl] = f2bf(gv.w);
    }
    __syncthreads();

    #pragma unroll
    for (int it=0; it<4; it++){
      int kc = it*32;
      int kg = half*128 + kc;
      // K as A-operand: frag rows = keys kc+mr / kc+16+mr
      bf16x8 kf0 = *(const bf16x8*)&Ks[kc + mr][quad*8];
      bf16x8 kf1 = *(const bf16x8*)&Ks[kc + 16 + mr][quad*8];
      f32x4 s0 = __builtin_amdgcn_mfma_f32_16x16x32_bf16(kf0, qf, (f32x4){0,0,0,0}, 0, 0, 0);
      f32x4 s1 = __builtin_amdgcn_mfma_f32_16x16x32_bf16(kf1, qf, (f32x4){0,0,0,0}, 0, 0, 0);
      // s0[r] = S[key=kg+quad*4+r][qg]; s1[r] = S[key=kg+16+quad*4+r][qg]
      float4 nb0 = *(const float4*)(nbq + kg + quad*4);
      float4 nb1 = *(const float4*)(nbq + kg + 16 + quad*4);
      float4 mk0 = *(const float4*)&mask_s[kg + quad*4];
      float4 mk1 = *(const float4*)&mask_s[kg + 16 + quad*4];
      s0[0] += nb0.x + mk0.x; s0[1] += nb0.y + mk0.y; s0[2] += nb0.z + mk0.z; s0[3] += nb0.w + mk0.w;
      s1[0] += nb1.x + mk1.x; s1[1] += nb1.y + mk1.y; s1[2] += nb1.z + mk1.z; s1[3] += nb1.w + mk1.w;

      // per-lane online softmax over the 32-key tile (cross-quad = 2 shfls)
      float tm = fmaxf(fmaxf(fmaxf(s0[0],s0[1]), fmaxf(s0[2],s0[3])),
                       fmaxf(fmaxf(s1[0],s1[1]), fmaxf(s1[2],s1[3])));
      tm = fmaxf(tm, __shfl_xor(tm, 16));
      tm = fmaxf(tm, __shfl_xor(tm, 32));
      float nm = fmaxf(mm, tm);
      float alpha = __expf(mm - nm);
      mm = nm;
      float e00 = __expf(s0[0]-nm), e01 = __expf(s0[1]-nm);
      float e02 = __expf(s0[2]-nm), e03 = __expf(s0[3]-nm);
      float e10 = __expf(s1[0]-nm), e11 = __expf(s1[1]-nm);
      float e12 = __expf(s1[2]-nm), e13 = __expf(s1[3]-nm);
      float ps = ((e00+e01) + (e02+e03)) + ((e10+e11) + (e12+e13));
      ps += __shfl_xor(ps, 16);
      ps += __shfl_xor(ps, 32);
      ll = ll*alpha + ps;
      o0 *= alpha; o1 *= alpha;
      // P[q=mr][key] packed bf16 pairs, 2x 8B writes (2-way banks = free)
      unsigned int p0 = (unsigned int)f2bf(e00) | ((unsigned int)f2bf(e01)<<16);
      unsigned int p1 = (unsigned int)f2bf(e02) | ((unsigned int)f2bf(e03)<<16);
      unsigned int p2 = (unsigned int)f2bf(e10) | ((unsigned int)f2bf(e11)<<16);
      unsigned int p3 = (unsigned int)f2bf(e12) | ((unsigned int)f2bf(e13)<<16);
      *(uint2*)&Pl[wave][mr][quad*4]      = make_uint2(p0, p1);
      *(uint2*)&Pl[wave][mr][16 + quad*4] = make_uint2(p2, p3);
      // PV (swapped): A = V^T rows=channels, B = P [k=key][n=q=mr]
      bf16x8 pf  = *(const bf16x8*)&Pl[wave][mr][quad*8];
      bf16x8 vf0 = *(const bf16x8*)&Vt[mr     ][kc + quad*8];
      bf16x8 vf1 = *(const bf16x8*)&Vt[16 + mr][kc + quad*8];
      o0 = __builtin_amdgcn_mfma_f32_16x16x32_bf16(vf0, pf, o0, 0, 0, 0);
      o1 = __builtin_amdgcn_mfma_f32_16x16x32_bf16(vf1, pf, o1, 0, 0, 0);
    }
  }

  float inv = 1.f/ll;
  float* wp = wa + base + (i64)qg*128;
  *(float4*)(wp + quad*4)      = make_float4(o0[0]*inv, o0[1]*inv, o0[2]*inv, o0[3]*inv);
  *(float4*)(wp + 16 + quad*4) = make_float4(o1[0]*inv, o1[1]*inv, o1[2]*inv, o1[3]*inv);
}

// ---------------- host dispatch ----------------
static void gemm(hipStream_t st, bool TA, bool TB,
                 const float* A, int lda, i64 sA,
                 const float* B, int ldb, i64 sB,
                 float* C, int ldc, i64 sC,
                 int M, int N, int K, int batch,
                 const float* bias, float scale, int act,
                 const float* rowmul, int combine)
{
  dim3 g((M+63)/64, (N+63)/64, batch), bl(256);
  if (!TA && !TB)      gemm_k<false,false><<<g,bl,0,st>>>(A,lda,sA,B,ldb,sB,C,ldc,sC,M,N,K,bias,scale,act,rowmul,combine);
  else if (!TA &&  TB) gemm_k<false,true ><<<g,bl,0,st>>>(A,lda,sA,B,ldb,sB,C,ldc,sC,M,N,K,bias,scale,act,rowmul,combine);
  else                 gemm_k<true ,false><<<g,bl,0,st>>>(A,lda,sA,B,ldb,sB,C,ldc,sC,M,N,K,bias,scale,act,rowmul,combine);
}

static void mgemm(hipStream_t st, bool TA, bool TB,
                  const float* A, int lda, i64 sA,
                  const float* B, int ldb, i64 sB,
                  float* C, int ldc, i64 sC,
                  int M, int N, int K, int batch,
                  const float* bias, float scale, int act,
                  const float* rowmul, int combine, const float* aux = nullptr)
{
  dim3 g(M/128, N/128, batch), bl(256);
  if (!TA && !TB)      mgemm_k<false,false><<<g,bl,0,st>>>(A,lda,sA,B,ldb,sB,C,ldc,sC,M,N,K,bias,scale,act,rowmul,combine,aux);
  else if (!TA &&  TB) mgemm_k<false,true ><<<g,bl,0,st>>>(A,lda,sA,B,ldb,sB,C,ldc,sC,M,N,K,bias,scale,act,rowmul,combine,aux);
  else                 mgemm_k<true ,false><<<g,bl,0,st>>>(A,lda,sA,B,ldb,sB,C,ldc,sC,M,N,K,bias,scale,act,rowmul,combine,aux);
}

static void gemm_thin(hipStream_t st,
                      const float* A, int lda, const float* B, int ldb,
                      float* C, int ldc, int M, int N, int K,
                      const float* bias, float scale, int act,
                      const float* rowmul, int combine, float* part)
{
  const int S = 8;
  int chunk = ((K/S + 15)/16)*16; if (chunk < 16) chunk = 16;
  dim3 g((M+15)/16, (N+63)/64, S);
  gemm_part_k<<<g,256,0,st>>>(A,lda,B,ldb,part,M,N,K,chunk);
  i64 t = (i64)M*N;
  gemm_reduce_k<<<(int)((t+255)/256),256,0,st>>>(part,C,ldc,M,N,S,bias,scale,act,rowmul,combine);
}

extern "C" void kernel_launch(void* const* d_in, const int* in_sizes, int n_in,
                              void* d_out, int out_size, void* d_ws, size_t ws_size,
                              hipStream_t stream)
{
  const float* IN[64];
  for (int i=0;i<n_in && i<64;i++) IN[i] = (const float*)d_in[i];

  const float* single_act = IN[0];
  const float* pair_act   = IN[1];
  const float* sm         = IN[2];
  const float* pm         = IN[3];
  const float* opm_ln     = IN[4];
  const float* opm_lr_w   = IN[5];
  const float* opm_lr_b   = IN[6];
  const float* opm_out_w  = IN[7];
  const float* opm_out_b  = IN[8];
  const float* ra_ln      = IN[9];
  const float* ra_pair_ln = IN[10];
  const float* ra_feat_w  = IN[11];
  const float* ra_qkv_w   = IN[12];
  const float* ra_gate_w  = IN[13];
  const float* ra_gate_b  = IN[14];
  const float* ra_o_w     = IN[15];
  const float* ra_o_b     = IN[16];
  const float* st_ln      = IN[17];
  const float* st_w1      = IN[18];
  const float* st_b1      = IN[19];
  const float* st_w2      = IN[20];
  const float* st_b2      = IN[21];
  const float* pt_ln      = IN[56];
  const float* pt_w1      = IN[57];
  const float* pt_b1      = IN[58];
  const float* pt_w2      = IN[59];
  const float* pt_b2      = IN[60];

  float* sa = (float*)d_out;           // [256,384]
  float* pa = (float*)d_out + 98304;   // [256,256,128]

  float* W  = (float*)d_ws;
  float* B0 = W;
  float* B1 = W + 8388608L;
  float* B2 = W + 16777216L;
  float* B3 = W + 25165824L;
  float* SMA = W + 33554432L;
  float* xs   = SMA;
  float* qb   = SMA +  98304;
  float* kb   = SMA + 196608;
  float* vb   = SMA + 294912;
  float* wab  = SMA + 393216;
  float* hst  = SMA + 491520;   // 393216
  float* nbra = SMA + 884736;   // 524288 (reused as nbQ in tri-attn phase)
  float* lbuf = SMA + 1409024;  // 8192
  float* rbuf = SMA + 1417216;  // 8192
  float* Wd   = SMA + 1425408;  // 1048576
  float* nbt  = SMA + 2473984;  // 262144

  // init sa with residual base (pa is initialized by opm_final_k's fused write)
  copy_k<<<384, 256, 0, stream>>>(sa, single_act, 98304L);

  // ---- 1) OPM -> pair residual (writes pa = pair_act + update) ----
  ln_k<<<256,128,0,stream>>>(single_act, xs, opm_ln, 384);
  gemm_thin(stream, xs,384, opm_lr_w,32,       lbuf,32, 256,32,384, opm_lr_b,    1.f,0, sm,0, B1);
  gemm_thin(stream, xs,384, opm_lr_w+12288,32, rbuf,32, 256,32,384, opm_lr_b+32, 1.f,0, sm,0, B1);
  opm_wd_k<<<dim3(256,32),128,0,stream>>>(rbuf, opm_out_w, Wd);
  opm_final_k<<<dim3(256,16),128,0,stream>>>(lbuf, Wd, opm_out_b, sm, pair_act, pa);

  // ---- 2) row attention with pair bias ----
  ln_k<<<256,128,0,stream>>>(sa, xs, ra_ln, 384);
  ln128_k<<<16384,256,0,stream>>>(pa, B0, ra_pair_ln, 0);
  gemm(stream,false,false, B0,128,0, ra_feat_w,8,0, nbra,8,0, 65536,8,128,1, nullptr,1.f,0,nullptr,0);
  const float qs_ra = 0.14433756729740643f; // 1/sqrt(48)
  gemm_thin(stream, xs,384, ra_qkv_w,384,        qb,384, 256,384,384, nullptr,qs_ra,0,nullptr,0, B1);
  gemm_thin(stream, xs,384, ra_qkv_w+147456,384, kb,384, 256,384,384, nullptr,1.f,0,nullptr,0, B1);
  gemm_thin(stream, xs,384, ra_qkv_w+294912,384, vb,384, 256,384,384, nullptr,1.f,0,nullptr,0, B1);
  ra_attn_k<<<dim3(256,8),256,0,stream>>>(qb, kb, vb, nbra, sm, wab);
  gemm_thin(stream, xs,384,  ra_gate_w,384, wab,384, 256,384,384, ra_gate_b,1.f,2,nullptr,2, B1);
  gemm_thin(stream, wab,384, ra_o_w,384,    sa,384,  256,384,384, ra_o_b,   1.f,0,nullptr,1, B1);

  // ---- 3) single transition ----
  ln_k<<<256,128,0,stream>>>(sa, xs, st_ln, 384);
  gemm_thin(stream, xs,384,   st_w1,1536, hst,1536, 256,1536,384, st_b1,1.f,1,nullptr,0, B1);
  gemm_thin(stream, hst,1536, st_w2,384,  sa,384,   256,384,1536, st_b2,1.f,0,nullptr,1, B1);

  // ---- 4/5) triangle multiplications ----
  auto tri_mult = [&](int base, bool outgoing){
    const float* ln_w = IN[base+0];
    const float* lr_w = IN[base+1];
    const float* lr_b = IN[base+2];
    const float* gw   = IN[base+3];
    const float* gb   = IN[base+4];
    const float* cln  = IN[base+5];
    const float* ow   = IN[base+6];
    const float* ob   = IN[base+7];
    const float* ogw  = IN[base+8];
    const float* ogb  = IN[base+9];
    ln128_k<<<16384,256,0,stream>>>(pa, B0, ln_w, 0);
    // left = mask * (X@Wl+bl) * sigmoid(X@Wg+bg): fused dual-MFMA, then transpose+mask -> B1 (ch-major)
    mlrgate_k<<<512,256,0,stream>>>(B0, lr_w, lr_b, gw, gb, B3);
    tr_mask_k<<<dim3(2048,4),256,0,stream>>>(B3, pm, B1);
    // right -> B2 (ch-major)
    mlrgate_k<<<512,256,0,stream>>>(B0, lr_w+16384, lr_b+128, gw+16384, gb+128, B3);
    tr_mask_k<<<dim3(2048,4),256,0,stream>>>(B3, pm, B2);
    if (outgoing) // out[i,j,c] = sum_k L_c[i,k] * R_c[j,k]
      mgemm(stream,false,true, B1,256,65536, B2,256,65536, B3,256,65536, 256,256,256,128, nullptr,1.f,0,nullptr,0);
    else          // out[i,j,c] = sum_k R_c[k,i] * L_c[k,j]
      mgemm(stream,true,false, B2,256,65536, B1,256,65536, B3,256,65536, 256,256,256,128, nullptr,1.f,0,nullptr,0);
    chw2hwc_k<<<dim3(2048,4),256,0,stream>>>(B3, B1);
    ln128_k<<<16384,256,0,stream>>>(B1, B3, cln, 0);
    mgemm(stream,false,false, B3,128,0, ow,128,0,  B1,128,0, 65536,128,128,1, ob,  1.f,0,nullptr,0);
    // fused: pa += B1 * sigmoid(B0@ogw + ogb)
    mgemm(stream,false,false, B0,128,0, ogw,128,0, pa,128,0, 65536,128,128,1, ogb, 1.f,2,nullptr,3, B1);
  };
  tri_mult(22, true);   // tmo
  tri_mult(32, false);  // tmi

  // ---- 6/7) triangle attentions ----
  auto tri_attn = [&](int base, bool percol){
    const float* ln_w   = IN[base+0];
    const float* feat_w = IN[base+1];
    const float* qkv_w  = IN[base+2];
    const float* gw     = IN[base+3];
    const float* gb     = IN[base+4];
    const float* ow     = IN[base+5];
    const float* ob     = IN[base+6];
    // LN with fused pair-transpose read for per-column attention
    ln128_k<<<16384,256,0,stream>>>(pa, B0, ln_w, percol?1:0);
    gemm(stream,false,false, B0,128,0, feat_w,4,0, nbt,4,0, 65536,4,128,1, nullptr,1.f,0,nullptr,0);
    nbQ_k<<<256,256,0,stream>>>(nbt, nbra);  // nbQ[h][q][k]
    const float qs = 0.17677669529663687f; // 1/sqrt(32)
    mgemm(stream,false,false, B0,128,0, qkv_w,128,0,       B1,128,0, 65536,128,128,1, nullptr,qs, 0,nullptr,0);
    mgemm(stream,false,false, B0,128,0, qkv_w+16384,128,0, B2,128,0, 65536,128,128,1, nullptr,1.f,0,nullptr,0);
    mgemm(stream,false,false, B0,128,0, qkv_w+32768,128,0, B3,128,0, 65536,128,128,1, nullptr,1.f,0,nullptr,0);
    ta_mfma_k<<<dim3(4,4,256),256,0,stream>>>(B1, B2, B3, nbra, pm, percol?1:0, B1);
    mgemm(stream,false,false, B0,128,0, gw,128,0, B1,128,0, 65536,128,128,1, gb,1.f,2,nullptr,2); // wa *= sigmoid(gate)
    // out-projection fused with residual add (4 = transpose-pair write for per-column)
    mgemm(stream,false,false, B1,128,0, ow,128,0, pa,128,0, 65536,128,128,1, ob,1.f,0,nullptr, percol?4:1);
  };
  tri_attn(42, false);  // tas (per-row)
  tri_attn(49, true);   // tae (per-column)

  // ---- 8) pair transition ----
  ln128_k<<<16384,256,0,stream>>>(pa, B0, pt_ln, 0);
  for (int half = 0; half < 2; half++){
    const float* xh = B0 + (i64)half*4194304;
    float* ph = pa + (i64)half*4194304;
    mgemm(stream,false,false, xh,128,0, pt_w1,512,0, B1,512,0, 32768,512,128,1, pt_b1,1.f,1,nullptr,0);
    mgemm(stream,false,false, B1,512,0, pt_w2,128,0, ph,128,0, 32768,128,512,1, pt_b2,1.f,0,nullptr,1);
  }
}

// Round 4
// 1660.608 us; speedup vs baseline: 1.2140x; 1.1155x over previous
//
#include <hip/hip_runtime.h>
#include <math.h>

typedef long long i64;
#define NN_ 65536L

typedef __attribute__((ext_vector_type(8))) short bf16x8;
typedef __attribute__((ext_vector_type(4))) float f32x4;

__device__ inline unsigned short f2bf(float f){
  unsigned int u = __float_as_uint(f);
  return (unsigned short)((u + 0x7FFFu + ((u>>16)&1u)) >> 16);
}

// ---------------- elementwise ----------------
__global__ __launch_bounds__(256) void copy_k(float* __restrict__ d, const float* __restrict__ s, long n){
  long i = (long)blockIdx.x*blockDim.x + threadIdx.x;
  if (i < n) d[i] = s[i];
}

// channel-major [128][65536] -> row-major [65536][128]
__global__ __launch_bounds__(256) void chw2hwc_k(const float* __restrict__ in, float* __restrict__ out){
  __shared__ float t[32][33];
  int r0 = blockIdx.x*32, c0 = blockIdx.y*32;
  int tx = threadIdx.x & 31, ty = threadIdx.x >> 5;
  for (int i = ty; i < 32; i += 8) t[i][tx] = in[(i64)(c0+i)*NN_ + r0 + tx];
  __syncthreads();
  for (int i = ty; i < 32; i += 8) out[(i64)(r0+i)*128 + c0 + tx] = t[tx][i];
}

// row-major [65536][128] -> ch-major [128][65536] with per-row mask
__global__ __launch_bounds__(256) void tr_mask_k(const float* __restrict__ in, const float* __restrict__ mask,
                                                 float* __restrict__ out){
  __shared__ float t[32][33];
  int r0 = blockIdx.x*32, c0 = blockIdx.y*32;
  int tx = threadIdx.x & 31, ty = threadIdx.x >> 5;
  for (int i = ty; i < 32; i += 8) t[i][tx] = in[(i64)(r0+i)*128 + c0 + tx];
  __syncthreads();
  for (int i = ty; i < 32; i += 8) out[(i64)(c0+i)*NN_ + r0 + tx] = t[tx][i] * mask[r0+tx];
}

// nb [q,k,h=4] -> nbQ [h][q][k]  (block = q row, thread = k: coalesced read AND write)
__global__ __launch_bounds__(256) void nbQ_k(const float* __restrict__ in, float* __restrict__ out){
  int qq = blockIdx.x, kk = threadIdx.x;
  float4 vv = *(const float4*)(in + ((i64)qq*256 + kk)*4);
  out[0*65536 + qq*256 + kk] = vv.x;
  out[1*65536 + qq*256 + kk] = vv.y;
  out[2*65536 + qq*256 + kk] = vv.z;
  out[3*65536 + qq*256 + kk] = vv.w;
}

// ---------------- LayerNorm generic (rowwise, C arbitrary) ----------------
__global__ __launch_bounds__(128) void ln_k(const float* __restrict__ in, float* __restrict__ out,
                                            const float* __restrict__ w, int C){
  i64 row = blockIdx.x;
  const float* x = in + row*C;
  float* y = out + row*C;
  int tid = threadIdx.x;
  float s=0.f, s2=0.f;
  for (int c=tid;c<C;c+=128){ float v = x[c]; s += v; s2 += v*v; }
  __shared__ float rs[128], rq[128];
  rs[tid]=s; rq[tid]=s2; __syncthreads();
  for (int off=64;off>0;off>>=1){ if (tid<off){ rs[tid]+=rs[tid+off]; rq[tid]+=rq[tid+off]; } __syncthreads(); }
  float mu = rs[0]/C;
  float var = rq[0]/C - mu*mu;
  float inv = rsqrtf(var + 1e-5f);
  for (int c=tid;c<C;c+=128) y[c] = (x[c]-mu)*inv*w[c] + w[C+c];
}

// ---------------- LayerNorm C=128: one wave per row, shuffle-only reduction ----------------
// T=1: read row rt = transpose-pair index of row (fused pa transpose for per-column attention)
__global__ __launch_bounds__(256) void ln128_k(const float* __restrict__ in, float* __restrict__ out,
                                               const float* __restrict__ w, int T){
  int wv = threadIdx.x >> 6, lane = threadIdx.x & 63;
  i64 row = (i64)blockIdx.x*4 + wv;
  i64 rr = T ? (i64)((((int)row & 255) << 8) | ((int)row >> 8)) : row;
  float2 v = *(const float2*)(in + rr*128 + lane*2);
  float s = v.x + v.y, s2 = v.x*v.x + v.y*v.y;
  #pragma unroll
  for (int off=32; off; off>>=1){ s += __shfl_down(s, off); s2 += __shfl_down(s2, off); }
  s = __shfl(s, 0); s2 = __shfl(s2, 0);
  float mu = s*(1.f/128.f);
  float var = s2*(1.f/128.f) - mu*mu;
  float inv = rsqrtf(var + 1e-5f);
  float2 wl = *(const float2*)(w + lane*2);
  float2 wb = *(const float2*)(w + 128 + lane*2);
  float2 y; y.x = (v.x-mu)*inv*wl.x + wb.x; y.y = (v.y-mu)*inv*wl.y + wb.y;
  *(float2*)(out + row*128 + lane*2) = y;
}

// ---------------- bf16 MFMA GEMM: 128x128 tile, 256 thr (2x2 waves of 64x64) ----------------
// combine: 0 store, 1 +=, 2 *=, 3: C += aux*v, 4: C[transpose-pair(m)] += v (pair tensor only)
template<bool TA, bool TB>
__global__ __launch_bounds__(256) void mgemm_k(
    const float* __restrict__ A, int lda, i64 sA,
    const float* __restrict__ B, int ldb, i64 sB,
    float* __restrict__ C, int ldc, i64 sC,
    int M, int N, int K,
    const float* __restrict__ bias, float scale, int act,
    const float* __restrict__ rowmul, int combine, const float* __restrict__ aux)
{
  A += (i64)blockIdx.z * sA;
  B += (i64)blockIdx.z * sB;
  C += (i64)blockIdx.z * sC;
  int m0 = blockIdx.x * 128, n0 = blockIdx.y * 128;
  int tid = threadIdx.x;
  int wave = tid >> 6, lane = tid & 63;
  int quad = lane >> 4, mr = lane & 15;
  int wm = (wave >> 1) * 64, wn = (wave & 1) * 64;
  __shared__ unsigned short As[128][40];
  __shared__ unsigned short Bs[128][40];
  f32x4 acc[4][4];
  #pragma unroll
  for (int i=0;i<4;i++)
    #pragma unroll
    for (int j=0;j<4;j++) acc[i][j] = (f32x4){0.f,0.f,0.f,0.f};

  for (int k0 = 0; k0 < K; k0 += 32){
    if (!TA){
      #pragma unroll
      for (int it=0; it<4; it++){
        int lin = tid + it*256;
        int r = lin >> 3, c4 = (lin & 7) * 4;
        float4 g = *(const float4*)&A[(i64)(m0+r)*lda + k0 + c4];
        As[r][c4]   = f2bf(g.x); As[r][c4+1] = f2bf(g.y);
        As[r][c4+2] = f2bf(g.z); As[r][c4+3] = f2bf(g.w);
      }
    } else {
      #pragma unroll
      for (int it=0; it<4; it++){
        int lin = tid + it*256;
        int m = lin & 127, kg = (lin >> 7) * 4;
        float v0 = A[(i64)(k0+kg  )*lda + m0 + m];
        float v1 = A[(i64)(k0+kg+1)*lda + m0 + m];
        float v2 = A[(i64)(k0+kg+2)*lda + m0 + m];
        float v3 = A[(i64)(k0+kg+3)*lda + m0 + m];
        As[m][kg] = f2bf(v0); As[m][kg+1] = f2bf(v1);
        As[m][kg+2] = f2bf(v2); As[m][kg+3] = f2bf(v3);
      }
    }
    if (!TB){
      #pragma unroll
      for (int it=0; it<4; it++){
        int lin = tid + it*256;
        int n = lin & 127, kg = (lin >> 7) * 4;
        float v0 = B[(i64)(k0+kg  )*ldb + n0 + n];
        float v1 = B[(i64)(k0+kg+1)*ldb + n0 + n];
        float v2 = B[(i64)(k0+kg+2)*ldb + n0 + n];
        float v3 = B[(i64)(k0+kg+3)*ldb + n0 + n];
        Bs[n][kg] = f2bf(v0); Bs[n][kg+1] = f2bf(v1);
        Bs[n][kg+2] = f2bf(v2); Bs[n][kg+3] = f2bf(v3);
      }
    } else {
      #pragma unroll
      for (int it=0; it<4; it++){
        int lin = tid + it*256;
        int r = lin >> 3, c4 = (lin & 7) * 4;
        float4 g = *(const float4*)&B[(i64)(n0+r)*ldb + k0 + c4];
        Bs[r][c4]   = f2bf(g.x); Bs[r][c4+1] = f2bf(g.y);
        Bs[r][c4+2] = f2bf(g.z); Bs[r][c4+3] = f2bf(g.w);
      }
    }
    __syncthreads();
    bf16x8 af[4], bfr[4];
    #pragma unroll
    for (int i=0;i<4;i++) af[i]  = *(const bf16x8*)&As[wm + i*16 + mr][quad*8];
    #pragma unroll
    for (int j=0;j<4;j++) bfr[j] = *(const bf16x8*)&Bs[wn + j*16 + mr][quad*8];
    #pragma unroll
    for (int i=0;i<4;i++)
      #pragma unroll
      for (int j=0;j<4;j++)
        acc[i][j] = __builtin_amdgcn_mfma_f32_16x16x32_bf16(af[i], bfr[j], acc[i][j], 0, 0, 0);
    __syncthreads();
  }
  #pragma unroll
  for (int i=0;i<4;i++){
    #pragma unroll
    for (int r=0;r<4;r++){
      int m = m0 + wm + i*16 + quad*4 + r;
      float rm = rowmul ? rowmul[m] : 1.f;
      i64 mrow = (combine == 4) ? (i64)(((m & 255) << 8) | (m >> 8)) : (i64)m;
      #pragma unroll
      for (int j=0;j<4;j++){
        int n = n0 + wn + j*16 + mr;
        float v = acc[i][j][r] * scale;
        if (bias) v += bias[n];
        if (act == 1) v = fmaxf(v, 0.f);
        else if (act == 2) v = 1.f/(1.f + __expf(-v));
        v *= rm;
        i64 idx = mrow*ldc + n;
        if (combine == 0) C[idx] = v;
        else if (combine == 1 || combine == 4) C[idx] += v;
        else if (combine == 2) C[idx] *= v;
        else C[idx] += aux[(i64)m*ldc + n] * v;
      }
    }
  }
}

// ---------------- bf16 MFMA GEMM: 64x64 tile, 256 thr (2x2 waves of 32x32) ----------------
// For dispatches whose 128-tile grid is <1024 blocks (2 blocks/CU): R3 showed tri-mult batched
// GEMM at grid 512 -> Occupancy 10.8%, MfmaUtil 1.8%, VALUBusy 5% (pure latency, 85 us).
// 64x64 tiles quadruple the grid (2048 blocks -> 6-8 blocks/CU); LDS 10 KB.
template<bool TA, bool TB>
__global__ __launch_bounds__(256) void mgemm64_k(
    const float* __restrict__ A, int lda, i64 sA,
    const float* __restrict__ B, int ldb, i64 sB,
    float* __restrict__ C, int ldc, i64 sC,
    int M, int N, int K,
    const float* __restrict__ bias, float scale, int act,
    const float* __restrict__ rowmul, int combine, const float* __restrict__ aux)
{
  A += (i64)blockIdx.z * sA;
  B += (i64)blockIdx.z * sB;
  C += (i64)blockIdx.z * sC;
  int m0 = blockIdx.x * 64, n0 = blockIdx.y * 64;
  int tid = threadIdx.x;
  int wave = tid >> 6, lane = tid & 63;
  int quad = lane >> 4, mr = lane & 15;
  int wm = (wave >> 1) * 32, wn = (wave & 1) * 32;
  __shared__ unsigned short As[64][40];
  __shared__ unsigned short Bs[64][40];
  f32x4 acc[2][2];
  #pragma unroll
  for (int i=0;i<2;i++)
    #pragma unroll
    for (int j=0;j<2;j++) acc[i][j] = (f32x4){0.f,0.f,0.f,0.f};

  for (int k0 = 0; k0 < K; k0 += 32){
    if (!TA){
      #pragma unroll
      for (int it=0; it<2; it++){
        int lin = tid + it*256;
        int r = lin >> 3, c4 = (lin & 7) * 4;
        float4 g = *(const float4*)&A[(i64)(m0+r)*lda + k0 + c4];
        As[r][c4]   = f2bf(g.x); As[r][c4+1] = f2bf(g.y);
        As[r][c4+2] = f2bf(g.z); As[r][c4+3] = f2bf(g.w);
      }
    } else {
      #pragma unroll
      for (int it=0; it<2; it++){
        int lin = tid + it*256;
        int m = lin & 63, kg = (lin >> 6) * 4;
        float v0 = A[(i64)(k0+kg  )*lda + m0 + m];
        float v1 = A[(i64)(k0+kg+1)*lda + m0 + m];
        float v2 = A[(i64)(k0+kg+2)*lda + m0 + m];
        float v3 = A[(i64)(k0+kg+3)*lda + m0 + m];
        As[m][kg] = f2bf(v0); As[m][kg+1] = f2bf(v1);
        As[m][kg+2] = f2bf(v2); As[m][kg+3] = f2bf(v3);
      }
    }
    if (!TB){
      #pragma unroll
      for (int it=0; it<2; it++){
        int lin = tid + it*256;
        int n = lin & 63, kg = (lin >> 6) * 4;
        float v0 = B[(i64)(k0+kg  )*ldb + n0 + n];
        float v1 = B[(i64)(k0+kg+1)*ldb + n0 + n];
        float v2 = B[(i64)(k0+kg+2)*ldb + n0 + n];
        float v3 = B[(i64)(k0+kg+3)*ldb + n0 + n];
        Bs[n][kg] = f2bf(v0); Bs[n][kg+1] = f2bf(v1);
        Bs[n][kg+2] = f2bf(v2); Bs[n][kg+3] = f2bf(v3);
      }
    } else {
      #pragma unroll
      for (int it=0; it<2; it++){
        int lin = tid + it*256;
        int r = lin >> 3, c4 = (lin & 7) * 4;
        float4 g = *(const float4*)&B[(i64)(n0+r)*ldb + k0 + c4];
        Bs[r][c4]   = f2bf(g.x); Bs[r][c4+1] = f2bf(g.y);
        Bs[r][c4+2] = f2bf(g.z); Bs[r][c4+3] = f2bf(g.w);
      }
    }
    __syncthreads();
    bf16x8 af[2], bfr[2];
    #pragma unroll
    for (int i=0;i<2;i++) af[i]  = *(const bf16x8*)&As[wm + i*16 + mr][quad*8];
    #pragma unroll
    for (int j=0;j<2;j++) bfr[j] = *(const bf16x8*)&Bs[wn + j*16 + mr][quad*8];
    #pragma unroll
    for (int i=0;i<2;i++)
      #pragma unroll
      for (int j=0;j<2;j++)
        acc[i][j] = __builtin_amdgcn_mfma_f32_16x16x32_bf16(af[i], bfr[j], acc[i][j], 0, 0, 0);
    __syncthreads();
  }
  #pragma unroll
  for (int i=0;i<2;i++){
    #pragma unroll
    for (int r=0;r<4;r++){
      int m = m0 + wm + i*16 + quad*4 + r;
      float rm = rowmul ? rowmul[m] : 1.f;
      i64 mrow = (combine == 4) ? (i64)(((m & 255) << 8) | (m >> 8)) : (i64)m;
      #pragma unroll
      for (int j=0;j<2;j++){
        int n = n0 + wn + j*16 + mr;
        float v = acc[i][j][r] * scale;
        if (bias) v += bias[n];
        if (act == 1) v = fmaxf(v, 0.f);
        else if (act == 2) v = 1.f/(1.f + __expf(-v));
        v *= rm;
        i64 idx = mrow*ldc + n;
        if (combine == 0) C[idx] = v;
        else if (combine == 1 || combine == 4) C[idx] += v;
        else if (combine == 2) C[idx] *= v;
        else C[idx] += aux[(i64)m*ldc + n] * v;
      }
    }
  }
}

// ---------------- fused dual-MFMA lin*sigmoid(gate) for tri-mult ----------------
// v2: 64x64 tile (was 128x128 at grid 512 -> 2 blocks/CU latency-bound like R3's mgemm_k).
// Grid (1024, 2) = 2048 blocks; LDS 15 KB.
__global__ __launch_bounds__(256) void mlrgate_k(
    const float* __restrict__ X,
    const float* __restrict__ Wl, const float* __restrict__ bl,
    const float* __restrict__ Wg, const float* __restrict__ bg,
    float* __restrict__ Out)
{
  int m0 = blockIdx.x * 64, n0 = blockIdx.y * 64;
  int tid = threadIdx.x;
  int wave = tid >> 6, lane = tid & 63;
  int quad = lane >> 4, mr = lane & 15;
  int wm = (wave >> 1) * 32, wn = (wave & 1) * 32;
  __shared__ unsigned short As[64][40], B1s[64][40], B2s[64][40];
  f32x4 acc1[2][2], acc2[2][2];
  #pragma unroll
  for (int i=0;i<2;i++)
    #pragma unroll
    for (int j=0;j<2;j++){ acc1[i][j] = (f32x4){0,0,0,0}; acc2[i][j] = (f32x4){0,0,0,0}; }

  for (int k0 = 0; k0 < 128; k0 += 32){
    #pragma unroll
    for (int it=0; it<2; it++){
      int lin = tid + it*256;
      int r = lin >> 3, c4 = (lin & 7) * 4;
      float4 g = *(const float4*)&X[(i64)(m0+r)*128 + k0 + c4];
      As[r][c4]   = f2bf(g.x); As[r][c4+1] = f2bf(g.y);
      As[r][c4+2] = f2bf(g.z); As[r][c4+3] = f2bf(g.w);
    }
    #pragma unroll
    for (int it=0; it<2; it++){
      int lin = tid + it*256;
      int n = lin & 63, kg = (lin >> 6) * 4;
      float a0 = Wl[(i64)(k0+kg  )*128 + n0 + n];
      float a1 = Wl[(i64)(k0+kg+1)*128 + n0 + n];
      float a2 = Wl[(i64)(k0+kg+2)*128 + n0 + n];
      float a3 = Wl[(i64)(k0+kg+3)*128 + n0 + n];
      B1s[n][kg] = f2bf(a0); B1s[n][kg+1] = f2bf(a1);
      B1s[n][kg+2] = f2bf(a2); B1s[n][kg+3] = f2bf(a3);
      float g0 = Wg[(i64)(k0+kg  )*128 + n0 + n];
      float g1 = Wg[(i64)(k0+kg+1)*128 + n0 + n];
      float g2 = Wg[(i64)(k0+kg+2)*128 + n0 + n];
      float g3 = Wg[(i64)(k0+kg+3)*128 + n0 + n];
      B2s[n][kg] = f2bf(g0); B2s[n][kg+1] = f2bf(g1);
      B2s[n][kg+2] = f2bf(g2); B2s[n][kg+3] = f2bf(g3);
    }
    __syncthreads();
    bf16x8 af[2], b1f[2], b2f[2];
    #pragma unroll
    for (int i=0;i<2;i++) af[i]  = *(const bf16x8*)&As[wm + i*16 + mr][quad*8];
    #pragma unroll
    for (int j=0;j<2;j++){
      b1f[j] = *(const bf16x8*)&B1s[wn + j*16 + mr][quad*8];
      b2f[j] = *(const bf16x8*)&B2s[wn + j*16 + mr][quad*8];
    }
    #pragma unroll
    for (int i=0;i<2;i++)
      #pragma unroll
      for (int j=0;j<2;j++){
        acc1[i][j] = __builtin_amdgcn_mfma_f32_16x16x32_bf16(af[i], b1f[j], acc1[i][j], 0, 0, 0);
        acc2[i][j] = __builtin_amdgcn_mfma_f32_16x16x32_bf16(af[i], b2f[j], acc2[i][j], 0, 0, 0);
      }
    __syncthreads();
  }
  #pragma unroll
  for (int i=0;i<2;i++){
    #pragma unroll
    for (int r=0;r<4;r++){
      int m = m0 + wm + i*16 + quad*4 + r;
      #pragma unroll
      for (int j=0;j<2;j++){
        int n = wn + j*16 + mr;
        float lv = acc1[i][j][r] + bl[n0 + n];
        float gv = acc2[i][j][r] + bg[n0 + n];
        Out[(i64)m*128 + n0 + n] = lv * (1.f/(1.f + __expf(-gv)));
      }
    }
  }
}

// ---------------- generic batched GEMM (fp32, 64x64 tile) ----------------
template<bool TA, bool TB>
__global__ __launch_bounds__(256) void gemm_k(
    const float* __restrict__ A, int lda, i64 sA,
    const float* __restrict__ B, int ldb, i64 sB,
    float* __restrict__ C, int ldc, i64 sC,
    int M, int N, int K,
    const float* __restrict__ bias, float scale, int act,
    const float* __restrict__ rowmul, int combine)
{
  A += (i64)blockIdx.z * sA;
  B += (i64)blockIdx.z * sB;
  C += (i64)blockIdx.z * sC;
  int m0 = blockIdx.x * 64, n0 = blockIdx.y * 64;
  int tid = threadIdx.x, tx = tid & 15, ty = tid >> 4;
  __shared__ float As[16][68], Bs[16][68];
  float acc[4][4] = {};
  for (int k0 = 0; k0 < K; k0 += 16){
    if (TA){
      for (int l = tid; l < 1024; l += 256){
        int kk = l >> 6, mi = l & 63; int m = m0 + mi;
        As[kk][mi] = (m < M) ? A[(i64)(k0+kk)*lda + m] : 0.f;
      }
    } else {
      for (int l = tid; l < 1024; l += 256){
        int mi = l >> 4, kk = l & 15; int m = m0 + mi;
        As[kk][mi] = (m < M) ? A[(i64)m*lda + k0 + kk] : 0.f;
      }
    }
    if (TB){
      for (int l = tid; l < 1024; l += 256){
        int ni = l >> 4, kk = l & 15; int n = n0 + ni;
        Bs[kk][ni] = (n < N) ? B[(i64)n*ldb + k0 + kk] : 0.f;
      }
    } else {
      for (int l = tid; l < 1024; l += 256){
        int kk = l >> 6, ni = l & 63; int n = n0 + ni;
        Bs[kk][ni] = (n < N) ? B[(i64)(k0+kk)*ldb + n] : 0.f;
      }
    }
    __syncthreads();
    #pragma unroll
    for (int kk = 0; kk < 16; ++kk){
      float4 av4 = *(const float4*)&As[kk][ty*4];
      float4 bv4 = *(const float4*)&Bs[kk][tx*4];
      float av[4] = {av4.x, av4.y, av4.z, av4.w};
      float bv[4] = {bv4.x, bv4.y, bv4.z, bv4.w};
      #pragma unroll
      for (int i=0;i<4;i++)
        #pragma unroll
        for (int j=0;j<4;j++) acc[i][j] = fmaf(av[i], bv[j], acc[i][j]);
    }
    __syncthreads();
  }
  #pragma unroll
  for (int i=0;i<4;i++){
    int m = m0 + ty*4 + i;
    if (m >= M) continue;
    float rm = rowmul ? rowmul[m] : 1.f;
    #pragma unroll
    for (int j=0;j<4;j++){
      int n = n0 + tx*4 + j;
      if (n >= N) continue;
      float v = acc[i][j] * scale;
      if (bias) v += bias[n];
      if (act == 1) v = fmaxf(v, 0.f);
      else if (act == 2) v = 1.f/(1.f + expf(-v));
      v *= rm;
      i64 idx = (i64)m*ldc + n;
      if (combine == 0) C[idx] = v;
      else if (combine == 1) C[idx] += v;
      else C[idx] *= v;
    }
  }
}

// ---------------- thin GEMM (small M): split-K two-phase ----------------
__global__ __launch_bounds__(256) void gemm_part_k(
    const float* __restrict__ A, int lda,
    const float* __restrict__ B, int ldb,
    float* __restrict__ Cp, int M, int N, int K, int chunk)
{
  int m0 = blockIdx.x*16, n0 = blockIdx.y*64, z = blockIdx.z;
  int kb = z*chunk, ke = min(K, kb+chunk);
  int tid = threadIdx.x;
  int mi = tid >> 4, ni4 = (tid & 15)*4;
  __shared__ float As[16][17], Bs[16][68];
  float acc[4] = {0.f,0.f,0.f,0.f};
  for (int k0 = kb; k0 < ke; k0 += 16){
    { int r = tid>>4, c = tid&15; int m = m0+r;
      As[c][r] = (m < M) ? A[(i64)m*lda + k0 + c] : 0.f; }
    for (int l = tid; l < 1024; l += 256){
      int kk = l>>6, nn = l&63; int n = n0+nn;
      Bs[kk][nn] = (n < N) ? B[(i64)(k0+kk)*ldb + n] : 0.f;
    }
    __syncthreads();
    #pragma unroll
    for (int kk=0;kk<16;kk++){
      float a = As[kk][mi];
      float4 b = *(const float4*)&Bs[kk][ni4];
      acc[0]=fmaf(a,b.x,acc[0]); acc[1]=fmaf(a,b.y,acc[1]);
      acc[2]=fmaf(a,b.z,acc[2]); acc[3]=fmaf(a,b.w,acc[3]);
    }
    __syncthreads();
  }
  int m = m0+mi, n = n0+ni4;
  if (m < M && n < N) *(float4*)&Cp[((i64)z*M + m)*N + n] = *(float4*)acc;
}

__global__ __launch_bounds__(256) void gemm_reduce_k(
    const float* __restrict__ Cp, float* __restrict__ C, int ldc,
    int M, int N, int S,
    const float* __restrict__ bias, float scale, int act,
    const float* __restrict__ rowmul, int combine)
{
  i64 idx = (i64)blockIdx.x*256 + threadIdx.x;
  if (idx >= (i64)M*N) return;
  int m = (int)(idx / N), n = (int)(idx % N);
  float s = 0.f;
  for (int z=0; z<S; z++) s += Cp[(i64)z*M*N + idx];
  float v = s*scale;
  if (bias) v += bias[n];
  if (act == 1) v = fmaxf(v, 0.f);
  else if (act == 2) v = 1.f/(1.f + expf(-v));
  if (rowmul) v *= rowmul[m];
  i64 o = (i64)m*ldc + n;
  if (combine == 0) C[o] = v;
  else if (combine == 1) C[o] += v;
  else C[o] *= v;
}

// ---------------- OPM ----------------
__global__ __launch_bounds__(128) void opm_wd_k(const float* __restrict__ right, const float* __restrict__ W,
                                                float* __restrict__ Wd){
  int d = blockIdx.x, c = blockIdx.y, f = threadIdx.x;
  float acc = 0.f;
  #pragma unroll
  for (int e=0;e<32;e++) acc = fmaf(right[d*32+e], W[((i64)c*32+e)*128 + f], acc);
  Wd[((i64)d*32+c)*128 + f] = acc;
}

// pa[d,b,f] = pair_act[d,b,f] + (sum_c left[b,c]*Wd[d,c,f] + ob[f]) / (1e-3 + sm[d]*sm[b])
__global__ __launch_bounds__(128) void opm_final_k(const float* __restrict__ left, const float* __restrict__ Wd,
                                                   const float* __restrict__ ob, const float* __restrict__ sm,
                                                   const float* __restrict__ pair_act, float* __restrict__ pa){
  int d = blockIdx.x, b0 = blockIdx.y*16, f = threadIdx.x;
  __shared__ float wd_s[32][128];
  __shared__ float l_s[16][32];
  for (int c=0;c<32;c++) wd_s[c][f] = Wd[((i64)d*32+c)*128 + f];
  for (int l = f; l < 512; l += 128){ int bi=l>>5, c=l&31; l_s[bi][c] = left[(b0+bi)*32 + c]; }
  __syncthreads();
  float md = sm[d], obf = ob[f];
  for (int bi=0;bi<16;bi++){
    float acc = 0.f;
    #pragma unroll
    for (int c=0;c<32;c++) acc = fmaf(l_s[bi][c], wd_s[c][f], acc);
    int b = b0+bi;
    i64 idx = ((i64)d*256 + b)*128 + f;
    pa[idx] = pair_act[idx] + (acc + obf) / (1e-3f + md*sm[b]);
  }
}

// ---------------- row attention core ----------------
__global__ __launch_bounds__(256) void ra_attn_k(const float* __restrict__ q, const float* __restrict__ k,
                                                 const float* __restrict__ v, const float* __restrict__ nb,
                                                 const float* __restrict__ sm, float* __restrict__ wa){
  int qi = blockIdx.x, h = blockIdx.y, tid = threadIdx.x;
  __shared__ float qv[48];
  __shared__ float p[256];
  __shared__ float red[256];
  if (tid < 48) qv[tid] = q[(i64)qi*384 + h*48 + tid];
  __syncthreads();
  float acc = 0.f;
  const float* kr = k + (i64)tid*384 + h*48;
  #pragma unroll
  for (int c=0;c<48;c++) acc = fmaf(qv[c], kr[c], acc);
  acc += 1e9f*(sm[tid]-1.f) + nb[((i64)qi*256 + tid)*8 + h];
  red[tid] = acc; __syncthreads();
  for (int off=128;off>0;off>>=1){ if (tid<off) red[tid] = fmaxf(red[tid], red[tid+off]); __syncthreads(); }
  float mx = red[0]; __syncthreads();
  float e = expf(acc - mx);
  red[tid] = e; __syncthreads();
  for (int off=128;off>0;off>>=1){ if (tid<off) red[tid] += red[tid+off]; __syncthreads(); }
  p[tid] = e / red[0];
  __syncthreads();
  if (tid < 48){
    float a = 0.f;
    for (int kk=0;kk<256;kk++) a = fmaf(p[kk], v[(i64)kk*384 + h*48 + tid], a);
    wa[(i64)qi*384 + h*48 + tid] = a;
  }
}

// ---------------- triangle attention core v7: swapped-operand MFMA flash ----------------
// S = mfma(K, Q): lane holds scores for ONE q-row (softmax per-lane, 4 shfl per tile);
// O^T = mfma(V^T, P): alpha/1/l per-lane scalars, coalesced float4 store.
// Grid (qblk,h,b): qblk fastest -> K/V L2 reuse across the 4 sharing blocks.
__global__ __launch_bounds__(256, 6) void ta_mfma_k(
    const float* __restrict__ q, const float* __restrict__ k, const float* __restrict__ v,
    const float* __restrict__ nbQ, const float* __restrict__ mask, int maskT,
    float* __restrict__ wa)
{
  int qblk = blockIdx.x, h = blockIdx.y, b = blockIdx.z;
  int tid = threadIdx.x;
  int wave = tid >> 6, lane = tid & 63;
  int quad = lane >> 4, mr = lane & 15;
  const i64 base = ((i64)b*256)*128 + h*32;

  __shared__ __align__(16) unsigned short Ks[128][40];   // [key][c], row 80B
  __shared__ __align__(16) unsigned short Vt[32][136];   // [c][key], row 272B
  __shared__ __align__(16) float mask_s[256];
  __shared__ __align__(16) unsigned short Pl[4][16][40]; // per-wave P [q][key]

  mask_s[tid] = 1e9f * ((maskT ? mask[(i64)tid*256 + b] : mask[(i64)b*256 + tid]) - 1.f);

  int q0w = qblk*64 + wave*16;
  int qg = q0w + mr;                      // this lane's q row (fixed for whole kernel)
  const float* nbq = nbQ + (i64)h*65536 + (i64)qg*256;

  // Q as B-operand fragment: [n=q=mr][k-ch quad*8..+7]
  bf16x8 qf;
  {
    const float* qp = q + base + (i64)qg*128 + quad*8;
    float4 a = *(const float4*)qp;
    float4 c = *(const float4*)(qp+4);
    qf[0]=(short)f2bf(a.x); qf[1]=(short)f2bf(a.y); qf[2]=(short)f2bf(a.z); qf[3]=(short)f2bf(a.w);
    qf[4]=(short)f2bf(c.x); qf[5]=(short)f2bf(c.y); qf[6]=(short)f2bf(c.z); qf[7]=(short)f2bf(c.w);
  }

  f32x4 o0 = (f32x4){0,0,0,0}, o1 = (f32x4){0,0,0,0}; // O^T[c=quad*4+r(+16)][q=mr]
  float mm = -1e30f, ll = 0.f;                         // per-lane softmax state (q = qg)

  for (int half = 0; half < 2; half++){
    __syncthreads();
    #pragma unroll
    for (int it=0; it<4; it++){
      int idx = it*256 + tid;              // 128 keys x 32 ch
      int kl = idx >> 3, c4 = (idx & 7)*4;
      i64 roff = base + (i64)(half*128 + kl)*128 + c4;
      float4 g  = *(const float4*)(k + roff);
      unsigned int w0 = (unsigned int)f2bf(g.x) | ((unsigned int)f2bf(g.y)<<16);
      unsigned int w1 = (unsigned int)f2bf(g.z) | ((unsigned int)f2bf(g.w)<<16);
      *(uint2*)&Ks[kl][c4] = make_uint2(w0, w1);
      float4 gv = *(const float4*)(v + roff);
      Vt[c4  ][kl] = f2bf(gv.x);
      Vt[c4+1][kl] = f2bf(gv.y);
      Vt[c4+2][kl] = f2bf(gv.z);
      Vt[c4+3][kl] = f2bf(gv.w);
    }
    __syncthreads();

    #pragma unroll
    for (int it=0; it<4; it++){
      int kc = it*32;
      int kg = half*128 + kc;
      // K as A-operand: frag rows = keys kc+mr / kc+16+mr
      bf16x8 kf0 = *(const bf16x8*)&Ks[kc + mr][quad*8];
      bf16x8 kf1 = *(const bf16x8*)&Ks[kc + 16 + mr][quad*8];
      f32x4 s0 = __builtin_amdgcn_mfma_f32_16x16x32_bf16(kf0, qf, (f32x4){0,0,0,0}, 0, 0, 0);
      f32x4 s1 = __builtin_amdgcn_mfma_f32_16x16x32_bf16(kf1, qf, (f32x4){0,0,0,0}, 0, 0, 0);
      // s0[r] = S[key=kg+quad*4+r][qg]; s1[r] = S[key=kg+16+quad*4+r][qg]
      float4 nb0 = *(const float4*)(nbq + kg + quad*4);
      float4 nb1 = *(const float4*)(nbq + kg + 16 + quad*4);
      float4 mk0 = *(const float4*)&mask_s[kg + quad*4];
      float4 mk1 = *(const float4*)&mask_s[kg + 16 + quad*4];
      s0[0] += nb0.x + mk0.x; s0[1] += nb0.y + mk0.y; s0[2] += nb0.z + mk0.z; s0[3] += nb0.w + mk0.w;
      s1[0] += nb1.x + mk1.x; s1[1] += nb1.y + mk1.y; s1[2] += nb1.z + mk1.z; s1[3] += nb1.w + mk1.w;

      // per-lane online softmax over the 32-key tile (cross-quad = 2 shfls)
      float tm = fmaxf(fmaxf(fmaxf(s0[0],s0[1]), fmaxf(s0[2],s0[3])),
                       fmaxf(fmaxf(s1[0],s1[1]), fmaxf(s1[2],s1[3])));
      tm = fmaxf(tm, __shfl_xor(tm, 16));
      tm = fmaxf(tm, __shfl_xor(tm, 32));
      float nm = fmaxf(mm, tm);
      float alpha = __expf(mm - nm);
      mm = nm;
      float e00 = __expf(s0[0]-nm), e01 = __expf(s0[1]-nm);
      float e02 = __expf(s0[2]-nm), e03 = __expf(s0[3]-nm);
      float e10 = __expf(s1[0]-nm), e11 = __expf(s1[1]-nm);
      float e12 = __expf(s1[2]-nm), e13 = __expf(s1[3]-nm);
      float ps = ((e00+e01) + (e02+e03)) + ((e10+e11) + (e12+e13));
      ps += __shfl_xor(ps, 16);
      ps += __shfl_xor(ps, 32);
      ll = ll*alpha + ps;
      o0 *= alpha; o1 *= alpha;
      // P[q=mr][key] packed bf16 pairs, 2x 8B writes (2-way banks = free)
      unsigned int p0 = (unsigned int)f2bf(e00) | ((unsigned int)f2bf(e01)<<16);
      unsigned int p1 = (unsigned int)f2bf(e02) | ((unsigned int)f2bf(e03)<<16);
      unsigned int p2 = (unsigned int)f2bf(e10) | ((unsigned int)f2bf(e11)<<16);
      unsigned int p3 = (unsigned int)f2bf(e12) | ((unsigned int)f2bf(e13)<<16);
      *(uint2*)&Pl[wave][mr][quad*4]      = make_uint2(p0, p1);
      *(uint2*)&Pl[wave][mr][16 + quad*4] = make_uint2(p2, p3);
      // PV (swapped): A = V^T rows=channels, B = P [k=key][n=q=mr]
      bf16x8 pf  = *(const bf16x8*)&Pl[wave][mr][quad*8];
      bf16x8 vf0 = *(const bf16x8*)&Vt[mr     ][kc + quad*8];
      bf16x8 vf1 = *(const bf16x8*)&Vt[16 + mr][kc + quad*8];
      o0 = __builtin_amdgcn_mfma_f32_16x16x32_bf16(vf0, pf, o0, 0, 0, 0);
      o1 = __builtin_amdgcn_mfma_f32_16x16x32_bf16(vf1, pf, o1, 0, 0, 0);
    }
  }

  float inv = 1.f/ll;
  float* wp = wa + base + (i64)qg*128;
  *(float4*)(wp + quad*4)      = make_float4(o0[0]*inv, o0[1]*inv, o0[2]*inv, o0[3]*inv);
  *(float4*)(wp + 16 + quad*4) = make_float4(o1[0]*inv, o1[1]*inv, o1[2]*inv, o1[3]*inv);
}

// ---------------- host dispatch ----------------
static void gemm(hipStream_t st, bool TA, bool TB,
                 const float* A, int lda, i64 sA,
                 const float* B, int ldb, i64 sB,
                 float* C, int ldc, i64 sC,
                 int M, int N, int K, int batch,
                 const float* bias, float scale, int act,
                 const float* rowmul, int combine)
{
  dim3 g((M+63)/64, (N+63)/64, batch), bl(256);
  if (!TA && !TB)      gemm_k<false,false><<<g,bl,0,st>>>(A,lda,sA,B,ldb,sB,C,ldc,sC,M,N,K,bias,scale,act,rowmul,combine);
  else if (!TA &&  TB) gemm_k<false,true ><<<g,bl,0,st>>>(A,lda,sA,B,ldb,sB,C,ldc,sC,M,N,K,bias,scale,act,rowmul,combine);
  else                 gemm_k<true ,false><<<g,bl,0,st>>>(A,lda,sA,B,ldb,sB,C,ldc,sC,M,N,K,bias,scale,act,rowmul,combine);
}

static void mgemm(hipStream_t st, bool TA, bool TB,
                  const float* A, int lda, i64 sA,
                  const float* B, int ldb, i64 sB,
                  float* C, int ldc, i64 sC,
                  int M, int N, int K, int batch,
                  const float* bias, float scale, int act,
                  const float* rowmul, int combine, const float* aux = nullptr)
{
  dim3 bl(256);
  i64 nb128 = (i64)(M/128)*(N/128)*batch;
  if (nb128 < 1024 && (M % 64) == 0 && (N % 64) == 0){
    // latency-regime fix (R3): <1024 blocks at 128-tile -> 2 blocks/CU; use 64x64 tiles
    dim3 g(M/64, N/64, batch);
    if (!TA && !TB)      mgemm64_k<false,false><<<g,bl,0,st>>>(A,lda,sA,B,ldb,sB,C,ldc,sC,M,N,K,bias,scale,act,rowmul,combine,aux);
    else if (!TA &&  TB) mgemm64_k<false,true ><<<g,bl,0,st>>>(A,lda,sA,B,ldb,sB,C,ldc,sC,M,N,K,bias,scale,act,rowmul,combine,aux);
    else                 mgemm64_k<true ,false><<<g,bl,0,st>>>(A,lda,sA,B,ldb,sB,C,ldc,sC,M,N,K,bias,scale,act,rowmul,combine,aux);
    return;
  }
  dim3 g(M/128, N/128, batch);
  if (!TA && !TB)      mgemm_k<false,false><<<g,bl,0,st>>>(A,lda,sA,B,ldb,sB,C,ldc,sC,M,N,K,bias,scale,act,rowmul,combine,aux);
  else if (!TA &&  TB) mgemm_k<false,true ><<<g,bl,0,st>>>(A,lda,sA,B,ldb,sB,C,ldc,sC,M,N,K,bias,scale,act,rowmul,combine,aux);
  else                 mgemm_k<true ,false><<<g,bl,0,st>>>(A,lda,sA,B,ldb,sB,C,ldc,sC,M,N,K,bias,scale,act,rowmul,combine,aux);
}

static void gemm_thin(hipStream_t st,
                      const float* A, int lda, const float* B, int ldb,
                      float* C, int ldc, int M, int N, int K,
                      const float* bias, float scale, int act,
                      const float* rowmul, int combine, float* part)
{
  const int S = 8;
  int chunk = ((K/S + 15)/16)*16; if (chunk < 16) chunk = 16;
  dim3 g((M+15)/16, (N+63)/64, S);
  gemm_part_k<<<g,256,0,st>>>(A,lda,B,ldb,part,M,N,K,chunk);
  i64 t = (i64)M*N;
  gemm_reduce_k<<<(int)((t+255)/256),256,0,st>>>(part,C,ldc,M,N,S,bias,scale,act,rowmul,combine);
}

extern "C" void kernel_launch(void* const* d_in, const int* in_sizes, int n_in,
                              void* d_out, int out_size, void* d_ws, size_t ws_size,
                              hipStream_t stream)
{
  const float* IN[64];
  for (int i=0;i<n_in && i<64;i++) IN[i] = (const float*)d_in[i];

  const float* single_act = IN[0];
  const float* pair_act   = IN[1];
  const float* sm         = IN[2];
  const float* pm         = IN[3];
  const float* opm_ln     = IN[4];
  const float* opm_lr_w   = IN[5];
  const float* opm_lr_b   = IN[6];
  const float* opm_out_w  = IN[7];
  const float* opm_out_b  = IN[8];
  const float* ra_ln      = IN[9];
  const float* ra_pair_ln = IN[10];
  const float* ra_feat_w  = IN[11];
  const float* ra_qkv_w   = IN[12];
  const float* ra_gate_w  = IN[13];
  const float* ra_gate_b  = IN[14];
  const float* ra_o_w     = IN[15];
  const float* ra_o_b     = IN[16];
  const float* st_ln      = IN[17];
  const float* st_w1      = IN[18];
  const float* st_b1      = IN[19];
  const float* st_w2      = IN[20];
  const float* st_b2      = IN[21];
  const float* pt_ln      = IN[56];
  const float* pt_w1      = IN[57];
  const float* pt_b1      = IN[58];
  const float* pt_w2      = IN[59];
  const float* pt_b2      = IN[60];

  float* sa = (float*)d_out;           // [256,384]
  float* pa = (float*)d_out + 98304;   // [256,256,128]

  float* W  = (float*)d_ws;
  float* B0 = W;
  float* B1 = W + 8388608L;
  float* B2 = W + 16777216L;
  float* B3 = W + 25165824L;
  float* SMA = W + 33554432L;
  float* xs   = SMA;
  float* qb   = SMA +  98304;
  float* kb   = SMA + 196608;
  float* vb   = SMA + 294912;
  float* wab  = SMA + 393216;
  float* hst  = SMA + 491520;   // 393216
  float* nbra = SMA + 884736;   // 524288 (reused as nbQ in tri-attn phase)
  float* lbuf = SMA + 1409024;  // 8192
  float* rbuf = SMA + 1417216;  // 8192
  float* Wd   = SMA + 1425408;  // 1048576
  float* nbt  = SMA + 2473984;  // 262144

  // init sa with residual base (pa is initialized by opm_final_k's fused write)
  copy_k<<<384, 256, 0, stream>>>(sa, single_act, 98304L);

  // ---- 1) OPM -> pair residual (writes pa = pair_act + update) ----
  ln_k<<<256,128,0,stream>>>(single_act, xs, opm_ln, 384);
  gemm_thin(stream, xs,384, opm_lr_w,32,       lbuf,32, 256,32,384, opm_lr_b,    1.f,0, sm,0, B1);
  gemm_thin(stream, xs,384, opm_lr_w+12288,32, rbuf,32, 256,32,384, opm_lr_b+32, 1.f,0, sm,0, B1);
  opm_wd_k<<<dim3(256,32),128,0,stream>>>(rbuf, opm_out_w, Wd);
  opm_final_k<<<dim3(256,16),128,0,stream>>>(lbuf, Wd, opm_out_b, sm, pair_act, pa);

  // ---- 2) row attention with pair bias ----
  ln_k<<<256,128,0,stream>>>(sa, xs, ra_ln, 384);
  ln128_k<<<16384,256,0,stream>>>(pa, B0, ra_pair_ln, 0);
  gemm(stream,false,false, B0,128,0, ra_feat_w,8,0, nbra,8,0, 65536,8,128,1, nullptr,1.f,0,nullptr,0);
  const float qs_ra = 0.14433756729740643f; // 1/sqrt(48)
  gemm_thin(stream, xs,384, ra_qkv_w,384,        qb,384, 256,384,384, nullptr,qs_ra,0,nullptr,0, B1);
  gemm_thin(stream, xs,384, ra_qkv_w+147456,384, kb,384, 256,384,384, nullptr,1.f,0,nullptr,0, B1);
  gemm_thin(stream, xs,384, ra_qkv_w+294912,384, vb,384, 256,384,384, nullptr,1.f,0,nullptr,0, B1);
  ra_attn_k<<<dim3(256,8),256,0,stream>>>(qb, kb, vb, nbra, sm, wab);
  gemm_thin(stream, xs,384,  ra_gate_w,384, wab,384, 256,384,384, ra_gate_b,1.f,2,nullptr,2, B1);
  gemm_thin(stream, wab,384, ra_o_w,384,    sa,384,  256,384,384, ra_o_b,   1.f,0,nullptr,1, B1);

  // ---- 3) single transition ----
  ln_k<<<256,128,0,stream>>>(sa, xs, st_ln, 384);
  gemm_thin(stream, xs,384,   st_w1,1536, hst,1536, 256,1536,384, st_b1,1.f,1,nullptr,0, B1);
  gemm_thin(stream, hst,1536, st_w2,384,  sa,384,   256,384,1536, st_b2,1.f,0,nullptr,1, B1);

  // ---- 4/5) triangle multiplications ----
  auto tri_mult = [&](int base, bool outgoing){
    const float* ln_w = IN[base+0];
    const float* lr_w = IN[base+1];
    const float* lr_b = IN[base+2];
    const float* gw   = IN[base+3];
    const float* gb   = IN[base+4];
    const float* cln  = IN[base+5];
    const float* ow   = IN[base+6];
    const float* ob   = IN[base+7];
    const float* ogw  = IN[base+8];
    const float* ogb  = IN[base+9];
    ln128_k<<<16384,256,0,stream>>>(pa, B0, ln_w, 0);
    // left = mask * (X@Wl+bl) * sigmoid(X@Wg+bg): fused dual-MFMA, then transpose+mask -> B1 (ch-major)
    mlrgate_k<<<dim3(1024,2),256,0,stream>>>(B0, lr_w, lr_b, gw, gb, B3);
    tr_mask_k<<<dim3(2048,4),256,0,stream>>>(B3, pm, B1);
    // right -> B2 (ch-major)
    mlrgate_k<<<dim3(1024,2),256,0,stream>>>(B0, lr_w+16384, lr_b+128, gw+16384, gb+128, B3);
    tr_mask_k<<<dim3(2048,4),256,0,stream>>>(B3, pm, B2);
    if (outgoing) // out[i,j,c] = sum_k L_c[i,k] * R_c[j,k]
      mgemm(stream,false,true, B1,256,65536, B2,256,65536, B3,256,65536, 256,256,256,128, nullptr,1.f,0,nullptr,0);
    else          // out[i,j,c] = sum_k R_c[k,i] * L_c[k,j]
      mgemm(stream,true,false, B2,256,65536, B1,256,65536, B3,256,65536, 256,256,256,128, nullptr,1.f,0,nullptr,0);
    chw2hwc_k<<<dim3(2048,4),256,0,stream>>>(B3, B1);
    ln128_k<<<16384,256,0,stream>>>(B1, B3, cln, 0);
    mgemm(stream,false,false, B3,128,0, ow,128,0,  B1,128,0, 65536,128,128,1, ob,  1.f,0,nullptr,0);
    // fused: pa += B1 * sigmoid(B0@ogw + ogb)
    mgemm(stream,false,false, B0,128,0, ogw,128,0, pa,128,0, 65536,128,128,1, ogb, 1.f,2,nullptr,3, B1);
  };
  tri_mult(22, true);   // tmo
  tri_mult(32, false);  // tmi

  // ---- 6/7) triangle attentions ----
  auto tri_attn = [&](int base, bool percol){
    const float* ln_w   = IN[base+0];
    const float* feat_w = IN[base+1];
    const float* qkv_w  = IN[base+2];
    const float* gw     = IN[base+3];
    const float* gb     = IN[base+4];
    const float* ow     = IN[base+5];
    const float* ob     = IN[base+6];
    // LN with fused pair-transpose read for per-column attention
    ln128_k<<<16384,256,0,stream>>>(pa, B0, ln_w, percol?1:0);
    gemm(stream,false,false, B0,128,0, feat_w,4,0, nbt,4,0, 65536,4,128,1, nullptr,1.f,0,nullptr,0);
    nbQ_k<<<256,256,0,stream>>>(nbt, nbra);  // nbQ[h][q][k]
    const float qs = 0.17677669529663687f; // 1/sqrt(32)
    mgemm(stream,false,false, B0,128,0, qkv_w,128,0,       B1,128,0, 65536,128,128,1, nullptr,qs, 0,nullptr,0);
    mgemm(stream,false,false, B0,128,0, qkv_w+16384,128,0, B2,128,0, 65536,128,128,1, nullptr,1.f,0,nullptr,0);
    mgemm(stream,false,false, B0,128,0, qkv_w+32768,128,0, B3,128,0, 65536,128,128,1, nullptr,1.f,0,nullptr,0);
    ta_mfma_k<<<dim3(4,4,256),256,0,stream>>>(B1, B2, B3, nbra, pm, percol?1:0, B1);
    mgemm(stream,false,false, B0,128,0, gw,128,0, B1,128,0, 65536,128,128,1, gb,1.f,2,nullptr,2); // wa *= sigmoid(gate)
    // out-projection fused with residual add (4 = transpose-pair write for per-column)
    mgemm(stream,false,false, B1,128,0, ow,128,0, pa,128,0, 65536,128,128,1, ob,1.f,0,nullptr, percol?4:1);
  };
  tri_attn(42, false);  // tas (per-row)
  tri_attn(49, true);   // tae (per-column)

  // ---- 8) pair transition ----
  ln128_k<<<16384,256,0,stream>>>(pa, B0, pt_ln, 0);
  for (int half = 0; half < 2; half++){
    const float* xh = B0 + (i64)half*4194304;
    float* ph = pa + (i64)half*4194304;
    mgemm(stream,false,false, xh,128,0, pt_w1,512,0, B1,512,0, 32768,512,128,1, pt_b1,1.f,1,nullptr,0);
    mgemm(stream,false,false, B1,512,0, pt_w2,128,0, ph,128,0, 32768,128,512,1, pt_b2,1.f,0,nullptr,1);
  }
}

// Round 8
// 1585.709 us; speedup vs baseline: 1.2714x; 1.0472x over previous
//
#include <hip/hip_runtime.h>
#include <math.h>

typedef long long i64;
#define NN_ 65536L

typedef __attribute__((ext_vector_type(8))) short bf16x8;
typedef __attribute__((ext_vector_type(4))) float f32x4;

__device__ inline unsigned short f2bf(float f){
  unsigned int u = __float_as_uint(f);
  return (unsigned short)((u + 0x7FFFu + ((u>>16)&1u)) >> 16);
}

// ---------------- elementwise ----------------
__global__ __launch_bounds__(256) void copy_k(float* __restrict__ d, const float* __restrict__ s, long n){
  long i = (long)blockIdx.x*blockDim.x + threadIdx.x;
  if (i < n) d[i] = s[i];
}

// channel-major [128][65536] -> row-major [65536][128]
__global__ __launch_bounds__(256) void chw2hwc_k(const float* __restrict__ in, float* __restrict__ out){
  __shared__ float t[32][33];
  int r0 = blockIdx.x*32, c0 = blockIdx.y*32;
  int tx = threadIdx.x & 31, ty = threadIdx.x >> 5;
  for (int i = ty; i < 32; i += 8) t[i][tx] = in[(i64)(c0+i)*NN_ + r0 + tx];
  __syncthreads();
  for (int i = ty; i < 32; i += 8) out[(i64)(r0+i)*128 + c0 + tx] = t[tx][i];
}

// row-major [65536][128] -> ch-major [128][65536] with per-row mask
__global__ __launch_bounds__(256) void tr_mask_k(const float* __restrict__ in, const float* __restrict__ mask,
                                                 float* __restrict__ out){
  __shared__ float t[32][33];
  int r0 = blockIdx.x*32, c0 = blockIdx.y*32;
  int tx = threadIdx.x & 31, ty = threadIdx.x >> 5;
  for (int i = ty; i < 32; i += 8) t[i][tx] = in[(i64)(r0+i)*128 + c0 + tx];
  __syncthreads();
  for (int i = ty; i < 32; i += 8) out[(i64)(c0+i)*NN_ + r0 + tx] = t[tx][i] * mask[r0+tx];
}

// nb [q,k,h=4] -> nbQ [h][q][k]  (block = q row, thread = k: coalesced read AND write)
__global__ __launch_bounds__(256) void nbQ_k(const float* __restrict__ in, float* __restrict__ out){
  int qq = blockIdx.x, kk = threadIdx.x;
  float4 vv = *(const float4*)(in + ((i64)qq*256 + kk)*4);
  out[0*65536 + qq*256 + kk] = vv.x;
  out[1*65536 + qq*256 + kk] = vv.y;
  out[2*65536 + qq*256 + kk] = vv.z;
  out[3*65536 + qq*256 + kk] = vv.w;
}

// ---------------- LayerNorm generic (rowwise, C arbitrary) ----------------
__global__ __launch_bounds__(128) void ln_k(const float* __restrict__ in, float* __restrict__ out,
                                            const float* __restrict__ w, int C){
  i64 row = blockIdx.x;
  const float* x = in + row*C;
  float* y = out + row*C;
  int tid = threadIdx.x;
  float s=0.f, s2=0.f;
  for (int c=tid;c<C;c+=128){ float v = x[c]; s += v; s2 += v*v; }
  __shared__ float rs[128], rq[128];
  rs[tid]=s; rq[tid]=s2; __syncthreads();
  for (int off=64;off>0;off>>=1){ if (tid<off){ rs[tid]+=rs[tid+off]; rq[tid]+=rq[tid+off]; } __syncthreads(); }
  float mu = rs[0]/C;
  float var = rq[0]/C - mu*mu;
  float inv = rsqrtf(var + 1e-5f);
  for (int c=tid;c<C;c+=128) y[c] = (x[c]-mu)*inv*w[c] + w[C+c];
}

// ---------------- LayerNorm C=128: one wave per row, shuffle-only reduction ----------------
// T=1: read row rt = transpose-pair index of row (fused pa transpose for per-column attention)
__global__ __launch_bounds__(256) void ln128_k(const float* __restrict__ in, float* __restrict__ out,
                                               const float* __restrict__ w, int T){
  int wv = threadIdx.x >> 6, lane = threadIdx.x & 63;
  i64 row = (i64)blockIdx.x*4 + wv;
  i64 rr = T ? (i64)((((int)row & 255) << 8) | ((int)row >> 8)) : row;
  float2 v = *(const float2*)(in + rr*128 + lane*2);
  float s = v.x + v.y, s2 = v.x*v.x + v.y*v.y;
  #pragma unroll
  for (int off=32; off; off>>=1){ s += __shfl_down(s, off); s2 += __shfl_down(s2, off); }
  s = __shfl(s, 0); s2 = __shfl(s2, 0);
  float mu = s*(1.f/128.f);
  float var = s2*(1.f/128.f) - mu*mu;
  float inv = rsqrtf(var + 1e-5f);
  float2 wl = *(const float2*)(w + lane*2);
  float2 wb = *(const float2*)(w + 128 + lane*2);
  float2 y; y.x = (v.x-mu)*inv*wl.x + wb.x; y.y = (v.y-mu)*inv*wl.y + wb.y;
  *(float2*)(out + row*128 + lane*2) = y;
}

// ---------------- bf16 MFMA GEMM: 128x128 tile, 256 thr (2x2 waves of 64x64) ----------------
// combine: 0 store, 1 +=, 2 *=, 3: C += aux*v, 4: C[transpose-pair(m)] += v (pair tensor only)
template<bool TA, bool TB>
__global__ __launch_bounds__(256) void mgemm_k(
    const float* __restrict__ A, int lda, i64 sA,
    const float* __restrict__ B, int ldb, i64 sB,
    float* __restrict__ C, int ldc, i64 sC,
    int M, int N, int K,
    const float* __restrict__ bias, float scale, int act,
    const float* __restrict__ rowmul, int combine, const float* __restrict__ aux)
{
  A += (i64)blockIdx.z * sA;
  B += (i64)blockIdx.z * sB;
  C += (i64)blockIdx.z * sC;
  int m0 = blockIdx.x * 128, n0 = blockIdx.y * 128;
  int tid = threadIdx.x;
  int wave = tid >> 6, lane = tid & 63;
  int quad = lane >> 4, mr = lane & 15;
  int wm = (wave >> 1) * 64, wn = (wave & 1) * 64;
  __shared__ unsigned short As[128][40];
  __shared__ unsigned short Bs[128][40];
  f32x4 acc[4][4];
  #pragma unroll
  for (int i=0;i<4;i++)
    #pragma unroll
    for (int j=0;j<4;j++) acc[i][j] = (f32x4){0.f,0.f,0.f,0.f};

  for (int k0 = 0; k0 < K; k0 += 32){
    if (!TA){
      #pragma unroll
      for (int it=0; it<4; it++){
        int lin = tid + it*256;
        int r = lin >> 3, c4 = (lin & 7) * 4;
        float4 g = *(const float4*)&A[(i64)(m0+r)*lda + k0 + c4];
        As[r][c4]   = f2bf(g.x); As[r][c4+1] = f2bf(g.y);
        As[r][c4+2] = f2bf(g.z); As[r][c4+3] = f2bf(g.w);
      }
    } else {
      #pragma unroll
      for (int it=0; it<4; it++){
        int lin = tid + it*256;
        int m = lin & 127, kg = (lin >> 7) * 4;
        float v0 = A[(i64)(k0+kg  )*lda + m0 + m];
        float v1 = A[(i64)(k0+kg+1)*lda + m0 + m];
        float v2 = A[(i64)(k0+kg+2)*lda + m0 + m];
        float v3 = A[(i64)(k0+kg+3)*lda + m0 + m];
        As[m][kg] = f2bf(v0); As[m][kg+1] = f2bf(v1);
        As[m][kg+2] = f2bf(v2); As[m][kg+3] = f2bf(v3);
      }
    }
    if (!TB){
      #pragma unroll
      for (int it=0; it<4; it++){
        int lin = tid + it*256;
        int n = lin & 127, kg = (lin >> 7) * 4;
        float v0 = B[(i64)(k0+kg  )*ldb + n0 + n];
        float v1 = B[(i64)(k0+kg+1)*ldb + n0 + n];
        float v2 = B[(i64)(k0+kg+2)*ldb + n0 + n];
        float v3 = B[(i64)(k0+kg+3)*ldb + n0 + n];
        Bs[n][kg] = f2bf(v0); Bs[n][kg+1] = f2bf(v1);
        Bs[n][kg+2] = f2bf(v2); Bs[n][kg+3] = f2bf(v3);
      }
    } else {
      #pragma unroll
      for (int it=0; it<4; it++){
        int lin = tid + it*256;
        int r = lin >> 3, c4 = (lin & 7) * 4;
        float4 g = *(const float4*)&B[(i64)(n0+r)*ldb + k0 + c4];
        Bs[r][c4]   = f2bf(g.x); Bs[r][c4+1] = f2bf(g.y);
        Bs[r][c4+2] = f2bf(g.z); Bs[r][c4+3] = f2bf(g.w);
      }
    }
    __syncthreads();
    bf16x8 af[4], bfr[4];
    #pragma unroll
    for (int i=0;i<4;i++) af[i]  = *(const bf16x8*)&As[wm + i*16 + mr][quad*8];
    #pragma unroll
    for (int j=0;j<4;j++) bfr[j] = *(const bf16x8*)&Bs[wn + j*16 + mr][quad*8];
    #pragma unroll
    for (int i=0;i<4;i++)
      #pragma unroll
      for (int j=0;j<4;j++)
        acc[i][j] = __builtin_amdgcn_mfma_f32_16x16x32_bf16(af[i], bfr[j], acc[i][j], 0, 0, 0);
    __syncthreads();
  }
  #pragma unroll
  for (int i=0;i<4;i++){
    #pragma unroll
    for (int r=0;r<4;r++){
      int m = m0 + wm + i*16 + quad*4 + r;
      float rm = rowmul ? rowmul[m] : 1.f;
      i64 mrow = (combine == 4) ? (i64)(((m & 255) << 8) | (m >> 8)) : (i64)m;
      #pragma unroll
      for (int j=0;j<4;j++){
        int n = n0 + wn + j*16 + mr;
        float v = acc[i][j][r] * scale;
        if (bias) v += bias[n];
        if (act == 1) v = fmaxf(v, 0.f);
        else if (act == 2) v = 1.f/(1.f + __expf(-v));
        v *= rm;
        i64 idx = mrow*ldc + n;
        if (combine == 0) C[idx] = v;
        else if (combine == 1 || combine == 4) C[idx] += v;
        else if (combine == 2) C[idx] *= v;
        else C[idx] += aux[(i64)m*ldc + n] * v;
      }
    }
  }
}

// ---------------- bf16 MFMA GEMM: 64x64 tile, 256 thr (2x2 waves of 32x32) ----------------
// For dispatches whose 128-tile grid is <1024 blocks (2 blocks/CU): R3 showed tri-mult batched
// GEMM at grid 512 -> Occupancy 10.8%, MfmaUtil 1.8%, VALUBusy 5% (pure latency, 85 us).
// 64x64 tiles quadruple the grid (2048 blocks -> 6-8 blocks/CU); LDS 10 KB.
template<bool TA, bool TB>
__global__ __launch_bounds__(256) void mgemm64_k(
    const float* __restrict__ A, int lda, i64 sA,
    const float* __restrict__ B, int ldb, i64 sB,
    float* __restrict__ C, int ldc, i64 sC,
    int M, int N, int K,
    const float* __restrict__ bias, float scale, int act,
    const float* __restrict__ rowmul, int combine, const float* __restrict__ aux)
{
  A += (i64)blockIdx.z * sA;
  B += (i64)blockIdx.z * sB;
  C += (i64)blockIdx.z * sC;
  int m0 = blockIdx.x * 64, n0 = blockIdx.y * 64;
  int tid = threadIdx.x;
  int wave = tid >> 6, lane = tid & 63;
  int quad = lane >> 4, mr = lane & 15;
  int wm = (wave >> 1) * 32, wn = (wave & 1) * 32;
  __shared__ unsigned short As[64][40];
  __shared__ unsigned short Bs[64][40];
  f32x4 acc[2][2];
  #pragma unroll
  for (int i=0;i<2;i++)
    #pragma unroll
    for (int j=0;j<2;j++) acc[i][j] = (f32x4){0.f,0.f,0.f,0.f};

  for (int k0 = 0; k0 < K; k0 += 32){
    if (!TA){
      #pragma unroll
      for (int it=0; it<2; it++){
        int lin = tid + it*256;
        int r = lin >> 3, c4 = (lin & 7) * 4;
        float4 g = *(const float4*)&A[(i64)(m0+r)*lda + k0 + c4];
        As[r][c4]   = f2bf(g.x); As[r][c4+1] = f2bf(g.y);
        As[r][c4+2] = f2bf(g.z); As[r][c4+3] = f2bf(g.w);
      }
    } else {
      #pragma unroll
      for (int it=0; it<2; it++){
        int lin = tid + it*256;
        int m = lin & 63, kg = (lin >> 6) * 4;
        float v0 = A[(i64)(k0+kg  )*lda + m0 + m];
        float v1 = A[(i64)(k0+kg+1)*lda + m0 + m];
        float v2 = A[(i64)(k0+kg+2)*lda + m0 + m];
        float v3 = A[(i64)(k0+kg+3)*lda + m0 + m];
        As[m][kg] = f2bf(v0); As[m][kg+1] = f2bf(v1);
        As[m][kg+2] = f2bf(v2); As[m][kg+3] = f2bf(v3);
      }
    }
    if (!TB){
      #pragma unroll
      for (int it=0; it<2; it++){
        int lin = tid + it*256;
        int n = lin & 63, kg = (lin >> 6) * 4;
        float v0 = B[(i64)(k0+kg  )*ldb + n0 + n];
        float v1 = B[(i64)(k0+kg+1)*ldb + n0 + n];
        float v2 = B[(i64)(k0+kg+2)*ldb + n0 + n];
        float v3 = B[(i64)(k0+kg+3)*ldb + n0 + n];
        Bs[n][kg] = f2bf(v0); Bs[n][kg+1] = f2bf(v1);
        Bs[n][kg+2] = f2bf(v2); Bs[n][kg+3] = f2bf(v3);
      }
    } else {
      #pragma unroll
      for (int it=0; it<2; it++){
        int lin = tid + it*256;
        int r = lin >> 3, c4 = (lin & 7) * 4;
        float4 g = *(const float4*)&B[(i64)(n0+r)*ldb + k0 + c4];
        Bs[r][c4]   = f2bf(g.x); Bs[r][c4+1] = f2bf(g.y);
        Bs[r][c4+2] = f2bf(g.z); Bs[r][c4+3] = f2bf(g.w);
      }
    }
    __syncthreads();
    bf16x8 af[2], bfr[2];
    #pragma unroll
    for (int i=0;i<2;i++) af[i]  = *(const bf16x8*)&As[wm + i*16 + mr][quad*8];
    #pragma unroll
    for (int j=0;j<2;j++) bfr[j] = *(const bf16x8*)&Bs[wn + j*16 + mr][quad*8];
    #pragma unroll
    for (int i=0;i<2;i++)
      #pragma unroll
      for (int j=0;j<2;j++)
        acc[i][j] = __builtin_amdgcn_mfma_f32_16x16x32_bf16(af[i], bfr[j], acc[i][j], 0, 0, 0);
    __syncthreads();
  }
  #pragma unroll
  for (int i=0;i<2;i++){
    #pragma unroll
    for (int r=0;r<4;r++){
      int m = m0 + wm + i*16 + quad*4 + r;
      float rm = rowmul ? rowmul[m] : 1.f;
      i64 mrow = (combine == 4) ? (i64)(((m & 255) << 8) | (m >> 8)) : (i64)m;
      #pragma unroll
      for (int j=0;j<2;j++){
        int n = n0 + wn + j*16 + mr;
        float v = acc[i][j][r] * scale;
        if (bias) v += bias[n];
        if (act == 1) v = fmaxf(v, 0.f);
        else if (act == 2) v = 1.f/(1.f + __expf(-v));
        v *= rm;
        i64 idx = mrow*ldc + n;
        if (combine == 0) C[idx] = v;
        else if (combine == 1 || combine == 4) C[idx] += v;
        else if (combine == 2) C[idx] *= v;
        else C[idx] += aux[(i64)m*ldc + n] * v;
      }
    }
  }
}

// ---------------- fused dual-MFMA lin*sigmoid(gate) for tri-mult ----------------
// v2: 64x64 tile (was 128x128 at grid 512 -> 2 blocks/CU latency-bound like R3's mgemm_k).
// Grid (1024, 2) = 2048 blocks; LDS 15 KB.
__global__ __launch_bounds__(256) void mlrgate_k(
    const float* __restrict__ X,
    const float* __restrict__ Wl, const float* __restrict__ bl,
    const float* __restrict__ Wg, const float* __restrict__ bg,
    float* __restrict__ Out)
{
  int m0 = blockIdx.x * 64, n0 = blockIdx.y * 64;
  int tid = threadIdx.x;
  int wave = tid >> 6, lane = tid & 63;
  int quad = lane >> 4, mr = lane & 15;
  int wm = (wave >> 1) * 32, wn = (wave & 1) * 32;
  __shared__ unsigned short As[64][40], B1s[64][40], B2s[64][40];
  f32x4 acc1[2][2], acc2[2][2];
  #pragma unroll
  for (int i=0;i<2;i++)
    #pragma unroll
    for (int j=0;j<2;j++){ acc1[i][j] = (f32x4){0,0,0,0}; acc2[i][j] = (f32x4){0,0,0,0}; }

  for (int k0 = 0; k0 < 128; k0 += 32){
    #pragma unroll
    for (int it=0; it<2; it++){
      int lin = tid + it*256;
      int r = lin >> 3, c4 = (lin & 7) * 4;
      float4 g = *(const float4*)&X[(i64)(m0+r)*128 + k0 + c4];
      As[r][c4]   = f2bf(g.x); As[r][c4+1] = f2bf(g.y);
      As[r][c4+2] = f2bf(g.z); As[r][c4+3] = f2bf(g.w);
    }
    #pragma unroll
    for (int it=0; it<2; it++){
      int lin = tid + it*256;
      int n = lin & 63, kg = (lin >> 6) * 4;
      float a0 = Wl[(i64)(k0+kg  )*128 + n0 + n];
      float a1 = Wl[(i64)(k0+kg+1)*128 + n0 + n];
      float a2 = Wl[(i64)(k0+kg+2)*128 + n0 + n];
      float a3 = Wl[(i64)(k0+kg+3)*128 + n0 + n];
      B1s[n][kg] = f2bf(a0); B1s[n][kg+1] = f2bf(a1);
      B1s[n][kg+2] = f2bf(a2); B1s[n][kg+3] = f2bf(a3);
      float g0 = Wg[(i64)(k0+kg  )*128 + n0 + n];
      float g1 = Wg[(i64)(k0+kg+1)*128 + n0 + n];
      float g2 = Wg[(i64)(k0+kg+2)*128 + n0 + n];
      float g3 = Wg[(i64)(k0+kg+3)*128 + n0 + n];
      B2s[n][kg] = f2bf(g0); B2s[n][kg+1] = f2bf(g1);
      B2s[n][kg+2] = f2bf(g2); B2s[n][kg+3] = f2bf(g3);
    }
    __syncthreads();
    bf16x8 af[2], b1f[2], b2f[2];
    #pragma unroll
    for (int i=0;i<2;i++) af[i]  = *(const bf16x8*)&As[wm + i*16 + mr][quad*8];
    #pragma unroll
    for (int j=0;j<2;j++){
      b1f[j] = *(const bf16x8*)&B1s[wn + j*16 + mr][quad*8];
      b2f[j] = *(const bf16x8*)&B2s[wn + j*16 + mr][quad*8];
    }
    #pragma unroll
    for (int i=0;i<2;i++)
      #pragma unroll
      for (int j=0;j<2;j++){
        acc1[i][j] = __builtin_amdgcn_mfma_f32_16x16x32_bf16(af[i], b1f[j], acc1[i][j], 0, 0, 0);
        acc2[i][j] = __builtin_amdgcn_mfma_f32_16x16x32_bf16(af[i], b2f[j], acc2[i][j], 0, 0, 0);
      }
    __syncthreads();
  }
  #pragma unroll
  for (int i=0;i<2;i++){
    #pragma unroll
    for (int r=0;r<4;r++){
      int m = m0 + wm + i*16 + quad*4 + r;
      #pragma unroll
      for (int j=0;j<2;j++){
        int n = wn + j*16 + mr;
        float lv = acc1[i][j][r] + bl[n0 + n];
        float gv = acc2[i][j][r] + bg[n0 + n];
        Out[(i64)m*128 + n0 + n] = lv * (1.f/(1.f + __expf(-gv)));
      }
    }
  }
}

// ---------------- generic batched GEMM (fp32, 64x64 tile) ----------------
template<bool TA, bool TB>
__global__ __launch_bounds__(256) void gemm_k(
    const float* __restrict__ A, int lda, i64 sA,
    const float* __restrict__ B, int ldb, i64 sB,
    float* __restrict__ C, int ldc, i64 sC,
    int M, int N, int K,
    const float* __restrict__ bias, float scale, int act,
    const float* __restrict__ rowmul, int combine)
{
  A += (i64)blockIdx.z * sA;
  B += (i64)blockIdx.z * sB;
  C += (i64)blockIdx.z * sC;
  int m0 = blockIdx.x * 64, n0 = blockIdx.y * 64;
  int tid = threadIdx.x, tx = tid & 15, ty = tid >> 4;
  __shared__ float As[16][68], Bs[16][68];
  float acc[4][4] = {};
  for (int k0 = 0; k0 < K; k0 += 16){
    if (TA){
      for (int l = tid; l < 1024; l += 256){
        int kk = l >> 6, mi = l & 63; int m = m0 + mi;
        As[kk][mi] = (m < M) ? A[(i64)(k0+kk)*lda + m] : 0.f;
      }
    } else {
      for (int l = tid; l < 1024; l += 256){
        int mi = l >> 4, kk = l & 15; int m = m0 + mi;
        As[kk][mi] = (m < M) ? A[(i64)m*lda + k0 + kk] : 0.f;
      }
    }
    if (TB){
      for (int l = tid; l < 1024; l += 256){
        int ni = l >> 4, kk = l & 15; int n = n0 + ni;
        Bs[kk][ni] = (n < N) ? B[(i64)n*ldb + k0 + kk] : 0.f;
      }
    } else {
      for (int l = tid; l < 1024; l += 256){
        int kk = l >> 6, ni = l & 63; int n = n0 + ni;
        Bs[kk][ni] = (n < N) ? B[(i64)(k0+kk)*ldb + n] : 0.f;
      }
    }
    __syncthreads();
    #pragma unroll
    for (int kk = 0; kk < 16; ++kk){
      float4 av4 = *(const float4*)&As[kk][ty*4];
      float4 bv4 = *(const float4*)&Bs[kk][tx*4];
      float av[4] = {av4.x, av4.y, av4.z, av4.w};
      float bv[4] = {bv4.x, bv4.y, bv4.z, bv4.w};
      #pragma unroll
      for (int i=0;i<4;i++)
        #pragma unroll
        for (int j=0;j<4;j++) acc[i][j] = fmaf(av[i], bv[j], acc[i][j]);
    }
    __syncthreads();
  }
  #pragma unroll
  for (int i=0;i<4;i++){
    int m = m0 + ty*4 + i;
    if (m >= M) continue;
    float rm = rowmul ? rowmul[m] : 1.f;
    #pragma unroll
    for (int j=0;j<4;j++){
      int n = n0 + tx*4 + j;
      if (n >= N) continue;
      float v = acc[i][j] * scale;
      if (bias) v += bias[n];
      if (act == 1) v = fmaxf(v, 0.f);
      else if (act == 2) v = 1.f/(1.f + expf(-v));
      v *= rm;
      i64 idx = (i64)m*ldc + n;
      if (combine == 0) C[idx] = v;
      else if (combine == 1) C[idx] += v;
      else C[idx] *= v;
    }
  }
}

// ---------------- thin GEMM (small M): split-K two-phase ----------------
__global__ __launch_bounds__(256) void gemm_part_k(
    const float* __restrict__ A, int lda,
    const float* __restrict__ B, int ldb,
    float* __restrict__ Cp, int M, int N, int K, int chunk)
{
  int m0 = blockIdx.x*16, n0 = blockIdx.y*64, z = blockIdx.z;
  int kb = z*chunk, ke = min(K, kb+chunk);
  int tid = threadIdx.x;
  int mi = tid >> 4, ni4 = (tid & 15)*4;
  __shared__ float As[16][17], Bs[16][68];
  float acc[4] = {0.f,0.f,0.f,0.f};
  for (int k0 = kb; k0 < ke; k0 += 16){
    { int r = tid>>4, c = tid&15; int m = m0+r;
      As[c][r] = (m < M) ? A[(i64)m*lda + k0 + c] : 0.f; }
    for (int l = tid; l < 1024; l += 256){
      int kk = l>>6, nn = l&63; int n = n0+nn;
      Bs[kk][nn] = (n < N) ? B[(i64)(k0+kk)*ldb + n] : 0.f;
    }
    __syncthreads();
    #pragma unroll
    for (int kk=0;kk<16;kk++){
      float a = As[kk][mi];
      float4 b = *(const float4*)&Bs[kk][ni4];
      acc[0]=fmaf(a,b.x,acc[0]); acc[1]=fmaf(a,b.y,acc[1]);
      acc[2]=fmaf(a,b.z,acc[2]); acc[3]=fmaf(a,b.w,acc[3]);
    }
    __syncthreads();
  }
  int m = m0+mi, n = n0+ni4;
  if (m < M && n < N) *(float4*)&Cp[((i64)z*M + m)*N + n] = *(float4*)acc;
}

__global__ __launch_bounds__(256) void gemm_reduce_k(
    const float* __restrict__ Cp, float* __restrict__ C, int ldc,
    int M, int N, int S,
    const float* __restrict__ bias, float scale, int act,
    const float* __restrict__ rowmul, int combine)
{
  i64 idx = (i64)blockIdx.x*256 + threadIdx.x;
  if (idx >= (i64)M*N) return;
  int m = (int)(idx / N), n = (int)(idx % N);
  float s = 0.f;
  for (int z=0; z<S; z++) s += Cp[(i64)z*M*N + idx];
  float v = s*scale;
  if (bias) v += bias[n];
  if (act == 1) v = fmaxf(v, 0.f);
  else if (act == 2) v = 1.f/(1.f + expf(-v));
  if (rowmul) v *= rowmul[m];
  i64 o = (i64)m*ldc + n;
  if (combine == 0) C[o] = v;
  else if (combine == 1) C[o] += v;
  else C[o] *= v;
}

// ---------------- OPM ----------------
__global__ __launch_bounds__(128) void opm_wd_k(const float* __restrict__ right, const float* __restrict__ W,
                                                float* __restrict__ Wd){
  int d = blockIdx.x, c = blockIdx.y, f = threadIdx.x;
  float acc = 0.f;
  #pragma unroll
  for (int e=0;e<32;e++) acc = fmaf(right[d*32+e], W[((i64)c*32+e)*128 + f], acc);
  Wd[((i64)d*32+c)*128 + f] = acc;
}

// pa[d,b,f] = pair_act[d,b,f] + (sum_c left[b,c]*Wd[d,c,f] + ob[f]) / (1e-3 + sm[d]*sm[b])
__global__ __launch_bounds__(128) void opm_final_k(const float* __restrict__ left, const float* __restrict__ Wd,
                                                   const float* __restrict__ ob, const float* __restrict__ sm,
                                                   const float* __restrict__ pair_act, float* __restrict__ pa){
  int d = blockIdx.x, b0 = blockIdx.y*16, f = threadIdx.x;
  __shared__ float wd_s[32][128];
  __shared__ float l_s[16][32];
  for (int c=0;c<32;c++) wd_s[c][f] = Wd[((i64)d*32+c)*128 + f];
  for (int l = f; l < 512; l += 128){ int bi=l>>5, c=l&31; l_s[bi][c] = left[(b0+bi)*32 + c]; }
  __syncthreads();
  float md = sm[d], obf = ob[f];
  for (int bi=0;bi<16;bi++){
    float acc = 0.f;
    #pragma unroll
    for (int c=0;c<32;c++) acc = fmaf(l_s[bi][c], wd_s[c][f], acc);
    int b = b0+bi;
    i64 idx = ((i64)d*256 + b)*128 + f;
    pa[idx] = pair_act[idx] + (acc + obf) / (1e-3f + md*sm[b]);
  }
}

// ---------------- row attention core ----------------
__global__ __launch_bounds__(256) void ra_attn_k(const float* __restrict__ q, const float* __restrict__ k,
                                                 const float* __restrict__ v, const float* __restrict__ nb,
                                                 const float* __restrict__ sm, float* __restrict__ wa){
  int qi = blockIdx.x, h = blockIdx.y, tid = threadIdx.x;
  __shared__ float qv[48];
  __shared__ float p[256];
  __shared__ float red[256];
  if (tid < 48) qv[tid] = q[(i64)qi*384 + h*48 + tid];
  __syncthreads();
  float acc = 0.f;
  const float* kr = k + (i64)tid*384 + h*48;
  #pragma unroll
  for (int c=0;c<48;c++) acc = fmaf(qv[c], kr[c], acc);
  acc += 1e9f*(sm[tid]-1.f) + nb[((i64)qi*256 + tid)*8 + h];
  red[tid] = acc; __syncthreads();
  for (int off=128;off>0;off>>=1){ if (tid<off) red[tid] = fmaxf(red[tid], red[tid+off]); __syncthreads(); }
  float mx = red[0]; __syncthreads();
  float e = expf(acc - mx);
  red[tid] = e; __syncthreads();
  for (int off=128;off>0;off>>=1){ if (tid<off) red[tid] += red[tid+off]; __syncthreads(); }
  p[tid] = e / red[0];
  __syncthreads();
  if (tid < 48){
    float a = 0.f;
    for (int kk=0;kk<256;kk++) a = fmaf(p[kk], v[(i64)kk*384 + h*48 + tid], a);
    wa[(i64)qi*384 + h*48 + tid] = a;
  }
}

// ---------------- triangle attention core v7: swapped-operand MFMA flash ----------------
// S = mfma(K, Q): lane holds scores for ONE q-row (softmax per-lane, 4 shfl per tile);
// O^T = mfma(V^T, P): alpha/1/l per-lane scalars, coalesced float4 store.
// Grid (qblk,h,b): qblk fastest -> K/V L2 reuse across the 4 sharing blocks.
__global__ __launch_bounds__(256, 6) void ta_mfma_k(
    const float* __restrict__ q, const float* __restrict__ k, const float* __restrict__ v,
    const float* __restrict__ nbQ, const float* __restrict__ mask, int maskT,
    float* __restrict__ wa)
{
  int qblk = blockIdx.x, h = blockIdx.y, b = blockIdx.z;
  int tid = threadIdx.x;
  int wave = tid >> 6, lane = tid & 63;
  int quad = lane >> 4, mr = lane & 15;
  const i64 base = ((i64)b*256)*128 + h*32;

  __shared__ __align__(16) unsigned short Ks[128][40];   // [key][c], row 80B
  __shared__ __align__(16) unsigned short Vt[32][136];   // [c][key], row 272B
  __shared__ __align__(16) float mask_s[256];
  __shared__ __align__(16) unsigned short Pl[4][16][40]; // per-wave P [q][key]

  mask_s[tid] = 1e9f * ((maskT ? mask[(i64)tid*256 + b] : mask[(i64)b*256 + tid]) - 1.f);

  int q0w = qblk*64 + wave*16;
  int qg = q0w + mr;                      // this lane's q row (fixed for whole kernel)
  const float* nbq = nbQ + (i64)h*65536 + (i64)qg*256;

  // Q as B-operand fragment: [n=q=mr][k-ch quad*8..+7]
  bf16x8 qf;
  {
    const float* qp = q + base + (i64)qg*128 + quad*8;
    float4 a = *(const float4*)qp;
    float4 c = *(const float4*)(qp+4);
    qf[0]=(short)f2bf(a.x); qf[1]=(short)f2bf(a.y); qf[2]=(short)f2bf(a.z); qf[3]=(short)f2bf(a.w);
    qf[4]=(short)f2bf(c.x); qf[5]=(short)f2bf(c.y); qf[6]=(short)f2bf(c.z); qf[7]=(short)f2bf(c.w);
  }

  f32x4 o0 = (f32x4){0,0,0,0}, o1 = (f32x4){0,0,0,0}; // O^T[c=quad*4+r(+16)][q=mr]
  float mm = -1e30f, ll = 0.f;                         // per-lane softmax state (q = qg)

  for (int half = 0; half < 2; half++){
    __syncthreads();
    #pragma unroll
    for (int it=0; it<4; it++){
      int idx = it*256 + tid;              // 128 keys x 32 ch
      int kl = idx >> 3, c4 = (idx & 7)*4;
      i64 roff = base + (i64)(half*128 + kl)*128 + c4;
      float4 g  = *(const float4*)(k + roff);
      unsigned int w0 = (unsigned int)f2bf(g.x) | ((unsigned int)f2bf(g.y)<<16);
      unsigned int w1 = (unsigned int)f2bf(g.z) | ((unsigned int)f2bf(g.w)<<16);
      *(uint2*)&Ks[kl][c4] = make_uint2(w0, w1);
      float4 gv = *(const float4*)(v + roff);
      Vt[c4  ][kl] = f2bf(gv.x);
      Vt[c4+1][kl] = f2bf(gv.y);
      Vt[c4+2][kl] = f2bf(gv.z);
      Vt[c4+3][kl] = f2bf(gv.w);
    }
    __syncthreads();

    #pragma unroll
    for (int it=0; it<4; it++){
      int kc = it*32;
      int kg = half*128 + kc;
      // K as A-operand: frag rows = keys kc+mr / kc+16+mr
      bf16x8 kf0 = *(const bf16x8*)&Ks[kc + mr][quad*8];
      bf16x8 kf1 = *(const bf16x8*)&Ks[kc + 16 + mr][quad*8];
      f32x4 s0 = __builtin_amdgcn_mfma_f32_16x16x32_bf16(kf0, qf, (f32x4){0,0,0,0}, 0, 0, 0);
      f32x4 s1 = __builtin_amdgcn_mfma_f32_16x16x32_bf16(kf1, qf, (f32x4){0,0,0,0}, 0, 0, 0);
      // s0[r] = S[key=kg+quad*4+r][qg]; s1[r] = S[key=kg+16+quad*4+r][qg]
      float4 nb0 = *(const float4*)(nbq + kg + quad*4);
      float4 nb1 = *(const float4*)(nbq + kg + 16 + quad*4);
      float4 mk0 = *(const float4*)&mask_s[kg + quad*4];
      float4 mk1 = *(const float4*)&mask_s[kg + 16 + quad*4];
      s0[0] += nb0.x + mk0.x; s0[1] += nb0.y + mk0.y; s0[2] += nb0.z + mk0.z; s0[3] += nb0.w + mk0.w;
      s1[0] += nb1.x + mk1.x; s1[1] += nb1.y + mk1.y; s1[2] += nb1.z + mk1.z; s1[3] += nb1.w + mk1.w;

      // per-lane online softmax over the 32-key tile (cross-quad = 2 shfls)
      float tm = fmaxf(fmaxf(fmaxf(s0[0],s0[1]), fmaxf(s0[2],s0[3])),
                       fmaxf(fmaxf(s1[0],s1[1]), fmaxf(s1[2],s1[3])));
      tm = fmaxf(tm, __shfl_xor(tm, 16));
      tm = fmaxf(tm, __shfl_xor(tm, 32));
      float nm = fmaxf(mm, tm);
      float alpha = __expf(mm - nm);
      mm = nm;
      float e00 = __expf(s0[0]-nm), e01 = __expf(s0[1]-nm);
      float e02 = __expf(s0[2]-nm), e03 = __expf(s0[3]-nm);
      float e10 = __expf(s1[0]-nm), e11 = __expf(s1[1]-nm);
      float e12 = __expf(s1[2]-nm), e13 = __expf(s1[3]-nm);
      float ps = ((e00+e01) + (e02+e03)) + ((e10+e11) + (e12+e13));
      ps += __shfl_xor(ps, 16);
      ps += __shfl_xor(ps, 32);
      ll = ll*alpha + ps;
      o0 *= alpha; o1 *= alpha;
      // P[q=mr][key] packed bf16 pairs, 2x 8B writes (2-way banks = free)
      unsigned int p0 = (unsigned int)f2bf(e00) | ((unsigned int)f2bf(e01)<<16);
      unsigned int p1 = (unsigned int)f2bf(e02) | ((unsigned int)f2bf(e03)<<16);
      unsigned int p2 = (unsigned int)f2bf(e10) | ((unsigned int)f2bf(e11)<<16);
      unsigned int p3 = (unsigned int)f2bf(e12) | ((unsigned int)f2bf(e13)<<16);
      *(uint2*)&Pl[wave][mr][quad*4]      = make_uint2(p0, p1);
      *(uint2*)&Pl[wave][mr][16 + quad*4] = make_uint2(p2, p3);
      // PV (swapped): A = V^T rows=channels, B = P [k=key][n=q=mr]
      bf16x8 pf  = *(const bf16x8*)&Pl[wave][mr][quad*8];
      bf16x8 vf0 = *(const bf16x8*)&Vt[mr     ][kc + quad*8];
      bf16x8 vf1 = *(const bf16x8*)&Vt[16 + mr][kc + quad*8];
      o0 = __builtin_amdgcn_mfma_f32_16x16x32_bf16(vf0, pf, o0, 0, 0, 0);
      o1 = __builtin_amdgcn_mfma_f32_16x16x32_bf16(vf1, pf, o1, 0, 0, 0);
    }
  }

  float inv = 1.f/ll;
  float* wp = wa + base + (i64)qg*128;
  *(float4*)(wp + quad*4)      = make_float4(o0[0]*inv, o0[1]*inv, o0[2]*inv, o0[3]*inv);
  *(float4*)(wp + 16 + quad*4) = make_float4(o1[0]*inv, o1[1]*inv, o1[2]*inv, o1[3]*inv);
}

// ---------------- host dispatch ----------------
static void gemm(hipStream_t st, bool TA, bool TB,
                 const float* A, int lda, i64 sA,
                 const float* B, int ldb, i64 sB,
                 float* C, int ldc, i64 sC,
                 int M, int N, int K, int batch,
                 const float* bias, float scale, int act,
                 const float* rowmul, int combine)
{
  dim3 g((M+63)/64, (N+63)/64, batch), bl(256);
  if (!TA && !TB)      gemm_k<false,false><<<g,bl,0,st>>>(A,lda,sA,B,ldb,sB,C,ldc,sC,M,N,K,bias,scale,act,rowmul,combine);
  else if (!TA &&  TB) gemm_k<false,true ><<<g,bl,0,st>>>(A,lda,sA,B,ldb,sB,C,ldc,sC,M,N,K,bias,scale,act,rowmul,combine);
  else                 gemm_k<true ,false><<<g,bl,0,st>>>(A,lda,sA,B,ldb,sB,C,ldc,sC,M,N,K,bias,scale,act,rowmul,combine);
}

static void mgemm(hipStream_t st, bool TA, bool TB,
                  const float* A, int lda, i64 sA,
                  const float* B, int ldb, i64 sB,
                  float* C, int ldc, i64 sC,
                  int M, int N, int K, int batch,
                  const float* bias, float scale, int act,
                  const float* rowmul, int combine, const float* aux = nullptr)
{
  dim3 bl(256);
  i64 nb128 = (i64)(M/128)*(N/128)*batch;
  if (nb128 < 1024 && (M % 64) == 0 && (N % 64) == 0){
    // latency-regime fix (R3): <1024 blocks at 128-tile -> 2 blocks/CU; use 64x64 tiles
    dim3 g(M/64, N/64, batch);
    if (!TA && !TB)      mgemm64_k<false,false><<<g,bl,0,st>>>(A,lda,sA,B,ldb,sB,C,ldc,sC,M,N,K,bias,scale,act,rowmul,combine,aux);
    else if (!TA &&  TB) mgemm64_k<false,true ><<<g,bl,0,st>>>(A,lda,sA,B,ldb,sB,C,ldc,sC,M,N,K,bias,scale,act,rowmul,combine,aux);
    else                 mgemm64_k<true ,false><<<g,bl,0,st>>>(A,lda,sA,B,ldb,sB,C,ldc,sC,M,N,K,bias,scale,act,rowmul,combine,aux);
    return;
  }
  dim3 g(M/128, N/128, batch);
  if (!TA && !TB)      mgemm_k<false,false><<<g,bl,0,st>>>(A,lda,sA,B,ldb,sB,C,ldc,sC,M,N,K,bias,scale,act,rowmul,combine,aux);
  else if (!TA &&  TB) mgemm_k<false,true ><<<g,bl,0,st>>>(A,lda,sA,B,ldb,sB,C,ldc,sC,M,N,K,bias,scale,act,rowmul,combine,aux);
  else                 mgemm_k<true ,false><<<g,bl,0,st>>>(A,lda,sA,B,ldb,sB,C,ldc,sC,M,N,K,bias,scale,act,rowmul,combine,aux);
}

static void gemm_thin(hipStream_t st,
                      const float* A, int lda, const float* B, int ldb,
                      float* C, int ldc, int M, int N, int K,
                      const float* bias, float scale, int act,
                      const float* rowmul, int combine, float* part)
{
  const int S = 8;
  int chunk = ((K/S + 15)/16)*16; if (chunk < 16) chunk = 16;
  dim3 g((M+15)/16, (N+63)/64, S);
  gemm_part_k<<<g,256,0,st>>>(A,lda,B,ldb,part,M,N,K,chunk);
  i64 t = (i64)M*N;
  gemm_reduce_k<<<(int)((t+255)/256),256,0,st>>>(part,C,ldc,M,N,S,bias,scale,act,rowmul,combine);
}

extern "C" void kernel_launch(void* const* d_in, const int* in_sizes, int n_in,
                              void* d_out, int out_size, void* d_ws, size_t ws_size,
                              hipStream_t stream)
{
  const float* IN[64];
  for (int i=0;i<n_in && i<64;i++) IN[i] = (const float*)d_in[i];

  const float* single_act = IN[0];
  const float* pair_act   = IN[1];
  const float* sm         = IN[2];
  const float* pm         = IN[3];
  const float* opm_ln     = IN[4];
  const float* opm_lr_w   = IN[5];
  const float* opm_lr_b   = IN[6];
  const float* opm_out_w  = IN[7];
  const float* opm_out_b  = IN[8];
  const float* ra_ln      = IN[9];
  const float* ra_pair_ln = IN[10];
  const float* ra_feat_w  = IN[11];
  const float* ra_qkv_w   = IN[12];
  const float* ra_gate_w  = IN[13];
  const float* ra_gate_b  = IN[14];
  const float* ra_o_w     = IN[15];
  const float* ra_o_b     = IN[16];
  const float* st_ln      = IN[17];
  const float* st_w1      = IN[18];
  const float* st_b1      = IN[19];
  const float* st_w2      = IN[20];
  const float* st_b2      = IN[21];
  const float* pt_ln      = IN[56];
  const float* pt_w1      = IN[57];
  const float* pt_b1      = IN[58];
  const float* pt_w2      = IN[59];
  const float* pt_b2      = IN[60];

  float* sa = (float*)d_out;           // [256,384]
  float* pa = (float*)d_out + 98304;   // [256,256,128]

  float* W  = (float*)d_ws;
  float* B0 = W;
  float* B1 = W + 8388608L;
  float* B2 = W + 16777216L;
  float* B3 = W + 25165824L;
  float* SMA = W + 33554432L;
  float* xs   = SMA;
  float* qb   = SMA +  98304;
  float* kb   = SMA + 196608;
  float* vb   = SMA + 294912;
  float* wab  = SMA + 393216;
  float* hst  = SMA + 491520;   // 393216
  float* nbra = SMA + 884736;   // 524288 (reused as nbQ in tri-attn phase)
  float* lbuf = SMA + 1409024;  // 8192
  float* rbuf = SMA + 1417216;  // 8192
  float* Wd   = SMA + 1425408;  // 1048576
  float* nbt  = SMA + 2473984;  // 262144

  // init sa with residual base (pa is initialized by opm_final_k's fused write)
  copy_k<<<384, 256, 0, stream>>>(sa, single_act, 98304L);

  // ---- 1) OPM -> pair residual (writes pa = pair_act + update) ----
  ln_k<<<256,128,0,stream>>>(single_act, xs, opm_ln, 384);
  gemm_thin(stream, xs,384, opm_lr_w,32,       lbuf,32, 256,32,384, opm_lr_b,    1.f,0, sm,0, B1);
  gemm_thin(stream, xs,384, opm_lr_w+12288,32, rbuf,32, 256,32,384, opm_lr_b+32, 1.f,0, sm,0, B1);
  opm_wd_k<<<dim3(256,32),128,0,stream>>>(rbuf, opm_out_w, Wd);
  opm_final_k<<<dim3(256,16),128,0,stream>>>(lbuf, Wd, opm_out_b, sm, pair_act, pa);

  // ---- 2) row attention with pair bias ----
  ln_k<<<256,128,0,stream>>>(sa, xs, ra_ln, 384);
  ln128_k<<<16384,256,0,stream>>>(pa, B0, ra_pair_ln, 0);
  gemm(stream,false,false, B0,128,0, ra_feat_w,8,0, nbra,8,0, 65536,8,128,1, nullptr,1.f,0,nullptr,0);
  const float qs_ra = 0.14433756729740643f; // 1/sqrt(48)
  gemm_thin(stream, xs,384, ra_qkv_w,384,        qb,384, 256,384,384, nullptr,qs_ra,0,nullptr,0, B1);
  gemm_thin(stream, xs,384, ra_qkv_w+147456,384, kb,384, 256,384,384, nullptr,1.f,0,nullptr,0, B1);
  gemm_thin(stream, xs,384, ra_qkv_w+294912,384, vb,384, 256,384,384, nullptr,1.f,0,nullptr,0, B1);
  ra_attn_k<<<dim3(256,8),256,0,stream>>>(qb, kb, vb, nbra, sm, wab);
  gemm_thin(stream, xs,384,  ra_gate_w,384, wab,384, 256,384,384, ra_gate_b,1.f,2,nullptr,2, B1);
  gemm_thin(stream, wab,384, ra_o_w,384,    sa,384,  256,384,384, ra_o_b,   1.f,0,nullptr,1, B1);

  // ---- 3) single transition ----
  ln_k<<<256,128,0,stream>>>(sa, xs, st_ln, 384);
  gemm_thin(stream, xs,384,   st_w1,1536, hst,1536, 256,1536,384, st_b1,1.f,1,nullptr,0, B1);
  gemm_thin(stream, hst,1536, st_w2,384,  sa,384,   256,384,1536, st_b2,1.f,0,nullptr,1, B1);

  // ---- 4/5) triangle multiplications ----
  auto tri_mult = [&](int base, bool outgoing){
    const float* ln_w = IN[base+0];
    const float* lr_w = IN[base+1];
    const float* lr_b = IN[base+2];
    const float* gw   = IN[base+3];
    const float* gb   = IN[base+4];
    const float* cln  = IN[base+5];
    const float* ow   = IN[base+6];
    const float* ob   = IN[base+7];
    const float* ogw  = IN[base+8];
    const float* ogb  = IN[base+9];
    ln128_k<<<16384,256,0,stream>>>(pa, B0, ln_w, 0);
    // left = mask * (X@Wl+bl) * sigmoid(X@Wg+bg): fused dual-MFMA, then transpose+mask -> B1 (ch-major)
    mlrgate_k<<<dim3(1024,2),256,0,stream>>>(B0, lr_w, lr_b, gw, gb, B3);
    tr_mask_k<<<dim3(2048,4),256,0,stream>>>(B3, pm, B1);
    // right -> B2 (ch-major)
    mlrgate_k<<<dim3(1024,2),256,0,stream>>>(B0, lr_w+16384, lr_b+128, gw+16384, gb+128, B3);
    tr_mask_k<<<dim3(2048,4),256,0,stream>>>(B3, pm, B2);
    if (outgoing) // out[i,j,c] = sum_k L_c[i,k] * R_c[j,k]
      mgemm(stream,false,true, B1,256,65536, B2,256,65536, B3,256,65536, 256,256,256,128, nullptr,1.f,0,nullptr,0);
    else          // out[i,j,c] = sum_k R_c[k,i] * L_c[k,j]
      mgemm(stream,true,false, B2,256,65536, B1,256,65536, B3,256,65536, 256,256,256,128, nullptr,1.f,0,nullptr,0);
    chw2hwc_k<<<dim3(2048,4),256,0,stream>>>(B3, B1);
    ln128_k<<<16384,256,0,stream>>>(B1, B3, cln, 0);
    mgemm(stream,false,false, B3,128,0, ow,128,0,  B1,128,0, 65536,128,128,1, ob,  1.f,0,nullptr,0);
    // fused: pa += B1 * sigmoid(B0@ogw + ogb)
    mgemm(stream,false,false, B0,128,0, ogw,128,0, pa,128,0, 65536,128,128,1, ogb, 1.f,2,nullptr,3, B1);
  };
  tri_mult(22, true);   // tmo
  tri_mult(32, false);  // tmi

  // ---- 6/7) triangle attentions ----
  auto tri_attn = [&](int base, bool percol){
    const float* ln_w   = IN[base+0];
    const float* feat_w = IN[base+1];
    const float* qkv_w  = IN[base+2];
    const float* gw     = IN[base+3];
    const float* gb     = IN[base+4];
    const float* ow     = IN[base+5];
    const float* ob     = IN[base+6];
    // LN with fused pair-transpose read for per-column attention
    ln128_k<<<16384,256,0,stream>>>(pa, B0, ln_w, percol?1:0);
    gemm(stream,false,false, B0,128,0, feat_w,4,0, nbt,4,0, 65536,4,128,1, nullptr,1.f,0,nullptr,0);
    nbQ_k<<<256,256,0,stream>>>(nbt, nbra);  // nbQ[h][q][k]
    const float qs = 0.17677669529663687f; // 1/sqrt(32)
    mgemm(stream,false,false, B0,128,0, qkv_w,128,0,       B1,128,0, 65536,128,128,1, nullptr,qs, 0,nullptr,0);
    mgemm(stream,false,false, B0,128,0, qkv_w+16384,128,0, B2,128,0, 65536,128,128,1, nullptr,1.f,0,nullptr,0);
    mgemm(stream,false,false, B0,128,0, qkv_w+32768,128,0, B3,128,0, 65536,128,128,1, nullptr,1.f,0,nullptr,0);
    ta_mfma_k<<<dim3(4,4,256),256,0,stream>>>(B1, B2, B3, nbra, pm, percol?1:0, B1);
    mgemm(stream,false,false, B0,128,0, gw,128,0, B1,128,0, 65536,128,128,1, gb,1.f,2,nullptr,2); // wa *= sigmoid(gate)
    // out-projection fused with residual add (4 = transpose-pair write for per-column)
    mgemm(stream,false,false, B1,128,0, ow,128,0, pa,128,0, 65536,128,128,1, ob,1.f,0,nullptr, percol?4:1);
  };
  tri_attn(42, false);  // tas (per-row)
  tri_attn(49, true);   // tae (per-column)

  // ---- 8) pair transition ----
  ln128_k<<<16384,256,0,stream>>>(pa, B0, pt_ln, 0);
  for (int half = 0; half < 2; half++){
    const float* xh = B0 + (i64)half*4194304;
    float* ph = pa + (i64)half*4194304;
    mgemm(stream,false,false, xh,128,0, pt_w1,512,0, B1,512,0, 32768,512,128,1, pt_b1,1.f,1,nullptr,0);
    mgemm(stream,false,false, B1,512,0, pt_w2,128,0, ph,128,0, 32768,128,512,1, pt_b2,1.f,0,nullptr,1);
  }
}

// Round 11
// 1464.571 us; speedup vs baseline: 1.3765x; 1.0827x over previous
//
#include <hip/hip_runtime.h>
#include <math.h>

typedef long long i64;
#define NN_ 65536L

typedef __attribute__((ext_vector_type(8))) short bf16x8;
typedef __attribute__((ext_vector_type(4))) float f32x4;

__device__ inline unsigned short f2bf(float f){
  unsigned int u = __float_as_uint(f);
  return (unsigned short)((u + 0x7FFFu + ((u>>16)&1u)) >> 16);
}

// ---------------- elementwise ----------------
__global__ __launch_bounds__(256) void copy_k(float* __restrict__ d, const float* __restrict__ s, long n){
  long i = (long)blockIdx.x*blockDim.x + threadIdx.x;
  if (i < n) d[i] = s[i];
}

// channel-major [128][65536] -> row-major [65536][128]
__global__ __launch_bounds__(256) void chw2hwc_k(const float* __restrict__ in, float* __restrict__ out){
  __shared__ float t[32][33];
  int r0 = blockIdx.x*32, c0 = blockIdx.y*32;
  int tx = threadIdx.x & 31, ty = threadIdx.x >> 5;
  for (int i = ty; i < 32; i += 8) t[i][tx] = in[(i64)(c0+i)*NN_ + r0 + tx];
  __syncthreads();
  for (int i = ty; i < 32; i += 8) out[(i64)(r0+i)*128 + c0 + tx] = t[tx][i];
}

// row-major [65536][128] -> ch-major [128][65536] with per-row mask
__global__ __launch_bounds__(256) void tr_mask_k(const float* __restrict__ in, const float* __restrict__ mask,
                                                 float* __restrict__ out){
  __shared__ float t[32][33];
  int r0 = blockIdx.x*32, c0 = blockIdx.y*32;
  int tx = threadIdx.x & 31, ty = threadIdx.x >> 5;
  for (int i = ty; i < 32; i += 8) t[i][tx] = in[(i64)(r0+i)*128 + c0 + tx];
  __syncthreads();
  for (int i = ty; i < 32; i += 8) out[(i64)(c0+i)*NN_ + r0 + tx] = t[tx][i] * mask[r0+tx];
}

// nb [q,k,h=4] -> nbQ [h][q][k]  (block = q row, thread = k: coalesced read AND write)
__global__ __launch_bounds__(256) void nbQ_k(const float* __restrict__ in, float* __restrict__ out){
  int qq = blockIdx.x, kk = threadIdx.x;
  float4 vv = *(const float4*)(in + ((i64)qq*256 + kk)*4);
  out[0*65536 + qq*256 + kk] = vv.x;
  out[1*65536 + qq*256 + kk] = vv.y;
  out[2*65536 + qq*256 + kk] = vv.z;
  out[3*65536 + qq*256 + kk] = vv.w;
}

// ---------------- LayerNorm generic (rowwise, C arbitrary) ----------------
__global__ __launch_bounds__(128) void ln_k(const float* __restrict__ in, float* __restrict__ out,
                                            const float* __restrict__ w, int C){
  i64 row = blockIdx.x;
  const float* x = in + row*C;
  float* y = out + row*C;
  int tid = threadIdx.x;
  float s=0.f, s2=0.f;
  for (int c=tid;c<C;c+=128){ float v = x[c]; s += v; s2 += v*v; }
  __shared__ float rs[128], rq[128];
  rs[tid]=s; rq[tid]=s2; __syncthreads();
  for (int off=64;off>0;off>>=1){ if (tid<off){ rs[tid]+=rs[tid+off]; rq[tid]+=rq[tid+off]; } __syncthreads(); }
  float mu = rs[0]/C;
  float var = rq[0]/C - mu*mu;
  float inv = rsqrtf(var + 1e-5f);
  for (int c=tid;c<C;c+=128) y[c] = (x[c]-mu)*inv*w[c] + w[C+c];
}

// ---------------- LayerNorm C=128: one wave per row, shuffle-only reduction ----------------
// T=1: read row rt = transpose-pair index of row (fused pa transpose for per-column attention)
__global__ __launch_bounds__(256) void ln128_k(const float* __restrict__ in, float* __restrict__ out,
                                               const float* __restrict__ w, int T){
  int wv = threadIdx.x >> 6, lane = threadIdx.x & 63;
  i64 row = (i64)blockIdx.x*4 + wv;
  i64 rr = T ? (i64)((((int)row & 255) << 8) | ((int)row >> 8)) : row;
  float2 v = *(const float2*)(in + rr*128 + lane*2);
  float s = v.x + v.y, s2 = v.x*v.x + v.y*v.y;
  #pragma unroll
  for (int off=32; off; off>>=1){ s += __shfl_down(s, off); s2 += __shfl_down(s2, off); }
  s = __shfl(s, 0); s2 = __shfl(s2, 0);
  float mu = s*(1.f/128.f);
  float var = s2*(1.f/128.f) - mu*mu;
  float inv = rsqrtf(var + 1e-5f);
  float2 wl = *(const float2*)(w + lane*2);
  float2 wb = *(const float2*)(w + 128 + lane*2);
  float2 y; y.x = (v.x-mu)*inv*wl.x + wb.x; y.y = (v.y-mu)*inv*wl.y + wb.y;
  *(float2*)(out + row*128 + lane*2) = y;
}

// ---------------- bf16 MFMA GEMM: 128x128 tile, 256 thr (2x2 waves of 64x64) ----------------
// combine: 0 store, 1 +=, 2 *=, 3: C += aux*v, 4: C[transpose-pair(m)] += v (pair tensor only)
template<bool TA, bool TB>
__global__ __launch_bounds__(256) void mgemm_k(
    const float* __restrict__ A, int lda, i64 sA,
    const float* __restrict__ B, int ldb, i64 sB,
    float* __restrict__ C, int ldc, i64 sC,
    int M, int N, int K,
    const float* __restrict__ bias, float scale, int act,
    const float* __restrict__ rowmul, int combine, const float* __restrict__ aux)
{
  A += (i64)blockIdx.z * sA;
  B += (i64)blockIdx.z * sB;
  C += (i64)blockIdx.z * sC;
  int m0 = blockIdx.x * 128, n0 = blockIdx.y * 128;
  int tid = threadIdx.x;
  int wave = tid >> 6, lane = tid & 63;
  int quad = lane >> 4, mr = lane & 15;
  int wm = (wave >> 1) * 64, wn = (wave & 1) * 64;
  __shared__ unsigned short As[128][40];
  __shared__ unsigned short Bs[128][40];
  f32x4 acc[4][4];
  #pragma unroll
  for (int i=0;i<4;i++)
    #pragma unroll
    for (int j=0;j<4;j++) acc[i][j] = (f32x4){0.f,0.f,0.f,0.f};

  for (int k0 = 0; k0 < K; k0 += 32){
    if (!TA){
      #pragma unroll
      for (int it=0; it<4; it++){
        int lin = tid + it*256;
        int r = lin >> 3, c4 = (lin & 7) * 4;
        float4 g = *(const float4*)&A[(i64)(m0+r)*lda + k0 + c4];
        As[r][c4]   = f2bf(g.x); As[r][c4+1] = f2bf(g.y);
        As[r][c4+2] = f2bf(g.z); As[r][c4+3] = f2bf(g.w);
      }
    } else {
      #pragma unroll
      for (int it=0; it<4; it++){
        int lin = tid + it*256;
        int m = lin & 127, kg = (lin >> 7) * 4;
        float v0 = A[(i64)(k0+kg  )*lda + m0 + m];
        float v1 = A[(i64)(k0+kg+1)*lda + m0 + m];
        float v2 = A[(i64)(k0+kg+2)*lda + m0 + m];
        float v3 = A[(i64)(k0+kg+3)*lda + m0 + m];
        As[m][kg] = f2bf(v0); As[m][kg+1] = f2bf(v1);
        As[m][kg+2] = f2bf(v2); As[m][kg+3] = f2bf(v3);
      }
    }
    if (!TB){
      #pragma unroll
      for (int it=0; it<4; it++){
        int lin = tid + it*256;
        int n = lin & 127, kg = (lin >> 7) * 4;
        float v0 = B[(i64)(k0+kg  )*ldb + n0 + n];
        float v1 = B[(i64)(k0+kg+1)*ldb + n0 + n];
        float v2 = B[(i64)(k0+kg+2)*ldb + n0 + n];
        float v3 = B[(i64)(k0+kg+3)*ldb + n0 + n];
        Bs[n][kg] = f2bf(v0); Bs[n][kg+1] = f2bf(v1);
        Bs[n][kg+2] = f2bf(v2); Bs[n][kg+3] = f2bf(v3);
      }
    } else {
      #pragma unroll
      for (int it=0; it<4; it++){
        int lin = tid + it*256;
        int r = lin >> 3, c4 = (lin & 7) * 4;
        float4 g = *(const float4*)&B[(i64)(n0+r)*ldb + k0 + c4];
        Bs[r][c4]   = f2bf(g.x); Bs[r][c4+1] = f2bf(g.y);
        Bs[r][c4+2] = f2bf(g.z); Bs[r][c4+3] = f2bf(g.w);
      }
    }
    __syncthreads();
    bf16x8 af[4], bfr[4];
    #pragma unroll
    for (int i=0;i<4;i++) af[i]  = *(const bf16x8*)&As[wm + i*16 + mr][quad*8];
    #pragma unroll
    for (int j=0;j<4;j++) bfr[j] = *(const bf16x8*)&Bs[wn + j*16 + mr][quad*8];
    #pragma unroll
    for (int i=0;i<4;i++)
      #pragma unroll
      for (int j=0;j<4;j++)
        acc[i][j] = __builtin_amdgcn_mfma_f32_16x16x32_bf16(af[i], bfr[j], acc[i][j], 0, 0, 0);
    __syncthreads();
  }
  #pragma unroll
  for (int i=0;i<4;i++){
    #pragma unroll
    for (int r=0;r<4;r++){
      int m = m0 + wm + i*16 + quad*4 + r;
      float rm = rowmul ? rowmul[m] : 1.f;
      i64 mrow = (combine == 4) ? (i64)(((m & 255) << 8) | (m >> 8)) : (i64)m;
      #pragma unroll
      for (int j=0;j<4;j++){
        int n = n0 + wn + j*16 + mr;
        float v = acc[i][j][r] * scale;
        if (bias) v += bias[n];
        if (act == 1) v = fmaxf(v, 0.f);
        else if (act == 2) v = 1.f/(1.f + __expf(-v));
        v *= rm;
        i64 idx = mrow*ldc + n;
        if (combine == 0) C[idx] = v;
        else if (combine == 1 || combine == 4) C[idx] += v;
        else if (combine == 2) C[idx] *= v;
        else C[idx] += aux[(i64)m*ldc + n] * v;
      }
    }
  }
}

// ---------------- bf16 MFMA GEMM: 64x64 tile, 256 thr (2x2 waves of 32x32) ----------------
// For dispatches whose 128-tile grid is <1024 blocks (2 blocks/CU): R3 showed tri-mult batched
// GEMM at grid 512 -> Occupancy 10.8%, MfmaUtil 1.8%, VALUBusy 5% (pure latency, 85 us).
// 64x64 tiles quadruple the grid (2048 blocks -> 6-8 blocks/CU); LDS 10 KB.
// NOTE (R5-R9): routing pt_w1 (M=32768,N=512,K=128,ldb=512) through this kernel correlates
// 4:0 with container failure; mechanism unknown. Do NOT route that shape here.
template<bool TA, bool TB>
__global__ __launch_bounds__(256) void mgemm64_k(
    const float* __restrict__ A, int lda, i64 sA,
    const float* __restrict__ B, int ldb, i64 sB,
    float* __restrict__ C, int ldc, i64 sC,
    int M, int N, int K,
    const float* __restrict__ bias, float scale, int act,
    const float* __restrict__ rowmul, int combine, const float* __restrict__ aux)
{
  A += (i64)blockIdx.z * sA;
  B += (i64)blockIdx.z * sB;
  C += (i64)blockIdx.z * sC;
  int m0 = blockIdx.x * 64, n0 = blockIdx.y * 64;
  int tid = threadIdx.x;
  int wave = tid >> 6, lane = tid & 63;
  int quad = lane >> 4, mr = lane & 15;
  int wm = (wave >> 1) * 32, wn = (wave & 1) * 32;
  __shared__ unsigned short As[64][40];
  __shared__ unsigned short Bs[64][40];
  f32x4 acc[2][2];
  #pragma unroll
  for (int i=0;i<2;i++)
    #pragma unroll
    for (int j=0;j<2;j++) acc[i][j] = (f32x4){0.f,0.f,0.f,0.f};

  for (int k0 = 0; k0 < K; k0 += 32){
    if (!TA){
      #pragma unroll
      for (int it=0; it<2; it++){
        int lin = tid + it*256;
        int r = lin >> 3, c4 = (lin & 7) * 4;
        float4 g = *(const float4*)&A[(i64)(m0+r)*lda + k0 + c4];
        As[r][c4]   = f2bf(g.x); As[r][c4+1] = f2bf(g.y);
        As[r][c4+2] = f2bf(g.z); As[r][c4+3] = f2bf(g.w);
      }
    } else {
      #pragma unroll
      for (int it=0; it<2; it++){
        int lin = tid + it*256;
        int m = lin & 63, kg = (lin >> 6) * 4;
        float v0 = A[(i64)(k0+kg  )*lda + m0 + m];
        float v1 = A[(i64)(k0+kg+1)*lda + m0 + m];
        float v2 = A[(i64)(k0+kg+2)*lda + m0 + m];
        float v3 = A[(i64)(k0+kg+3)*lda + m0 + m];
        As[m][kg] = f2bf(v0); As[m][kg+1] = f2bf(v1);
        As[m][kg+2] = f2bf(v2); As[m][kg+3] = f2bf(v3);
      }
    }
    if (!TB){
      #pragma unroll
      for (int it=0; it<2; it++){
        int lin = tid + it*256;
        int n = lin & 63, kg = (lin >> 6) * 4;
        float v0 = B[(i64)(k0+kg  )*ldb + n0 + n];
        float v1 = B[(i64)(k0+kg+1)*ldb + n0 + n];
        float v2 = B[(i64)(k0+kg+2)*ldb + n0 + n];
        float v3 = B[(i64)(k0+kg+3)*ldb + n0 + n];
        Bs[n][kg] = f2bf(v0); Bs[n][kg+1] = f2bf(v1);
        Bs[n][kg+2] = f2bf(v2); Bs[n][kg+3] = f2bf(v3);
      }
    } else {
      #pragma unroll
      for (int it=0; it<2; it++){
        int lin = tid + it*256;
        int r = lin >> 3, c4 = (lin & 7) * 4;
        float4 g = *(const float4*)&B[(i64)(n0+r)*ldb + k0 + c4];
        Bs[r][c4]   = f2bf(g.x); Bs[r][c4+1] = f2bf(g.y);
        Bs[r][c4+2] = f2bf(g.z); Bs[r][c4+3] = f2bf(g.w);
      }
    }
    __syncthreads();
    bf16x8 af[2], bfr[2];
    #pragma unroll
    for (int i=0;i<2;i++) af[i]  = *(const bf16x8*)&As[wm + i*16 + mr][quad*8];
    #pragma unroll
    for (int j=0;j<2;j++) bfr[j] = *(const bf16x8*)&Bs[wn + j*16 + mr][quad*8];
    #pragma unroll
    for (int i=0;i<2;i++)
      #pragma unroll
      for (int j=0;j<2;j++)
        acc[i][j] = __builtin_amdgcn_mfma_f32_16x16x32_bf16(af[i], bfr[j], acc[i][j], 0, 0, 0);
    __syncthreads();
  }
  #pragma unroll
  for (int i=0;i<2;i++){
    #pragma unroll
    for (int r=0;r<4;r++){
      int m = m0 + wm + i*16 + quad*4 + r;
      float rm = rowmul ? rowmul[m] : 1.f;
      i64 mrow = (combine == 4) ? (i64)(((m & 255) << 8) | (m >> 8)) : (i64)m;
      #pragma unroll
      for (int j=0;j<2;j++){
        int n = n0 + wn + j*16 + mr;
        float v = acc[i][j][r] * scale;
        if (bias) v += bias[n];
        if (act == 1) v = fmaxf(v, 0.f);
        else if (act == 2) v = 1.f/(1.f + __expf(-v));
        v *= rm;
        i64 idx = mrow*ldc + n;
        if (combine == 0) C[idx] = v;
        else if (combine == 1 || combine == 4) C[idx] += v;
        else if (combine == 2) C[idx] *= v;
        else C[idx] += aux[(i64)m*ldc + n] * v;
      }
    }
  }
}

// ---------------- fused dual-MFMA lin*sigmoid(gate) for tri-mult ----------------
// 64x64 tile; grid (1024, 2) = 2048 blocks; LDS 15 KB.
__global__ __launch_bounds__(256) void mlrgate_k(
    const float* __restrict__ X,
    const float* __restrict__ Wl, const float* __restrict__ bl,
    const float* __restrict__ Wg, const float* __restrict__ bg,
    float* __restrict__ Out)
{
  int m0 = blockIdx.x * 64, n0 = blockIdx.y * 64;
  int tid = threadIdx.x;
  int wave = tid >> 6, lane = tid & 63;
  int quad = lane >> 4, mr = lane & 15;
  int wm = (wave >> 1) * 32, wn = (wave & 1) * 32;
  __shared__ unsigned short As[64][40], B1s[64][40], B2s[64][40];
  f32x4 acc1[2][2], acc2[2][2];
  #pragma unroll
  for (int i=0;i<2;i++)
    #pragma unroll
    for (int j=0;j<2;j++){ acc1[i][j] = (f32x4){0,0,0,0}; acc2[i][j] = (f32x4){0,0,0,0}; }

  for (int k0 = 0; k0 < 128; k0 += 32){
    #pragma unroll
    for (int it=0; it<2; it++){
      int lin = tid + it*256;
      int r = lin >> 3, c4 = (lin & 7) * 4;
      float4 g = *(const float4*)&X[(i64)(m0+r)*128 + k0 + c4];
      As[r][c4]   = f2bf(g.x); As[r][c4+1] = f2bf(g.y);
      As[r][c4+2] = f2bf(g.z); As[r][c4+3] = f2bf(g.w);
    }
    #pragma unroll
    for (int it=0; it<2; it++){
      int lin = tid + it*256;
      int n = lin & 63, kg = (lin >> 6) * 4;
      float a0 = Wl[(i64)(k0+kg  )*128 + n0 + n];
      float a1 = Wl[(i64)(k0+kg+1)*128 + n0 + n];
      float a2 = Wl[(i64)(k0+kg+2)*128 + n0 + n];
      float a3 = Wl[(i64)(k0+kg+3)*128 + n0 + n];
      B1s[n][kg] = f2bf(a0); B1s[n][kg+1] = f2bf(a1);
      B1s[n][kg+2] = f2bf(a2); B1s[n][kg+3] = f2bf(a3);
      float g0 = Wg[(i64)(k0+kg  )*128 + n0 + n];
      float g1 = Wg[(i64)(k0+kg+1)*128 + n0 + n];
      float g2 = Wg[(i64)(k0+kg+2)*128 + n0 + n];
      float g3 = Wg[(i64)(k0+kg+3)*128 + n0 + n];
      B2s[n][kg] = f2bf(g0); B2s[n][kg+1] = f2bf(g1);
      B2s[n][kg+2] = f2bf(g2); B2s[n][kg+3] = f2bf(g3);
    }
    __syncthreads();
    bf16x8 af[2], b1f[2], b2f[2];
    #pragma unroll
    for (int i=0;i<2;i++) af[i]  = *(const bf16x8*)&As[wm + i*16 + mr][quad*8];
    #pragma unroll
    for (int j=0;j<2;j++){
      b1f[j] = *(const bf16x8*)&B1s[wn + j*16 + mr][quad*8];
      b2f[j] = *(const bf16x8*)&B2s[wn + j*16 + mr][quad*8];
    }
    #pragma unroll
    for (int i=0;i<2;i++)
      #pragma unroll
      for (int j=0;j<2;j++){
        acc1[i][j] = __builtin_amdgcn_mfma_f32_16x16x32_bf16(af[i], b1f[j], acc1[i][j], 0, 0, 0);
        acc2[i][j] = __builtin_amdgcn_mfma_f32_16x16x32_bf16(af[i], b2f[j], acc2[i][j], 0, 0, 0);
      }
    __syncthreads();
  }
  #pragma unroll
  for (int i=0;i<2;i++){
    #pragma unroll
    for (int r=0;r<4;r++){
      int m = m0 + wm + i*16 + quad*4 + r;
      #pragma unroll
      for (int j=0;j<2;j++){
        int n = wn + j*16 + mr;
        float lv = acc1[i][j][r] + bl[n0 + n];
        float gv = acc2[i][j][r] + bg[n0 + n];
        Out[(i64)m*128 + n0 + n] = lv * (1.f/(1.f + __expf(-gv)));
      }
    }
  }
}

// ---------------- pair transition, stage 1: H(bf16) = relu(X @ W1 + b1) ----------------
// Dedicated kernel (R9 post-mortem: pt_w1 on mgemm64_k correlates 4:0 with container failure;
// 128-tile mgemm_k at half-M was grid 1024 = 4/CU, 76 us, occ 22%). Full M=65536, N=512,
// K=128 -> grid (512,4) = 2048 blocks, 8/CU. H stored bf16 (bit-identical to the old
// f32-store + f2bf-at-staging path) -> fits B1+B2, halves H traffic.
__global__ __launch_bounds__(256) void ptw1_k(
    const float* __restrict__ X, const float* __restrict__ W1,
    const float* __restrict__ b1, unsigned short* __restrict__ H)
{
  int m0 = blockIdx.x * 128, n0 = blockIdx.y * 128;
  int tid = threadIdx.x;
  int wave = tid >> 6, lane = tid & 63;
  int quad = lane >> 4, mr = lane & 15;
  int wm = (wave >> 1) * 64, wn = (wave & 1) * 64;
  __shared__ unsigned short As[128][40];
  __shared__ unsigned short Bs[128][40];
  f32x4 acc[4][4];
  #pragma unroll
  for (int i=0;i<4;i++)
    #pragma unroll
    for (int j=0;j<4;j++) acc[i][j] = (f32x4){0.f,0.f,0.f,0.f};

  for (int k0 = 0; k0 < 128; k0 += 32){
    #pragma unroll
    for (int it=0; it<4; it++){
      int lin = tid + it*256;
      int r = lin >> 3, c4 = (lin & 7) * 4;
      float4 g = *(const float4*)&X[(i64)(m0+r)*128 + k0 + c4];
      As[r][c4]   = f2bf(g.x); As[r][c4+1] = f2bf(g.y);
      As[r][c4+2] = f2bf(g.z); As[r][c4+3] = f2bf(g.w);
    }
    #pragma unroll
    for (int it=0; it<4; it++){
      int lin = tid + it*256;
      int n = lin & 127, kg = (lin >> 7) * 4;
      float v0 = W1[(i64)(k0+kg  )*512 + n0 + n];
      float v1 = W1[(i64)(k0+kg+1)*512 + n0 + n];
      float v2 = W1[(i64)(k0+kg+2)*512 + n0 + n];
      float v3 = W1[(i64)(k0+kg+3)*512 + n0 + n];
      Bs[n][kg] = f2bf(v0); Bs[n][kg+1] = f2bf(v1);
      Bs[n][kg+2] = f2bf(v2); Bs[n][kg+3] = f2bf(v3);
    }
    __syncthreads();
    bf16x8 af[4], bfr[4];
    #pragma unroll
    for (int i=0;i<4;i++) af[i]  = *(const bf16x8*)&As[wm + i*16 + mr][quad*8];
    #pragma unroll
    for (int j=0;j<4;j++) bfr[j] = *(const bf16x8*)&Bs[wn + j*16 + mr][quad*8];
    #pragma unroll
    for (int i=0;i<4;i++)
      #pragma unroll
      for (int j=0;j<4;j++)
        acc[i][j] = __builtin_amdgcn_mfma_f32_16x16x32_bf16(af[i], bfr[j], acc[i][j], 0, 0, 0);
    __syncthreads();
  }
  #pragma unroll
  for (int i=0;i<4;i++){
    #pragma unroll
    for (int r=0;r<4;r++){
      int m = m0 + wm + i*16 + quad*4 + r;
      #pragma unroll
      for (int j=0;j<4;j++){
        int n = n0 + wn + j*16 + mr;
        float v = fmaxf(acc[i][j][r] + b1[n], 0.f);
        H[(i64)m*512 + n] = f2bf(v);
      }
    }
  }
}

// ---------------- pair transition, stage 2: pa += H(bf16) @ W2 + b2 ----------------
// 64x64 tile; M=65536, N=128, K=512 -> grid (1024,2) = 2048 blocks (matches the shape family
// that passes on the 64-tile path: N=128, ldb=128). A staged directly from bf16 H (uint2 copy).
__global__ __launch_bounds__(256) void ptw2_k(
    const unsigned short* __restrict__ H, const float* __restrict__ W2,
    const float* __restrict__ b2, float* __restrict__ pa)
{
  int m0 = blockIdx.x * 64, n0 = blockIdx.y * 64;
  int tid = threadIdx.x;
  int wave = tid >> 6, lane = tid & 63;
  int quad = lane >> 4, mr = lane & 15;
  int wm = (wave >> 1) * 32, wn = (wave & 1) * 32;
  __shared__ unsigned short As[64][40];
  __shared__ unsigned short Bs[64][40];
  f32x4 acc[2][2];
  #pragma unroll
  for (int i=0;i<2;i++)
    #pragma unroll
    for (int j=0;j<2;j++) acc[i][j] = (f32x4){0.f,0.f,0.f,0.f};

  for (int k0 = 0; k0 < 512; k0 += 32){
    #pragma unroll
    for (int it=0; it<2; it++){
      int lin = tid + it*256;
      int r = lin >> 3, c4 = (lin & 7) * 4;
      *(uint2*)&As[r][c4] = *(const uint2*)&H[(i64)(m0+r)*512 + k0 + c4];
    }
    #pragma unroll
    for (int it=0; it<2; it++){
      int lin = tid + it*256;
      int n = lin & 63, kg = (lin >> 6) * 4;
      float v0 = W2[(i64)(k0+kg  )*128 + n0 + n];
      float v1 = W2[(i64)(k0+kg+1)*128 + n0 + n];
      float v2 = W2[(i64)(k0+kg+2)*128 + n0 + n];
      float v3 = W2[(i64)(k0+kg+3)*128 + n0 + n];
      Bs[n][kg] = f2bf(v0); Bs[n][kg+1] = f2bf(v1);
      Bs[n][kg+2] = f2bf(v2); Bs[n][kg+3] = f2bf(v3);
    }
    __syncthreads();
    bf16x8 af[2], bfr[2];
    #pragma unroll
    for (int i=0;i<2;i++) af[i]  = *(const bf16x8*)&As[wm + i*16 + mr][quad*8];
    #pragma unroll
    for (int j=0;j<2;j++) bfr[j] = *(const bf16x8*)&Bs[wn + j*16 + mr][quad*8];
    #pragma unroll
    for (int i=0;i<2;i++)
      #pragma unroll
      for (int j=0;j<2;j++)
        acc[i][j] = __builtin_amdgcn_mfma_f32_16x16x32_bf16(af[i], bfr[j], acc[i][j], 0, 0, 0);
    __syncthreads();
  }
  #pragma unroll
  for (int i=0;i<2;i++){
    #pragma unroll
    for (int r=0;r<4;r++){
      int m = m0 + wm + i*16 + quad*4 + r;
      #pragma unroll
      for (int j=0;j<2;j++){
        int n = n0 + wn + j*16 + mr;
        pa[(i64)m*128 + n] += acc[i][j][r] + b2[n];
      }
    }
  }
}

// ---------------- generic batched GEMM (fp32, 64x64 tile) ----------------
template<bool TA, bool TB>
__global__ __launch_bounds__(256) void gemm_k(
    const float* __restrict__ A, int lda, i64 sA,
    const float* __restrict__ B, int ldb, i64 sB,
    float* __restrict__ C, int ldc, i64 sC,
    int M, int N, int K,
    const float* __restrict__ bias, float scale, int act,
    const float* __restrict__ rowmul, int combine)
{
  A += (i64)blockIdx.z * sA;
  B += (i64)blockIdx.z * sB;
  C += (i64)blockIdx.z * sC;
  int m0 = blockIdx.x * 64, n0 = blockIdx.y * 64;
  int tid = threadIdx.x, tx = tid & 15, ty = tid >> 4;
  __shared__ float As[16][68], Bs[16][68];
  float acc[4][4] = {};
  for (int k0 = 0; k0 < K; k0 += 16){
    if (TA){
      for (int l = tid; l < 1024; l += 256){
        int kk = l >> 6, mi = l & 63; int m = m0 + mi;
        As[kk][mi] = (m < M) ? A[(i64)(k0+kk)*lda + m] : 0.f;
      }
    } else {
      for (int l = tid; l < 1024; l += 256){
        int mi = l >> 4, kk = l & 15; int m = m0 + mi;
        As[kk][mi] = (m < M) ? A[(i64)m*lda + k0 + kk] : 0.f;
      }
    }
    if (TB){
      for (int l = tid; l < 1024; l += 256){
        int ni = l >> 4, kk = l & 15; int n = n0 + ni;
        Bs[kk][ni] = (n < N) ? B[(i64)n*ldb + k0 + kk] : 0.f;
      }
    } else {
      for (int l = tid; l < 1024; l += 256){
        int kk = l >> 6, ni = l & 63; int n = n0 + ni;
        Bs[kk][ni] = (n < N) ? B[(i64)(k0+kk)*ldb + n] : 0.f;
      }
    }
    __syncthreads();
    #pragma unroll
    for (int kk = 0; kk < 16; ++kk){
      float4 av4 = *(const float4*)&As[kk][ty*4];
      float4 bv4 = *(const float4*)&Bs[kk][tx*4];
      float av[4] = {av4.x, av4.y, av4.z, av4.w};
      float bv[4] = {bv4.x, bv4.y, bv4.z, bv4.w};
      #pragma unroll
      for (int i=0;i<4;i++)
        #pragma unroll
        for (int j=0;j<4;j++) acc[i][j] = fmaf(av[i], bv[j], acc[i][j]);
    }
    __syncthreads();
  }
  #pragma unroll
  for (int i=0;i<4;i++){
    int m = m0 + ty*4 + i;
    if (m >= M) continue;
    float rm = rowmul ? rowmul[m] : 1.f;
    #pragma unroll
    for (int j=0;j<4;j++){
      int n = n0 + tx*4 + j;
      if (n >= N) continue;
      float v = acc[i][j] * scale;
      if (bias) v += bias[n];
      if (act == 1) v = fmaxf(v, 0.f);
      else if (act == 2) v = 1.f/(1.f + expf(-v));
      v *= rm;
      i64 idx = (i64)m*ldc + n;
      if (combine == 0) C[idx] = v;
      else if (combine == 1) C[idx] += v;
      else C[idx] *= v;
    }
  }
}

// ---------------- thin GEMM (small M): split-K two-phase ----------------
__global__ __launch_bounds__(256) void gemm_part_k(
    const float* __restrict__ A, int lda,
    const float* __restrict__ B, int ldb,
    float* __restrict__ Cp, int M, int N, int K, int chunk)
{
  int m0 = blockIdx.x*16, n0 = blockIdx.y*64, z = blockIdx.z;
  int kb = z*chunk, ke = min(K, kb+chunk);
  int tid = threadIdx.x;
  int mi = tid >> 4, ni4 = (tid & 15)*4;
  __shared__ float As[16][17], Bs[16][68];
  float acc[4] = {0.f,0.f,0.f,0.f};
  for (int k0 = kb; k0 < ke; k0 += 16){
    { int r = tid>>4, c = tid&15; int m = m0+r;
      As[c][r] = (m < M) ? A[(i64)m*lda + k0 + c] : 0.f; }
    for (int l = tid; l < 1024; l += 256){
      int kk = l>>6, nn = l&63; int n = n0+nn;
      Bs[kk][nn] = (n < N) ? B[(i64)(k0+kk)*ldb + n] : 0.f;
    }
    __syncthreads();
    #pragma unroll
    for (int kk=0;kk<16;kk++){
      float a = As[kk][mi];
      float4 b = *(const float4*)&Bs[kk][ni4];
      acc[0]=fmaf(a,b.x,acc[0]); acc[1]=fmaf(a,b.y,acc[1]);
      acc[2]=fmaf(a,b.z,acc[2]); acc[3]=fmaf(a,b.w,acc[3]);
    }
    __syncthreads();
  }
  int m = m0+mi, n = n0+ni4;
  if (m < M && n < N) *(float4*)&Cp[((i64)z*M + m)*N + n] = *(float4*)acc;
}

__global__ __launch_bounds__(256) void gemm_reduce_k(
    const float* __restrict__ Cp, float* __restrict__ C, int ldc,
    int M, int N, int S,
    const float* __restrict__ bias, float scale, int act,
    const float* __restrict__ rowmul, int combine)
{
  i64 idx = (i64)blockIdx.x*256 + threadIdx.x;
  if (idx >= (i64)M*N) return;
  int m = (int)(idx / N), n = (int)(idx % N);
  float s = 0.f;
  for (int z=0; z<S; z++) s += Cp[(i64)z*M*N + idx];
  float v = s*scale;
  if (bias) v += bias[n];
  if (act == 1) v = fmaxf(v, 0.f);
  else if (act == 2) v = 1.f/(1.f + expf(-v));
  if (rowmul) v *= rowmul[m];
  i64 o = (i64)m*ldc + n;
  if (combine == 0) C[o] = v;
  else if (combine == 1) C[o] += v;
  else C[o] *= v;
}

// ---------------- OPM ----------------
__global__ __launch_bounds__(128) void opm_wd_k(const float* __restrict__ right, const float* __restrict__ W,
                                                float* __restrict__ Wd){
  int d = blockIdx.x, c = blockIdx.y, f = threadIdx.x;
  float acc = 0.f;
  #pragma unroll
  for (int e=0;e<32;e++) acc = fmaf(right[d*32+e], W[((i64)c*32+e)*128 + f], acc);
  Wd[((i64)d*32+c)*128 + f] = acc;
}

// pa[d,b,f] = pair_act[d,b,f] + (sum_c left[b,c]*Wd[d,c,f] + ob[f]) / (1e-3 + sm[d]*sm[b])
__global__ __launch_bounds__(128) void opm_final_k(const float* __restrict__ left, const float* __restrict__ Wd,
                                                   const float* __restrict__ ob, const float* __restrict__ sm,
                                                   const float* __restrict__ pair_act, float* __restrict__ pa){
  int d = blockIdx.x, b0 = blockIdx.y*16, f = threadIdx.x;
  __shared__ float wd_s[32][128];
  __shared__ float l_s[16][32];
  for (int c=0;c<32;c++) wd_s[c][f] = Wd[((i64)d*32+c)*128 + f];
  for (int l = f; l < 512; l += 128){ int bi=l>>5, c=l&31; l_s[bi][c] = left[(b0+bi)*32 + c]; }
  __syncthreads();
  float md = sm[d], obf = ob[f];
  for (int bi=0;bi<16;bi++){
    float acc = 0.f;
    #pragma unroll
    for (int c=0;c<32;c++) acc = fmaf(l_s[bi][c], wd_s[c][f], acc);
    int b = b0+bi;
    i64 idx = ((i64)d*256 + b)*128 + f;
    pa[idx] = pair_act[idx] + (acc + obf) / (1e-3f + md*sm[b]);
  }
}

// ---------------- row attention core ----------------
__global__ __launch_bounds__(256) void ra_attn_k(const float* __restrict__ q, const float* __restrict__ k,
                                                 const float* __restrict__ v, const float* __restrict__ nb,
                                                 const float* __restrict__ sm, float* __restrict__ wa){
  int qi = blockIdx.x, h = blockIdx.y, tid = threadIdx.x;
  __shared__ float qv[48];
  __shared__ float p[256];
  __shared__ float red[256];
  if (tid < 48) qv[tid] = q[(i64)qi*384 + h*48 + tid];
  __syncthreads();
  float acc = 0.f;
  const float* kr = k + (i64)tid*384 + h*48;
  #pragma unroll
  for (int c=0;c<48;c++) acc = fmaf(qv[c], kr[c], acc);
  acc += 1e9f*(sm[tid]-1.f) + nb[((i64)qi*256 + tid)*8 + h];
  red[tid] = acc; __syncthreads();
  for (int off=128;off>0;off>>=1){ if (tid<off) red[tid] = fmaxf(red[tid], red[tid+off]); __syncthreads(); }
  float mx = red[0]; __syncthreads();
  float e = expf(acc - mx);
  red[tid] = e; __syncthreads();
  for (int off=128;off>0;off>>=1){ if (tid<off) red[tid] += red[tid+off]; __syncthreads(); }
  p[tid] = e / red[0];
  __syncthreads();
  if (tid < 48){
    float a = 0.f;
    for (int kk=0;kk<256;kk++) a = fmaf(p[kk], v[(i64)kk*384 + h*48 + tid], a);
    wa[(i64)qi*384 + h*48 + tid] = a;
  }
}

// ---------------- triangle attention core v7: swapped-operand MFMA flash ----------------
// S = mfma(K, Q): lane holds scores for ONE q-row (softmax per-lane, 4 shfl per tile);
// O^T = mfma(V^T, P): alpha/1/l per-lane scalars, coalesced float4 store.
// Grid (qblk,h,b): qblk fastest -> K/V L2 reuse across the 4 sharing blocks.
__global__ __launch_bounds__(256, 6) void ta_mfma_k(
    const float* __restrict__ q, const float* __restrict__ k, const float* __restrict__ v,
    const float* __restrict__ nbQ, const float* __restrict__ mask, int maskT,
    float* __restrict__ wa)
{
  int qblk = blockIdx.x, h = blockIdx.y, b = blockIdx.z;
  int tid = threadIdx.x;
  int wave = tid >> 6, lane = tid & 63;
  int quad = lane >> 4, mr = lane & 15;
  const i64 base = ((i64)b*256)*128 + h*32;

  __shared__ __align__(16) unsigned short Ks[128][40];   // [key][c], row 80B
  __shared__ __align__(16) unsigned short Vt[32][136];   // [c][key], row 272B
  __shared__ __align__(16) float mask_s[256];
  __shared__ __align__(16) unsigned short Pl[4][16][40]; // per-wave P [q][key]

  mask_s[tid] = 1e9f * ((maskT ? mask[(i64)tid*256 + b] : mask[(i64)b*256 + tid]) - 1.f);

  int q0w = qblk*64 + wave*16;
  int qg = q0w + mr;                      // this lane's q row (fixed for whole kernel)
  const float* nbq = nbQ + (i64)h*65536 + (i64)qg*256;

  // Q as B-operand fragment: [n=q=mr][k-ch quad*8..+7]
  bf16x8 qf;
  {
    const float* qp = q + base + (i64)qg*128 + quad*8;
    float4 a = *(const float4*)qp;
    float4 c = *(const float4*)(qp+4);
    qf[0]=(short)f2bf(a.x); qf[1]=(short)f2bf(a.y); qf[2]=(short)f2bf(a.z); qf[3]=(short)f2bf(a.w);
    qf[4]=(short)f2bf(c.x); qf[5]=(short)f2bf(c.y); qf[6]=(short)f2bf(c.z); qf[7]=(short)f2bf(c.w);
  }

  f32x4 o0 = (f32x4){0,0,0,0}, o1 = (f32x4){0,0,0,0}; // O^T[c=quad*4+r(+16)][q=mr]
  float mm = -1e30f, ll = 0.f;                         // per-lane softmax state (q = qg)

  for (int half = 0; half < 2; half++){
    __syncthreads();
    #pragma unroll
    for (int it=0; it<4; it++){
      int idx = it*256 + tid;              // 128 keys x 32 ch
      int kl = idx >> 3, c4 = (idx & 7)*4;
      i64 roff = base + (i64)(half*128 + kl)*128 + c4;
      float4 g  = *(const float4*)(k + roff);
      unsigned int w0 = (unsigned int)f2bf(g.x) | ((unsigned int)f2bf(g.y)<<16);
      unsigned int w1 = (unsigned int)f2bf(g.z) | ((unsigned int)f2bf(g.w)<<16);
      *(uint2*)&Ks[kl][c4] = make_uint2(w0, w1);
      float4 gv = *(const float4*)(v + roff);
      Vt[c4  ][kl] = f2bf(gv.x);
      Vt[c4+1][kl] = f2bf(gv.y);
      Vt[c4+2][kl] = f2bf(gv.z);
      Vt[c4+3][kl] = f2bf(gv.w);
    }
    __syncthreads();

    #pragma unroll
    for (int it=0; it<4; it++){
      int kc = it*32;
      int kg = half*128 + kc;
      // K as A-operand: frag rows = keys kc+mr / kc+16+mr
      bf16x8 kf0 = *(const bf16x8*)&Ks[kc + mr][quad*8];
      bf16x8 kf1 = *(const bf16x8*)&Ks[kc + 16 + mr][quad*8];
      f32x4 s0 = __builtin_amdgcn_mfma_f32_16x16x32_bf16(kf0, qf, (f32x4){0,0,0,0}, 0, 0, 0);
      f32x4 s1 = __builtin_amdgcn_mfma_f32_16x16x32_bf16(kf1, qf, (f32x4){0,0,0,0}, 0, 0, 0);
      // s0[r] = S[key=kg+quad*4+r][qg]; s1[r] = S[key=kg+16+quad*4+r][qg]
      float4 nb0 = *(const float4*)(nbq + kg + quad*4);
      float4 nb1 = *(const float4*)(nbq + kg + 16 + quad*4);
      float4 mk0 = *(const float4*)&mask_s[kg + quad*4];
      float4 mk1 = *(const float4*)&mask_s[kg + 16 + quad*4];
      s0[0] += nb0.x + mk0.x; s0[1] += nb0.y + mk0.y; s0[2] += nb0.z + mk0.z; s0[3] += nb0.w + mk0.w;
      s1[0] += nb1.x + mk1.x; s1[1] += nb1.y + mk1.y; s1[2] += nb1.z + mk1.z; s1[3] += nb1.w + mk1.w;

      // per-lane online softmax over the 32-key tile (cross-quad = 2 shfls)
      float tm = fmaxf(fmaxf(fmaxf(s0[0],s0[1]), fmaxf(s0[2],s0[3])),
                       fmaxf(fmaxf(s1[0],s1[1]), fmaxf(s1[2],s1[3])));
      tm = fmaxf(tm, __shfl_xor(tm, 16));
      tm = fmaxf(tm, __shfl_xor(tm, 32));
      float nm = fmaxf(mm, tm);
      float alpha = __expf(mm - nm);
      mm = nm;
      float e00 = __expf(s0[0]-nm), e01 = __expf(s0[1]-nm);
      float e02 = __expf(s0[2]-nm), e03 = __expf(s0[3]-nm);
      float e10 = __expf(s1[0]-nm), e11 = __expf(s1[1]-nm);
      float e12 = __expf(s1[2]-nm), e13 = __expf(s1[3]-nm);
      float ps = ((e00+e01) + (e02+e03)) + ((e10+e11) + (e12+e13));
      ps += __shfl_xor(ps, 16);
      ps += __shfl_xor(ps, 32);
      ll = ll*alpha + ps;
      o0 *= alpha; o1 *= alpha;
      // P[q=mr][key] packed bf16 pairs, 2x 8B writes (2-way banks = free)
      unsigned int p0 = (unsigned int)f2bf(e00) | ((unsigned int)f2bf(e01)<<16);
      unsigned int p1 = (unsigned int)f2bf(e02) | ((unsigned int)f2bf(e03)<<16);
      unsigned int p2 = (unsigned int)f2bf(e10) | ((unsigned int)f2bf(e11)<<16);
      unsigned int p3 = (unsigned int)f2bf(e12) | ((unsigned int)f2bf(e13)<<16);
      *(uint2*)&Pl[wave][mr][quad*4]      = make_uint2(p0, p1);
      *(uint2*)&Pl[wave][mr][16 + quad*4] = make_uint2(p2, p3);
      // PV (swapped): A = V^T rows=channels, B = P [k=key][n=q=mr]
      bf16x8 pf  = *(const bf16x8*)&Pl[wave][mr][quad*8];
      bf16x8 vf0 = *(const bf16x8*)&Vt[mr     ][kc + quad*8];
      bf16x8 vf1 = *(const bf16x8*)&Vt[16 + mr][kc + quad*8];
      o0 = __builtin_amdgcn_mfma_f32_16x16x32_bf16(vf0, pf, o0, 0, 0, 0);
      o1 = __builtin_amdgcn_mfma_f32_16x16x32_bf16(vf1, pf, o1, 0, 0, 0);
    }
  }

  float inv = 1.f/ll;
  float* wp = wa + base + (i64)qg*128;
  *(float4*)(wp + quad*4)      = make_float4(o0[0]*inv, o0[1]*inv, o0[2]*inv, o0[3]*inv);
  *(float4*)(wp + 16 + quad*4) = make_float4(o1[0]*inv, o1[1]*inv, o1[2]*inv, o1[3]*inv);
}

// ---------------- host dispatch ----------------
static void gemm(hipStream_t st, bool TA, bool TB,
                 const float* A, int lda, i64 sA,
                 const float* B, int ldb, i64 sB,
                 float* C, int ldc, i64 sC,
                 int M, int N, int K, int batch,
                 const float* bias, float scale, int act,
                 const float* rowmul, int combine)
{
  dim3 g((M+63)/64, (N+63)/64, batch), bl(256);
  if (!TA && !TB)      gemm_k<false,false><<<g,bl,0,st>>>(A,lda,sA,B,ldb,sB,C,ldc,sC,M,N,K,bias,scale,act,rowmul,combine);
  else if (!TA &&  TB) gemm_k<false,true ><<<g,bl,0,st>>>(A,lda,sA,B,ldb,sB,C,ldc,sC,M,N,K,bias,scale,act,rowmul,combine);
  else                 gemm_k<true ,false><<<g,bl,0,st>>>(A,lda,sA,B,ldb,sB,C,ldc,sC,M,N,K,bias,scale,act,rowmul,combine);
}

static void mgemm(hipStream_t st, bool TA, bool TB,
                  const float* A, int lda, i64 sA,
                  const float* B, int ldb, i64 sB,
                  float* C, int ldc, i64 sC,
                  int M, int N, int K, int batch,
                  const float* bias, float scale, int act,
                  const float* rowmul, int combine, const float* aux = nullptr)
{
  dim3 bl(256);
  i64 nb128 = (i64)(M/128)*(N/128)*batch;
  if (nb128 < 1024 && (M % 64) == 0 && (N % 64) == 0){
    // latency-regime fix (R3): <1024 blocks at 128-tile -> 2 blocks/CU; use 64x64 tiles
    dim3 g(M/64, N/64, batch);
    if (!TA && !TB)      mgemm64_k<false,false><<<g,bl,0,st>>>(A,lda,sA,B,ldb,sB,C,ldc,sC,M,N,K,bias,scale,act,rowmul,combine,aux);
    else if (!TA &&  TB) mgemm64_k<false,true ><<<g,bl,0,st>>>(A,lda,sA,B,ldb,sB,C,ldc,sC,M,N,K,bias,scale,act,rowmul,combine,aux);
    else                 mgemm64_k<true ,false><<<g,bl,0,st>>>(A,lda,sA,B,ldb,sB,C,ldc,sC,M,N,K,bias,scale,act,rowmul,combine,aux);
    return;
  }
  dim3 g(M/128, N/128, batch);
  if (!TA && !TB)      mgemm_k<false,false><<<g,bl,0,st>>>(A,lda,sA,B,ldb,sB,C,ldc,sC,M,N,K,bias,scale,act,rowmul,combine,aux);
  else if (!TA &&  TB) mgemm_k<false,true ><<<g,bl,0,st>>>(A,lda,sA,B,ldb,sB,C,ldc,sC,M,N,K,bias,scale,act,rowmul,combine,aux);
  else                 mgemm_k<true ,false><<<g,bl,0,st>>>(A,lda,sA,B,ldb,sB,C,ldc,sC,M,N,K,bias,scale,act,rowmul,combine,aux);
}

static void gemm_thin(hipStream_t st,
                      const float* A, int lda, const float* B, int ldb,
                      float* C, int ldc, int M, int N, int K,
                      const float* bias, float scale, int act,
                      const float* rowmul, int combine, float* part)
{
  const int S = 8;
  int chunk = ((K/S + 15)/16)*16; if (chunk < 16) chunk = 16;
  dim3 g((M+15)/16, (N+63)/64, S);
  gemm_part_k<<<g,256,0,st>>>(A,lda,B,ldb,part,M,N,K,chunk);
  i64 t = (i64)M*N;
  gemm_reduce_k<<<(int)((t+255)/256),256,0,st>>>(part,C,ldc,M,N,S,bias,scale,act,rowmul,combine);
}

extern "C" void kernel_launch(void* const* d_in, const int* in_sizes, int n_in,
                              void* d_out, int out_size, void* d_ws, size_t ws_size,
                              hipStream_t stream)
{
  const float* IN[64];
  for (int i=0;i<n_in && i<64;i++) IN[i] = (const float*)d_in[i];

  const float* single_act = IN[0];
  const float* pair_act   = IN[1];
  const float* sm         = IN[2];
  const float* pm         = IN[3];
  const float* opm_ln     = IN[4];
  const float* opm_lr_w   = IN[5];
  const float* opm_lr_b   = IN[6];
  const float* opm_out_w  = IN[7];
  const float* opm_out_b  = IN[8];
  const float* ra_ln      = IN[9];
  const float* ra_pair_ln = IN[10];
  const float* ra_feat_w  = IN[11];
  const float* ra_qkv_w   = IN[12];
  const float* ra_gate_w  = IN[13];
  const float* ra_gate_b  = IN[14];
  const float* ra_o_w     = IN[15];
  const float* ra_o_b     = IN[16];
  const float* st_ln      = IN[17];
  const float* st_w1      = IN[18];
  const float* st_b1      = IN[19];
  const float* st_w2      = IN[20];
  const float* st_b2      = IN[21];
  const float* pt_ln      = IN[56];
  const float* pt_w1      = IN[57];
  const float* pt_b1      = IN[58];
  const float* pt_w2      = IN[59];
  const float* pt_b2      = IN[60];

  float* sa = (float*)d_out;           // [256,384]
  float* pa = (float*)d_out + 98304;   // [256,256,128]

  float* W  = (float*)d_ws;
  float* B0 = W;
  float* B1 = W + 8388608L;
  float* B2 = W + 16777216L;
  float* B3 = W + 25165824L;
  float* SMA = W + 33554432L;
  float* xs   = SMA;
  float* qb   = SMA +  98304;
  float* kb   = SMA + 196608;
  float* vb   = SMA + 294912;
  float* wab  = SMA + 393216;
  float* hst  = SMA + 491520;   // 393216
  float* nbra = SMA + 884736;   // 524288 (reused as nbQ in tri-attn phase)
  float* lbuf = SMA + 1409024;  // 8192
  float* rbuf = SMA + 1417216;  // 8192
  float* Wd   = SMA + 1425408;  // 1048576
  float* nbt  = SMA + 2473984;  // 262144

  // init sa with residual base (pa is initialized by opm_final_k's fused write)
  copy_k<<<384, 256, 0, stream>>>(sa, single_act, 98304L);

  // ---- 1) OPM -> pair residual (writes pa = pair_act + update) ----
  ln_k<<<256,128,0,stream>>>(single_act, xs, opm_ln, 384);
  gemm_thin(stream, xs,384, opm_lr_w,32,       lbuf,32, 256,32,384, opm_lr_b,    1.f,0, sm,0, B1);
  gemm_thin(stream, xs,384, opm_lr_w+12288,32, rbuf,32, 256,32,384, opm_lr_b+32, 1.f,0, sm,0, B1);
  opm_wd_k<<<dim3(256,32),128,0,stream>>>(rbuf, opm_out_w, Wd);
  opm_final_k<<<dim3(256,16),128,0,stream>>>(lbuf, Wd, opm_out_b, sm, pair_act, pa);

  // ---- 2) row attention with pair bias ----
  ln_k<<<256,128,0,stream>>>(sa, xs, ra_ln, 384);
  ln128_k<<<16384,256,0,stream>>>(pa, B0, ra_pair_ln, 0);
  gemm(stream,false,false, B0,128,0, ra_feat_w,8,0, nbra,8,0, 65536,8,128,1, nullptr,1.f,0,nullptr,0);
  const float qs_ra = 0.14433756729740643f; // 1/sqrt(48)
  gemm_thin(stream, xs,384, ra_qkv_w,384,        qb,384, 256,384,384, nullptr,qs_ra,0,nullptr,0, B1);
  gemm_thin(stream, xs,384, ra_qkv_w+147456,384, kb,384, 256,384,384, nullptr,1.f,0,nullptr,0, B1);
  gemm_thin(stream, xs,384, ra_qkv_w+294912,384, vb,384, 256,384,384, nullptr,1.f,0,nullptr,0, B1);
  ra_attn_k<<<dim3(256,8),256,0,stream>>>(qb, kb, vb, nbra, sm, wab);
  gemm_thin(stream, xs,384,  ra_gate_w,384, wab,384, 256,384,384, ra_gate_b,1.f,2,nullptr,2, B1);
  gemm_thin(stream, wab,384, ra_o_w,384,    sa,384,  256,384,384, ra_o_b,   1.f,0,nullptr,1, B1);

  // ---- 3) single transition ----
  ln_k<<<256,128,0,stream>>>(sa, xs, st_ln, 384);
  gemm_thin(stream, xs,384,   st_w1,1536, hst,1536, 256,1536,384, st_b1,1.f,1,nullptr,0, B1);
  gemm_thin(stream, hst,1536, st_w2,384,  sa,384,   256,384,1536, st_b2,1.f,0,nullptr,1, B1);

  // ---- 4/5) triangle multiplications ----
  auto tri_mult = [&](int base, bool outgoing){
    const float* ln_w = IN[base+0];
    const float* lr_w = IN[base+1];
    const float* lr_b = IN[base+2];
    const float* gw   = IN[base+3];
    const float* gb   = IN[base+4];
    const float* cln  = IN[base+5];
    const float* ow   = IN[base+6];
    const float* ob   = IN[base+7];
    const float* ogw  = IN[base+8];
    const float* ogb  = IN[base+9];
    ln128_k<<<16384,256,0,stream>>>(pa, B0, ln_w, 0);
    // left = mask * (X@Wl+bl) * sigmoid(X@Wg+bg): fused dual-MFMA, then transpose+mask -> B1 (ch-major)
    mlrgate_k<<<dim3(1024,2),256,0,stream>>>(B0, lr_w, lr_b, gw, gb, B3);
    tr_mask_k<<<dim3(2048,4),256,0,stream>>>(B3, pm, B1);
    // right -> B2 (ch-major)
    mlrgate_k<<<dim3(1024,2),256,0,stream>>>(B0, lr_w+16384, lr_b+128, gw+16384, gb+128, B3);
    tr_mask_k<<<dim3(2048,4),256,0,stream>>>(B3, pm, B2);
    if (outgoing) // out[i,j,c] = sum_k L_c[i,k] * R_c[j,k]
      mgemm(stream,false,true, B1,256,65536, B2,256,65536, B3,256,65536, 256,256,256,128, nullptr,1.f,0,nullptr,0);
    else          // out[i,j,c] = sum_k R_c[k,i] * L_c[k,j]
      mgemm(stream,true,false, B2,256,65536, B1,256,65536, B3,256,65536, 256,256,256,128, nullptr,1.f,0,nullptr,0);
    chw2hwc_k<<<dim3(2048,4),256,0,stream>>>(B3, B1);
    ln128_k<<<16384,256,0,stream>>>(B1, B3, cln, 0);
    mgemm(stream,false,false, B3,128,0, ow,128,0,  B1,128,0, 65536,128,128,1, ob,  1.f,0,nullptr,0);
    // fused: pa += B1 * sigmoid(B0@ogw + ogb)
    mgemm(stream,false,false, B0,128,0, ogw,128,0, pa,128,0, 65536,128,128,1, ogb, 1.f,2,nullptr,3, B1);
  };
  tri_mult(22, true);   // tmo
  tri_mult(32, false);  // tmi

  // ---- 6/7) triangle attentions ----
  auto tri_attn = [&](int base, bool percol){
    const float* ln_w   = IN[base+0];
    const float* feat_w = IN[base+1];
    const float* qkv_w  = IN[base+2];
    const float* gw     = IN[base+3];
    const float* gb     = IN[base+4];
    const float* ow     = IN[base+5];
    const float* ob     = IN[base+6];
    // LN with fused pair-transpose read for per-column attention
    ln128_k<<<16384,256,0,stream>>>(pa, B0, ln_w, percol?1:0);
    gemm(stream,false,false, B0,128,0, feat_w,4,0, nbt,4,0, 65536,4,128,1, nullptr,1.f,0,nullptr,0);
    nbQ_k<<<256,256,0,stream>>>(nbt, nbra);  // nbQ[h][q][k]
    const float qs = 0.17677669529663687f; // 1/sqrt(32)
    mgemm(stream,false,false, B0,128,0, qkv_w,128,0,       B1,128,0, 65536,128,128,1, nullptr,qs, 0,nullptr,0);
    mgemm(stream,false,false, B0,128,0, qkv_w+16384,128,0, B2,128,0, 65536,128,128,1, nullptr,1.f,0,nullptr,0);
    mgemm(stream,false,false, B0,128,0, qkv_w+32768,128,0, B3,128,0, 65536,128,128,1, nullptr,1.f,0,nullptr,0);
    ta_mfma_k<<<dim3(4,4,256),256,0,stream>>>(B1, B2, B3, nbra, pm, percol?1:0, B1);
    mgemm(stream,false,false, B0,128,0, gw,128,0, B1,128,0, 65536,128,128,1, gb,1.f,2,nullptr,2); // wa *= sigmoid(gate)
    // out-projection fused with residual add (4 = transpose-pair write for per-column)
    mgemm(stream,false,false, B1,128,0, ow,128,0, pa,128,0, 65536,128,128,1, ob,1.f,0,nullptr, percol?4:1);
  };
  tri_attn(42, false);  // tas (per-row)
  tri_attn(49, true);   // tae (per-column)

  // ---- 8) pair transition: full-M, H in bf16 spanning B1+B2 ----
  ln128_k<<<16384,256,0,stream>>>(pa, B0, pt_ln, 0);
  ptw1_k<<<dim3(512,4),256,0,stream>>>(B0, pt_w1, pt_b1, (unsigned short*)B1);
  ptw2_k<<<dim3(1024,2),256,0,stream>>>((const unsigned short*)B1, pt_w2, pt_b2, pa);
}

// Round 12
// 1386.357 us; speedup vs baseline: 1.4542x; 1.0564x over previous
//
#include <hip/hip_runtime.h>
#include <math.h>

typedef long long i64;
#define NN_ 65536L

typedef __attribute__((ext_vector_type(8))) short bf16x8;
typedef __attribute__((ext_vector_type(4))) float f32x4;

__device__ inline unsigned short f2bf(float f){
  unsigned int u = __float_as_uint(f);
  return (unsigned short)((u + 0x7FFFu + ((u>>16)&1u)) >> 16);
}

// ---------------- elementwise ----------------
__global__ __launch_bounds__(256) void copy_k(float* __restrict__ d, const float* __restrict__ s, long n){
  long i = (long)blockIdx.x*blockDim.x + threadIdx.x;
  if (i < n) d[i] = s[i];
}

// channel-major [128][65536] -> row-major [65536][128]
__global__ __launch_bounds__(256) void chw2hwc_k(const float* __restrict__ in, float* __restrict__ out){
  __shared__ float t[32][33];
  int r0 = blockIdx.x*32, c0 = blockIdx.y*32;
  int tx = threadIdx.x & 31, ty = threadIdx.x >> 5;
  for (int i = ty; i < 32; i += 8) t[i][tx] = in[(i64)(c0+i)*NN_ + r0 + tx];
  __syncthreads();
  for (int i = ty; i < 32; i += 8) out[(i64)(r0+i)*128 + c0 + tx] = t[tx][i];
}

// row-major [65536][128] -> ch-major [128][65536] with per-row mask
__global__ __launch_bounds__(256) void tr_mask_k(const float* __restrict__ in, const float* __restrict__ mask,
                                                 float* __restrict__ out){
  __shared__ float t[32][33];
  int r0 = blockIdx.x*32, c0 = blockIdx.y*32;
  int tx = threadIdx.x & 31, ty = threadIdx.x >> 5;
  for (int i = ty; i < 32; i += 8) t[i][tx] = in[(i64)(r0+i)*128 + c0 + tx];
  __syncthreads();
  for (int i = ty; i < 32; i += 8) out[(i64)(c0+i)*NN_ + r0 + tx] = t[tx][i] * mask[r0+tx];
}

// ---------------- fused pair-bias features ----------------
// Replaces fp32 gemm_k at N=4 (grid 1024 -> latency regime, R3) + nbQ_k transpose.
// nb[h][q][k] = sum_c X[(q*256+k)*128+c] * W[c*4+h]; one 32MB streaming read, W in LDS.
__global__ __launch_bounds__(256) void feat4_k(const float* __restrict__ X, const float* __restrict__ W,
                                               float* __restrict__ out){
  __shared__ float4 w_s[128];
  int q = blockIdx.x, k = threadIdx.x;
  if (k < 128) w_s[k] = *(const float4*)(W + k*4);
  __syncthreads();
  const float* x = X + ((i64)q*256 + k)*128;
  float a0=0.f, a1=0.f, a2=0.f, a3=0.f;
  #pragma unroll
  for (int c=0;c<128;c+=4){
    float4 v = *(const float4*)(x+c);
    float4 w0 = w_s[c], w1 = w_s[c+1], w2 = w_s[c+2], w3 = w_s[c+3];
    a0 = fmaf(v.x,w0.x,a0); a1 = fmaf(v.x,w0.y,a1); a2 = fmaf(v.x,w0.z,a2); a3 = fmaf(v.x,w0.w,a3);
    a0 = fmaf(v.y,w1.x,a0); a1 = fmaf(v.y,w1.y,a1); a2 = fmaf(v.y,w1.z,a2); a3 = fmaf(v.y,w1.w,a3);
    a0 = fmaf(v.z,w2.x,a0); a1 = fmaf(v.z,w2.y,a1); a2 = fmaf(v.z,w2.z,a2); a3 = fmaf(v.z,w2.w,a3);
    a0 = fmaf(v.w,w3.x,a0); a1 = fmaf(v.w,w3.y,a1); a2 = fmaf(v.w,w3.z,a2); a3 = fmaf(v.w,w3.w,a3);
  }
  i64 o = (i64)q*256 + k;
  out[o] = a0; out[65536+o] = a1; out[131072+o] = a2; out[196608+o] = a3;
}

// nb[(q*256+k)*8+h] = sum_c X[(q*256+k)*128+c] * W[c*8+h]  (row attention, H=8)
__global__ __launch_bounds__(256) void feat8_k(const float* __restrict__ X, const float* __restrict__ W,
                                               float* __restrict__ out){
  __shared__ float w_s[128][8];
  int q = blockIdx.x, k = threadIdx.x;
  for (int i = k; i < 1024; i += 256) ((float*)w_s)[i] = W[i];
  __syncthreads();
  const float* x = X + ((i64)q*256 + k)*128;
  float acc[8] = {};
  #pragma unroll
  for (int c=0;c<128;c+=4){
    float4 v = *(const float4*)(x+c);
    #pragma unroll
    for (int h=0;h<8;h++){
      acc[h] = fmaf(v.x, w_s[c  ][h], acc[h]);
      acc[h] = fmaf(v.y, w_s[c+1][h], acc[h]);
      acc[h] = fmaf(v.z, w_s[c+2][h], acc[h]);
      acc[h] = fmaf(v.w, w_s[c+3][h], acc[h]);
    }
  }
  float* o = out + ((i64)q*256 + k)*8;
  *(float4*)o     = make_float4(acc[0],acc[1],acc[2],acc[3]);
  *(float4*)(o+4) = make_float4(acc[4],acc[5],acc[6],acc[7]);
}

// ---------------- LayerNorm generic (rowwise, C arbitrary) ----------------
__global__ __launch_bounds__(128) void ln_k(const float* __restrict__ in, float* __restrict__ out,
                                            const float* __restrict__ w, int C){
  i64 row = blockIdx.x;
  const float* x = in + row*C;
  float* y = out + row*C;
  int tid = threadIdx.x;
  float s=0.f, s2=0.f;
  for (int c=tid;c<C;c+=128){ float v = x[c]; s += v; s2 += v*v; }
  __shared__ float rs[128], rq[128];
  rs[tid]=s; rq[tid]=s2; __syncthreads();
  for (int off=64;off>0;off>>=1){ if (tid<off){ rs[tid]+=rs[tid+off]; rq[tid]+=rq[tid+off]; } __syncthreads(); }
  float mu = rs[0]/C;
  float var = rq[0]/C - mu*mu;
  float inv = rsqrtf(var + 1e-5f);
  for (int c=tid;c<C;c+=128) y[c] = (x[c]-mu)*inv*w[c] + w[C+c];
}

// ---------------- LayerNorm C=128: one wave per row, shuffle-only reduction ----------------
// T=1: read row rt = transpose-pair index of row (fused pa transpose for per-column attention)
__global__ __launch_bounds__(256) void ln128_k(const float* __restrict__ in, float* __restrict__ out,
                                               const float* __restrict__ w, int T){
  int wv = threadIdx.x >> 6, lane = threadIdx.x & 63;
  i64 row = (i64)blockIdx.x*4 + wv;
  i64 rr = T ? (i64)((((int)row & 255) << 8) | ((int)row >> 8)) : row;
  float2 v = *(const float2*)(in + rr*128 + lane*2);
  float s = v.x + v.y, s2 = v.x*v.x + v.y*v.y;
  #pragma unroll
  for (int off=32; off; off>>=1){ s += __shfl_down(s, off); s2 += __shfl_down(s2, off); }
  s = __shfl(s, 0); s2 = __shfl(s2, 0);
  float mu = s*(1.f/128.f);
  float var = s2*(1.f/128.f) - mu*mu;
  float inv = rsqrtf(var + 1e-5f);
  float2 wl = *(const float2*)(w + lane*2);
  float2 wb = *(const float2*)(w + 128 + lane*2);
  float2 y; y.x = (v.x-mu)*inv*wl.x + wb.x; y.y = (v.y-mu)*inv*wl.y + wb.y;
  *(float2*)(out + row*128 + lane*2) = y;
}

// ---------------- bf16 MFMA GEMM: 128x128 tile, 256 thr (2x2 waves of 64x64) ----------------
// combine: 0 store, 1 +=, 2 *=, 3: C += aux*v, 4: C[transpose-pair(m)] += v (pair tensor only)
template<bool TA, bool TB>
__global__ __launch_bounds__(256) void mgemm_k(
    const float* __restrict__ A, int lda, i64 sA,
    const float* __restrict__ B, int ldb, i64 sB,
    float* __restrict__ C, int ldc, i64 sC,
    int M, int N, int K,
    const float* __restrict__ bias, float scale, int act,
    const float* __restrict__ rowmul, int combine, const float* __restrict__ aux)
{
  A += (i64)blockIdx.z * sA;
  B += (i64)blockIdx.z * sB;
  C += (i64)blockIdx.z * sC;
  int m0 = blockIdx.x * 128, n0 = blockIdx.y * 128;
  int tid = threadIdx.x;
  int wave = tid >> 6, lane = tid & 63;
  int quad = lane >> 4, mr = lane & 15;
  int wm = (wave >> 1) * 64, wn = (wave & 1) * 64;
  __shared__ unsigned short As[128][40];
  __shared__ unsigned short Bs[128][40];
  f32x4 acc[4][4];
  #pragma unroll
  for (int i=0;i<4;i++)
    #pragma unroll
    for (int j=0;j<4;j++) acc[i][j] = (f32x4){0.f,0.f,0.f,0.f};

  for (int k0 = 0; k0 < K; k0 += 32){
    if (!TA){
      #pragma unroll
      for (int it=0; it<4; it++){
        int lin = tid + it*256;
        int r = lin >> 3, c4 = (lin & 7) * 4;
        float4 g = *(const float4*)&A[(i64)(m0+r)*lda + k0 + c4];
        As[r][c4]   = f2bf(g.x); As[r][c4+1] = f2bf(g.y);
        As[r][c4+2] = f2bf(g.z); As[r][c4+3] = f2bf(g.w);
      }
    } else {
      #pragma unroll
      for (int it=0; it<4; it++){
        int lin = tid + it*256;
        int m = lin & 127, kg = (lin >> 7) * 4;
        float v0 = A[(i64)(k0+kg  )*lda + m0 + m];
        float v1 = A[(i64)(k0+kg+1)*lda + m0 + m];
        float v2 = A[(i64)(k0+kg+2)*lda + m0 + m];
        float v3 = A[(i64)(k0+kg+3)*lda + m0 + m];
        As[m][kg] = f2bf(v0); As[m][kg+1] = f2bf(v1);
        As[m][kg+2] = f2bf(v2); As[m][kg+3] = f2bf(v3);
      }
    }
    if (!TB){
      #pragma unroll
      for (int it=0; it<4; it++){
        int lin = tid + it*256;
        int n = lin & 127, kg = (lin >> 7) * 4;
        float v0 = B[(i64)(k0+kg  )*ldb + n0 + n];
        float v1 = B[(i64)(k0+kg+1)*ldb + n0 + n];
        float v2 = B[(i64)(k0+kg+2)*ldb + n0 + n];
        float v3 = B[(i64)(k0+kg+3)*ldb + n0 + n];
        Bs[n][kg] = f2bf(v0); Bs[n][kg+1] = f2bf(v1);
        Bs[n][kg+2] = f2bf(v2); Bs[n][kg+3] = f2bf(v3);
      }
    } else {
      #pragma unroll
      for (int it=0; it<4; it++){
        int lin = tid + it*256;
        int r = lin >> 3, c4 = (lin & 7) * 4;
        float4 g = *(const float4*)&B[(i64)(n0+r)*ldb + k0 + c4];
        Bs[r][c4]   = f2bf(g.x); Bs[r][c4+1] = f2bf(g.y);
        Bs[r][c4+2] = f2bf(g.z); Bs[r][c4+3] = f2bf(g.w);
      }
    }
    __syncthreads();
    bf16x8 af[4], bfr[4];
    #pragma unroll
    for (int i=0;i<4;i++) af[i]  = *(const bf16x8*)&As[wm + i*16 + mr][quad*8];
    #pragma unroll
    for (int j=0;j<4;j++) bfr[j] = *(const bf16x8*)&Bs[wn + j*16 + mr][quad*8];
    #pragma unroll
    for (int i=0;i<4;i++)
      #pragma unroll
      for (int j=0;j<4;j++)
        acc[i][j] = __builtin_amdgcn_mfma_f32_16x16x32_bf16(af[i], bfr[j], acc[i][j], 0, 0, 0);
    __syncthreads();
  }
  #pragma unroll
  for (int i=0;i<4;i++){
    #pragma unroll
    for (int r=0;r<4;r++){
      int m = m0 + wm + i*16 + quad*4 + r;
      float rm = rowmul ? rowmul[m] : 1.f;
      i64 mrow = (combine == 4) ? (i64)(((m & 255) << 8) | (m >> 8)) : (i64)m;
      #pragma unroll
      for (int j=0;j<4;j++){
        int n = n0 + wn + j*16 + mr;
        float v = acc[i][j][r] * scale;
        if (bias) v += bias[n];
        if (act == 1) v = fmaxf(v, 0.f);
        else if (act == 2) v = 1.f/(1.f + __expf(-v));
        v *= rm;
        i64 idx = mrow*ldc + n;
        if (combine == 0) C[idx] = v;
        else if (combine == 1 || combine == 4) C[idx] += v;
        else if (combine == 2) C[idx] *= v;
        else C[idx] += aux[(i64)m*ldc + n] * v;
      }
    }
  }
}

// ---------------- bf16 MFMA GEMM: 64x64 tile, 256 thr (2x2 waves of 32x32) ----------------
// For dispatches whose 128-tile grid is <1024 blocks (2 blocks/CU): R3 showed tri-mult batched
// GEMM at grid 512 -> Occupancy 10.8%, MfmaUtil 1.8%, VALUBusy 5% (pure latency, 85 us).
// 64x64 tiles quadruple the grid (2048 blocks -> 6-8 blocks/CU); LDS 10 KB.
// NOTE (R5-R9): routing pt_w1 (M=32768,N=512,K=128,ldb=512) through this kernel correlates
// 4:0 with container failure; mechanism unknown. Do NOT route that shape here.
template<bool TA, bool TB>
__global__ __launch_bounds__(256) void mgemm64_k(
    const float* __restrict__ A, int lda, i64 sA,
    const float* __restrict__ B, int ldb, i64 sB,
    float* __restrict__ C, int ldc, i64 sC,
    int M, int N, int K,
    const float* __restrict__ bias, float scale, int act,
    const float* __restrict__ rowmul, int combine, const float* __restrict__ aux)
{
  A += (i64)blockIdx.z * sA;
  B += (i64)blockIdx.z * sB;
  C += (i64)blockIdx.z * sC;
  int m0 = blockIdx.x * 64, n0 = blockIdx.y * 64;
  int tid = threadIdx.x;
  int wave = tid >> 6, lane = tid & 63;
  int quad = lane >> 4, mr = lane & 15;
  int wm = (wave >> 1) * 32, wn = (wave & 1) * 32;
  __shared__ unsigned short As[64][40];
  __shared__ unsigned short Bs[64][40];
  f32x4 acc[2][2];
  #pragma unroll
  for (int i=0;i<2;i++)
    #pragma unroll
    for (int j=0;j<2;j++) acc[i][j] = (f32x4){0.f,0.f,0.f,0.f};

  for (int k0 = 0; k0 < K; k0 += 32){
    if (!TA){
      #pragma unroll
      for (int it=0; it<2; it++){
        int lin = tid + it*256;
        int r = lin >> 3, c4 = (lin & 7) * 4;
        float4 g = *(const float4*)&A[(i64)(m0+r)*lda + k0 + c4];
        As[r][c4]   = f2bf(g.x); As[r][c4+1] = f2bf(g.y);
        As[r][c4+2] = f2bf(g.z); As[r][c4+3] = f2bf(g.w);
      }
    } else {
      #pragma unroll
      for (int it=0; it<2; it++){
        int lin = tid + it*256;
        int m = lin & 63, kg = (lin >> 6) * 4;
        float v0 = A[(i64)(k0+kg  )*lda + m0 + m];
        float v1 = A[(i64)(k0+kg+1)*lda + m0 + m];
        float v2 = A[(i64)(k0+kg+2)*lda + m0 + m];
        float v3 = A[(i64)(k0+kg+3)*lda + m0 + m];
        As[m][kg] = f2bf(v0); As[m][kg+1] = f2bf(v1);
        As[m][kg+2] = f2bf(v2); As[m][kg+3] = f2bf(v3);
      }
    }
    if (!TB){
      #pragma unroll
      for (int it=0; it<2; it++){
        int lin = tid + it*256;
        int n = lin & 63, kg = (lin >> 6) * 4;
        float v0 = B[(i64)(k0+kg  )*ldb + n0 + n];
        float v1 = B[(i64)(k0+kg+1)*ldb + n0 + n];
        float v2 = B[(i64)(k0+kg+2)*ldb + n0 + n];
        float v3 = B[(i64)(k0+kg+3)*ldb + n0 + n];
        Bs[n][kg] = f2bf(v0); Bs[n][kg+1] = f2bf(v1);
        Bs[n][kg+2] = f2bf(v2); Bs[n][kg+3] = f2bf(v3);
      }
    } else {
      #pragma unroll
      for (int it=0; it<2; it++){
        int lin = tid + it*256;
        int r = lin >> 3, c4 = (lin & 7) * 4;
        float4 g = *(const float4*)&B[(i64)(n0+r)*ldb + k0 + c4];
        Bs[r][c4]   = f2bf(g.x); Bs[r][c4+1] = f2bf(g.y);
        Bs[r][c4+2] = f2bf(g.z); Bs[r][c4+3] = f2bf(g.w);
      }
    }
    __syncthreads();
    bf16x8 af[2], bfr[2];
    #pragma unroll
    for (int i=0;i<2;i++) af[i]  = *(const bf16x8*)&As[wm + i*16 + mr][quad*8];
    #pragma unroll
    for (int j=0;j<2;j++) bfr[j] = *(const bf16x8*)&Bs[wn + j*16 + mr][quad*8];
    #pragma unroll
    for (int i=0;i<2;i++)
      #pragma unroll
      for (int j=0;j<2;j++)
        acc[i][j] = __builtin_amdgcn_mfma_f32_16x16x32_bf16(af[i], bfr[j], acc[i][j], 0, 0, 0);
    __syncthreads();
  }
  #pragma unroll
  for (int i=0;i<2;i++){
    #pragma unroll
    for (int r=0;r<4;r++){
      int m = m0 + wm + i*16 + quad*4 + r;
      float rm = rowmul ? rowmul[m] : 1.f;
      i64 mrow = (combine == 4) ? (i64)(((m & 255) << 8) | (m >> 8)) : (i64)m;
      #pragma unroll
      for (int j=0;j<2;j++){
        int n = n0 + wn + j*16 + mr;
        float v = acc[i][j][r] * scale;
        if (bias) v += bias[n];
        if (act == 1) v = fmaxf(v, 0.f);
        else if (act == 2) v = 1.f/(1.f + __expf(-v));
        v *= rm;
        i64 idx = mrow*ldc + n;
        if (combine == 0) C[idx] = v;
        else if (combine == 1 || combine == 4) C[idx] += v;
        else if (combine == 2) C[idx] *= v;
        else C[idx] += aux[(i64)m*ldc + n] * v;
      }
    }
  }
}

// ---------------- fused dual-MFMA lin*sigmoid(gate) for tri-mult ----------------
// 64x64 tile; grid (1024, 2) = 2048 blocks; LDS 15 KB.
__global__ __launch_bounds__(256) void mlrgate_k(
    const float* __restrict__ X,
    const float* __restrict__ Wl, const float* __restrict__ bl,
    const float* __restrict__ Wg, const float* __restrict__ bg,
    float* __restrict__ Out)
{
  int m0 = blockIdx.x * 64, n0 = blockIdx.y * 64;
  int tid = threadIdx.x;
  int wave = tid >> 6, lane = tid & 63;
  int quad = lane >> 4, mr = lane & 15;
  int wm = (wave >> 1) * 32, wn = (wave & 1) * 32;
  __shared__ unsigned short As[64][40], B1s[64][40], B2s[64][40];
  f32x4 acc1[2][2], acc2[2][2];
  #pragma unroll
  for (int i=0;i<2;i++)
    #pragma unroll
    for (int j=0;j<2;j++){ acc1[i][j] = (f32x4){0,0,0,0}; acc2[i][j] = (f32x4){0,0,0,0}; }

  for (int k0 = 0; k0 < 128; k0 += 32){
    #pragma unroll
    for (int it=0; it<2; it++){
      int lin = tid + it*256;
      int r = lin >> 3, c4 = (lin & 7) * 4;
      float4 g = *(const float4*)&X[(i64)(m0+r)*128 + k0 + c4];
      As[r][c4]   = f2bf(g.x); As[r][c4+1] = f2bf(g.y);
      As[r][c4+2] = f2bf(g.z); As[r][c4+3] = f2bf(g.w);
    }
    #pragma unroll
    for (int it=0; it<2; it++){
      int lin = tid + it*256;
      int n = lin & 63, kg = (lin >> 6) * 4;
      float a0 = Wl[(i64)(k0+kg  )*128 + n0 + n];
      float a1 = Wl[(i64)(k0+kg+1)*128 + n0 + n];
      float a2 = Wl[(i64)(k0+kg+2)*128 + n0 + n];
      float a3 = Wl[(i64)(k0+kg+3)*128 + n0 + n];
      B1s[n][kg] = f2bf(a0); B1s[n][kg+1] = f2bf(a1);
      B1s[n][kg+2] = f2bf(a2); B1s[n][kg+3] = f2bf(a3);
      float g0 = Wg[(i64)(k0+kg  )*128 + n0 + n];
      float g1 = Wg[(i64)(k0+kg+1)*128 + n0 + n];
      float g2 = Wg[(i64)(k0+kg+2)*128 + n0 + n];
      float g3 = Wg[(i64)(k0+kg+3)*128 + n0 + n];
      B2s[n][kg] = f2bf(g0); B2s[n][kg+1] = f2bf(g1);
      B2s[n][kg+2] = f2bf(g2); B2s[n][kg+3] = f2bf(g3);
    }
    __syncthreads();
    bf16x8 af[2], b1f[2], b2f[2];
    #pragma unroll
    for (int i=0;i<2;i++) af[i]  = *(const bf16x8*)&As[wm + i*16 + mr][quad*8];
    #pragma unroll
    for (int j=0;j<2;j++){
      b1f[j] = *(const bf16x8*)&B1s[wn + j*16 + mr][quad*8];
      b2f[j] = *(const bf16x8*)&B2s[wn + j*16 + mr][quad*8];
    }
    #pragma unroll
    for (int i=0;i<2;i++)
      #pragma unroll
      for (int j=0;j<2;j++){
        acc1[i][j] = __builtin_amdgcn_mfma_f32_16x16x32_bf16(af[i], b1f[j], acc1[i][j], 0, 0, 0);
        acc2[i][j] = __builtin_amdgcn_mfma_f32_16x16x32_bf16(af[i], b2f[j], acc2[i][j], 0, 0, 0);
      }
    __syncthreads();
  }
  #pragma unroll
  for (int i=0;i<2;i++){
    #pragma unroll
    for (int r=0;r<4;r++){
      int m = m0 + wm + i*16 + quad*4 + r;
      #pragma unroll
      for (int j=0;j<2;j++){
        int n = wn + j*16 + mr;
        float lv = acc1[i][j][r] + bl[n0 + n];
        float gv = acc2[i][j][r] + bg[n0 + n];
        Out[(i64)m*128 + n0 + n] = lv * (1.f/(1.f + __expf(-gv)));
      }
    }
  }
}

// ---------------- pair transition, stage 1: H(bf16) = relu(X @ W1 + b1) ----------------
// Full M=65536, N=512, K=128 -> grid (512,4) = 2048 blocks, 8/CU. H stored bf16.
__global__ __launch_bounds__(256) void ptw1_k(
    const float* __restrict__ X, const float* __restrict__ W1,
    const float* __restrict__ b1, unsigned short* __restrict__ H)
{
  int m0 = blockIdx.x * 128, n0 = blockIdx.y * 128;
  int tid = threadIdx.x;
  int wave = tid >> 6, lane = tid & 63;
  int quad = lane >> 4, mr = lane & 15;
  int wm = (wave >> 1) * 64, wn = (wave & 1) * 64;
  __shared__ unsigned short As[128][40];
  __shared__ unsigned short Bs[128][40];
  f32x4 acc[4][4];
  #pragma unroll
  for (int i=0;i<4;i++)
    #pragma unroll
    for (int j=0;j<4;j++) acc[i][j] = (f32x4){0.f,0.f,0.f,0.f};

  for (int k0 = 0; k0 < 128; k0 += 32){
    #pragma unroll
    for (int it=0; it<4; it++){
      int lin = tid + it*256;
      int r = lin >> 3, c4 = (lin & 7) * 4;
      float4 g = *(const float4*)&X[(i64)(m0+r)*128 + k0 + c4];
      As[r][c4]   = f2bf(g.x); As[r][c4+1] = f2bf(g.y);
      As[r][c4+2] = f2bf(g.z); As[r][c4+3] = f2bf(g.w);
    }
    #pragma unroll
    for (int it=0; it<4; it++){
      int lin = tid + it*256;
      int n = lin & 127, kg = (lin >> 7) * 4;
      float v0 = W1[(i64)(k0+kg  )*512 + n0 + n];
      float v1 = W1[(i64)(k0+kg+1)*512 + n0 + n];
      float v2 = W1[(i64)(k0+kg+2)*512 + n0 + n];
      float v3 = W1[(i64)(k0+kg+3)*512 + n0 + n];
      Bs[n][kg] = f2bf(v0); Bs[n][kg+1] = f2bf(v1);
      Bs[n][kg+2] = f2bf(v2); Bs[n][kg+3] = f2bf(v3);
    }
    __syncthreads();
    bf16x8 af[4], bfr[4];
    #pragma unroll
    for (int i=0;i<4;i++) af[i]  = *(const bf16x8*)&As[wm + i*16 + mr][quad*8];
    #pragma unroll
    for (int j=0;j<4;j++) bfr[j] = *(const bf16x8*)&Bs[wn + j*16 + mr][quad*8];
    #pragma unroll
    for (int i=0;i<4;i++)
      #pragma unroll
      for (int j=0;j<4;j++)
        acc[i][j] = __builtin_amdgcn_mfma_f32_16x16x32_bf16(af[i], bfr[j], acc[i][j], 0, 0, 0);
    __syncthreads();
  }
  #pragma unroll
  for (int i=0;i<4;i++){
    #pragma unroll
    for (int r=0;r<4;r++){
      int m = m0 + wm + i*16 + quad*4 + r;
      #pragma unroll
      for (int j=0;j<4;j++){
        int n = n0 + wn + j*16 + mr;
        float v = fmaxf(acc[i][j][r] + b1[n], 0.f);
        H[(i64)m*512 + n] = f2bf(v);
      }
    }
  }
}

// ---------------- pair transition, stage 2: pa += H(bf16) @ W2 + b2 ----------------
// 64x64 tile; M=65536, N=128, K=512 -> grid (1024,2) = 2048 blocks.
__global__ __launch_bounds__(256) void ptw2_k(
    const unsigned short* __restrict__ H, const float* __restrict__ W2,
    const float* __restrict__ b2, float* __restrict__ pa)
{
  int m0 = blockIdx.x * 64, n0 = blockIdx.y * 64;
  int tid = threadIdx.x;
  int wave = tid >> 6, lane = tid & 63;
  int quad = lane >> 4, mr = lane & 15;
  int wm = (wave >> 1) * 32, wn = (wave & 1) * 32;
  __shared__ unsigned short As[64][40];
  __shared__ unsigned short Bs[64][40];
  f32x4 acc[2][2];
  #pragma unroll
  for (int i=0;i<2;i++)
    #pragma unroll
    for (int j=0;j<2;j++) acc[i][j] = (f32x4){0.f,0.f,0.f,0.f};

  for (int k0 = 0; k0 < 512; k0 += 32){
    #pragma unroll
    for (int it=0; it<2; it++){
      int lin = tid + it*256;
      int r = lin >> 3, c4 = (lin & 7) * 4;
      *(uint2*)&As[r][c4] = *(const uint2*)&H[(i64)(m0+r)*512 + k0 + c4];
    }
    #pragma unroll
    for (int it=0; it<2; it++){
      int lin = tid + it*256;
      int n = lin & 63, kg = (lin >> 6) * 4;
      float v0 = W2[(i64)(k0+kg  )*128 + n0 + n];
      float v1 = W2[(i64)(k0+kg+1)*128 + n0 + n];
      float v2 = W2[(i64)(k0+kg+2)*128 + n0 + n];
      float v3 = W2[(i64)(k0+kg+3)*128 + n0 + n];
      Bs[n][kg] = f2bf(v0); Bs[n][kg+1] = f2bf(v1);
      Bs[n][kg+2] = f2bf(v2); Bs[n][kg+3] = f2bf(v3);
    }
    __syncthreads();
    bf16x8 af[2], bfr[2];
    #pragma unroll
    for (int i=0;i<2;i++) af[i]  = *(const bf16x8*)&As[wm + i*16 + mr][quad*8];
    #pragma unroll
    for (int j=0;j<2;j++) bfr[j] = *(const bf16x8*)&Bs[wn + j*16 + mr][quad*8];
    #pragma unroll
    for (int i=0;i<2;i++)
      #pragma unroll
      for (int j=0;j<2;j++)
        acc[i][j] = __builtin_amdgcn_mfma_f32_16x16x32_bf16(af[i], bfr[j], acc[i][j], 0, 0, 0);
    __syncthreads();
  }
  #pragma unroll
  for (int i=0;i<2;i++){
    #pragma unroll
    for (int r=0;r<4;r++){
      int m = m0 + wm + i*16 + quad*4 + r;
      #pragma unroll
      for (int j=0;j<2;j++){
        int n = n0 + wn + j*16 + mr;
        pa[(i64)m*128 + n] += acc[i][j][r] + b2[n];
      }
    }
  }
}

// ---------------- generic batched GEMM (fp32, 64x64 tile) ----------------
template<bool TA, bool TB>
__global__ __launch_bounds__(256) void gemm_k(
    const float* __restrict__ A, int lda, i64 sA,
    const float* __restrict__ B, int ldb, i64 sB,
    float* __restrict__ C, int ldc, i64 sC,
    int M, int N, int K,
    const float* __restrict__ bias, float scale, int act,
    const float* __restrict__ rowmul, int combine)
{
  A += (i64)blockIdx.z * sA;
  B += (i64)blockIdx.z * sB;
  C += (i64)blockIdx.z * sC;
  int m0 = blockIdx.x * 64, n0 = blockIdx.y * 64;
  int tid = threadIdx.x, tx = tid & 15, ty = tid >> 4;
  __shared__ float As[16][68], Bs[16][68];
  float acc[4][4] = {};
  for (int k0 = 0; k0 < K; k0 += 16){
    if (TA){
      for (int l = tid; l < 1024; l += 256){
        int kk = l >> 6, mi = l & 63; int m = m0 + mi;
        As[kk][mi] = (m < M) ? A[(i64)(k0+kk)*lda + m] : 0.f;
      }
    } else {
      for (int l = tid; l < 1024; l += 256){
        int mi = l >> 4, kk = l & 15; int m = m0 + mi;
        As[kk][mi] = (m < M) ? A[(i64)m*lda + k0 + kk] : 0.f;
      }
    }
    if (TB){
      for (int l = tid; l < 1024; l += 256){
        int ni = l >> 4, kk = l & 15; int n = n0 + ni;
        Bs[kk][ni] = (n < N) ? B[(i64)n*ldb + k0 + kk] : 0.f;
      }
    } else {
      for (int l = tid; l < 1024; l += 256){
        int kk = l >> 6, ni = l & 63; int n = n0 + ni;
        Bs[kk][ni] = (n < N) ? B[(i64)(k0+kk)*ldb + n] : 0.f;
      }
    }
    __syncthreads();
    #pragma unroll
    for (int kk = 0; kk < 16; ++kk){
      float4 av4 = *(const float4*)&As[kk][ty*4];
      float4 bv4 = *(const float4*)&Bs[kk][tx*4];
      float av[4] = {av4.x, av4.y, av4.z, av4.w};
      float bv[4] = {bv4.x, bv4.y, bv4.z, bv4.w};
      #pragma unroll
      for (int i=0;i<4;i++)
        #pragma unroll
        for (int j=0;j<4;j++) acc[i][j] = fmaf(av[i], bv[j], acc[i][j]);
    }
    __syncthreads();
  }
  #pragma unroll
  for (int i=0;i<4;i++){
    int m = m0 + ty*4 + i;
    if (m >= M) continue;
    float rm = rowmul ? rowmul[m] : 1.f;
    #pragma unroll
    for (int j=0;j<4;j++){
      int n = n0 + tx*4 + j;
      if (n >= N) continue;
      float v = acc[i][j] * scale;
      if (bias) v += bias[n];
      if (act == 1) v = fmaxf(v, 0.f);
      else if (act == 2) v = 1.f/(1.f + expf(-v));
      v *= rm;
      i64 idx = (i64)m*ldc + n;
      if (combine == 0) C[idx] = v;
      else if (combine == 1) C[idx] += v;
      else C[idx] *= v;
    }
  }
}

// ---------------- thin GEMM (small M): split-K two-phase ----------------
__global__ __launch_bounds__(256) void gemm_part_k(
    const float* __restrict__ A, int lda,
    const float* __restrict__ B, int ldb,
    float* __restrict__ Cp, int M, int N, int K, int chunk)
{
  int m0 = blockIdx.x*16, n0 = blockIdx.y*64, z = blockIdx.z;
  int kb = z*chunk, ke = min(K, kb+chunk);
  int tid = threadIdx.x;
  int mi = tid >> 4, ni4 = (tid & 15)*4;
  __shared__ float As[16][17], Bs[16][68];
  float acc[4] = {0.f,0.f,0.f,0.f};
  for (int k0 = kb; k0 < ke; k0 += 16){
    { int r = tid>>4, c = tid&15; int m = m0+r;
      As[c][r] = (m < M) ? A[(i64)m*lda + k0 + c] : 0.f; }
    for (int l = tid; l < 1024; l += 256){
      int kk = l>>6, nn = l&63; int n = n0+nn;
      Bs[kk][nn] = (n < N) ? B[(i64)(k0+kk)*ldb + n] : 0.f;
    }
    __syncthreads();
    #pragma unroll
    for (int kk=0;kk<16;kk++){
      float a = As[kk][mi];
      float4 b = *(const float4*)&Bs[kk][ni4];
      acc[0]=fmaf(a,b.x,acc[0]); acc[1]=fmaf(a,b.y,acc[1]);
      acc[2]=fmaf(a,b.z,acc[2]); acc[3]=fmaf(a,b.w,acc[3]);
    }
    __syncthreads();
  }
  int m = m0+mi, n = n0+ni4;
  if (m < M && n < N) *(float4*)&Cp[((i64)z*M + m)*N + n] = *(float4*)acc;
}

__global__ __launch_bounds__(256) void gemm_reduce_k(
    const float* __restrict__ Cp, float* __restrict__ C, int ldc,
    int M, int N, int S,
    const float* __restrict__ bias, float scale, int act,
    const float* __restrict__ rowmul, int combine)
{
  i64 idx = (i64)blockIdx.x*256 + threadIdx.x;
  if (idx >= (i64)M*N) return;
  int m = (int)(idx / N), n = (int)(idx % N);
  float s = 0.f;
  for (int z=0; z<S; z++) s += Cp[(i64)z*M*N + idx];
  float v = s*scale;
  if (bias) v += bias[n];
  if (act == 1) v = fmaxf(v, 0.f);
  else if (act == 2) v = 1.f/(1.f + expf(-v));
  if (rowmul) v *= rowmul[m];
  i64 o = (i64)m*ldc + n;
  if (combine == 0) C[o] = v;
  else if (combine == 1) C[o] += v;
  else C[o] *= v;
}

// ---------------- OPM ----------------
__global__ __launch_bounds__(128) void opm_wd_k(const float* __restrict__ right, const float* __restrict__ W,
                                                float* __restrict__ Wd){
  int d = blockIdx.x, c = blockIdx.y, f = threadIdx.x;
  float acc = 0.f;
  #pragma unroll
  for (int e=0;e<32;e++) acc = fmaf(right[d*32+e], W[((i64)c*32+e)*128 + f], acc);
  Wd[((i64)d*32+c)*128 + f] = acc;
}

// pa[d,b,f] = pair_act[d,b,f] + (sum_c left[b,c]*Wd[d,c,f] + ob[f]) / (1e-3 + sm[d]*sm[b])
__global__ __launch_bounds__(128) void opm_final_k(const float* __restrict__ left, const float* __restrict__ Wd,
                                                   const float* __restrict__ ob, const float* __restrict__ sm,
                                                   const float* __restrict__ pair_act, float* __restrict__ pa){
  int d = blockIdx.x, b0 = blockIdx.y*16, f = threadIdx.x;
  __shared__ float wd_s[32][128];
  __shared__ float l_s[16][32];
  for (int c=0;c<32;c++) wd_s[c][f] = Wd[((i64)d*32+c)*128 + f];
  for (int l = f; l < 512; l += 128){ int bi=l>>5, c=l&31; l_s[bi][c] = left[(b0+bi)*32 + c]; }
  __syncthreads();
  float md = sm[d], obf = ob[f];
  for (int bi=0;bi<16;bi++){
    float acc = 0.f;
    #pragma unroll
    for (int c=0;c<32;c++) acc = fmaf(l_s[bi][c], wd_s[c][f], acc);
    int b = b0+bi;
    i64 idx = ((i64)d*256 + b)*128 + f;
    pa[idx] = pair_act[idx] + (acc + obf) / (1e-3f + md*sm[b]);
  }
}

// ---------------- row attention core ----------------
__global__ __launch_bounds__(256) void ra_attn_k(const float* __restrict__ q, const float* __restrict__ k,
                                                 const float* __restrict__ v, const float* __restrict__ nb,
                                                 const float* __restrict__ sm, float* __restrict__ wa){
  int qi = blockIdx.x, h = blockIdx.y, tid = threadIdx.x;
  __shared__ float qv[48];
  __shared__ float p[256];
  __shared__ float red[256];
  if (tid < 48) qv[tid] = q[(i64)qi*384 + h*48 + tid];
  __syncthreads();
  float acc = 0.f;
  const float* kr = k + (i64)tid*384 + h*48;
  #pragma unroll
  for (int c=0;c<48;c++) acc = fmaf(qv[c], kr[c], acc);
  acc += 1e9f*(sm[tid]-1.f) + nb[((i64)qi*256 + tid)*8 + h];
  red[tid] = acc; __syncthreads();
  for (int off=128;off>0;off>>=1){ if (tid<off) red[tid] = fmaxf(red[tid], red[tid+off]); __syncthreads(); }
  float mx = red[0]; __syncthreads();
  float e = expf(acc - mx);
  red[tid] = e; __syncthreads();
  for (int off=128;off>0;off>>=1){ if (tid<off) red[tid] += red[tid+off]; __syncthreads(); }
  p[tid] = e / red[0];
  __syncthreads();
  if (tid < 48){
    float a = 0.f;
    for (int kk=0;kk<256;kk++) a = fmaf(p[kk], v[(i64)kk*384 + h*48 + tid], a);
    wa[(i64)qi*384 + h*48 + tid] = a;
  }
}

// ---------------- triangle attention core v8: swapped-operand MFMA flash + XCD swizzle ----
// R11: dur == bytes/BW (2.55 TB/s) -> traffic-limited; FETCH 150MB vs 97 ideal. Cause: grid
// (4,4,256) round-robins XCDs, so the 16 blocks sharing one b's K/V land on 8 XCDs (L2
// duplication) and the 4 h-blocks' partial-line O writes RFO separately. Fix: flat grid 4096,
// dispatch d -> xcd = d%8 (HW round-robin); assign all 16 (qblk,h) of b = xcd*32 + (d>>3)/16
// to one XCD. K/V fetched once per XCD; O-write lines combine in that XCD's L2.
__global__ __launch_bounds__(256, 6) void ta_mfma_k(
    const float* __restrict__ q, const float* __restrict__ k, const float* __restrict__ v,
    const float* __restrict__ nbQ, const float* __restrict__ mask, int maskT,
    float* __restrict__ wa)
{
  int d = blockIdx.x;
  int xcd = d & 7, y = d >> 3;
  int b = xcd*32 + (y >> 4);
  int w = y & 15;
  int qblk = w & 3, h = w >> 2;
  int tid = threadIdx.x;
  int wave = tid >> 6, lane = tid & 63;
  int quad = lane >> 4, mr = lane & 15;
  const i64 base = ((i64)b*256)*128 + h*32;

  __shared__ __align__(16) unsigned short Ks[128][40];   // [key][c], row 80B
  __shared__ __align__(16) unsigned short Vt[32][136];   // [c][key], row 272B
  __shared__ __align__(16) float mask_s[256];
  __shared__ __align__(16) unsigned short Pl[4][16][40]; // per-wave P [q][key]

  mask_s[tid] = 1e9f * ((maskT ? mask[(i64)tid*256 + b] : mask[(i64)b*256 + tid]) - 1.f);

  int q0w = qblk*64 + wave*16;
  int qg = q0w + mr;                      // this lane's q row (fixed for whole kernel)
  const float* nbq = nbQ + (i64)h*65536 + (i64)qg*256;

  // Q as B-operand fragment: [n=q=mr][k-ch quad*8..+7]
  bf16x8 qf;
  {
    const float* qp = q + base + (i64)qg*128 + quad*8;
    float4 a = *(const float4*)qp;
    float4 c = *(const float4*)(qp+4);
    qf[0]=(short)f2bf(a.x); qf[1]=(short)f2bf(a.y); qf[2]=(short)f2bf(a.z); qf[3]=(short)f2bf(a.w);
    qf[4]=(short)f2bf(c.x); qf[5]=(short)f2bf(c.y); qf[6]=(short)f2bf(c.z); qf[7]=(short)f2bf(c.w);
  }

  f32x4 o0 = (f32x4){0,0,0,0}, o1 = (f32x4){0,0,0,0}; // O^T[c=quad*4+r(+16)][q=mr]
  float mm = -1e30f, ll = 0.f;                         // per-lane softmax state (q = qg)

  for (int half = 0; half < 2; half++){
    __syncthreads();
    #pragma unroll
    for (int it=0; it<4; it++){
      int idx = it*256 + tid;              // 128 keys x 32 ch
      int kl = idx >> 3, c4 = (idx & 7)*4;
      i64 roff = base + (i64)(half*128 + kl)*128 + c4;
      float4 g  = *(const float4*)(k + roff);
      unsigned int w0 = (unsigned int)f2bf(g.x) | ((unsigned int)f2bf(g.y)<<16);
      unsigned int w1 = (unsigned int)f2bf(g.z) | ((unsigned int)f2bf(g.w)<<16);
      *(uint2*)&Ks[kl][c4] = make_uint2(w0, w1);
      float4 gv = *(const float4*)(v + roff);
      Vt[c4  ][kl] = f2bf(gv.x);
      Vt[c4+1][kl] = f2bf(gv.y);
      Vt[c4+2][kl] = f2bf(gv.z);
      Vt[c4+3][kl] = f2bf(gv.w);
    }
    __syncthreads();

    #pragma unroll
    for (int it=0; it<4; it++){
      int kc = it*32;
      int kg = half*128 + kc;
      // K as A-operand: frag rows = keys kc+mr / kc+16+mr
      bf16x8 kf0 = *(const bf16x8*)&Ks[kc + mr][quad*8];
      bf16x8 kf1 = *(const bf16x8*)&Ks[kc + 16 + mr][quad*8];
      f32x4 s0 = __builtin_amdgcn_mfma_f32_16x16x32_bf16(kf0, qf, (f32x4){0,0,0,0}, 0, 0, 0);
      f32x4 s1 = __builtin_amdgcn_mfma_f32_16x16x32_bf16(kf1, qf, (f32x4){0,0,0,0}, 0, 0, 0);
      // s0[r] = S[key=kg+quad*4+r][qg]; s1[r] = S[key=kg+16+quad*4+r][qg]
      float4 nb0 = *(const float4*)(nbq + kg + quad*4);
      float4 nb1 = *(const float4*)(nbq + kg + 16 + quad*4);
      float4 mk0 = *(const float4*)&mask_s[kg + quad*4];
      float4 mk1 = *(const float4*)&mask_s[kg + 16 + quad*4];
      s0[0] += nb0.x + mk0.x; s0[1] += nb0.y + mk0.y; s0[2] += nb0.z + mk0.z; s0[3] += nb0.w + mk0.w;
      s1[0] += nb1.x + mk1.x; s1[1] += nb1.y + mk1.y; s1[2] += nb1.z + mk1.z; s1[3] += nb1.w + mk1.w;

      // per-lane online softmax over the 32-key tile (cross-quad = 2 shfls)
      float tm = fmaxf(fmaxf(fmaxf(s0[0],s0[1]), fmaxf(s0[2],s0[3])),
                       fmaxf(fmaxf(s1[0],s1[1]), fmaxf(s1[2],s1[3])));
      tm = fmaxf(tm, __shfl_xor(tm, 16));
      tm = fmaxf(tm, __shfl_xor(tm, 32));
      float nm = fmaxf(mm, tm);
      float alpha = __expf(mm - nm);
      mm = nm;
      float e00 = __expf(s0[0]-nm), e01 = __expf(s0[1]-nm);
      float e02 = __expf(s0[2]-nm), e03 = __expf(s0[3]-nm);
      float e10 = __expf(s1[0]-nm), e11 = __expf(s1[1]-nm);
      float e12 = __expf(s1[2]-nm), e13 = __expf(s1[3]-nm);
      float ps = ((e00+e01) + (e02+e03)) + ((e10+e11) + (e12+e13));
      ps += __shfl_xor(ps, 16);
      ps += __shfl_xor(ps, 32);
      ll = ll*alpha + ps;
      o0 *= alpha; o1 *= alpha;
      // P[q=mr][key] packed bf16 pairs, 2x 8B writes (2-way banks = free)
      unsigned int p0 = (unsigned int)f2bf(e00) | ((unsigned int)f2bf(e01)<<16);
      unsigned int p1 = (unsigned int)f2bf(e02) | ((unsigned int)f2bf(e03)<<16);
      unsigned int p2 = (unsigned int)f2bf(e10) | ((unsigned int)f2bf(e11)<<16);
      unsigned int p3 = (unsigned int)f2bf(e12) | ((unsigned int)f2bf(e13)<<16);
      *(uint2*)&Pl[wave][mr][quad*4]      = make_uint2(p0, p1);
      *(uint2*)&Pl[wave][mr][16 + quad*4] = make_uint2(p2, p3);
      // PV (swapped): A = V^T rows=channels, B = P [k=key][n=q=mr]
      bf16x8 pf  = *(const bf16x8*)&Pl[wave][mr][quad*8];
      bf16x8 vf0 = *(const bf16x8*)&Vt[mr     ][kc + quad*8];
      bf16x8 vf1 = *(const bf16x8*)&Vt[16 + mr][kc + quad*8];
      o0 = __builtin_amdgcn_mfma_f32_16x16x32_bf16(vf0, pf, o0, 0, 0, 0);
      o1 = __builtin_amdgcn_mfma_f32_16x16x32_bf16(vf1, pf, o1, 0, 0, 0);
    }
  }

  float inv = 1.f/ll;
  float* wp = wa + base + (i64)qg*128;
  *(float4*)(wp + quad*4)      = make_float4(o0[0]*inv, o0[1]*inv, o0[2]*inv, o0[3]*inv);
  *(float4*)(wp + 16 + quad*4) = make_float4(o1[0]*inv, o1[1]*inv, o1[2]*inv, o1[3]*inv);
}

// ---------------- host dispatch ----------------
static void gemm(hipStream_t st, bool TA, bool TB,
                 const float* A, int lda, i64 sA,
                 const float* B, int ldb, i64 sB,
                 float* C, int ldc, i64 sC,
                 int M, int N, int K, int batch,
                 const float* bias, float scale, int act,
                 const float* rowmul, int combine)
{
  dim3 g((M+63)/64, (N+63)/64, batch), bl(256);
  if (!TA && !TB)      gemm_k<false,false><<<g,bl,0,st>>>(A,lda,sA,B,ldb,sB,C,ldc,sC,M,N,K,bias,scale,act,rowmul,combine);
  else if (!TA &&  TB) gemm_k<false,true ><<<g,bl,0,st>>>(A,lda,sA,B,ldb,sB,C,ldc,sC,M,N,K,bias,scale,act,rowmul,combine);
  else                 gemm_k<true ,false><<<g,bl,0,st>>>(A,lda,sA,B,ldb,sB,C,ldc,sC,M,N,K,bias,scale,act,rowmul,combine);
}

static void mgemm(hipStream_t st, bool TA, bool TB,
                  const float* A, int lda, i64 sA,
                  const float* B, int ldb, i64 sB,
                  float* C, int ldc, i64 sC,
                  int M, int N, int K, int batch,
                  const float* bias, float scale, int act,
                  const float* rowmul, int combine, const float* aux = nullptr)
{
  dim3 bl(256);
  i64 nb128 = (i64)(M/128)*(N/128)*batch;
  if (nb128 < 1024 && (M % 64) == 0 && (N % 64) == 0){
    // latency-regime fix (R3): <1024 blocks at 128-tile -> 2 blocks/CU; use 64x64 tiles
    dim3 g(M/64, N/64, batch);
    if (!TA && !TB)      mgemm64_k<false,false><<<g,bl,0,st>>>(A,lda,sA,B,ldb,sB,C,ldc,sC,M,N,K,bias,scale,act,rowmul,combine,aux);
    else if (!TA &&  TB) mgemm64_k<false,true ><<<g,bl,0,st>>>(A,lda,sA,B,ldb,sB,C,ldc,sC,M,N,K,bias,scale,act,rowmul,combine,aux);
    else                 mgemm64_k<true ,false><<<g,bl,0,st>>>(A,lda,sA,B,ldb,sB,C,ldc,sC,M,N,K,bias,scale,act,rowmul,combine,aux);
    return;
  }
  dim3 g(M/128, N/128, batch);
  if (!TA && !TB)      mgemm_k<false,false><<<g,bl,0,st>>>(A,lda,sA,B,ldb,sB,C,ldc,sC,M,N,K,bias,scale,act,rowmul,combine,aux);
  else if (!TA &&  TB) mgemm_k<false,true ><<<g,bl,0,st>>>(A,lda,sA,B,ldb,sB,C,ldc,sC,M,N,K,bias,scale,act,rowmul,combine,aux);
  else                 mgemm_k<true ,false><<<g,bl,0,st>>>(A,lda,sA,B,ldb,sB,C,ldc,sC,M,N,K,bias,scale,act,rowmul,combine,aux);
}

static void gemm_thin(hipStream_t st,
                      const float* A, int lda, const float* B, int ldb,
                      float* C, int ldc, int M, int N, int K,
                      const float* bias, float scale, int act,
                      const float* rowmul, int combine, float* part)
{
  const int S = 8;
  int chunk = ((K/S + 15)/16)*16; if (chunk < 16) chunk = 16;
  dim3 g((M+15)/16, (N+63)/64, S);
  gemm_part_k<<<g,256,0,st>>>(A,lda,B,ldb,part,M,N,K,chunk);
  i64 t = (i64)M*N;
  gemm_reduce_k<<<(int)((t+255)/256),256,0,st>>>(part,C,ldc,M,N,S,bias,scale,act,rowmul,combine);
}

extern "C" void kernel_launch(void* const* d_in, const int* in_sizes, int n_in,
                              void* d_out, int out_size, void* d_ws, size_t ws_size,
                              hipStream_t stream)
{
  const float* IN[64];
  for (int i=0;i<n_in && i<64;i++) IN[i] = (const float*)d_in[i];

  const float* single_act = IN[0];
  const float* pair_act   = IN[1];
  const float* sm         = IN[2];
  const float* pm         = IN[3];
  const float* opm_ln     = IN[4];
  const float* opm_lr_w   = IN[5];
  const float* opm_lr_b   = IN[6];
  const float* opm_out_w  = IN[7];
  const float* opm_out_b  = IN[8];
  const float* ra_ln      = IN[9];
  const float* ra_pair_ln = IN[10];
  const float* ra_feat_w  = IN[11];
  const float* ra_qkv_w   = IN[12];
  const float* ra_gate_w  = IN[13];
  const float* ra_gate_b  = IN[14];
  const float* ra_o_w     = IN[15];
  const float* ra_o_b     = IN[16];
  const float* st_ln      = IN[17];
  const float* st_w1      = IN[18];
  const float* st_b1      = IN[19];
  const float* st_w2      = IN[20];
  const float* st_b2      = IN[21];
  const float* pt_ln      = IN[56];
  const float* pt_w1      = IN[57];
  const float* pt_b1      = IN[58];
  const float* pt_w2      = IN[59];
  const float* pt_b2      = IN[60];

  float* sa = (float*)d_out;           // [256,384]
  float* pa = (float*)d_out + 98304;   // [256,256,128]

  float* W  = (float*)d_ws;
  float* B0 = W;
  float* B1 = W + 8388608L;
  float* B2 = W + 16777216L;
  float* B3 = W + 25165824L;
  float* SMA = W + 33554432L;
  float* xs   = SMA;
  float* qb   = SMA +  98304;
  float* kb   = SMA + 196608;
  float* vb   = SMA + 294912;
  float* wab  = SMA + 393216;
  float* hst  = SMA + 491520;   // 393216
  float* nbra = SMA + 884736;   // 524288 (nb buffers: ra qkh-major / ta [h][q][k])
  float* lbuf = SMA + 1409024;  // 8192
  float* rbuf = SMA + 1417216;  // 8192
  float* Wd   = SMA + 1425408;  // 1048576

  // init sa with residual base (pa is initialized by opm_final_k's fused write)
  copy_k<<<384, 256, 0, stream>>>(sa, single_act, 98304L);

  // ---- 1) OPM -> pair residual (writes pa = pair_act + update) ----
  ln_k<<<256,128,0,stream>>>(single_act, xs, opm_ln, 384);
  gemm_thin(stream, xs,384, opm_lr_w,32,       lbuf,32, 256,32,384, opm_lr_b,    1.f,0, sm,0, B1);
  gemm_thin(stream, xs,384, opm_lr_w+12288,32, rbuf,32, 256,32,384, opm_lr_b+32, 1.f,0, sm,0, B1);
  opm_wd_k<<<dim3(256,32),128,0,stream>>>(rbuf, opm_out_w, Wd);
  opm_final_k<<<dim3(256,16),128,0,stream>>>(lbuf, Wd, opm_out_b, sm, pair_act, pa);

  // ---- 2) row attention with pair bias ----
  ln_k<<<256,128,0,stream>>>(sa, xs, ra_ln, 384);
  ln128_k<<<16384,256,0,stream>>>(pa, B0, ra_pair_ln, 0);
  feat8_k<<<256,256,0,stream>>>(B0, ra_feat_w, nbra);
  const float qs_ra = 0.14433756729740643f; // 1/sqrt(48)
  gemm_thin(stream, xs,384, ra_qkv_w,384,        qb,384, 256,384,384, nullptr,qs_ra,0,nullptr,0, B1);
  gemm_thin(stream, xs,384, ra_qkv_w+147456,384, kb,384, 256,384,384, nullptr,1.f,0,nullptr,0, B1);
  gemm_thin(stream, xs,384, ra_qkv_w+294912,384, vb,384, 256,384,384, nullptr,1.f,0,nullptr,0, B1);
  ra_attn_k<<<dim3(256,8),256,0,stream>>>(qb, kb, vb, nbra, sm, wab);
  gemm_thin(stream, xs,384,  ra_gate_w,384, wab,384, 256,384,384, ra_gate_b,1.f,2,nullptr,2, B1);
  gemm_thin(stream, wab,384, ra_o_w,384,    sa,384,  256,384,384, ra_o_b,   1.f,0,nullptr,1, B1);

  // ---- 3) single transition ----
  ln_k<<<256,128,0,stream>>>(sa, xs, st_ln, 384);
  gemm_thin(stream, xs,384,   st_w1,1536, hst,1536, 256,1536,384, st_b1,1.f,1,nullptr,0, B1);
  gemm_thin(stream, hst,1536, st_w2,384,  sa,384,   256,384,1536, st_b2,1.f,0,nullptr,1, B1);

  // ---- 4/5) triangle multiplications ----
  auto tri_mult = [&](int base, bool outgoing){
    const float* ln_w = IN[base+0];
    const float* lr_w = IN[base+1];
    const float* lr_b = IN[base+2];
    const float* gw   = IN[base+3];
    const float* gb   = IN[base+4];
    const float* cln  = IN[base+5];
    const float* ow   = IN[base+6];
    const float* ob   = IN[base+7];
    const float* ogw  = IN[base+8];
    const float* ogb  = IN[base+9];
    ln128_k<<<16384,256,0,stream>>>(pa, B0, ln_w, 0);
    // left = mask * (X@Wl+bl) * sigmoid(X@Wg+bg): fused dual-MFMA, then transpose+mask -> B1 (ch-major)
    mlrgate_k<<<dim3(1024,2),256,0,stream>>>(B0, lr_w, lr_b, gw, gb, B3);
    tr_mask_k<<<dim3(2048,4),256,0,stream>>>(B3, pm, B1);
    // right -> B2 (ch-major)
    mlrgate_k<<<dim3(1024,2),256,0,stream>>>(B0, lr_w+16384, lr_b+128, gw+16384, gb+128, B3);
    tr_mask_k<<<dim3(2048,4),256,0,stream>>>(B3, pm, B2);
    if (outgoing) // out[i,j,c] = sum_k L_c[i,k] * R_c[j,k]
      mgemm(stream,false,true, B1,256,65536, B2,256,65536, B3,256,65536, 256,256,256,128, nullptr,1.f,0,nullptr,0);
    else          // out[i,j,c] = sum_k R_c[k,i] * L_c[k,j]
      mgemm(stream,true,false, B2,256,65536, B1,256,65536, B3,256,65536, 256,256,256,128, nullptr,1.f,0,nullptr,0);
    chw2hwc_k<<<dim3(2048,4),256,0,stream>>>(B3, B1);
    ln128_k<<<16384,256,0,stream>>>(B1, B3, cln, 0);
    mgemm(stream,false,false, B3,128,0, ow,128,0,  B1,128,0, 65536,128,128,1, ob,  1.f,0,nullptr,0);
    // fused: pa += B1 * sigmoid(B0@ogw + ogb)
    mgemm(stream,false,false, B0,128,0, ogw,128,0, pa,128,0, 65536,128,128,1, ogb, 1.f,2,nullptr,3, B1);
  };
  tri_mult(22, true);   // tmo
  tri_mult(32, false);  // tmi

  // ---- 6/7) triangle attentions ----
  auto tri_attn = [&](int base, bool percol){
    const float* ln_w   = IN[base+0];
    const float* feat_w = IN[base+1];
    const float* qkv_w  = IN[base+2];
    const float* gw     = IN[base+3];
    const float* gb     = IN[base+4];
    const float* ow     = IN[base+5];
    const float* ob     = IN[base+6];
    // LN with fused pair-transpose read for per-column attention
    ln128_k<<<16384,256,0,stream>>>(pa, B0, ln_w, percol?1:0);
    feat4_k<<<256,256,0,stream>>>(B0, feat_w, nbra);  // nb[h][q][k] direct
    const float qs = 0.17677669529663687f; // 1/sqrt(32)
    mgemm(stream,false,false, B0,128,0, qkv_w,128,0,       B1,128,0, 65536,128,128,1, nullptr,qs, 0,nullptr,0);
    mgemm(stream,false,false, B0,128,0, qkv_w+16384,128,0, B2,128,0, 65536,128,128,1, nullptr,1.f,0,nullptr,0);
    mgemm(stream,false,false, B0,128,0, qkv_w+32768,128,0, B3,128,0, 65536,128,128,1, nullptr,1.f,0,nullptr,0);
    ta_mfma_k<<<dim3(4096),256,0,stream>>>(B1, B2, B3, nbra, pm, percol?1:0, B1);
    mgemm(stream,false,false, B0,128,0, gw,128,0, B1,128,0, 65536,128,128,1, gb,1.f,2,nullptr,2); // wa *= sigmoid(gate)
    // out-projection fused with residual add (4 = transpose-pair write for per-column)
    mgemm(stream,false,false, B1,128,0, ow,128,0, pa,128,0, 65536,128,128,1, ob,1.f,0,nullptr, percol?4:1);
  };
  tri_attn(42, false);  // tas (per-row)
  tri_attn(49, true);   // tae (per-column)

  // ---- 8) pair transition: full-M, H in bf16 spanning B1+B2 ----
  ln128_k<<<16384,256,0,stream>>>(pa, B0, pt_ln, 0);
  ptw1_k<<<dim3(512,4),256,0,stream>>>(B0, pt_w1, pt_b1, (unsigned short*)B1);
  ptw2_k<<<dim3(1024,2),256,0,stream>>>((const unsigned short*)B1, pt_w2, pt_b2, pa);
}

// Round 13
// 1328.683 us; speedup vs baseline: 1.5173x; 1.0434x over previous
//
#include <hip/hip_runtime.h>
#include <math.h>

typedef long long i64;
#define NN_ 65536L

typedef __attribute__((ext_vector_type(8))) short bf16x8;
typedef __attribute__((ext_vector_type(4))) float f32x4;

__device__ inline unsigned short f2bf(float f){
  unsigned int u = __float_as_uint(f);
  return (unsigned short)((u + 0x7FFFu + ((u>>16)&1u)) >> 16);
}

// ---------------- elementwise ----------------
__global__ __launch_bounds__(256) void copy_k(float* __restrict__ d, const float* __restrict__ s, long n){
  long i = (long)blockIdx.x*blockDim.x + threadIdx.x;
  if (i < n) d[i] = s[i];
}

// channel-major [128][65536] -> row-major [65536][128]
__global__ __launch_bounds__(256) void chw2hwc_k(const float* __restrict__ in, float* __restrict__ out){
  __shared__ float t[32][33];
  int r0 = blockIdx.x*32, c0 = blockIdx.y*32;
  int tx = threadIdx.x & 31, ty = threadIdx.x >> 5;
  for (int i = ty; i < 32; i += 8) t[i][tx] = in[(i64)(c0+i)*NN_ + r0 + tx];
  __syncthreads();
  for (int i = ty; i < 32; i += 8) out[(i64)(r0+i)*128 + c0 + tx] = t[tx][i];
}

// row-major [65536][128] -> ch-major [128][65536] with per-row mask
__global__ __launch_bounds__(256) void tr_mask_k(const float* __restrict__ in, const float* __restrict__ mask,
                                                 float* __restrict__ out){
  __shared__ float t[32][33];
  int r0 = blockIdx.x*32, c0 = blockIdx.y*32;
  int tx = threadIdx.x & 31, ty = threadIdx.x >> 5;
  for (int i = ty; i < 32; i += 8) t[i][tx] = in[(i64)(r0+i)*128 + c0 + tx];
  __syncthreads();
  for (int i = ty; i < 32; i += 8) out[(i64)(c0+i)*NN_ + r0 + tx] = t[tx][i] * mask[r0+tx];
}

// ---------------- fused pair-bias features ----------------
// nb[h][q][k] = sum_c X[(q*256+k)*128+c] * W[c*4+h]; one 32MB streaming read, W in LDS.
__global__ __launch_bounds__(256) void feat4_k(const float* __restrict__ X, const float* __restrict__ W,
                                               float* __restrict__ out){
  __shared__ float4 w_s[128];
  int q = blockIdx.x, k = threadIdx.x;
  if (k < 128) w_s[k] = *(const float4*)(W + k*4);
  __syncthreads();
  const float* x = X + ((i64)q*256 + k)*128;
  float a0=0.f, a1=0.f, a2=0.f, a3=0.f;
  #pragma unroll
  for (int c=0;c<128;c+=4){
    float4 v = *(const float4*)(x+c);
    float4 w0 = w_s[c], w1 = w_s[c+1], w2 = w_s[c+2], w3 = w_s[c+3];
    a0 = fmaf(v.x,w0.x,a0); a1 = fmaf(v.x,w0.y,a1); a2 = fmaf(v.x,w0.z,a2); a3 = fmaf(v.x,w0.w,a3);
    a0 = fmaf(v.y,w1.x,a0); a1 = fmaf(v.y,w1.y,a1); a2 = fmaf(v.y,w1.z,a2); a3 = fmaf(v.y,w1.w,a3);
    a0 = fmaf(v.z,w2.x,a0); a1 = fmaf(v.z,w2.y,a1); a2 = fmaf(v.z,w2.z,a2); a3 = fmaf(v.z,w2.w,a3);
    a0 = fmaf(v.w,w3.x,a0); a1 = fmaf(v.w,w3.y,a1); a2 = fmaf(v.w,w3.z,a2); a3 = fmaf(v.w,w3.w,a3);
  }
  i64 o = (i64)q*256 + k;
  out[o] = a0; out[65536+o] = a1; out[131072+o] = a2; out[196608+o] = a3;
}

// nb[(q*256+k)*8+h] = sum_c X[(q*256+k)*128+c] * W[c*8+h]  (row attention, H=8)
__global__ __launch_bounds__(256) void feat8_k(const float* __restrict__ X, const float* __restrict__ W,
                                               float* __restrict__ out){
  __shared__ float w_s[128][8];
  int q = blockIdx.x, k = threadIdx.x;
  for (int i = k; i < 1024; i += 256) ((float*)w_s)[i] = W[i];
  __syncthreads();
  const float* x = X + ((i64)q*256 + k)*128;
  float acc[8] = {};
  #pragma unroll
  for (int c=0;c<128;c+=4){
    float4 v = *(const float4*)(x+c);
    #pragma unroll
    for (int h=0;h<8;h++){
      acc[h] = fmaf(v.x, w_s[c  ][h], acc[h]);
      acc[h] = fmaf(v.y, w_s[c+1][h], acc[h]);
      acc[h] = fmaf(v.z, w_s[c+2][h], acc[h]);
      acc[h] = fmaf(v.w, w_s[c+3][h], acc[h]);
    }
  }
  float* o = out + ((i64)q*256 + k)*8;
  *(float4*)o     = make_float4(acc[0],acc[1],acc[2],acc[3]);
  *(float4*)(o+4) = make_float4(acc[4],acc[5],acc[6],acc[7]);
}

// ---------------- LayerNorm generic (rowwise, C arbitrary) ----------------
__global__ __launch_bounds__(128) void ln_k(const float* __restrict__ in, float* __restrict__ out,
                                            const float* __restrict__ w, int C){
  i64 row = blockIdx.x;
  const float* x = in + row*C;
  float* y = out + row*C;
  int tid = threadIdx.x;
  float s=0.f, s2=0.f;
  for (int c=tid;c<C;c+=128){ float v = x[c]; s += v; s2 += v*v; }
  __shared__ float rs[128], rq[128];
  rs[tid]=s; rq[tid]=s2; __syncthreads();
  for (int off=64;off>0;off>>=1){ if (tid<off){ rs[tid]+=rs[tid+off]; rq[tid]+=rq[tid+off]; } __syncthreads(); }
  float mu = rs[0]/C;
  float var = rq[0]/C - mu*mu;
  float inv = rsqrtf(var + 1e-5f);
  for (int c=tid;c<C;c+=128) y[c] = (x[c]-mu)*inv*w[c] + w[C+c];
}

// ---------------- LayerNorm C=128: one wave per row, shuffle-only reduction ----------------
// T=1: read row rt = transpose-pair index of row (fused pa transpose for per-column attention)
__global__ __launch_bounds__(256) void ln128_k(const float* __restrict__ in, float* __restrict__ out,
                                               const float* __restrict__ w, int T){
  int wv = threadIdx.x >> 6, lane = threadIdx.x & 63;
  i64 row = (i64)blockIdx.x*4 + wv;
  i64 rr = T ? (i64)((((int)row & 255) << 8) | ((int)row >> 8)) : row;
  float2 v = *(const float2*)(in + rr*128 + lane*2);
  float s = v.x + v.y, s2 = v.x*v.x + v.y*v.y;
  #pragma unroll
  for (int off=32; off; off>>=1){ s += __shfl_down(s, off); s2 += __shfl_down(s2, off); }
  s = __shfl(s, 0); s2 = __shfl(s2, 0);
  float mu = s*(1.f/128.f);
  float var = s2*(1.f/128.f) - mu*mu;
  float inv = rsqrtf(var + 1e-5f);
  float2 wl = *(const float2*)(w + lane*2);
  float2 wb = *(const float2*)(w + 128 + lane*2);
  float2 y; y.x = (v.x-mu)*inv*wl.x + wb.x; y.y = (v.y-mu)*inv*wl.y + wb.y;
  *(float2*)(out + row*128 + lane*2) = y;
}

// ---------------- bf16 MFMA GEMM: 128x128 tile, 256 thr (2x2 waves of 64x64) ----------------
// combine: 0 store, 1 +=, 2 *=, 3: C += aux*v, 4: C[transpose-pair(m)] += v (pair tensor only)
template<bool TA, bool TB>
__global__ __launch_bounds__(256) void mgemm_k(
    const float* __restrict__ A, int lda, i64 sA,
    const float* __restrict__ B, int ldb, i64 sB,
    float* __restrict__ C, int ldc, i64 sC,
    int M, int N, int K,
    const float* __restrict__ bias, float scale, int act,
    const float* __restrict__ rowmul, int combine, const float* __restrict__ aux)
{
  A += (i64)blockIdx.z * sA;
  B += (i64)blockIdx.z * sB;
  C += (i64)blockIdx.z * sC;
  int m0 = blockIdx.x * 128, n0 = blockIdx.y * 128;
  int tid = threadIdx.x;
  int wave = tid >> 6, lane = tid & 63;
  int quad = lane >> 4, mr = lane & 15;
  int wm = (wave >> 1) * 64, wn = (wave & 1) * 64;
  __shared__ unsigned short As[128][40];
  __shared__ unsigned short Bs[128][40];
  f32x4 acc[4][4];
  #pragma unroll
  for (int i=0;i<4;i++)
    #pragma unroll
    for (int j=0;j<4;j++) acc[i][j] = (f32x4){0.f,0.f,0.f,0.f};

  for (int k0 = 0; k0 < K; k0 += 32){
    if (!TA){
      #pragma unroll
      for (int it=0; it<4; it++){
        int lin = tid + it*256;
        int r = lin >> 3, c4 = (lin & 7) * 4;
        float4 g = *(const float4*)&A[(i64)(m0+r)*lda + k0 + c4];
        As[r][c4]   = f2bf(g.x); As[r][c4+1] = f2bf(g.y);
        As[r][c4+2] = f2bf(g.z); As[r][c4+3] = f2bf(g.w);
      }
    } else {
      #pragma unroll
      for (int it=0; it<4; it++){
        int lin = tid + it*256;
        int m = lin & 127, kg = (lin >> 7) * 4;
        float v0 = A[(i64)(k0+kg  )*lda + m0 + m];
        float v1 = A[(i64)(k0+kg+1)*lda + m0 + m];
        float v2 = A[(i64)(k0+kg+2)*lda + m0 + m];
        float v3 = A[(i64)(k0+kg+3)*lda + m0 + m];
        As[m][kg] = f2bf(v0); As[m][kg+1] = f2bf(v1);
        As[m][kg+2] = f2bf(v2); As[m][kg+3] = f2bf(v3);
      }
    }
    if (!TB){
      #pragma unroll
      for (int it=0; it<4; it++){
        int lin = tid + it*256;
        int n = lin & 127, kg = (lin >> 7) * 4;
        float v0 = B[(i64)(k0+kg  )*ldb + n0 + n];
        float v1 = B[(i64)(k0+kg+1)*ldb + n0 + n];
        float v2 = B[(i64)(k0+kg+2)*ldb + n0 + n];
        float v3 = B[(i64)(k0+kg+3)*ldb + n0 + n];
        Bs[n][kg] = f2bf(v0); Bs[n][kg+1] = f2bf(v1);
        Bs[n][kg+2] = f2bf(v2); Bs[n][kg+3] = f2bf(v3);
      }
    } else {
      #pragma unroll
      for (int it=0; it<4; it++){
        int lin = tid + it*256;
        int r = lin >> 3, c4 = (lin & 7) * 4;
        float4 g = *(const float4*)&B[(i64)(n0+r)*ldb + k0 + c4];
        Bs[r][c4]   = f2bf(g.x); Bs[r][c4+1] = f2bf(g.y);
        Bs[r][c4+2] = f2bf(g.z); Bs[r][c4+3] = f2bf(g.w);
      }
    }
    __syncthreads();
    bf16x8 af[4], bfr[4];
    #pragma unroll
    for (int i=0;i<4;i++) af[i]  = *(const bf16x8*)&As[wm + i*16 + mr][quad*8];
    #pragma unroll
    for (int j=0;j<4;j++) bfr[j] = *(const bf16x8*)&Bs[wn + j*16 + mr][quad*8];
    #pragma unroll
    for (int i=0;i<4;i++)
      #pragma unroll
      for (int j=0;j<4;j++)
        acc[i][j] = __builtin_amdgcn_mfma_f32_16x16x32_bf16(af[i], bfr[j], acc[i][j], 0, 0, 0);
    __syncthreads();
  }
  #pragma unroll
  for (int i=0;i<4;i++){
    #pragma unroll
    for (int r=0;r<4;r++){
      int m = m0 + wm + i*16 + quad*4 + r;
      float rm = rowmul ? rowmul[m] : 1.f;
      i64 mrow = (combine == 4) ? (i64)(((m & 255) << 8) | (m >> 8)) : (i64)m;
      #pragma unroll
      for (int j=0;j<4;j++){
        int n = n0 + wn + j*16 + mr;
        float v = acc[i][j][r] * scale;
        if (bias) v += bias[n];
        if (act == 1) v = fmaxf(v, 0.f);
        else if (act == 2) v = 1.f/(1.f + __expf(-v));
        v *= rm;
        i64 idx = mrow*ldc + n;
        if (combine == 0) C[idx] = v;
        else if (combine == 1 || combine == 4) C[idx] += v;
        else if (combine == 2) C[idx] *= v;
        else C[idx] += aux[(i64)m*ldc + n] * v;
      }
    }
  }
}

// ---------------- bf16 MFMA GEMM: 64x64 tile, 256 thr (2x2 waves of 32x32) ----------------
// NOTE (R5-R9): routing pt_w1 (M=32768,N=512,K=128,ldb=512) through this kernel correlates
// 4:0 with container failure; mechanism unknown. Do NOT route that shape here.
template<bool TA, bool TB>
__global__ __launch_bounds__(256) void mgemm64_k(
    const float* __restrict__ A, int lda, i64 sA,
    const float* __restrict__ B, int ldb, i64 sB,
    float* __restrict__ C, int ldc, i64 sC,
    int M, int N, int K,
    const float* __restrict__ bias, float scale, int act,
    const float* __restrict__ rowmul, int combine, const float* __restrict__ aux)
{
  A += (i64)blockIdx.z * sA;
  B += (i64)blockIdx.z * sB;
  C += (i64)blockIdx.z * sC;
  int m0 = blockIdx.x * 64, n0 = blockIdx.y * 64;
  int tid = threadIdx.x;
  int wave = tid >> 6, lane = tid & 63;
  int quad = lane >> 4, mr = lane & 15;
  int wm = (wave >> 1) * 32, wn = (wave & 1) * 32;
  __shared__ unsigned short As[64][40];
  __shared__ unsigned short Bs[64][40];
  f32x4 acc[2][2];
  #pragma unroll
  for (int i=0;i<2;i++)
    #pragma unroll
    for (int j=0;j<2;j++) acc[i][j] = (f32x4){0.f,0.f,0.f,0.f};

  for (int k0 = 0; k0 < K; k0 += 32){
    if (!TA){
      #pragma unroll
      for (int it=0; it<2; it++){
        int lin = tid + it*256;
        int r = lin >> 3, c4 = (lin & 7) * 4;
        float4 g = *(const float4*)&A[(i64)(m0+r)*lda + k0 + c4];
        As[r][c4]   = f2bf(g.x); As[r][c4+1] = f2bf(g.y);
        As[r][c4+2] = f2bf(g.z); As[r][c4+3] = f2bf(g.w);
      }
    } else {
      #pragma unroll
      for (int it=0; it<2; it++){
        int lin = tid + it*256;
        int m = lin & 63, kg = (lin >> 6) * 4;
        float v0 = A[(i64)(k0+kg  )*lda + m0 + m];
        float v1 = A[(i64)(k0+kg+1)*lda + m0 + m];
        float v2 = A[(i64)(k0+kg+2)*lda + m0 + m];
        float v3 = A[(i64)(k0+kg+3)*lda + m0 + m];
        As[m][kg] = f2bf(v0); As[m][kg+1] = f2bf(v1);
        As[m][kg+2] = f2bf(v2); As[m][kg+3] = f2bf(v3);
      }
    }
    if (!TB){
      #pragma unroll
      for (int it=0; it<2; it++){
        int lin = tid + it*256;
        int n = lin & 63, kg = (lin >> 6) * 4;
        float v0 = B[(i64)(k0+kg  )*ldb + n0 + n];
        float v1 = B[(i64)(k0+kg+1)*ldb + n0 + n];
        float v2 = B[(i64)(k0+kg+2)*ldb + n0 + n];
        float v3 = B[(i64)(k0+kg+3)*ldb + n0 + n];
        Bs[n][kg] = f2bf(v0); Bs[n][kg+1] = f2bf(v1);
        Bs[n][kg+2] = f2bf(v2); Bs[n][kg+3] = f2bf(v3);
      }
    } else {
      #pragma unroll
      for (int it=0; it<2; it++){
        int lin = tid + it*256;
        int r = lin >> 3, c4 = (lin & 7) * 4;
        float4 g = *(const float4*)&B[(i64)(n0+r)*ldb + k0 + c4];
        Bs[r][c4]   = f2bf(g.x); Bs[r][c4+1] = f2bf(g.y);
        Bs[r][c4+2] = f2bf(g.z); Bs[r][c4+3] = f2bf(g.w);
      }
    }
    __syncthreads();
    bf16x8 af[2], bfr[2];
    #pragma unroll
    for (int i=0;i<2;i++) af[i]  = *(const bf16x8*)&As[wm + i*16 + mr][quad*8];
    #pragma unroll
    for (int j=0;j<2;j++) bfr[j] = *(const bf16x8*)&Bs[wn + j*16 + mr][quad*8];
    #pragma unroll
    for (int i=0;i<2;i++)
      #pragma unroll
      for (int j=0;j<2;j++)
        acc[i][j] = __builtin_amdgcn_mfma_f32_16x16x32_bf16(af[i], bfr[j], acc[i][j], 0, 0, 0);
    __syncthreads();
  }
  #pragma unroll
  for (int i=0;i<2;i++){
    #pragma unroll
    for (int r=0;r<4;r++){
      int m = m0 + wm + i*16 + quad*4 + r;
      float rm = rowmul ? rowmul[m] : 1.f;
      i64 mrow = (combine == 4) ? (i64)(((m & 255) << 8) | (m >> 8)) : (i64)m;
      #pragma unroll
      for (int j=0;j<2;j++){
        int n = n0 + wn + j*16 + mr;
        float v = acc[i][j][r] * scale;
        if (bias) v += bias[n];
        if (act == 1) v = fmaxf(v, 0.f);
        else if (act == 2) v = 1.f/(1.f + __expf(-v));
        v *= rm;
        i64 idx = mrow*ldc + n;
        if (combine == 0) C[idx] = v;
        else if (combine == 1 || combine == 4) C[idx] += v;
        else if (combine == 2) C[idx] *= v;
        else C[idx] += aux[(i64)m*ldc + n] * v;
      }
    }
  }
}

// ---------------- QKV projection with bf16 output (tri-attn) ----------------
// M=65536, N=128, K=128, grid (1024,2) — the routinely-passing mgemm64 shape family.
// Emits f2bf(acc*scale) directly: halves projection WRITE and removes f2bf + half the
// FETCH from the ta_mfma hot loop (R12: ta VALUBusy 47%, f2bf at staging was a top cost).
__global__ __launch_bounds__(256) void qkvb_k(
    const float* __restrict__ A, const float* __restrict__ B,
    unsigned short* __restrict__ C, float scale)
{
  int m0 = blockIdx.x * 64, n0 = blockIdx.y * 64;
  int tid = threadIdx.x;
  int wave = tid >> 6, lane = tid & 63;
  int quad = lane >> 4, mr = lane & 15;
  int wm = (wave >> 1) * 32, wn = (wave & 1) * 32;
  __shared__ unsigned short As[64][40];
  __shared__ unsigned short Bs[64][40];
  f32x4 acc[2][2];
  #pragma unroll
  for (int i=0;i<2;i++)
    #pragma unroll
    for (int j=0;j<2;j++) acc[i][j] = (f32x4){0.f,0.f,0.f,0.f};

  for (int k0 = 0; k0 < 128; k0 += 32){
    #pragma unroll
    for (int it=0; it<2; it++){
      int lin = tid + it*256;
      int r = lin >> 3, c4 = (lin & 7) * 4;
      float4 g = *(const float4*)&A[(i64)(m0+r)*128 + k0 + c4];
      As[r][c4]   = f2bf(g.x); As[r][c4+1] = f2bf(g.y);
      As[r][c4+2] = f2bf(g.z); As[r][c4+3] = f2bf(g.w);
    }
    #pragma unroll
    for (int it=0; it<2; it++){
      int lin = tid + it*256;
      int n = lin & 63, kg = (lin >> 6) * 4;
      float v0 = B[(i64)(k0+kg  )*128 + n0 + n];
      float v1 = B[(i64)(k0+kg+1)*128 + n0 + n];
      float v2 = B[(i64)(k0+kg+2)*128 + n0 + n];
      float v3 = B[(i64)(k0+kg+3)*128 + n0 + n];
      Bs[n][kg] = f2bf(v0); Bs[n][kg+1] = f2bf(v1);
      Bs[n][kg+2] = f2bf(v2); Bs[n][kg+3] = f2bf(v3);
    }
    __syncthreads();
    bf16x8 af[2], bfr[2];
    #pragma unroll
    for (int i=0;i<2;i++) af[i]  = *(const bf16x8*)&As[wm + i*16 + mr][quad*8];
    #pragma unroll
    for (int j=0;j<2;j++) bfr[j] = *(const bf16x8*)&Bs[wn + j*16 + mr][quad*8];
    #pragma unroll
    for (int i=0;i<2;i++)
      #pragma unroll
      for (int j=0;j<2;j++)
        acc[i][j] = __builtin_amdgcn_mfma_f32_16x16x32_bf16(af[i], bfr[j], acc[i][j], 0, 0, 0);
    __syncthreads();
  }
  #pragma unroll
  for (int i=0;i<2;i++){
    #pragma unroll
    for (int r=0;r<4;r++){
      int m = m0 + wm + i*16 + quad*4 + r;
      #pragma unroll
      for (int j=0;j<2;j++){
        int n = n0 + wn + j*16 + mr;
        C[(i64)m*128 + n] = f2bf(acc[i][j][r] * scale);
      }
    }
  }
}

// ---------------- fused dual-MFMA lin*sigmoid(gate) for tri-mult ----------------
// 64x64 tile; grid (1024, 2) = 2048 blocks; LDS 15 KB.
__global__ __launch_bounds__(256) void mlrgate_k(
    const float* __restrict__ X,
    const float* __restrict__ Wl, const float* __restrict__ bl,
    const float* __restrict__ Wg, const float* __restrict__ bg,
    float* __restrict__ Out)
{
  int m0 = blockIdx.x * 64, n0 = blockIdx.y * 64;
  int tid = threadIdx.x;
  int wave = tid >> 6, lane = tid & 63;
  int quad = lane >> 4, mr = lane & 15;
  int wm = (wave >> 1) * 32, wn = (wave & 1) * 32;
  __shared__ unsigned short As[64][40], B1s[64][40], B2s[64][40];
  f32x4 acc1[2][2], acc2[2][2];
  #pragma unroll
  for (int i=0;i<2;i++)
    #pragma unroll
    for (int j=0;j<2;j++){ acc1[i][j] = (f32x4){0,0,0,0}; acc2[i][j] = (f32x4){0,0,0,0}; }

  for (int k0 = 0; k0 < 128; k0 += 32){
    #pragma unroll
    for (int it=0; it<2; it++){
      int lin = tid + it*256;
      int r = lin >> 3, c4 = (lin & 7) * 4;
      float4 g = *(const float4*)&X[(i64)(m0+r)*128 + k0 + c4];
      As[r][c4]   = f2bf(g.x); As[r][c4+1] = f2bf(g.y);
      As[r][c4+2] = f2bf(g.z); As[r][c4+3] = f2bf(g.w);
    }
    #pragma unroll
    for (int it=0; it<2; it++){
      int lin = tid + it*256;
      int n = lin & 63, kg = (lin >> 6) * 4;
      float a0 = Wl[(i64)(k0+kg  )*128 + n0 + n];
      float a1 = Wl[(i64)(k0+kg+1)*128 + n0 + n];
      float a2 = Wl[(i64)(k0+kg+2)*128 + n0 + n];
      float a3 = Wl[(i64)(k0+kg+3)*128 + n0 + n];
      B1s[n][kg] = f2bf(a0); B1s[n][kg+1] = f2bf(a1);
      B1s[n][kg+2] = f2bf(a2); B1s[n][kg+3] = f2bf(a3);
      float g0 = Wg[(i64)(k0+kg  )*128 + n0 + n];
      float g1 = Wg[(i64)(k0+kg+1)*128 + n0 + n];
      float g2 = Wg[(i64)(k0+kg+2)*128 + n0 + n];
      float g3 = Wg[(i64)(k0+kg+3)*128 + n0 + n];
      B2s[n][kg] = f2bf(g0); B2s[n][kg+1] = f2bf(g1);
      B2s[n][kg+2] = f2bf(g2); B2s[n][kg+3] = f2bf(g3);
    }
    __syncthreads();
    bf16x8 af[2], b1f[2], b2f[2];
    #pragma unroll
    for (int i=0;i<2;i++) af[i]  = *(const bf16x8*)&As[wm + i*16 + mr][quad*8];
    #pragma unroll
    for (int j=0;j<2;j++){
      b1f[j] = *(const bf16x8*)&B1s[wn + j*16 + mr][quad*8];
      b2f[j] = *(const bf16x8*)&B2s[wn + j*16 + mr][quad*8];
    }
    #pragma unroll
    for (int i=0;i<2;i++)
      #pragma unroll
      for (int j=0;j<2;j++){
        acc1[i][j] = __builtin_amdgcn_mfma_f32_16x16x32_bf16(af[i], b1f[j], acc1[i][j], 0, 0, 0);
        acc2[i][j] = __builtin_amdgcn_mfma_f32_16x16x32_bf16(af[i], b2f[j], acc2[i][j], 0, 0, 0);
      }
    __syncthreads();
  }
  #pragma unroll
  for (int i=0;i<2;i++){
    #pragma unroll
    for (int r=0;r<4;r++){
      int m = m0 + wm + i*16 + quad*4 + r;
      #pragma unroll
      for (int j=0;j<2;j++){
        int n = wn + j*16 + mr;
        float lv = acc1[i][j][r] + bl[n0 + n];
        float gv = acc2[i][j][r] + bg[n0 + n];
        Out[(i64)m*128 + n0 + n] = lv * (1.f/(1.f + __expf(-gv)));
      }
    }
  }
}

// ---------------- pair transition, stage 1: H(bf16) = relu(X @ W1 + b1) ----------------
__global__ __launch_bounds__(256) void ptw1_k(
    const float* __restrict__ X, const float* __restrict__ W1,
    const float* __restrict__ b1, unsigned short* __restrict__ H)
{
  int m0 = blockIdx.x * 128, n0 = blockIdx.y * 128;
  int tid = threadIdx.x;
  int wave = tid >> 6, lane = tid & 63;
  int quad = lane >> 4, mr = lane & 15;
  int wm = (wave >> 1) * 64, wn = (wave & 1) * 64;
  __shared__ unsigned short As[128][40];
  __shared__ unsigned short Bs[128][40];
  f32x4 acc[4][4];
  #pragma unroll
  for (int i=0;i<4;i++)
    #pragma unroll
    for (int j=0;j<4;j++) acc[i][j] = (f32x4){0.f,0.f,0.f,0.f};

  for (int k0 = 0; k0 < 128; k0 += 32){
    #pragma unroll
    for (int it=0; it<4; it++){
      int lin = tid + it*256;
      int r = lin >> 3, c4 = (lin & 7) * 4;
      float4 g = *(const float4*)&X[(i64)(m0+r)*128 + k0 + c4];
      As[r][c4]   = f2bf(g.x); As[r][c4+1] = f2bf(g.y);
      As[r][c4+2] = f2bf(g.z); As[r][c4+3] = f2bf(g.w);
    }
    #pragma unroll
    for (int it=0; it<4; it++){
      int lin = tid + it*256;
      int n = lin & 127, kg = (lin >> 7) * 4;
      float v0 = W1[(i64)(k0+kg  )*512 + n0 + n];
      float v1 = W1[(i64)(k0+kg+1)*512 + n0 + n];
      float v2 = W1[(i64)(k0+kg+2)*512 + n0 + n];
      float v3 = W1[(i64)(k0+kg+3)*512 + n0 + n];
      Bs[n][kg] = f2bf(v0); Bs[n][kg+1] = f2bf(v1);
      Bs[n][kg+2] = f2bf(v2); Bs[n][kg+3] = f2bf(v3);
    }
    __syncthreads();
    bf16x8 af[4], bfr[4];
    #pragma unroll
    for (int i=0;i<4;i++) af[i]  = *(const bf16x8*)&As[wm + i*16 + mr][quad*8];
    #pragma unroll
    for (int j=0;j<4;j++) bfr[j] = *(const bf16x8*)&Bs[wn + j*16 + mr][quad*8];
    #pragma unroll
    for (int i=0;i<4;i++)
      #pragma unroll
      for (int j=0;j<4;j++)
        acc[i][j] = __builtin_amdgcn_mfma_f32_16x16x32_bf16(af[i], bfr[j], acc[i][j], 0, 0, 0);
    __syncthreads();
  }
  #pragma unroll
  for (int i=0;i<4;i++){
    #pragma unroll
    for (int r=0;r<4;r++){
      int m = m0 + wm + i*16 + quad*4 + r;
      #pragma unroll
      for (int j=0;j<4;j++){
        int n = n0 + wn + j*16 + mr;
        float v = fmaxf(acc[i][j][r] + b1[n], 0.f);
        H[(i64)m*512 + n] = f2bf(v);
      }
    }
  }
}

// ---------------- pair transition, stage 2: pa += H(bf16) @ W2 + b2 ----------------
__global__ __launch_bounds__(256) void ptw2_k(
    const unsigned short* __restrict__ H, const float* __restrict__ W2,
    const float* __restrict__ b2, float* __restrict__ pa)
{
  int m0 = blockIdx.x * 64, n0 = blockIdx.y * 64;
  int tid = threadIdx.x;
  int wave = tid >> 6, lane = tid & 63;
  int quad = lane >> 4, mr = lane & 15;
  int wm = (wave >> 1) * 32, wn = (wave & 1) * 32;
  __shared__ unsigned short As[64][40];
  __shared__ unsigned short Bs[64][40];
  f32x4 acc[2][2];
  #pragma unroll
  for (int i=0;i<2;i++)
    #pragma unroll
    for (int j=0;j<2;j++) acc[i][j] = (f32x4){0.f,0.f,0.f,0.f};

  for (int k0 = 0; k0 < 512; k0 += 32){
    #pragma unroll
    for (int it=0; it<2; it++){
      int lin = tid + it*256;
      int r = lin >> 3, c4 = (lin & 7) * 4;
      *(uint2*)&As[r][c4] = *(const uint2*)&H[(i64)(m0+r)*512 + k0 + c4];
    }
    #pragma unroll
    for (int it=0; it<2; it++){
      int lin = tid + it*256;
      int n = lin & 63, kg = (lin >> 6) * 4;
      float v0 = W2[(i64)(k0+kg  )*128 + n0 + n];
      float v1 = W2[(i64)(k0+kg+1)*128 + n0 + n];
      float v2 = W2[(i64)(k0+kg+2)*128 + n0 + n];
      float v3 = W2[(i64)(k0+kg+3)*128 + n0 + n];
      Bs[n][kg] = f2bf(v0); Bs[n][kg+1] = f2bf(v1);
      Bs[n][kg+2] = f2bf(v2); Bs[n][kg+3] = f2bf(v3);
    }
    __syncthreads();
    bf16x8 af[2], bfr[2];
    #pragma unroll
    for (int i=0;i<2;i++) af[i]  = *(const bf16x8*)&As[wm + i*16 + mr][quad*8];
    #pragma unroll
    for (int j=0;j<2;j++) bfr[j] = *(const bf16x8*)&Bs[wn + j*16 + mr][quad*8];
    #pragma unroll
    for (int i=0;i<2;i++)
      #pragma unroll
      for (int j=0;j<2;j++)
        acc[i][j] = __builtin_amdgcn_mfma_f32_16x16x32_bf16(af[i], bfr[j], acc[i][j], 0, 0, 0);
    __syncthreads();
  }
  #pragma unroll
  for (int i=0;i<2;i++){
    #pragma unroll
    for (int r=0;r<4;r++){
      int m = m0 + wm + i*16 + quad*4 + r;
      #pragma unroll
      for (int j=0;j<2;j++){
        int n = n0 + wn + j*16 + mr;
        pa[(i64)m*128 + n] += acc[i][j][r] + b2[n];
      }
    }
  }
}

// ---------------- generic batched GEMM (fp32, 64x64 tile) ----------------
template<bool TA, bool TB>
__global__ __launch_bounds__(256) void gemm_k(
    const float* __restrict__ A, int lda, i64 sA,
    const float* __restrict__ B, int ldb, i64 sB,
    float* __restrict__ C, int ldc, i64 sC,
    int M, int N, int K,
    const float* __restrict__ bias, float scale, int act,
    const float* __restrict__ rowmul, int combine)
{
  A += (i64)blockIdx.z * sA;
  B += (i64)blockIdx.z * sB;
  C += (i64)blockIdx.z * sC;
  int m0 = blockIdx.x * 64, n0 = blockIdx.y * 64;
  int tid = threadIdx.x, tx = tid & 15, ty = tid >> 4;
  __shared__ float As[16][68], Bs[16][68];
  float acc[4][4] = {};
  for (int k0 = 0; k0 < K; k0 += 16){
    if (TA){
      for (int l = tid; l < 1024; l += 256){
        int kk = l >> 6, mi = l & 63; int m = m0 + mi;
        As[kk][mi] = (m < M) ? A[(i64)(k0+kk)*lda + m] : 0.f;
      }
    } else {
      for (int l = tid; l < 1024; l += 256){
        int mi = l >> 4, kk = l & 15; int m = m0 + mi;
        As[kk][mi] = (m < M) ? A[(i64)m*lda + k0 + kk] : 0.f;
      }
    }
    if (TB){
      for (int l = tid; l < 1024; l += 256){
        int ni = l >> 4, kk = l & 15; int n = n0 + ni;
        Bs[kk][ni] = (n < N) ? B[(i64)n*ldb + k0 + kk] : 0.f;
      }
    } else {
      for (int l = tid; l < 1024; l += 256){
        int kk = l >> 6, ni = l & 63; int n = n0 + ni;
        Bs[kk][ni] = (n < N) ? B[(i64)(k0+kk)*ldb + n] : 0.f;
      }
    }
    __syncthreads();
    #pragma unroll
    for (int kk = 0; kk < 16; ++kk){
      float4 av4 = *(const float4*)&As[kk][ty*4];
      float4 bv4 = *(const float4*)&Bs[kk][tx*4];
      float av[4] = {av4.x, av4.y, av4.z, av4.w};
      float bv[4] = {bv4.x, bv4.y, bv4.z, bv4.w};
      #pragma unroll
      for (int i=0;i<4;i++)
        #pragma unroll
        for (int j=0;j<4;j++) acc[i][j] = fmaf(av[i], bv[j], acc[i][j]);
    }
    __syncthreads();
  }
  #pragma unroll
  for (int i=0;i<4;i++){
    int m = m0 + ty*4 + i;
    if (m >= M) continue;
    float rm = rowmul ? rowmul[m] : 1.f;
    #pragma unroll
    for (int j=0;j<4;j++){
      int n = n0 + tx*4 + j;
      if (n >= N) continue;
      float v = acc[i][j] * scale;
      if (bias) v += bias[n];
      if (act == 1) v = fmaxf(v, 0.f);
      else if (act == 2) v = 1.f/(1.f + expf(-v));
      v *= rm;
      i64 idx = (i64)m*ldc + n;
      if (combine == 0) C[idx] = v;
      else if (combine == 1) C[idx] += v;
      else C[idx] *= v;
    }
  }
}

// ---------------- thin GEMM (small M): split-K two-phase ----------------
__global__ __launch_bounds__(256) void gemm_part_k(
    const float* __restrict__ A, int lda,
    const float* __restrict__ B, int ldb,
    float* __restrict__ Cp, int M, int N, int K, int chunk)
{
  int m0 = blockIdx.x*16, n0 = blockIdx.y*64, z = blockIdx.z;
  int kb = z*chunk, ke = min(K, kb+chunk);
  int tid = threadIdx.x;
  int mi = tid >> 4, ni4 = (tid & 15)*4;
  __shared__ float As[16][17], Bs[16][68];
  float acc[4] = {0.f,0.f,0.f,0.f};
  for (int k0 = kb; k0 < ke; k0 += 16){
    { int r = tid>>4, c = tid&15; int m = m0+r;
      As[c][r] = (m < M) ? A[(i64)m*lda + k0 + c] : 0.f; }
    for (int l = tid; l < 1024; l += 256){
      int kk = l>>6, nn = l&63; int n = n0+nn;
      Bs[kk][nn] = (n < N) ? B[(i64)(k0+kk)*ldb + n] : 0.f;
    }
    __syncthreads();
    #pragma unroll
    for (int kk=0;kk<16;kk++){
      float a = As[kk][mi];
      float4 b = *(const float4*)&Bs[kk][ni4];
      acc[0]=fmaf(a,b.x,acc[0]); acc[1]=fmaf(a,b.y,acc[1]);
      acc[2]=fmaf(a,b.z,acc[2]); acc[3]=fmaf(a,b.w,acc[3]);
    }
    __syncthreads();
  }
  int m = m0+mi, n = n0+ni4;
  if (m < M && n < N) *(float4*)&Cp[((i64)z*M + m)*N + n] = *(float4*)acc;
}

__global__ __launch_bounds__(256) void gemm_reduce_k(
    const float* __restrict__ Cp, float* __restrict__ C, int ldc,
    int M, int N, int S,
    const float* __restrict__ bias, float scale, int act,
    const float* __restrict__ rowmul, int combine)
{
  i64 idx = (i64)blockIdx.x*256 + threadIdx.x;
  if (idx >= (i64)M*N) return;
  int m = (int)(idx / N), n = (int)(idx % N);
  float s = 0.f;
  for (int z=0; z<S; z++) s += Cp[(i64)z*M*N + idx];
  float v = s*scale;
  if (bias) v += bias[n];
  if (act == 1) v = fmaxf(v, 0.f);
  else if (act == 2) v = 1.f/(1.f + expf(-v));
  if (rowmul) v *= rowmul[m];
  i64 o = (i64)m*ldc + n;
  if (combine == 0) C[o] = v;
  else if (combine == 1) C[o] += v;
  else C[o] *= v;
}

// ---------------- OPM ----------------
__global__ __launch_bounds__(128) void opm_wd_k(const float* __restrict__ right, const float* __restrict__ W,
                                                float* __restrict__ Wd){
  int d = blockIdx.x, c = blockIdx.y, f = threadIdx.x;
  float acc = 0.f;
  #pragma unroll
  for (int e=0;e<32;e++) acc = fmaf(right[d*32+e], W[((i64)c*32+e)*128 + f], acc);
  Wd[((i64)d*32+c)*128 + f] = acc;
}

// pa[d,b,f] = pair_act[d,b,f] + (sum_c left[b,c]*Wd[d,c,f] + ob[f]) / (1e-3 + sm[d]*sm[b])
__global__ __launch_bounds__(128) void opm_final_k(const float* __restrict__ left, const float* __restrict__ Wd,
                                                   const float* __restrict__ ob, const float* __restrict__ sm,
                                                   const float* __restrict__ pair_act, float* __restrict__ pa){
  int d = blockIdx.x, b0 = blockIdx.y*16, f = threadIdx.x;
  __shared__ float wd_s[32][128];
  __shared__ float l_s[16][32];
  for (int c=0;c<32;c++) wd_s[c][f] = Wd[((i64)d*32+c)*128 + f];
  for (int l = f; l < 512; l += 128){ int bi=l>>5, c=l&31; l_s[bi][c] = left[(b0+bi)*32 + c]; }
  __syncthreads();
  float md = sm[d], obf = ob[f];
  for (int bi=0;bi<16;bi++){
    float acc = 0.f;
    #pragma unroll
    for (int c=0;c<32;c++) acc = fmaf(l_s[bi][c], wd_s[c][f], acc);
    int b = b0+bi;
    i64 idx = ((i64)d*256 + b)*128 + f;
    pa[idx] = pair_act[idx] + (acc + obf) / (1e-3f + md*sm[b]);
  }
}

// ---------------- row attention core ----------------
__global__ __launch_bounds__(256) void ra_attn_k(const float* __restrict__ q, const float* __restrict__ k,
                                                 const float* __restrict__ v, const float* __restrict__ nb,
                                                 const float* __restrict__ sm, float* __restrict__ wa){
  int qi = blockIdx.x, h = blockIdx.y, tid = threadIdx.x;
  __shared__ float qv[48];
  __shared__ float p[256];
  __shared__ float red[256];
  if (tid < 48) qv[tid] = q[(i64)qi*384 + h*48 + tid];
  __syncthreads();
  float acc = 0.f;
  const float* kr = k + (i64)tid*384 + h*48;
  #pragma unroll
  for (int c=0;c<48;c++) acc = fmaf(qv[c], kr[c], acc);
  acc += 1e9f*(sm[tid]-1.f) + nb[((i64)qi*256 + tid)*8 + h];
  red[tid] = acc; __syncthreads();
  for (int off=128;off>0;off>>=1){ if (tid<off) red[tid] = fmaxf(red[tid], red[tid+off]); __syncthreads(); }
  float mx = red[0]; __syncthreads();
  float e = expf(acc - mx);
  red[tid] = e; __syncthreads();
  for (int off=128;off>0;off>>=1){ if (tid<off) red[tid] += red[tid+off]; __syncthreads(); }
  p[tid] = e / red[0];
  __syncthreads();
  if (tid < 48){
    float a = 0.f;
    for (int kk=0;kk<256;kk++) a = fmaf(p[kk], v[(i64)kk*384 + h*48 + tid], a);
    wa[(i64)qi*384 + h*48 + tid] = a;
  }
}

// ---------------- triangle attention core v9: bf16 QKV inputs + XCD swizzle ----------------
// R12: FETCH 150->59.5MB via XCD swizzle; now VALU/latency-mixed (VALUBusy 47%). v9 takes
// Q/K/V as bf16 (converted once in qkvb_k epilogue, numerically identical): halves QKV
// fetch (96->48MB logical) and removes ~70 f2bf (~280 VALU ops) per thread from the hot loop.
__global__ __launch_bounds__(256, 6) void ta_mfma_k(
    const unsigned short* __restrict__ q, const unsigned short* __restrict__ k,
    const unsigned short* __restrict__ v,
    const float* __restrict__ nbQ, const float* __restrict__ mask, int maskT,
    float* __restrict__ wa)
{
  int d = blockIdx.x;
  int xcd = d & 7, y = d >> 3;
  int b = xcd*32 + (y >> 4);
  int w = y & 15;
  int qblk = w & 3, h = w >> 2;
  int tid = threadIdx.x;
  int wave = tid >> 6, lane = tid & 63;
  int quad = lane >> 4, mr = lane & 15;
  const i64 base = ((i64)b*256)*128 + h*32;

  __shared__ __align__(16) unsigned short Ks[128][40];   // [key][c], row 80B
  __shared__ __align__(16) unsigned short Vt[32][136];   // [c][key], row 272B
  __shared__ __align__(16) float mask_s[256];
  __shared__ __align__(16) unsigned short Pl[4][16][40]; // per-wave P [q][key]

  mask_s[tid] = 1e9f * ((maskT ? mask[(i64)tid*256 + b] : mask[(i64)b*256 + tid]) - 1.f);

  int q0w = qblk*64 + wave*16;
  int qg = q0w + mr;                      // this lane's q row (fixed for whole kernel)
  const float* nbq = nbQ + (i64)h*65536 + (i64)qg*256;

  // Q as B-operand fragment: direct 16B bf16 load
  bf16x8 qf = *(const bf16x8*)(q + base + (i64)qg*128 + quad*8);

  f32x4 o0 = (f32x4){0,0,0,0}, o1 = (f32x4){0,0,0,0}; // O^T[c=quad*4+r(+16)][q=mr]
  float mm = -1e30f, ll = 0.f;                         // per-lane softmax state (q = qg)

  for (int half = 0; half < 2; half++){
    __syncthreads();
    #pragma unroll
    for (int it=0; it<4; it++){
      int idx = it*256 + tid;              // 128 keys x 32 ch (4 bf16 = 8B per slot)
      int kl = idx >> 3, c4 = (idx & 7)*4;
      i64 roff = base + (i64)(half*128 + kl)*128 + c4;
      *(uint2*)&Ks[kl][c4] = *(const uint2*)(k + roff);
      uint2 gv = *(const uint2*)(v + roff);
      const unsigned short* pv = (const unsigned short*)&gv;
      Vt[c4  ][kl] = pv[0];
      Vt[c4+1][kl] = pv[1];
      Vt[c4+2][kl] = pv[2];
      Vt[c4+3][kl] = pv[3];
    }
    __syncthreads();

    #pragma unroll
    for (int it=0; it<4; it++){
      int kc = it*32;
      int kg = half*128 + kc;
      // K as A-operand: frag rows = keys kc+mr / kc+16+mr
      bf16x8 kf0 = *(const bf16x8*)&Ks[kc + mr][quad*8];
      bf16x8 kf1 = *(const bf16x8*)&Ks[kc + 16 + mr][quad*8];
      f32x4 s0 = __builtin_amdgcn_mfma_f32_16x16x32_bf16(kf0, qf, (f32x4){0,0,0,0}, 0, 0, 0);
      f32x4 s1 = __builtin_amdgcn_mfma_f32_16x16x32_bf16(kf1, qf, (f32x4){0,0,0,0}, 0, 0, 0);
      // s0[r] = S[key=kg+quad*4+r][qg]; s1[r] = S[key=kg+16+quad*4+r][qg]
      float4 nb0 = *(const float4*)(nbq + kg + quad*4);
      float4 nb1 = *(const float4*)(nbq + kg + 16 + quad*4);
      float4 mk0 = *(const float4*)&mask_s[kg + quad*4];
      float4 mk1 = *(const float4*)&mask_s[kg + 16 + quad*4];
      s0[0] += nb0.x + mk0.x; s0[1] += nb0.y + mk0.y; s0[2] += nb0.z + mk0.z; s0[3] += nb0.w + mk0.w;
      s1[0] += nb1.x + mk1.x; s1[1] += nb1.y + mk1.y; s1[2] += nb1.z + mk1.z; s1[3] += nb1.w + mk1.w;

      // per-lane online softmax over the 32-key tile (cross-quad = 2 shfls)
      float tm = fmaxf(fmaxf(fmaxf(s0[0],s0[1]), fmaxf(s0[2],s0[3])),
                       fmaxf(fmaxf(s1[0],s1[1]), fmaxf(s1[2],s1[3])));
      tm = fmaxf(tm, __shfl_xor(tm, 16));
      tm = fmaxf(tm, __shfl_xor(tm, 32));
      float nm = fmaxf(mm, tm);
      float alpha = __expf(mm - nm);
      mm = nm;
      float e00 = __expf(s0[0]-nm), e01 = __expf(s0[1]-nm);
      float e02 = __expf(s0[2]-nm), e03 = __expf(s0[3]-nm);
      float e10 = __expf(s1[0]-nm), e11 = __expf(s1[1]-nm);
      float e12 = __expf(s1[2]-nm), e13 = __expf(s1[3]-nm);
      float ps = ((e00+e01) + (e02+e03)) + ((e10+e11) + (e12+e13));
      ps += __shfl_xor(ps, 16);
      ps += __shfl_xor(ps, 32);
      ll = ll*alpha + ps;
      o0 *= alpha; o1 *= alpha;
      // P[q=mr][key] packed bf16 pairs, 2x 8B writes (2-way banks = free)
      unsigned int p0 = (unsigned int)f2bf(e00) | ((unsigned int)f2bf(e01)<<16);
      unsigned int p1 = (unsigned int)f2bf(e02) | ((unsigned int)f2bf(e03)<<16);
      unsigned int p2 = (unsigned int)f2bf(e10) | ((unsigned int)f2bf(e11)<<16);
      unsigned int p3 = (unsigned int)f2bf(e12) | ((unsigned int)f2bf(e13)<<16);
      *(uint2*)&Pl[wave][mr][quad*4]      = make_uint2(p0, p1);
      *(uint2*)&Pl[wave][mr][16 + quad*4] = make_uint2(p2, p3);
      // PV (swapped): A = V^T rows=channels, B = P [k=key][n=q=mr]
      bf16x8 pf  = *(const bf16x8*)&Pl[wave][mr][quad*8];
      bf16x8 vf0 = *(const bf16x8*)&Vt[mr     ][kc + quad*8];
      bf16x8 vf1 = *(const bf16x8*)&Vt[16 + mr][kc + quad*8];
      o0 = __builtin_amdgcn_mfma_f32_16x16x32_bf16(vf0, pf, o0, 0, 0, 0);
      o1 = __builtin_amdgcn_mfma_f32_16x16x32_bf16(vf1, pf, o1, 0, 0, 0);
    }
  }

  float inv = 1.f/ll;
  float* wp = wa + base + (i64)qg*128;
  *(float4*)(wp + quad*4)      = make_float4(o0[0]*inv, o0[1]*inv, o0[2]*inv, o0[3]*inv);
  *(float4*)(wp + 16 + quad*4) = make_float4(o1[0]*inv, o1[1]*inv, o1[2]*inv, o1[3]*inv);
}

// ---------------- host dispatch ----------------
static void gemm(hipStream_t st, bool TA, bool TB,
                 const float* A, int lda, i64 sA,
                 const float* B, int ldb, i64 sB,
                 float* C, int ldc, i64 sC,
                 int M, int N, int K, int batch,
                 const float* bias, float scale, int act,
                 const float* rowmul, int combine)
{
  dim3 g((M+63)/64, (N+63)/64, batch), bl(256);
  if (!TA && !TB)      gemm_k<false,false><<<g,bl,0,st>>>(A,lda,sA,B,ldb,sB,C,ldc,sC,M,N,K,bias,scale,act,rowmul,combine);
  else if (!TA &&  TB) gemm_k<false,true ><<<g,bl,0,st>>>(A,lda,sA,B,ldb,sB,C,ldc,sC,M,N,K,bias,scale,act,rowmul,combine);
  else                 gemm_k<true ,false><<<g,bl,0,st>>>(A,lda,sA,B,ldb,sB,C,ldc,sC,M,N,K,bias,scale,act,rowmul,combine);
}

static void mgemm(hipStream_t st, bool TA, bool TB,
                  const float* A, int lda, i64 sA,
                  const float* B, int ldb, i64 sB,
                  float* C, int ldc, i64 sC,
                  int M, int N, int K, int batch,
                  const float* bias, float scale, int act,
                  const float* rowmul, int combine, const float* aux = nullptr)
{
  dim3 bl(256);
  i64 nb128 = (i64)(M/128)*(N/128)*batch;
  if (nb128 < 1024 && (M % 64) == 0 && (N % 64) == 0){
    dim3 g(M/64, N/64, batch);
    if (!TA && !TB)      mgemm64_k<false,false><<<g,bl,0,st>>>(A,lda,sA,B,ldb,sB,C,ldc,sC,M,N,K,bias,scale,act,rowmul,combine,aux);
    else if (!TA &&  TB) mgemm64_k<false,true ><<<g,bl,0,st>>>(A,lda,sA,B,ldb,sB,C,ldc,sC,M,N,K,bias,scale,act,rowmul,combine,aux);
    else                 mgemm64_k<true ,false><<<g,bl,0,st>>>(A,lda,sA,B,ldb,sB,C,ldc,sC,M,N,K,bias,scale,act,rowmul,combine,aux);
    return;
  }
  dim3 g(M/128, N/128, batch);
  if (!TA && !TB)      mgemm_k<false,false><<<g,bl,0,st>>>(A,lda,sA,B,ldb,sB,C,ldc,sC,M,N,K,bias,scale,act,rowmul,combine,aux);
  else if (!TA &&  TB) mgemm_k<false,true ><<<g,bl,0,st>>>(A,lda,sA,B,ldb,sB,C,ldc,sC,M,N,K,bias,scale,act,rowmul,combine,aux);
  else                 mgemm_k<true ,false><<<g,bl,0,st>>>(A,lda,sA,B,ldb,sB,C,ldc,sC,M,N,K,bias,scale,act,rowmul,combine,aux);
}

static void gemm_thin(hipStream_t st,
                      const float* A, int lda, const float* B, int ldb,
                      float* C, int ldc, int M, int N, int K,
                      const float* bias, float scale, int act,
                      const float* rowmul, int combine, float* part)
{
  const int S = 8;
  int chunk = ((K/S + 15)/16)*16; if (chunk < 16) chunk = 16;
  dim3 g((M+15)/16, (N+63)/64, S);
  gemm_part_k<<<g,256,0,st>>>(A,lda,B,ldb,part,M,N,K,chunk);
  i64 t = (i64)M*N;
  gemm_reduce_k<<<(int)((t+255)/256),256,0,st>>>(part,C,ldc,M,N,S,bias,scale,act,rowmul,combine);
}

extern "C" void kernel_launch(void* const* d_in, const int* in_sizes, int n_in,
                              void* d_out, int out_size, void* d_ws, size_t ws_size,
                              hipStream_t stream)
{
  const float* IN[64];
  for (int i=0;i<n_in && i<64;i++) IN[i] = (const float*)d_in[i];

  const float* single_act = IN[0];
  const float* pair_act   = IN[1];
  const float* sm         = IN[2];
  const float* pm         = IN[3];
  const float* opm_ln     = IN[4];
  const float* opm_lr_w   = IN[5];
  const float* opm_lr_b   = IN[6];
  const float* opm_out_w  = IN[7];
  const float* opm_out_b  = IN[8];
  const float* ra_ln      = IN[9];
  const float* ra_pair_ln = IN[10];
  const float* ra_feat_w  = IN[11];
  const float* ra_qkv_w   = IN[12];
  const float* ra_gate_w  = IN[13];
  const float* ra_gate_b  = IN[14];
  const float* ra_o_w     = IN[15];
  const float* ra_o_b     = IN[16];
  const float* st_ln      = IN[17];
  const float* st_w1      = IN[18];
  const float* st_b1      = IN[19];
  const float* st_w2      = IN[20];
  const float* st_b2      = IN[21];
  const float* pt_ln      = IN[56];
  const float* pt_w1      = IN[57];
  const float* pt_b1      = IN[58];
  const float* pt_w2      = IN[59];
  const float* pt_b2      = IN[60];

  float* sa = (float*)d_out;           // [256,384]
  float* pa = (float*)d_out + 98304;   // [256,256,128]

  float* W  = (float*)d_ws;
  float* B0 = W;
  float* B1 = W + 8388608L;
  float* B2 = W + 16777216L;
  float* B3 = W + 25165824L;
  float* SMA = W + 33554432L;
  float* xs   = SMA;
  float* qb   = SMA +  98304;
  float* kb   = SMA + 196608;
  float* vb   = SMA + 294912;
  float* wab  = SMA + 393216;
  float* hst  = SMA + 491520;   // 393216
  float* nbra = SMA + 884736;   // 524288 (nb buffers: ra qkh-major / ta [h][q][k])
  float* lbuf = SMA + 1409024;  // 8192
  float* rbuf = SMA + 1417216;  // 8192
  float* Wd   = SMA + 1425408;  // 1048576

  // bf16 QKV buffers for tri-attn (each 65536x128 bf16 = 16MB):
  // q,k packed into B2 (32MB), v into first half of B3.
  unsigned short* qb16 = (unsigned short*)B2;
  unsigned short* kb16 = (unsigned short*)B2 + 8388608L;
  unsigned short* vb16 = (unsigned short*)B3;

  // init sa with residual base (pa is initialized by opm_final_k's fused write)
  copy_k<<<384, 256, 0, stream>>>(sa, single_act, 98304L);

  // ---- 1) OPM -> pair residual (writes pa = pair_act + update) ----
  ln_k<<<256,128,0,stream>>>(single_act, xs, opm_ln, 384);
  gemm_thin(stream, xs,384, opm_lr_w,32,       lbuf,32, 256,32,384, opm_lr_b,    1.f,0, sm,0, B1);
  gemm_thin(stream, xs,384, opm_lr_w+12288,32, rbuf,32, 256,32,384, opm_lr_b+32, 1.f,0, sm,0, B1);
  opm_wd_k<<<dim3(256,32),128,0,stream>>>(rbuf, opm_out_w, Wd);
  opm_final_k<<<dim3(256,16),128,0,stream>>>(lbuf, Wd, opm_out_b, sm, pair_act, pa);

  // ---- 2) row attention with pair bias ----
  ln_k<<<256,128,0,stream>>>(sa, xs, ra_ln, 384);
  ln128_k<<<16384,256,0,stream>>>(pa, B0, ra_pair_ln, 0);
  feat8_k<<<256,256,0,stream>>>(B0, ra_feat_w, nbra);
  const float qs_ra = 0.14433756729740643f; // 1/sqrt(48)
  gemm_thin(stream, xs,384, ra_qkv_w,384,        qb,384, 256,384,384, nullptr,qs_ra,0,nullptr,0, B1);
  gemm_thin(stream, xs,384, ra_qkv_w+147456,384, kb,384, 256,384,384, nullptr,1.f,0,nullptr,0, B1);
  gemm_thin(stream, xs,384, ra_qkv_w+294912,384, vb,384, 256,384,384, nullptr,1.f,0,nullptr,0, B1);
  ra_attn_k<<<dim3(256,8),256,0,stream>>>(qb, kb, vb, nbra, sm, wab);
  gemm_thin(stream, xs,384,  ra_gate_w,384, wab,384, 256,384,384, ra_gate_b,1.f,2,nullptr,2, B1);
  gemm_thin(stream, wab,384, ra_o_w,384,    sa,384,  256,384,384, ra_o_b,   1.f,0,nullptr,1, B1);

  // ---- 3) single transition ----
  ln_k<<<256,128,0,stream>>>(sa, xs, st_ln, 384);
  gemm_thin(stream, xs,384,   st_w1,1536, hst,1536, 256,1536,384, st_b1,1.f,1,nullptr,0, B1);
  gemm_thin(stream, hst,1536, st_w2,384,  sa,384,   256,384,1536, st_b2,1.f,0,nullptr,1, B1);

  // ---- 4/5) triangle multiplications ----
  auto tri_mult = [&](int base, bool outgoing){
    const float* ln_w = IN[base+0];
    const float* lr_w = IN[base+1];
    const float* lr_b = IN[base+2];
    const float* gw   = IN[base+3];
    const float* gb   = IN[base+4];
    const float* cln  = IN[base+5];
    const float* ow   = IN[base+6];
    const float* ob   = IN[base+7];
    const float* ogw  = IN[base+8];
    const float* ogb  = IN[base+9];
    ln128_k<<<16384,256,0,stream>>>(pa, B0, ln_w, 0);
    // left = mask * (X@Wl+bl) * sigmoid(X@Wg+bg): fused dual-MFMA, then transpose+mask -> B1 (ch-major)
    mlrgate_k<<<dim3(1024,2),256,0,stream>>>(B0, lr_w, lr_b, gw, gb, B3);
    tr_mask_k<<<dim3(2048,4),256,0,stream>>>(B3, pm, B1);
    // right -> B2 (ch-major)
    mlrgate_k<<<dim3(1024,2),256,0,stream>>>(B0, lr_w+16384, lr_b+128, gw+16384, gb+128, B3);
    tr_mask_k<<<dim3(2048,4),256,0,stream>>>(B3, pm, B2);
    if (outgoing) // out[i,j,c] = sum_k L_c[i,k] * R_c[j,k]
      mgemm(stream,false,true, B1,256,65536, B2,256,65536, B3,256,65536, 256,256,256,128, nullptr,1.f,0,nullptr,0);
    else          // out[i,j,c] = sum_k R_c[k,i] * L_c[k,j]
      mgemm(stream,true,false, B2,256,65536, B1,256,65536, B3,256,65536, 256,256,256,128, nullptr,1.f,0,nullptr,0);
    chw2hwc_k<<<dim3(2048,4),256,0,stream>>>(B3, B1);
    ln128_k<<<16384,256,0,stream>>>(B1, B3, cln, 0);
    mgemm(stream,false,false, B3,128,0, ow,128,0,  B1,128,0, 65536,128,128,1, ob,  1.f,0,nullptr,0);
    // fused: pa += B1 * sigmoid(B0@ogw + ogb)
    mgemm(stream,false,false, B0,128,0, ogw,128,0, pa,128,0, 65536,128,128,1, ogb, 1.f,2,nullptr,3, B1);
  };
  tri_mult(22, true);   // tmo
  tri_mult(32, false);  // tmi

  // ---- 6/7) triangle attentions ----
  auto tri_attn = [&](int base, bool percol){
    const float* ln_w   = IN[base+0];
    const float* feat_w = IN[base+1];
    const float* qkv_w  = IN[base+2];
    const float* gw     = IN[base+3];
    const float* gb     = IN[base+4];
    const float* ow     = IN[base+5];
    const float* ob     = IN[base+6];
    // LN with fused pair-transpose read for per-column attention
    ln128_k<<<16384,256,0,stream>>>(pa, B0, ln_w, percol?1:0);
    feat4_k<<<256,256,0,stream>>>(B0, feat_w, nbra);  // nb[h][q][k] direct
    const float qs = 0.17677669529663687f; // 1/sqrt(32)
    // bf16 QKV projections (f2bf moved out of ta hot loop; numerically identical)
    qkvb_k<<<dim3(1024,2),256,0,stream>>>(B0, qkv_w,       qb16, qs);
    qkvb_k<<<dim3(1024,2),256,0,stream>>>(B0, qkv_w+16384, kb16, 1.f);
    qkvb_k<<<dim3(1024,2),256,0,stream>>>(B0, qkv_w+32768, vb16, 1.f);
    ta_mfma_k<<<dim3(4096),256,0,stream>>>(qb16, kb16, vb16, nbra, pm, percol?1:0, B1);
    mgemm(stream,false,false, B0,128,0, gw,128,0, B1,128,0, 65536,128,128,1, gb,1.f,2,nullptr,2); // wa *= sigmoid(gate)
    // out-projection fused with residual add (4 = transpose-pair write for per-column)
    mgemm(stream,false,false, B1,128,0, ow,128,0, pa,128,0, 65536,128,128,1, ob,1.f,0,nullptr, percol?4:1);
  };
  tri_attn(42, false);  // tas (per-row)
  tri_attn(49, true);   // tae (per-column)

  // ---- 8) pair transition: full-M, H in bf16 spanning B1+B2 ----
  ln128_k<<<16384,256,0,stream>>>(pa, B0, pt_ln, 0);
  ptw1_k<<<dim3(512,4),256,0,stream>>>(B0, pt_w1, pt_b1, (unsigned short*)B1);
  ptw2_k<<<dim3(1024,2),256,0,stream>>>((const unsigned short*)B1, pt_w2, pt_b2, pa);
}

// Round 14
// 1272.178 us; speedup vs baseline: 1.5847x; 1.0444x over previous
//
#include <hip/hip_runtime.h>
#include <math.h>

typedef long long i64;
#define NN_ 65536L

typedef __attribute__((ext_vector_type(8))) short bf16x8;
typedef __attribute__((ext_vector_type(4))) float f32x4;

__device__ inline unsigned short f2bf(float f){
  unsigned int u = __float_as_uint(f);
  return (unsigned short)((u + 0x7FFFu + ((u>>16)&1u)) >> 16);
}

// ---------------- elementwise ----------------
__global__ __launch_bounds__(256) void copy_k(float* __restrict__ d, const float* __restrict__ s, long n){
  long i = (long)blockIdx.x*blockDim.x + threadIdx.x;
  if (i < n) d[i] = s[i];
}

// channel-major [128][65536] -> row-major [65536][128]
__global__ __launch_bounds__(256) void chw2hwc_k(const float* __restrict__ in, float* __restrict__ out){
  __shared__ float t[32][33];
  int r0 = blockIdx.x*32, c0 = blockIdx.y*32;
  int tx = threadIdx.x & 31, ty = threadIdx.x >> 5;
  for (int i = ty; i < 32; i += 8) t[i][tx] = in[(i64)(c0+i)*NN_ + r0 + tx];
  __syncthreads();
  for (int i = ty; i < 32; i += 8) out[(i64)(r0+i)*128 + c0 + tx] = t[tx][i];
}

// ---------------- fused pair-bias features ----------------
// nb[h][q][k] = sum_c X[(q*256+k)*128+c] * W[c*4+h]; one 32MB streaming read, W in LDS.
__global__ __launch_bounds__(256) void feat4_k(const float* __restrict__ X, const float* __restrict__ W,
                                               float* __restrict__ out){
  __shared__ float4 w_s[128];
  int q = blockIdx.x, k = threadIdx.x;
  if (k < 128) w_s[k] = *(const float4*)(W + k*4);
  __syncthreads();
  const float* x = X + ((i64)q*256 + k)*128;
  float a0=0.f, a1=0.f, a2=0.f, a3=0.f;
  #pragma unroll
  for (int c=0;c<128;c+=4){
    float4 v = *(const float4*)(x+c);
    float4 w0 = w_s[c], w1 = w_s[c+1], w2 = w_s[c+2], w3 = w_s[c+3];
    a0 = fmaf(v.x,w0.x,a0); a1 = fmaf(v.x,w0.y,a1); a2 = fmaf(v.x,w0.z,a2); a3 = fmaf(v.x,w0.w,a3);
    a0 = fmaf(v.y,w1.x,a0); a1 = fmaf(v.y,w1.y,a1); a2 = fmaf(v.y,w1.z,a2); a3 = fmaf(v.y,w1.w,a3);
    a0 = fmaf(v.z,w2.x,a0); a1 = fmaf(v.z,w2.y,a1); a2 = fmaf(v.z,w2.z,a2); a3 = fmaf(v.z,w2.w,a3);
    a0 = fmaf(v.w,w3.x,a0); a1 = fmaf(v.w,w3.y,a1); a2 = fmaf(v.w,w3.z,a2); a3 = fmaf(v.w,w3.w,a3);
  }
  i64 o = (i64)q*256 + k;
  out[o] = a0; out[65536+o] = a1; out[131072+o] = a2; out[196608+o] = a3;
}

// nb[(q*256+k)*8+h] = sum_c X[(q*256+k)*128+c] * W[c*8+h]  (row attention, H=8)
__global__ __launch_bounds__(256) void feat8_k(const float* __restrict__ X, const float* __restrict__ W,
                                               float* __restrict__ out){
  __shared__ float w_s[128][8];
  int q = blockIdx.x, k = threadIdx.x;
  for (int i = k; i < 1024; i += 256) ((float*)w_s)[i] = W[i];
  __syncthreads();
  const float* x = X + ((i64)q*256 + k)*128;
  float acc[8] = {};
  #pragma unroll
  for (int c=0;c<128;c+=4){
    float4 v = *(const float4*)(x+c);
    #pragma unroll
    for (int h=0;h<8;h++){
      acc[h] = fmaf(v.x, w_s[c  ][h], acc[h]);
      acc[h] = fmaf(v.y, w_s[c+1][h], acc[h]);
      acc[h] = fmaf(v.z, w_s[c+2][h], acc[h]);
      acc[h] = fmaf(v.w, w_s[c+3][h], acc[h]);
    }
  }
  float* o = out + ((i64)q*256 + k)*8;
  *(float4*)o     = make_float4(acc[0],acc[1],acc[2],acc[3]);
  *(float4*)(o+4) = make_float4(acc[4],acc[5],acc[6],acc[7]);
}

// ---------------- LayerNorm generic (rowwise, C arbitrary) ----------------
__global__ __launch_bounds__(128) void ln_k(const float* __restrict__ in, float* __restrict__ out,
                                            const float* __restrict__ w, int C){
  i64 row = blockIdx.x;
  const float* x = in + row*C;
  float* y = out + row*C;
  int tid = threadIdx.x;
  float s=0.f, s2=0.f;
  for (int c=tid;c<C;c+=128){ float v = x[c]; s += v; s2 += v*v; }
  __shared__ float rs[128], rq[128];
  rs[tid]=s; rq[tid]=s2; __syncthreads();
  for (int off=64;off>0;off>>=1){ if (tid<off){ rs[tid]+=rs[tid+off]; rq[tid]+=rq[tid+off]; } __syncthreads(); }
  float mu = rs[0]/C;
  float var = rq[0]/C - mu*mu;
  float inv = rsqrtf(var + 1e-5f);
  for (int c=tid;c<C;c+=128) y[c] = (x[c]-mu)*inv*w[c] + w[C+c];
}

// ---------------- LayerNorm C=128: one wave per row, shuffle-only reduction ----------------
// T=1: read row rt = transpose-pair index of row (fused pa transpose for per-column attention)
__global__ __launch_bounds__(256) void ln128_k(const float* __restrict__ in, float* __restrict__ out,
                                               const float* __restrict__ w, int T){
  int wv = threadIdx.x >> 6, lane = threadIdx.x & 63;
  i64 row = (i64)blockIdx.x*4 + wv;
  i64 rr = T ? (i64)((((int)row & 255) << 8) | ((int)row >> 8)) : row;
  float2 v = *(const float2*)(in + rr*128 + lane*2);
  float s = v.x + v.y, s2 = v.x*v.x + v.y*v.y;
  #pragma unroll
  for (int off=32; off; off>>=1){ s += __shfl_down(s, off); s2 += __shfl_down(s2, off); }
  s = __shfl(s, 0); s2 = __shfl(s2, 0);
  float mu = s*(1.f/128.f);
  float var = s2*(1.f/128.f) - mu*mu;
  float inv = rsqrtf(var + 1e-5f);
  float2 wl = *(const float2*)(w + lane*2);
  float2 wb = *(const float2*)(w + 128 + lane*2);
  float2 y; y.x = (v.x-mu)*inv*wl.x + wb.x; y.y = (v.y-mu)*inv*wl.y + wb.y;
  *(float2*)(out + row*128 + lane*2) = y;
}

// ---------------- bf16 MFMA GEMM: 128x128 tile, 256 thr (2x2 waves of 64x64) ----------------
// combine: 0 store, 1 +=, 2 *=, 3: C += aux*v, 4: C[transpose-pair(m)] += v (pair tensor only)
template<bool TA, bool TB>
__global__ __launch_bounds__(256) void mgemm_k(
    const float* __restrict__ A, int lda, i64 sA,
    const float* __restrict__ B, int ldb, i64 sB,
    float* __restrict__ C, int ldc, i64 sC,
    int M, int N, int K,
    const float* __restrict__ bias, float scale, int act,
    const float* __restrict__ rowmul, int combine, const float* __restrict__ aux)
{
  A += (i64)blockIdx.z * sA;
  B += (i64)blockIdx.z * sB;
  C += (i64)blockIdx.z * sC;
  int m0 = blockIdx.x * 128, n0 = blockIdx.y * 128;
  int tid = threadIdx.x;
  int wave = tid >> 6, lane = tid & 63;
  int quad = lane >> 4, mr = lane & 15;
  int wm = (wave >> 1) * 64, wn = (wave & 1) * 64;
  __shared__ unsigned short As[128][40];
  __shared__ unsigned short Bs[128][40];
  f32x4 acc[4][4];
  #pragma unroll
  for (int i=0;i<4;i++)
    #pragma unroll
    for (int j=0;j<4;j++) acc[i][j] = (f32x4){0.f,0.f,0.f,0.f};

  for (int k0 = 0; k0 < K; k0 += 32){
    if (!TA){
      #pragma unroll
      for (int it=0; it<4; it++){
        int lin = tid + it*256;
        int r = lin >> 3, c4 = (lin & 7) * 4;
        float4 g = *(const float4*)&A[(i64)(m0+r)*lda + k0 + c4];
        As[r][c4]   = f2bf(g.x); As[r][c4+1] = f2bf(g.y);
        As[r][c4+2] = f2bf(g.z); As[r][c4+3] = f2bf(g.w);
      }
    } else {
      #pragma unroll
      for (int it=0; it<4; it++){
        int lin = tid + it*256;
        int m = lin & 127, kg = (lin >> 7) * 4;
        float v0 = A[(i64)(k0+kg  )*lda + m0 + m];
        float v1 = A[(i64)(k0+kg+1)*lda + m0 + m];
        float v2 = A[(i64)(k0+kg+2)*lda + m0 + m];
        float v3 = A[(i64)(k0+kg+3)*lda + m0 + m];
        As[m][kg] = f2bf(v0); As[m][kg+1] = f2bf(v1);
        As[m][kg+2] = f2bf(v2); As[m][kg+3] = f2bf(v3);
      }
    }
    if (!TB){
      #pragma unroll
      for (int it=0; it<4; it++){
        int lin = tid + it*256;
        int n = lin & 127, kg = (lin >> 7) * 4;
        float v0 = B[(i64)(k0+kg  )*ldb + n0 + n];
        float v1 = B[(i64)(k0+kg+1)*ldb + n0 + n];
        float v2 = B[(i64)(k0+kg+2)*ldb + n0 + n];
        float v3 = B[(i64)(k0+kg+3)*ldb + n0 + n];
        Bs[n][kg] = f2bf(v0); Bs[n][kg+1] = f2bf(v1);
        Bs[n][kg+2] = f2bf(v2); Bs[n][kg+3] = f2bf(v3);
      }
    } else {
      #pragma unroll
      for (int it=0; it<4; it++){
        int lin = tid + it*256;
        int r = lin >> 3, c4 = (lin & 7) * 4;
        float4 g = *(const float4*)&B[(i64)(n0+r)*ldb + k0 + c4];
        Bs[r][c4]   = f2bf(g.x); Bs[r][c4+1] = f2bf(g.y);
        Bs[r][c4+2] = f2bf(g.z); Bs[r][c4+3] = f2bf(g.w);
      }
    }
    __syncthreads();
    bf16x8 af[4], bfr[4];
    #pragma unroll
    for (int i=0;i<4;i++) af[i]  = *(const bf16x8*)&As[wm + i*16 + mr][quad*8];
    #pragma unroll
    for (int j=0;j<4;j++) bfr[j] = *(const bf16x8*)&Bs[wn + j*16 + mr][quad*8];
    #pragma unroll
    for (int i=0;i<4;i++)
      #pragma unroll
      for (int j=0;j<4;j++)
        acc[i][j] = __builtin_amdgcn_mfma_f32_16x16x32_bf16(af[i], bfr[j], acc[i][j], 0, 0, 0);
    __syncthreads();
  }
  #pragma unroll
  for (int i=0;i<4;i++){
    #pragma unroll
    for (int r=0;r<4;r++){
      int m = m0 + wm + i*16 + quad*4 + r;
      float rm = rowmul ? rowmul[m] : 1.f;
      i64 mrow = (combine == 4) ? (i64)(((m & 255) << 8) | (m >> 8)) : (i64)m;
      #pragma unroll
      for (int j=0;j<4;j++){
        int n = n0 + wn + j*16 + mr;
        float v = acc[i][j][r] * scale;
        if (bias) v += bias[n];
        if (act == 1) v = fmaxf(v, 0.f);
        else if (act == 2) v = 1.f/(1.f + __expf(-v));
        v *= rm;
        i64 idx = mrow*ldc + n;
        if (combine == 0) C[idx] = v;
        else if (combine == 1 || combine == 4) C[idx] += v;
        else if (combine == 2) C[idx] *= v;
        else C[idx] += aux[(i64)m*ldc + n] * v;
      }
    }
  }
}

// ---------------- bf16 MFMA GEMM: 64x64 tile, 256 thr (2x2 waves of 32x32) ----------------
// NOTE (R5-R9): routing pt_w1 (M=32768,N=512,K=128,ldb=512) through this kernel correlates
// 4:0 with container failure; mechanism unknown. Do NOT route that shape here.
template<bool TA, bool TB>
__global__ __launch_bounds__(256) void mgemm64_k(
    const float* __restrict__ A, int lda, i64 sA,
    const float* __restrict__ B, int ldb, i64 sB,
    float* __restrict__ C, int ldc, i64 sC,
    int M, int N, int K,
    const float* __restrict__ bias, float scale, int act,
    const float* __restrict__ rowmul, int combine, const float* __restrict__ aux)
{
  A += (i64)blockIdx.z * sA;
  B += (i64)blockIdx.z * sB;
  C += (i64)blockIdx.z * sC;
  int m0 = blockIdx.x * 64, n0 = blockIdx.y * 64;
  int tid = threadIdx.x;
  int wave = tid >> 6, lane = tid & 63;
  int quad = lane >> 4, mr = lane & 15;
  int wm = (wave >> 1) * 32, wn = (wave & 1) * 32;
  __shared__ unsigned short As[64][40];
  __shared__ unsigned short Bs[64][40];
  f32x4 acc[2][2];
  #pragma unroll
  for (int i=0;i<2;i++)
    #pragma unroll
    for (int j=0;j<2;j++) acc[i][j] = (f32x4){0.f,0.f,0.f,0.f};

  for (int k0 = 0; k0 < K; k0 += 32){
    if (!TA){
      #pragma unroll
      for (int it=0; it<2; it++){
        int lin = tid + it*256;
        int r = lin >> 3, c4 = (lin & 7) * 4;
        float4 g = *(const float4*)&A[(i64)(m0+r)*lda + k0 + c4];
        As[r][c4]   = f2bf(g.x); As[r][c4+1] = f2bf(g.y);
        As[r][c4+2] = f2bf(g.z); As[r][c4+3] = f2bf(g.w);
      }
    } else {
      #pragma unroll
      for (int it=0; it<2; it++){
        int lin = tid + it*256;
        int m = lin & 63, kg = (lin >> 6) * 4;
        float v0 = A[(i64)(k0+kg  )*lda + m0 + m];
        float v1 = A[(i64)(k0+kg+1)*lda + m0 + m];
        float v2 = A[(i64)(k0+kg+2)*lda + m0 + m];
        float v3 = A[(i64)(k0+kg+3)*lda + m0 + m];
        As[m][kg] = f2bf(v0); As[m][kg+1] = f2bf(v1);
        As[m][kg+2] = f2bf(v2); As[m][kg+3] = f2bf(v3);
      }
    }
    if (!TB){
      #pragma unroll
      for (int it=0; it<2; it++){
        int lin = tid + it*256;
        int n = lin & 63, kg = (lin >> 6) * 4;
        float v0 = B[(i64)(k0+kg  )*ldb + n0 + n];
        float v1 = B[(i64)(k0+kg+1)*ldb + n0 + n];
        float v2 = B[(i64)(k0+kg+2)*ldb + n0 + n];
        float v3 = B[(i64)(k0+kg+3)*ldb + n0 + n];
        Bs[n][kg] = f2bf(v0); Bs[n][kg+1] = f2bf(v1);
        Bs[n][kg+2] = f2bf(v2); Bs[n][kg+3] = f2bf(v3);
      }
    } else {
      #pragma unroll
      for (int it=0; it<2; it++){
        int lin = tid + it*256;
        int r = lin >> 3, c4 = (lin & 7) * 4;
        float4 g = *(const float4*)&B[(i64)(n0+r)*ldb + k0 + c4];
        Bs[r][c4]   = f2bf(g.x); Bs[r][c4+1] = f2bf(g.y);
        Bs[r][c4+2] = f2bf(g.z); Bs[r][c4+3] = f2bf(g.w);
      }
    }
    __syncthreads();
    bf16x8 af[2], bfr[2];
    #pragma unroll
    for (int i=0;i<2;i++) af[i]  = *(const bf16x8*)&As[wm + i*16 + mr][quad*8];
    #pragma unroll
    for (int j=0;j<2;j++) bfr[j] = *(const bf16x8*)&Bs[wn + j*16 + mr][quad*8];
    #pragma unroll
    for (int i=0;i<2;i++)
      #pragma unroll
      for (int j=0;j<2;j++)
        acc[i][j] = __builtin_amdgcn_mfma_f32_16x16x32_bf16(af[i], bfr[j], acc[i][j], 0, 0, 0);
    __syncthreads();
  }
  #pragma unroll
  for (int i=0;i<2;i++){
    #pragma unroll
    for (int r=0;r<4;r++){
      int m = m0 + wm + i*16 + quad*4 + r;
      float rm = rowmul ? rowmul[m] : 1.f;
      i64 mrow = (combine == 4) ? (i64)(((m & 255) << 8) | (m >> 8)) : (i64)m;
      #pragma unroll
      for (int j=0;j<2;j++){
        int n = n0 + wn + j*16 + mr;
        float v = acc[i][j][r] * scale;
        if (bias) v += bias[n];
        if (act == 1) v = fmaxf(v, 0.f);
        else if (act == 2) v = 1.f/(1.f + __expf(-v));
        v *= rm;
        i64 idx = mrow*ldc + n;
        if (combine == 0) C[idx] = v;
        else if (combine == 1 || combine == 4) C[idx] += v;
        else if (combine == 2) C[idx] *= v;
        else C[idx] += aux[(i64)m*ldc + n] * v;
      }
    }
  }
}

// ---------------- QKV projection with bf16 output (tri-attn) ----------------
__global__ __launch_bounds__(256) void qkvb_k(
    const float* __restrict__ A, const float* __restrict__ B,
    unsigned short* __restrict__ C, float scale)
{
  int m0 = blockIdx.x * 64, n0 = blockIdx.y * 64;
  int tid = threadIdx.x;
  int wave = tid >> 6, lane = tid & 63;
  int quad = lane >> 4, mr = lane & 15;
  int wm = (wave >> 1) * 32, wn = (wave & 1) * 32;
  __shared__ unsigned short As[64][40];
  __shared__ unsigned short Bs[64][40];
  f32x4 acc[2][2];
  #pragma unroll
  for (int i=0;i<2;i++)
    #pragma unroll
    for (int j=0;j<2;j++) acc[i][j] = (f32x4){0.f,0.f,0.f,0.f};

  for (int k0 = 0; k0 < 128; k0 += 32){
    #pragma unroll
    for (int it=0; it<2; it++){
      int lin = tid + it*256;
      int r = lin >> 3, c4 = (lin & 7) * 4;
      float4 g = *(const float4*)&A[(i64)(m0+r)*128 + k0 + c4];
      As[r][c4]   = f2bf(g.x); As[r][c4+1] = f2bf(g.y);
      As[r][c4+2] = f2bf(g.z); As[r][c4+3] = f2bf(g.w);
    }
    #pragma unroll
    for (int it=0; it<2; it++){
      int lin = tid + it*256;
      int n = lin & 63, kg = (lin >> 6) * 4;
      float v0 = B[(i64)(k0+kg  )*128 + n0 + n];
      float v1 = B[(i64)(k0+kg+1)*128 + n0 + n];
      float v2 = B[(i64)(k0+kg+2)*128 + n0 + n];
      float v3 = B[(i64)(k0+kg+3)*128 + n0 + n];
      Bs[n][kg] = f2bf(v0); Bs[n][kg+1] = f2bf(v1);
      Bs[n][kg+2] = f2bf(v2); Bs[n][kg+3] = f2bf(v3);
    }
    __syncthreads();
    bf16x8 af[2], bfr[2];
    #pragma unroll
    for (int i=0;i<2;i++) af[i]  = *(const bf16x8*)&As[wm + i*16 + mr][quad*8];
    #pragma unroll
    for (int j=0;j<2;j++) bfr[j] = *(const bf16x8*)&Bs[wn + j*16 + mr][quad*8];
    #pragma unroll
    for (int i=0;i<2;i++)
      #pragma unroll
      for (int j=0;j<2;j++)
        acc[i][j] = __builtin_amdgcn_mfma_f32_16x16x32_bf16(af[i], bfr[j], acc[i][j], 0, 0, 0);
    __syncthreads();
  }
  #pragma unroll
  for (int i=0;i<2;i++){
    #pragma unroll
    for (int r=0;r<4;r++){
      int m = m0 + wm + i*16 + quad*4 + r;
      #pragma unroll
      for (int j=0;j<2;j++){
        int n = n0 + wn + j*16 + mr;
        C[(i64)m*128 + n] = f2bf(acc[i][j][r] * scale);
      }
    }
  }
}

// ---------------- fused dual-MFMA lin*sigmoid(gate) + transpose + mask for tri-mult ------
// v3 (R14): writes masked CH-MAJOR output directly via LDS transpose (staging LDS aliased
// with the f32 transpose tile after the K-loop's final barrier). Removes the 4 tr_mask
// dispatches (read+write 32MB each). T rows padded to 65 floats: transposed stores hit
// consecutive banks (stride 65 % 32 == 1 per n) -> conflict-free; reads are scalar.
__global__ __launch_bounds__(256) void mlrgateT_k(
    const float* __restrict__ X,
    const float* __restrict__ Wl, const float* __restrict__ bl,
    const float* __restrict__ Wg, const float* __restrict__ bg,
    const float* __restrict__ mask, float* __restrict__ Out)
{
  int m0 = blockIdx.x * 64, n0 = blockIdx.y * 64;
  int tid = threadIdx.x;
  int wave = tid >> 6, lane = tid & 63;
  int quad = lane >> 4, mr = lane & 15;
  int wm = (wave >> 1) * 32, wn = (wave & 1) * 32;
  __shared__ __align__(16) char smem[16640];   // max(3*5120 staging, 64*65*4 transpose)
  unsigned short (*As)[40]  = (unsigned short(*)[40])(smem);
  unsigned short (*B1s)[40] = (unsigned short(*)[40])(smem + 5120);
  unsigned short (*B2s)[40] = (unsigned short(*)[40])(smem + 10240);
  float (*T)[65] = (float(*)[65])(smem);
  f32x4 acc1[2][2], acc2[2][2];
  #pragma unroll
  for (int i=0;i<2;i++)
    #pragma unroll
    for (int j=0;j<2;j++){ acc1[i][j] = (f32x4){0,0,0,0}; acc2[i][j] = (f32x4){0,0,0,0}; }

  for (int k0 = 0; k0 < 128; k0 += 32){
    #pragma unroll
    for (int it=0; it<2; it++){
      int lin = tid + it*256;
      int r = lin >> 3, c4 = (lin & 7) * 4;
      float4 g = *(const float4*)&X[(i64)(m0+r)*128 + k0 + c4];
      As[r][c4]   = f2bf(g.x); As[r][c4+1] = f2bf(g.y);
      As[r][c4+2] = f2bf(g.z); As[r][c4+3] = f2bf(g.w);
    }
    #pragma unroll
    for (int it=0; it<2; it++){
      int lin = tid + it*256;
      int n = lin & 63, kg = (lin >> 6) * 4;
      float a0 = Wl[(i64)(k0+kg  )*128 + n0 + n];
      float a1 = Wl[(i64)(k0+kg+1)*128 + n0 + n];
      float a2 = Wl[(i64)(k0+kg+2)*128 + n0 + n];
      float a3 = Wl[(i64)(k0+kg+3)*128 + n0 + n];
      B1s[n][kg] = f2bf(a0); B1s[n][kg+1] = f2bf(a1);
      B1s[n][kg+2] = f2bf(a2); B1s[n][kg+3] = f2bf(a3);
      float g0 = Wg[(i64)(k0+kg  )*128 + n0 + n];
      float g1 = Wg[(i64)(k0+kg+1)*128 + n0 + n];
      float g2 = Wg[(i64)(k0+kg+2)*128 + n0 + n];
      float g3 = Wg[(i64)(k0+kg+3)*128 + n0 + n];
      B2s[n][kg] = f2bf(g0); B2s[n][kg+1] = f2bf(g1);
      B2s[n][kg+2] = f2bf(g2); B2s[n][kg+3] = f2bf(g3);
    }
    __syncthreads();
    bf16x8 af[2], b1f[2], b2f[2];
    #pragma unroll
    for (int i=0;i<2;i++) af[i]  = *(const bf16x8*)&As[wm + i*16 + mr][quad*8];
    #pragma unroll
    for (int j=0;j<2;j++){
      b1f[j] = *(const bf16x8*)&B1s[wn + j*16 + mr][quad*8];
      b2f[j] = *(const bf16x8*)&B2s[wn + j*16 + mr][quad*8];
    }
    #pragma unroll
    for (int i=0;i<2;i++)
      #pragma unroll
      for (int j=0;j<2;j++){
        acc1[i][j] = __builtin_amdgcn_mfma_f32_16x16x32_bf16(af[i], b1f[j], acc1[i][j], 0, 0, 0);
        acc2[i][j] = __builtin_amdgcn_mfma_f32_16x16x32_bf16(af[i], b2f[j], acc2[i][j], 0, 0, 0);
      }
    __syncthreads();
  }
  // epilogue: gated value -> transposed LDS tile T[n_local][m_local]
  #pragma unroll
  for (int i=0;i<2;i++){
    #pragma unroll
    for (int r=0;r<4;r++){
      int ml = wm + i*16 + quad*4 + r;
      #pragma unroll
      for (int j=0;j<2;j++){
        int nl = wn + j*16 + mr;
        float lv = acc1[i][j][r] + bl[n0 + nl];
        float gv = acc2[i][j][r] + bg[n0 + nl];
        T[nl][ml] = lv * (1.f/(1.f + __expf(-gv)));
      }
    }
  }
  __syncthreads();
  // coalesced masked write: thread -> row n = tid>>2, 16-col segment ms = (tid&3)*16
  int n = tid >> 2, ms = (tid & 3) * 16;
  const float* mk = mask + m0 + ms;
  float* op = Out + (i64)(n0 + n)*NN_ + m0 + ms;
  #pragma unroll
  for (int e=0; e<16; e+=4){
    float4 t4;
    t4.x = T[n][ms+e]   * mk[e];
    t4.y = T[n][ms+e+1] * mk[e+1];
    t4.z = T[n][ms+e+2] * mk[e+2];
    t4.w = T[n][ms+e+3] * mk[e+3];
    *(float4*)(op + e) = t4;
  }
}

// ---------------- pair transition, stage 1: H(bf16) = relu(X @ W1 + b1) ----------------
__global__ __launch_bounds__(256) void ptw1_k(
    const float* __restrict__ X, const float* __restrict__ W1,
    const float* __restrict__ b1, unsigned short* __restrict__ H)
{
  int m0 = blockIdx.x * 128, n0 = blockIdx.y * 128;
  int tid = threadIdx.x;
  int wave = tid >> 6, lane = tid & 63;
  int quad = lane >> 4, mr = lane & 15;
  int wm = (wave >> 1) * 64, wn = (wave & 1) * 64;
  __shared__ unsigned short As[128][40];
  __shared__ unsigned short Bs[128][40];
  f32x4 acc[4][4];
  #pragma unroll
  for (int i=0;i<4;i++)
    #pragma unroll
    for (int j=0;j<4;j++) acc[i][j] = (f32x4){0.f,0.f,0.f,0.f};

  for (int k0 = 0; k0 < 128; k0 += 32){
    #pragma unroll
    for (int it=0; it<4; it++){
      int lin = tid + it*256;
      int r = lin >> 3, c4 = (lin & 7) * 4;
      float4 g = *(const float4*)&X[(i64)(m0+r)*128 + k0 + c4];
      As[r][c4]   = f2bf(g.x); As[r][c4+1] = f2bf(g.y);
      As[r][c4+2] = f2bf(g.z); As[r][c4+3] = f2bf(g.w);
    }
    #pragma unroll
    for (int it=0; it<4; it++){
      int lin = tid + it*256;
      int n = lin & 127, kg = (lin >> 7) * 4;
      float v0 = W1[(i64)(k0+kg  )*512 + n0 + n];
      float v1 = W1[(i64)(k0+kg+1)*512 + n0 + n];
      float v2 = W1[(i64)(k0+kg+2)*512 + n0 + n];
      float v3 = W1[(i64)(k0+kg+3)*512 + n0 + n];
      Bs[n][kg] = f2bf(v0); Bs[n][kg+1] = f2bf(v1);
      Bs[n][kg+2] = f2bf(v2); Bs[n][kg+3] = f2bf(v3);
    }
    __syncthreads();
    bf16x8 af[4], bfr[4];
    #pragma unroll
    for (int i=0;i<4;i++) af[i]  = *(const bf16x8*)&As[wm + i*16 + mr][quad*8];
    #pragma unroll
    for (int j=0;j<4;j++) bfr[j] = *(const bf16x8*)&Bs[wn + j*16 + mr][quad*8];
    #pragma unroll
    for (int i=0;i<4;i++)
      #pragma unroll
      for (int j=0;j<4;j++)
        acc[i][j] = __builtin_amdgcn_mfma_f32_16x16x32_bf16(af[i], bfr[j], acc[i][j], 0, 0, 0);
    __syncthreads();
  }
  #pragma unroll
  for (int i=0;i<4;i++){
    #pragma unroll
    for (int r=0;r<4;r++){
      int m = m0 + wm + i*16 + quad*4 + r;
      #pragma unroll
      for (int j=0;j<4;j++){
        int n = n0 + wn + j*16 + mr;
        float v = fmaxf(acc[i][j][r] + b1[n], 0.f);
        H[(i64)m*512 + n] = f2bf(v);
      }
    }
  }
}

// ---------------- pair transition, stage 2: pa += H(bf16) @ W2 + b2 ----------------
__global__ __launch_bounds__(256) void ptw2_k(
    const unsigned short* __restrict__ H, const float* __restrict__ W2,
    const float* __restrict__ b2, float* __restrict__ pa)
{
  int m0 = blockIdx.x * 64, n0 = blockIdx.y * 64;
  int tid = threadIdx.x;
  int wave = tid >> 6, lane = tid & 63;
  int quad = lane >> 4, mr = lane & 15;
  int wm = (wave >> 1) * 32, wn = (wave & 1) * 32;
  __shared__ unsigned short As[64][40];
  __shared__ unsigned short Bs[64][40];
  f32x4 acc[2][2];
  #pragma unroll
  for (int i=0;i<2;i++)
    #pragma unroll
    for (int j=0;j<2;j++) acc[i][j] = (f32x4){0.f,0.f,0.f,0.f};

  for (int k0 = 0; k0 < 512; k0 += 32){
    #pragma unroll
    for (int it=0; it<2; it++){
      int lin = tid + it*256;
      int r = lin >> 3, c4 = (lin & 7) * 4;
      *(uint2*)&As[r][c4] = *(const uint2*)&H[(i64)(m0+r)*512 + k0 + c4];
    }
    #pragma unroll
    for (int it=0; it<2; it++){
      int lin = tid + it*256;
      int n = lin & 63, kg = (lin >> 6) * 4;
      float v0 = W2[(i64)(k0+kg  )*128 + n0 + n];
      float v1 = W2[(i64)(k0+kg+1)*128 + n0 + n];
      float v2 = W2[(i64)(k0+kg+2)*128 + n0 + n];
      float v3 = W2[(i64)(k0+kg+3)*128 + n0 + n];
      Bs[n][kg] = f2bf(v0); Bs[n][kg+1] = f2bf(v1);
      Bs[n][kg+2] = f2bf(v2); Bs[n][kg+3] = f2bf(v3);
    }
    __syncthreads();
    bf16x8 af[2], bfr[2];
    #pragma unroll
    for (int i=0;i<2;i++) af[i]  = *(const bf16x8*)&As[wm + i*16 + mr][quad*8];
    #pragma unroll
    for (int j=0;j<2;j++) bfr[j] = *(const bf16x8*)&Bs[wn + j*16 + mr][quad*8];
    #pragma unroll
    for (int i=0;i<2;i++)
      #pragma unroll
      for (int j=0;j<2;j++)
        acc[i][j] = __builtin_amdgcn_mfma_f32_16x16x32_bf16(af[i], bfr[j], acc[i][j], 0, 0, 0);
    __syncthreads();
  }
  #pragma unroll
  for (int i=0;i<2;i++){
    #pragma unroll
    for (int r=0;r<4;r++){
      int m = m0 + wm + i*16 + quad*4 + r;
      #pragma unroll
      for (int j=0;j<2;j++){
        int n = n0 + wn + j*16 + mr;
        pa[(i64)m*128 + n] += acc[i][j][r] + b2[n];
      }
    }
  }
}

// ---------------- generic batched GEMM (fp32, 64x64 tile) ----------------
template<bool TA, bool TB>
__global__ __launch_bounds__(256) void gemm_k(
    const float* __restrict__ A, int lda, i64 sA,
    const float* __restrict__ B, int ldb, i64 sB,
    float* __restrict__ C, int ldc, i64 sC,
    int M, int N, int K,
    const float* __restrict__ bias, float scale, int act,
    const float* __restrict__ rowmul, int combine)
{
  A += (i64)blockIdx.z * sA;
  B += (i64)blockIdx.z * sB;
  C += (i64)blockIdx.z * sC;
  int m0 = blockIdx.x * 64, n0 = blockIdx.y * 64;
  int tid = threadIdx.x, tx = tid & 15, ty = tid >> 4;
  __shared__ float As[16][68], Bs[16][68];
  float acc[4][4] = {};
  for (int k0 = 0; k0 < K; k0 += 16){
    if (TA){
      for (int l = tid; l < 1024; l += 256){
        int kk = l >> 6, mi = l & 63; int m = m0 + mi;
        As[kk][mi] = (m < M) ? A[(i64)(k0+kk)*lda + m] : 0.f;
      }
    } else {
      for (int l = tid; l < 1024; l += 256){
        int mi = l >> 4, kk = l & 15; int m = m0 + mi;
        As[kk][mi] = (m < M) ? A[(i64)m*lda + k0 + kk] : 0.f;
      }
    }
    if (TB){
      for (int l = tid; l < 1024; l += 256){
        int ni = l >> 4, kk = l & 15; int n = n0 + ni;
        Bs[kk][ni] = (n < N) ? B[(i64)n*ldb + k0 + kk] : 0.f;
      }
    } else {
      for (int l = tid; l < 1024; l += 256){
        int kk = l >> 6, ni = l & 63; int n = n0 + ni;
        Bs[kk][ni] = (n < N) ? B[(i64)(k0+kk)*ldb + n] : 0.f;
      }
    }
    __syncthreads();
    #pragma unroll
    for (int kk = 0; kk < 16; ++kk){
      float4 av4 = *(const float4*)&As[kk][ty*4];
      float4 bv4 = *(const float4*)&Bs[kk][tx*4];
      float av[4] = {av4.x, av4.y, av4.z, av4.w};
      float bv[4] = {bv4.x, bv4.y, bv4.z, bv4.w};
      #pragma unroll
      for (int i=0;i<4;i++)
        #pragma unroll
        for (int j=0;j<4;j++) acc[i][j] = fmaf(av[i], bv[j], acc[i][j]);
    }
    __syncthreads();
  }
  #pragma unroll
  for (int i=0;i<4;i++){
    int m = m0 + ty*4 + i;
    if (m >= M) continue;
    float rm = rowmul ? rowmul[m] : 1.f;
    #pragma unroll
    for (int j=0;j<4;j++){
      int n = n0 + tx*4 + j;
      if (n >= N) continue;
      float v = acc[i][j] * scale;
      if (bias) v += bias[n];
      if (act == 1) v = fmaxf(v, 0.f);
      else if (act == 2) v = 1.f/(1.f + expf(-v));
      v *= rm;
      i64 idx = (i64)m*ldc + n;
      if (combine == 0) C[idx] = v;
      else if (combine == 1) C[idx] += v;
      else C[idx] *= v;
    }
  }
}

// ---------------- thin GEMM (small M): split-K two-phase ----------------
__global__ __launch_bounds__(256) void gemm_part_k(
    const float* __restrict__ A, int lda,
    const float* __restrict__ B, int ldb,
    float* __restrict__ Cp, int M, int N, int K, int chunk)
{
  int m0 = blockIdx.x*16, n0 = blockIdx.y*64, z = blockIdx.z;
  int kb = z*chunk, ke = min(K, kb+chunk);
  int tid = threadIdx.x;
  int mi = tid >> 4, ni4 = (tid & 15)*4;
  __shared__ float As[16][17], Bs[16][68];
  float acc[4] = {0.f,0.f,0.f,0.f};
  for (int k0 = kb; k0 < ke; k0 += 16){
    { int r = tid>>4, c = tid&15; int m = m0+r;
      As[c][r] = (m < M) ? A[(i64)m*lda + k0 + c] : 0.f; }
    for (int l = tid; l < 1024; l += 256){
      int kk = l>>6, nn = l&63; int n = n0+nn;
      Bs[kk][nn] = (n < N) ? B[(i64)(k0+kk)*ldb + n] : 0.f;
    }
    __syncthreads();
    #pragma unroll
    for (int kk=0;kk<16;kk++){
      float a = As[kk][mi];
      float4 b = *(const float4*)&Bs[kk][ni4];
      acc[0]=fmaf(a,b.x,acc[0]); acc[1]=fmaf(a,b.y,acc[1]);
      acc[2]=fmaf(a,b.z,acc[2]); acc[3]=fmaf(a,b.w,acc[3]);
    }
    __syncthreads();
  }
  int m = m0+mi, n = n0+ni4;
  if (m < M && n < N) *(float4*)&Cp[((i64)z*M + m)*N + n] = *(float4*)acc;
}

__global__ __launch_bounds__(256) void gemm_reduce_k(
    const float* __restrict__ Cp, float* __restrict__ C, int ldc,
    int M, int N, int S,
    const float* __restrict__ bias, float scale, int act,
    const float* __restrict__ rowmul, int combine)
{
  i64 idx = (i64)blockIdx.x*256 + threadIdx.x;
  if (idx >= (i64)M*N) return;
  int m = (int)(idx / N), n = (int)(idx % N);
  float s = 0.f;
  for (int z=0; z<S; z++) s += Cp[(i64)z*M*N + idx];
  float v = s*scale;
  if (bias) v += bias[n];
  if (act == 1) v = fmaxf(v, 0.f);
  else if (act == 2) v = 1.f/(1.f + expf(-v));
  if (rowmul) v *= rowmul[m];
  i64 o = (i64)m*ldc + n;
  if (combine == 0) C[o] = v;
  else if (combine == 1) C[o] += v;
  else C[o] *= v;
}

// ---------------- OPM ----------------
__global__ __launch_bounds__(128) void opm_wd_k(const float* __restrict__ right, const float* __restrict__ W,
                                                float* __restrict__ Wd){
  int d = blockIdx.x, c = blockIdx.y, f = threadIdx.x;
  float acc = 0.f;
  #pragma unroll
  for (int e=0;e<32;e++) acc = fmaf(right[d*32+e], W[((i64)c*32+e)*128 + f], acc);
  Wd[((i64)d*32+c)*128 + f] = acc;
}

// pa[d,b,f] = pair_act[d,b,f] + (sum_c left[b,c]*Wd[d,c,f] + ob[f]) / (1e-3 + sm[d]*sm[b])
__global__ __launch_bounds__(128) void opm_final_k(const float* __restrict__ left, const float* __restrict__ Wd,
                                                   const float* __restrict__ ob, const float* __restrict__ sm,
                                                   const float* __restrict__ pair_act, float* __restrict__ pa){
  int d = blockIdx.x, b0 = blockIdx.y*16, f = threadIdx.x;
  __shared__ float wd_s[32][128];
  __shared__ float l_s[16][32];
  for (int c=0;c<32;c++) wd_s[c][f] = Wd[((i64)d*32+c)*128 + f];
  for (int l = f; l < 512; l += 128){ int bi=l>>5, c=l&31; l_s[bi][c] = left[(b0+bi)*32 + c]; }
  __syncthreads();
  float md = sm[d], obf = ob[f];
  for (int bi=0;bi<16;bi++){
    float acc = 0.f;
    #pragma unroll
    for (int c=0;c<32;c++) acc = fmaf(l_s[bi][c], wd_s[c][f], acc);
    int b = b0+bi;
    i64 idx = ((i64)d*256 + b)*128 + f;
    pa[idx] = pair_act[idx] + (acc + obf) / (1e-3f + md*sm[b]);
  }
}

// ---------------- row attention core ----------------
__global__ __launch_bounds__(256) void ra_attn_k(const float* __restrict__ q, const float* __restrict__ k,
                                                 const float* __restrict__ v, const float* __restrict__ nb,
                                                 const float* __restrict__ sm, float* __restrict__ wa){
  int qi = blockIdx.x, h = blockIdx.y, tid = threadIdx.x;
  __shared__ float qv[48];
  __shared__ float p[256];
  __shared__ float red[256];
  if (tid < 48) qv[tid] = q[(i64)qi*384 + h*48 + tid];
  __syncthreads();
  float acc = 0.f;
  const float* kr = k + (i64)tid*384 + h*48;
  #pragma unroll
  for (int c=0;c<48;c++) acc = fmaf(qv[c], kr[c], acc);
  acc += 1e9f*(sm[tid]-1.f) + nb[((i64)qi*256 + tid)*8 + h];
  red[tid] = acc; __syncthreads();
  for (int off=128;off>0;off>>=1){ if (tid<off) red[tid] = fmaxf(red[tid], red[tid+off]); __syncthreads(); }
  float mx = red[0]; __syncthreads();
  float e = expf(acc - mx);
  red[tid] = e; __syncthreads();
  for (int off=128;off>0;off>>=1){ if (tid<off) red[tid] += red[tid+off]; __syncthreads(); }
  p[tid] = e / red[0];
  __syncthreads();
  if (tid < 48){
    float a = 0.f;
    for (int kk=0;kk<256;kk++) a = fmaf(p[kk], v[(i64)kk*384 + h*48 + tid], a);
    wa[(i64)qi*384 + h*48 + tid] = a;
  }
}

// ---------------- triangle attention core v10: 64-key quarters for occupancy --------------
// R13: latency-bound (occ 49%, VALU 43%, HBM 14%); LDS 25KB capped residency at ~4 blocks/CU.
// v10 stages K/V in 64-key quarters: LDS 15.9KB -> 8 blocks/CU (wave cap), launch_bounds(...,8).
__global__ __launch_bounds__(256, 8) void ta_mfma_k(
    const unsigned short* __restrict__ q, const unsigned short* __restrict__ k,
    const unsigned short* __restrict__ v,
    const float* __restrict__ nbQ, const float* __restrict__ mask, int maskT,
    float* __restrict__ wa)
{
  int d = blockIdx.x;
  int xcd = d & 7, y = d >> 3;
  int b = xcd*32 + (y >> 4);
  int w = y & 15;
  int qblk = w & 3, h = w >> 2;
  int tid = threadIdx.x;
  int wave = tid >> 6, lane = tid & 63;
  int quad = lane >> 4, mr = lane & 15;
  const i64 base = ((i64)b*256)*128 + h*32;

  __shared__ __align__(16) unsigned short Ks[64][40];    // [key][c], 64-key quarter
  __shared__ __align__(16) unsigned short Vt[32][72];    // [c][key], 64-key quarter
  __shared__ __align__(16) float mask_s[256];
  __shared__ __align__(16) unsigned short Pl[4][16][40]; // per-wave P [q][key]

  mask_s[tid] = 1e9f * ((maskT ? mask[(i64)tid*256 + b] : mask[(i64)b*256 + tid]) - 1.f);

  int q0w = qblk*64 + wave*16;
  int qg = q0w + mr;                      // this lane's q row (fixed for whole kernel)
  const float* nbq = nbQ + (i64)h*65536 + (i64)qg*256;

  // Q as B-operand fragment: direct 16B bf16 load
  bf16x8 qf = *(const bf16x8*)(q + base + (i64)qg*128 + quad*8);

  f32x4 o0 = (f32x4){0,0,0,0}, o1 = (f32x4){0,0,0,0}; // O^T[c=quad*4+r(+16)][q=mr]
  float mm = -1e30f, ll = 0.f;                         // per-lane softmax state (q = qg)

  for (int qt = 0; qt < 4; qt++){
    __syncthreads();
    #pragma unroll
    for (int it=0; it<2; it++){
      int idx = it*256 + tid;              // 64 keys x 32 ch (4 bf16 = 8B per slot)
      int kl = idx >> 3, c4 = (idx & 7)*4;
      i64 roff = base + (i64)(qt*64 + kl)*128 + c4;
      *(uint2*)&Ks[kl][c4] = *(const uint2*)(k + roff);
      uint2 gv = *(const uint2*)(v + roff);
      const unsigned short* pv = (const unsigned short*)&gv;
      Vt[c4  ][kl] = pv[0];
      Vt[c4+1][kl] = pv[1];
      Vt[c4+2][kl] = pv[2];
      Vt[c4+3][kl] = pv[3];
    }
    __syncthreads();

    #pragma unroll
    for (int it=0; it<2; it++){
      int kc = it*32;
      int kg = qt*64 + kc;
      // K as A-operand: frag rows = keys kc+mr / kc+16+mr
      bf16x8 kf0 = *(const bf16x8*)&Ks[kc + mr][quad*8];
      bf16x8 kf1 = *(const bf16x8*)&Ks[kc + 16 + mr][quad*8];
      f32x4 s0 = __builtin_amdgcn_mfma_f32_16x16x32_bf16(kf0, qf, (f32x4){0,0,0,0}, 0, 0, 0);
      f32x4 s1 = __builtin_amdgcn_mfma_f32_16x16x32_bf16(kf1, qf, (f32x4){0,0,0,0}, 0, 0, 0);
      // s0[r] = S[key=kg+quad*4+r][qg]; s1[r] = S[key=kg+16+quad*4+r][qg]
      float4 nb0 = *(const float4*)(nbq + kg + quad*4);
      float4 nb1 = *(const float4*)(nbq + kg + 16 + quad*4);
      float4 mk0 = *(const float4*)&mask_s[kg + quad*4];
      float4 mk1 = *(const float4*)&mask_s[kg + 16 + quad*4];
      s0[0] += nb0.x + mk0.x; s0[1] += nb0.y + mk0.y; s0[2] += nb0.z + mk0.z; s0[3] += nb0.w + mk0.w;
      s1[0] += nb1.x + mk1.x; s1[1] += nb1.y + mk1.y; s1[2] += nb1.z + mk1.z; s1[3] += nb1.w + mk1.w;

      // per-lane online softmax over the 32-key tile (cross-quad = 2 shfls)
      float tm = fmaxf(fmaxf(fmaxf(s0[0],s0[1]), fmaxf(s0[2],s0[3])),
                       fmaxf(fmaxf(s1[0],s1[1]), fmaxf(s1[2],s1[3])));
      tm = fmaxf(tm, __shfl_xor(tm, 16));
      tm = fmaxf(tm, __shfl_xor(tm, 32));
      float nm = fmaxf(mm, tm);
      float alpha = __expf(mm - nm);
      mm = nm;
      float e00 = __expf(s0[0]-nm), e01 = __expf(s0[1]-nm);
      float e02 = __expf(s0[2]-nm), e03 = __expf(s0[3]-nm);
      float e10 = __expf(s1[0]-nm), e11 = __expf(s1[1]-nm);
      float e12 = __expf(s1[2]-nm), e13 = __expf(s1[3]-nm);
      float ps = ((e00+e01) + (e02+e03)) + ((e10+e11) + (e12+e13));
      ps += __shfl_xor(ps, 16);
      ps += __shfl_xor(ps, 32);
      ll = ll*alpha + ps;
      o0 *= alpha; o1 *= alpha;
      // P[q=mr][key] packed bf16 pairs, 2x 8B writes (2-way banks = free)
      unsigned int p0 = (unsigned int)f2bf(e00) | ((unsigned int)f2bf(e01)<<16);
      unsigned int p1 = (unsigned int)f2bf(e02) | ((unsigned int)f2bf(e03)<<16);
      unsigned int p2 = (unsigned int)f2bf(e10) | ((unsigned int)f2bf(e11)<<16);
      unsigned int p3 = (unsigned int)f2bf(e12) | ((unsigned int)f2bf(e13)<<16);
      *(uint2*)&Pl[wave][mr][quad*4]      = make_uint2(p0, p1);
      *(uint2*)&Pl[wave][mr][16 + quad*4] = make_uint2(p2, p3);
      // PV (swapped): A = V^T rows=channels, B = P [k=key][n=q=mr]
      bf16x8 pf  = *(const bf16x8*)&Pl[wave][mr][quad*8];
      bf16x8 vf0 = *(const bf16x8*)&Vt[mr     ][kc + quad*8];
      bf16x8 vf1 = *(const bf16x8*)&Vt[16 + mr][kc + quad*8];
      o0 = __builtin_amdgcn_mfma_f32_16x16x32_bf16(vf0, pf, o0, 0, 0, 0);
      o1 = __builtin_amdgcn_mfma_f32_16x16x32_bf16(vf1, pf, o1, 0, 0, 0);
    }
  }

  float inv = 1.f/ll;
  float* wp = wa + base + (i64)qg*128;
  *(float4*)(wp + quad*4)      = make_float4(o0[0]*inv, o0[1]*inv, o0[2]*inv, o0[3]*inv);
  *(float4*)(wp + 16 + quad*4) = make_float4(o1[0]*inv, o1[1]*inv, o1[2]*inv, o1[3]*inv);
}

// ---------------- host dispatch ----------------
static void gemm(hipStream_t st, bool TA, bool TB,
                 const float* A, int lda, i64 sA,
                 const float* B, int ldb, i64 sB,
                 float* C, int ldc, i64 sC,
                 int M, int N, int K, int batch,
                 const float* bias, float scale, int act,
                 const float* rowmul, int combine)
{
  dim3 g((M+63)/64, (N+63)/64, batch), bl(256);
  if (!TA && !TB)      gemm_k<false,false><<<g,bl,0,st>>>(A,lda,sA,B,ldb,sB,C,ldc,sC,M,N,K,bias,scale,act,rowmul,combine);
  else if (!TA &&  TB) gemm_k<false,true ><<<g,bl,0,st>>>(A,lda,sA,B,ldb,sB,C,ldc,sC,M,N,K,bias,scale,act,rowmul,combine);
  else                 gemm_k<true ,false><<<g,bl,0,st>>>(A,lda,sA,B,ldb,sB,C,ldc,sC,M,N,K,bias,scale,act,rowmul,combine);
}

static void mgemm(hipStream_t st, bool TA, bool TB,
                  const float* A, int lda, i64 sA,
                  const float* B, int ldb, i64 sB,
                  float* C, int ldc, i64 sC,
                  int M, int N, int K, int batch,
                  const float* bias, float scale, int act,
                  const float* rowmul, int combine, const float* aux = nullptr)
{
  dim3 bl(256);
  i64 nb128 = (i64)(M/128)*(N/128)*batch;
  if (nb128 < 1024 && (M % 64) == 0 && (N % 64) == 0){
    dim3 g(M/64, N/64, batch);
    if (!TA && !TB)      mgemm64_k<false,false><<<g,bl,0,st>>>(A,lda,sA,B,ldb,sB,C,ldc,sC,M,N,K,bias,scale,act,rowmul,combine,aux);
    else if (!TA &&  TB) mgemm64_k<false,true ><<<g,bl,0,st>>>(A,lda,sA,B,ldb,sB,C,ldc,sC,M,N,K,bias,scale,act,rowmul,combine,aux);
    else                 mgemm64_k<true ,false><<<g,bl,0,st>>>(A,lda,sA,B,ldb,sB,C,ldc,sC,M,N,K,bias,scale,act,rowmul,combine,aux);
    return;
  }
  dim3 g(M/128, N/128, batch);
  if (!TA && !TB)      mgemm_k<false,false><<<g,bl,0,st>>>(A,lda,sA,B,ldb,sB,C,ldc,sC,M,N,K,bias,scale,act,rowmul,combine,aux);
  else if (!TA &&  TB) mgemm_k<false,true ><<<g,bl,0,st>>>(A,lda,sA,B,ldb,sB,C,ldc,sC,M,N,K,bias,scale,act,rowmul,combine,aux);
  else                 mgemm_k<true ,false><<<g,bl,0,st>>>(A,lda,sA,B,ldb,sB,C,ldc,sC,M,N,K,bias,scale,act,rowmul,combine,aux);
}

static void gemm_thin(hipStream_t st,
                      const float* A, int lda, const float* B, int ldb,
                      float* C, int ldc, int M, int N, int K,
                      const float* bias, float scale, int act,
                      const float* rowmul, int combine, float* part)
{
  const int S = 8;
  int chunk = ((K/S + 15)/16)*16; if (chunk < 16) chunk = 16;
  dim3 g((M+15)/16, (N+63)/64, S);
  gemm_part_k<<<g,256,0,st>>>(A,lda,B,ldb,part,M,N,K,chunk);
  i64 t = (i64)M*N;
  gemm_reduce_k<<<(int)((t+255)/256),256,0,st>>>(part,C,ldc,M,N,S,bias,scale,act,rowmul,combine);
}

extern "C" void kernel_launch(void* const* d_in, const int* in_sizes, int n_in,
                              void* d_out, int out_size, void* d_ws, size_t ws_size,
                              hipStream_t stream)
{
  const float* IN[64];
  for (int i=0;i<n_in && i<64;i++) IN[i] = (const float*)d_in[i];

  const float* single_act = IN[0];
  const float* pair_act   = IN[1];
  const float* sm         = IN[2];
  const float* pm         = IN[3];
  const float* opm_ln     = IN[4];
  const float* opm_lr_w   = IN[5];
  const float* opm_lr_b   = IN[6];
  const float* opm_out_w  = IN[7];
  const float* opm_out_b  = IN[8];
  const float* ra_ln      = IN[9];
  const float* ra_pair_ln = IN[10];
  const float* ra_feat_w  = IN[11];
  const float* ra_qkv_w   = IN[12];
  const float* ra_gate_w  = IN[13];
  const float* ra_gate_b  = IN[14];
  const float* ra_o_w     = IN[15];
  const float* ra_o_b     = IN[16];
  const float* st_ln      = IN[17];
  const float* st_w1      = IN[18];
  const float* st_b1      = IN[19];
  const float* st_w2      = IN[20];
  const float* st_b2      = IN[21];
  const float* pt_ln      = IN[56];
  const float* pt_w1      = IN[57];
  const float* pt_b1      = IN[58];
  const float* pt_w2      = IN[59];
  const float* pt_b2      = IN[60];

  float* sa = (float*)d_out;           // [256,384]
  float* pa = (float*)d_out + 98304;   // [256,256,128]

  float* W  = (float*)d_ws;
  float* B0 = W;
  float* B1 = W + 8388608L;
  float* B2 = W + 16777216L;
  float* B3 = W + 25165824L;
  float* SMA = W + 33554432L;
  float* xs   = SMA;
  float* qb   = SMA +  98304;
  float* kb   = SMA + 196608;
  float* vb   = SMA + 294912;
  float* wab  = SMA + 393216;
  float* hst  = SMA + 491520;   // 393216
  float* nbra = SMA + 884736;   // 524288 (nb buffers: ra qkh-major / ta [h][q][k])
  float* lbuf = SMA + 1409024;  // 8192
  float* rbuf = SMA + 1417216;  // 8192
  float* Wd   = SMA + 1425408;  // 1048576

  // bf16 QKV buffers for tri-attn (each 65536x128 bf16 = 16MB):
  // q,k packed into B2 (32MB), v into first half of B3.
  unsigned short* qb16 = (unsigned short*)B2;
  unsigned short* kb16 = (unsigned short*)B2 + 8388608L;
  unsigned short* vb16 = (unsigned short*)B3;

  // init sa with residual base (pa is initialized by opm_final_k's fused write)
  copy_k<<<384, 256, 0, stream>>>(sa, single_act, 98304L);

  // ---- 1) OPM -> pair residual (writes pa = pair_act + update) ----
  ln_k<<<256,128,0,stream>>>(single_act, xs, opm_ln, 384);
  gemm_thin(stream, xs,384, opm_lr_w,32,       lbuf,32, 256,32,384, opm_lr_b,    1.f,0, sm,0, B1);
  gemm_thin(stream, xs,384, opm_lr_w+12288,32, rbuf,32, 256,32,384, opm_lr_b+32, 1.f,0, sm,0, B1);
  opm_wd_k<<<dim3(256,32),128,0,stream>>>(rbuf, opm_out_w, Wd);
  opm_final_k<<<dim3(256,16),128,0,stream>>>(lbuf, Wd, opm_out_b, sm, pair_act, pa);

  // ---- 2) row attention with pair bias ----
  ln_k<<<256,128,0,stream>>>(sa, xs, ra_ln, 384);
  ln128_k<<<16384,256,0,stream>>>(pa, B0, ra_pair_ln, 0);
  feat8_k<<<256,256,0,stream>>>(B0, ra_feat_w, nbra);
  const float qs_ra = 0.14433756729740643f; // 1/sqrt(48)
  gemm_thin(stream, xs,384, ra_qkv_w,384,        qb,384, 256,384,384, nullptr,qs_ra,0,nullptr,0, B1);
  gemm_thin(stream, xs,384, ra_qkv_w+147456,384, kb,384, 256,384,384, nullptr,1.f,0,nullptr,0, B1);
  gemm_thin(stream, xs,384, ra_qkv_w+294912,384, vb,384, 256,384,384, nullptr,1.f,0,nullptr,0, B1);
  ra_attn_k<<<dim3(256,8),256,0,stream>>>(qb, kb, vb, nbra, sm, wab);
  gemm_thin(stream, xs,384,  ra_gate_w,384, wab,384, 256,384,384, ra_gate_b,1.f,2,nullptr,2, B1);
  gemm_thin(stream, wab,384, ra_o_w,384,    sa,384,  256,384,384, ra_o_b,   1.f,0,nullptr,1, B1);

  // ---- 3) single transition ----
  ln_k<<<256,128,0,stream>>>(sa, xs, st_ln, 384);
  gemm_thin(stream, xs,384,   st_w1,1536, hst,1536, 256,1536,384, st_b1,1.f,1,nullptr,0, B1);
  gemm_thin(stream, hst,1536, st_w2,384,  sa,384,   256,384,1536, st_b2,1.f,0,nullptr,1, B1);

  // ---- 4/5) triangle multiplications ----
  auto tri_mult = [&](int base, bool outgoing){
    const float* ln_w = IN[base+0];
    const float* lr_w = IN[base+1];
    const float* lr_b = IN[base+2];
    const float* gw   = IN[base+3];
    const float* gb   = IN[base+4];
    const float* cln  = IN[base+5];
    const float* ow   = IN[base+6];
    const float* ob   = IN[base+7];
    const float* ogw  = IN[base+8];
    const float* ogb  = IN[base+9];
    ln128_k<<<16384,256,0,stream>>>(pa, B0, ln_w, 0);
    // left/right = mask * (X@W+b) * sigmoid(X@Wg+bg), written DIRECTLY ch-major (fused transpose)
    mlrgateT_k<<<dim3(1024,2),256,0,stream>>>(B0, lr_w, lr_b, gw, gb, pm, B1);
    mlrgateT_k<<<dim3(1024,2),256,0,stream>>>(B0, lr_w+16384, lr_b+128, gw+16384, gb+128, pm, B2);
    if (outgoing) // out[i,j,c] = sum_k L_c[i,k] * R_c[j,k]
      mgemm(stream,false,true, B1,256,65536, B2,256,65536, B3,256,65536, 256,256,256,128, nullptr,1.f,0,nullptr,0);
    else          // out[i,j,c] = sum_k R_c[k,i] * L_c[k,j]
      mgemm(stream,true,false, B2,256,65536, B1,256,65536, B3,256,65536, 256,256,256,128, nullptr,1.f,0,nullptr,0);
    chw2hwc_k<<<dim3(2048,4),256,0,stream>>>(B3, B1);
    ln128_k<<<16384,256,0,stream>>>(B1, B3, cln, 0);
    mgemm(stream,false,false, B3,128,0, ow,128,0,  B1,128,0, 65536,128,128,1, ob,  1.f,0,nullptr,0);
    // fused: pa += B1 * sigmoid(B0@ogw + ogb)
    mgemm(stream,false,false, B0,128,0, ogw,128,0, pa,128,0, 65536,128,128,1, ogb, 1.f,2,nullptr,3, B1);
  };
  tri_mult(22, true);   // tmo
  tri_mult(32, false);  // tmi

  // ---- 6/7) triangle attentions ----
  auto tri_attn = [&](int base, bool percol){
    const float* ln_w   = IN[base+0];
    const float* feat_w = IN[base+1];
    const float* qkv_w  = IN[base+2];
    const float* gw     = IN[base+3];
    const float* gb     = IN[base+4];
    const float* ow     = IN[base+5];
    const float* ob     = IN[base+6];
    // LN with fused pair-transpose read for per-column attention
    ln128_k<<<16384,256,0,stream>>>(pa, B0, ln_w, percol?1:0);
    feat4_k<<<256,256,0,stream>>>(B0, feat_w, nbra);  // nb[h][q][k] direct
    const float qs = 0.17677669529663687f; // 1/sqrt(32)
    // bf16 QKV projections (f2bf moved out of ta hot loop; numerically identical)
    qkvb_k<<<dim3(1024,2),256,0,stream>>>(B0, qkv_w,       qb16, qs);
    qkvb_k<<<dim3(1024,2),256,0,stream>>>(B0, qkv_w+16384, kb16, 1.f);
    qkvb_k<<<dim3(1024,2),256,0,stream>>>(B0, qkv_w+32768, vb16, 1.f);
    ta_mfma_k<<<dim3(4096),256,0,stream>>>(qb16, kb16, vb16, nbra, pm, percol?1:0, B1);
    mgemm(stream,false,false, B0,128,0, gw,128,0, B1,128,0, 65536,128,128,1, gb,1.f,2,nullptr,2); // wa *= sigmoid(gate)
    // out-projection fused with residual add (4 = transpose-pair write for per-column)
    mgemm(stream,false,false, B1,128,0, ow,128,0, pa,128,0, 65536,128,128,1, ob,1.f,0,nullptr, percol?4:1);
  };
  tri_attn(42, false);  // tas (per-row)
  tri_attn(49, true);   // tae (per-column)

  // ---- 8) pair transition: full-M, H in bf16 spanning B1+B2 ----
  ln128_k<<<16384,256,0,stream>>>(pa, B0, pt_ln, 0);
  ptw1_k<<<dim3(512,4),256,0,stream>>>(B0, pt_w1, pt_b1, (unsigned short*)B1);
  ptw2_k<<<dim3(1024,2),256,0,stream>>>((const unsigned short*)B1, pt_w2, pt_b2, pa);
}

// Round 15
// 1268.234 us; speedup vs baseline: 1.5896x; 1.0031x over previous
//
#include <hip/hip_runtime.h>
#include <math.h>

typedef long long i64;
#define NN_ 65536L

typedef __attribute__((ext_vector_type(8))) short bf16x8;
typedef __attribute__((ext_vector_type(4))) float f32x4;

__device__ inline unsigned short f2bf(float f){
  unsigned int u = __float_as_uint(f);
  return (unsigned short)((u + 0x7FFFu + ((u>>16)&1u)) >> 16);
}

// ---------------- elementwise ----------------
__global__ __launch_bounds__(256) void copy_k(float* __restrict__ d, const float* __restrict__ s, long n){
  long i = (long)blockIdx.x*blockDim.x + threadIdx.x;
  if (i < n) d[i] = s[i];
}

// channel-major [128][65536] -> row-major [65536][128]
__global__ __launch_bounds__(256) void chw2hwc_k(const float* __restrict__ in, float* __restrict__ out){
  __shared__ float t[32][33];
  int r0 = blockIdx.x*32, c0 = blockIdx.y*32;
  int tx = threadIdx.x & 31, ty = threadIdx.x >> 5;
  for (int i = ty; i < 32; i += 8) t[i][tx] = in[(i64)(c0+i)*NN_ + r0 + tx];
  __syncthreads();
  for (int i = ty; i < 32; i += 8) out[(i64)(r0+i)*128 + c0 + tx] = t[tx][i];
}

// ---------------- fused pair-bias features ----------------
__global__ __launch_bounds__(256) void feat4_k(const float* __restrict__ X, const float* __restrict__ W,
                                               float* __restrict__ out){
  __shared__ float4 w_s[128];
  int q = blockIdx.x, k = threadIdx.x;
  if (k < 128) w_s[k] = *(const float4*)(W + k*4);
  __syncthreads();
  const float* x = X + ((i64)q*256 + k)*128;
  float a0=0.f, a1=0.f, a2=0.f, a3=0.f;
  #pragma unroll
  for (int c=0;c<128;c+=4){
    float4 v = *(const float4*)(x+c);
    float4 w0 = w_s[c], w1 = w_s[c+1], w2 = w_s[c+2], w3 = w_s[c+3];
    a0 = fmaf(v.x,w0.x,a0); a1 = fmaf(v.x,w0.y,a1); a2 = fmaf(v.x,w0.z,a2); a3 = fmaf(v.x,w0.w,a3);
    a0 = fmaf(v.y,w1.x,a0); a1 = fmaf(v.y,w1.y,a1); a2 = fmaf(v.y,w1.z,a2); a3 = fmaf(v.y,w1.w,a3);
    a0 = fmaf(v.z,w2.x,a0); a1 = fmaf(v.z,w2.y,a1); a2 = fmaf(v.z,w2.z,a2); a3 = fmaf(v.z,w2.w,a3);
    a0 = fmaf(v.w,w3.x,a0); a1 = fmaf(v.w,w3.y,a1); a2 = fmaf(v.w,w3.z,a2); a3 = fmaf(v.w,w3.w,a3);
  }
  i64 o = (i64)q*256 + k;
  out[o] = a0; out[65536+o] = a1; out[131072+o] = a2; out[196608+o] = a3;
}

// nb[(q*256+k)*8+h] (row attention, H=8)
__global__ __launch_bounds__(256) void feat8_k(const float* __restrict__ X, const float* __restrict__ W,
                                               float* __restrict__ out){
  __shared__ float w_s[128][8];
  int q = blockIdx.x, k = threadIdx.x;
  for (int i = k; i < 1024; i += 256) ((float*)w_s)[i] = W[i];
  __syncthreads();
  const float* x = X + ((i64)q*256 + k)*128;
  float acc[8] = {};
  #pragma unroll
  for (int c=0;c<128;c+=4){
    float4 v = *(const float4*)(x+c);
    #pragma unroll
    for (int h=0;h<8;h++){
      acc[h] = fmaf(v.x, w_s[c  ][h], acc[h]);
      acc[h] = fmaf(v.y, w_s[c+1][h], acc[h]);
      acc[h] = fmaf(v.z, w_s[c+2][h], acc[h]);
      acc[h] = fmaf(v.w, w_s[c+3][h], acc[h]);
    }
  }
  float* o = out + ((i64)q*256 + k)*8;
  *(float4*)o     = make_float4(acc[0],acc[1],acc[2],acc[3]);
  *(float4*)(o+4) = make_float4(acc[4],acc[5],acc[6],acc[7]);
}

// ---------------- LayerNorm generic (rowwise, C arbitrary) ----------------
__global__ __launch_bounds__(128) void ln_k(const float* __restrict__ in, float* __restrict__ out,
                                            const float* __restrict__ w, int C){
  i64 row = blockIdx.x;
  const float* x = in + row*C;
  float* y = out + row*C;
  int tid = threadIdx.x;
  float s=0.f, s2=0.f;
  for (int c=tid;c<C;c+=128){ float v = x[c]; s += v; s2 += v*v; }
  __shared__ float rs[128], rq[128];
  rs[tid]=s; rq[tid]=s2; __syncthreads();
  for (int off=64;off>0;off>>=1){ if (tid<off){ rs[tid]+=rs[tid+off]; rq[tid]+=rq[tid+off]; } __syncthreads(); }
  float mu = rs[0]/C;
  float var = rq[0]/C - mu*mu;
  float inv = rsqrtf(var + 1e-5f);
  for (int c=tid;c<C;c+=128) y[c] = (x[c]-mu)*inv*w[c] + w[C+c];
}

// ---------------- LayerNorm C=128 ----------------
__global__ __launch_bounds__(256) void ln128_k(const float* __restrict__ in, float* __restrict__ out,
                                               const float* __restrict__ w, int T){
  int wv = threadIdx.x >> 6, lane = threadIdx.x & 63;
  i64 row = (i64)blockIdx.x*4 + wv;
  i64 rr = T ? (i64)((((int)row & 255) << 8) | ((int)row >> 8)) : row;
  float2 v = *(const float2*)(in + rr*128 + lane*2);
  float s = v.x + v.y, s2 = v.x*v.x + v.y*v.y;
  #pragma unroll
  for (int off=32; off; off>>=1){ s += __shfl_down(s, off); s2 += __shfl_down(s2, off); }
  s = __shfl(s, 0); s2 = __shfl(s2, 0);
  float mu = s*(1.f/128.f);
  float var = s2*(1.f/128.f) - mu*mu;
  float inv = rsqrtf(var + 1e-5f);
  float2 wl = *(const float2*)(w + lane*2);
  float2 wb = *(const float2*)(w + 128 + lane*2);
  float2 y; y.x = (v.x-mu)*inv*wl.x + wb.x; y.y = (v.y-mu)*inv*wl.y + wb.y;
  *(float2*)(out + row*128 + lane*2) = y;
}

// ---------------- bf16 MFMA GEMM: 128x128 tile ----------------
template<bool TA, bool TB>
__global__ __launch_bounds__(256) void mgemm_k(
    const float* __restrict__ A, int lda, i64 sA,
    const float* __restrict__ B, int ldb, i64 sB,
    float* __restrict__ C, int ldc, i64 sC,
    int M, int N, int K,
    const float* __restrict__ bias, float scale, int act,
    const float* __restrict__ rowmul, int combine, const float* __restrict__ aux)
{
  A += (i64)blockIdx.z * sA;
  B += (i64)blockIdx.z * sB;
  C += (i64)blockIdx.z * sC;
  int m0 = blockIdx.x * 128, n0 = blockIdx.y * 128;
  int tid = threadIdx.x;
  int wave = tid >> 6, lane = tid & 63;
  int quad = lane >> 4, mr = lane & 15;
  int wm = (wave >> 1) * 64, wn = (wave & 1) * 64;
  __shared__ unsigned short As[128][40];
  __shared__ unsigned short Bs[128][40];
  f32x4 acc[4][4];
  #pragma unroll
  for (int i=0;i<4;i++)
    #pragma unroll
    for (int j=0;j<4;j++) acc[i][j] = (f32x4){0.f,0.f,0.f,0.f};

  for (int k0 = 0; k0 < K; k0 += 32){
    if (!TA){
      #pragma unroll
      for (int it=0; it<4; it++){
        int lin = tid + it*256;
        int r = lin >> 3, c4 = (lin & 7) * 4;
        float4 g = *(const float4*)&A[(i64)(m0+r)*lda + k0 + c4];
        As[r][c4]   = f2bf(g.x); As[r][c4+1] = f2bf(g.y);
        As[r][c4+2] = f2bf(g.z); As[r][c4+3] = f2bf(g.w);
      }
    } else {
      #pragma unroll
      for (int it=0; it<4; it++){
        int lin = tid + it*256;
        int m = lin & 127, kg = (lin >> 7) * 4;
        float v0 = A[(i64)(k0+kg  )*lda + m0 + m];
        float v1 = A[(i64)(k0+kg+1)*lda + m0 + m];
        float v2 = A[(i64)(k0+kg+2)*lda + m0 + m];
        float v3 = A[(i64)(k0+kg+3)*lda + m0 + m];
        As[m][kg] = f2bf(v0); As[m][kg+1] = f2bf(v1);
        As[m][kg+2] = f2bf(v2); As[m][kg+3] = f2bf(v3);
      }
    }
    if (!TB){
      #pragma unroll
      for (int it=0; it<4; it++){
        int lin = tid + it*256;
        int n = lin & 127, kg = (lin >> 7) * 4;
        float v0 = B[(i64)(k0+kg  )*ldb + n0 + n];
        float v1 = B[(i64)(k0+kg+1)*ldb + n0 + n];
        float v2 = B[(i64)(k0+kg+2)*ldb + n0 + n];
        float v3 = B[(i64)(k0+kg+3)*ldb + n0 + n];
        Bs[n][kg] = f2bf(v0); Bs[n][kg+1] = f2bf(v1);
        Bs[n][kg+2] = f2bf(v2); Bs[n][kg+3] = f2bf(v3);
      }
    } else {
      #pragma unroll
      for (int it=0; it<4; it++){
        int lin = tid + it*256;
        int r = lin >> 3, c4 = (lin & 7) * 4;
        float4 g = *(const float4*)&B[(i64)(n0+r)*ldb + k0 + c4];
        Bs[r][c4]   = f2bf(g.x); Bs[r][c4+1] = f2bf(g.y);
        Bs[r][c4+2] = f2bf(g.z); Bs[r][c4+3] = f2bf(g.w);
      }
    }
    __syncthreads();
    bf16x8 af[4], bfr[4];
    #pragma unroll
    for (int i=0;i<4;i++) af[i]  = *(const bf16x8*)&As[wm + i*16 + mr][quad*8];
    #pragma unroll
    for (int j=0;j<4;j++) bfr[j] = *(const bf16x8*)&Bs[wn + j*16 + mr][quad*8];
    #pragma unroll
    for (int i=0;i<4;i++)
      #pragma unroll
      for (int j=0;j<4;j++)
        acc[i][j] = __builtin_amdgcn_mfma_f32_16x16x32_bf16(af[i], bfr[j], acc[i][j], 0, 0, 0);
    __syncthreads();
  }
  #pragma unroll
  for (int i=0;i<4;i++){
    #pragma unroll
    for (int r=0;r<4;r++){
      int m = m0 + wm + i*16 + quad*4 + r;
      float rm = rowmul ? rowmul[m] : 1.f;
      i64 mrow = (combine == 4) ? (i64)(((m & 255) << 8) | (m >> 8)) : (i64)m;
      #pragma unroll
      for (int j=0;j<4;j++){
        int n = n0 + wn + j*16 + mr;
        float v = acc[i][j][r] * scale;
        if (bias) v += bias[n];
        if (act == 1) v = fmaxf(v, 0.f);
        else if (act == 2) v = 1.f/(1.f + __expf(-v));
        v *= rm;
        i64 idx = mrow*ldc + n;
        if (combine == 0) C[idx] = v;
        else if (combine == 1 || combine == 4) C[idx] += v;
        else if (combine == 2) C[idx] *= v;
        else C[idx] += aux[(i64)m*ldc + n] * v;
      }
    }
  }
}

// ---------------- bf16 MFMA GEMM: 64x64 tile ----------------
// NOTE (R5-R9): routing pt_w1 (M=32768,N=512,K=128,ldb=512) through this kernel correlates
// 4:0 with container failure; mechanism unknown. Do NOT route that shape here.
template<bool TA, bool TB>
__global__ __launch_bounds__(256) void mgemm64_k(
    const float* __restrict__ A, int lda, i64 sA,
    const float* __restrict__ B, int ldb, i64 sB,
    float* __restrict__ C, int ldc, i64 sC,
    int M, int N, int K,
    const float* __restrict__ bias, float scale, int act,
    const float* __restrict__ rowmul, int combine, const float* __restrict__ aux)
{
  A += (i64)blockIdx.z * sA;
  B += (i64)blockIdx.z * sB;
  C += (i64)blockIdx.z * sC;
  int m0 = blockIdx.x * 64, n0 = blockIdx.y * 64;
  int tid = threadIdx.x;
  int wave = tid >> 6, lane = tid & 63;
  int quad = lane >> 4, mr = lane & 15;
  int wm = (wave >> 1) * 32, wn = (wave & 1) * 32;
  __shared__ unsigned short As[64][40];
  __shared__ unsigned short Bs[64][40];
  f32x4 acc[2][2];
  #pragma unroll
  for (int i=0;i<2;i++)
    #pragma unroll
    for (int j=0;j<2;j++) acc[i][j] = (f32x4){0.f,0.f,0.f,0.f};

  for (int k0 = 0; k0 < K; k0 += 32){
    if (!TA){
      #pragma unroll
      for (int it=0; it<2; it++){
        int lin = tid + it*256;
        int r = lin >> 3, c4 = (lin & 7) * 4;
        float4 g = *(const float4*)&A[(i64)(m0+r)*lda + k0 + c4];
        As[r][c4]   = f2bf(g.x); As[r][c4+1] = f2bf(g.y);
        As[r][c4+2] = f2bf(g.z); As[r][c4+3] = f2bf(g.w);
      }
    } else {
      #pragma unroll
      for (int it=0; it<2; it++){
        int lin = tid + it*256;
        int m = lin & 63, kg = (lin >> 6) * 4;
        float v0 = A[(i64)(k0+kg  )*lda + m0 + m];
        float v1 = A[(i64)(k0+kg+1)*lda + m0 + m];
        float v2 = A[(i64)(k0+kg+2)*lda + m0 + m];
        float v3 = A[(i64)(k0+kg+3)*lda + m0 + m];
        As[m][kg] = f2bf(v0); As[m][kg+1] = f2bf(v1);
        As[m][kg+2] = f2bf(v2); As[m][kg+3] = f2bf(v3);
      }
    }
    if (!TB){
      #pragma unroll
      for (int it=0; it<2; it++){
        int lin = tid + it*256;
        int n = lin & 63, kg = (lin >> 6) * 4;
        float v0 = B[(i64)(k0+kg  )*ldb + n0 + n];
        float v1 = B[(i64)(k0+kg+1)*ldb + n0 + n];
        float v2 = B[(i64)(k0+kg+2)*ldb + n0 + n];
        float v3 = B[(i64)(k0+kg+3)*ldb + n0 + n];
        Bs[n][kg] = f2bf(v0); Bs[n][kg+1] = f2bf(v1);
        Bs[n][kg+2] = f2bf(v2); Bs[n][kg+3] = f2bf(v3);
      }
    } else {
      #pragma unroll
      for (int it=0; it<2; it++){
        int lin = tid + it*256;
        int r = lin >> 3, c4 = (lin & 7) * 4;
        float4 g = *(const float4*)&B[(i64)(n0+r)*ldb + k0 + c4];
        Bs[r][c4]   = f2bf(g.x); Bs[r][c4+1] = f2bf(g.y);
        Bs[r][c4+2] = f2bf(g.z); Bs[r][c4+3] = f2bf(g.w);
      }
    }
    __syncthreads();
    bf16x8 af[2], bfr[2];
    #pragma unroll
    for (int i=0;i<2;i++) af[i]  = *(const bf16x8*)&As[wm + i*16 + mr][quad*8];
    #pragma unroll
    for (int j=0;j<2;j++) bfr[j] = *(const bf16x8*)&Bs[wn + j*16 + mr][quad*8];
    #pragma unroll
    for (int i=0;i<2;i++)
      #pragma unroll
      for (int j=0;j<2;j++)
        acc[i][j] = __builtin_amdgcn_mfma_f32_16x16x32_bf16(af[i], bfr[j], acc[i][j], 0, 0, 0);
    __syncthreads();
  }
  #pragma unroll
  for (int i=0;i<2;i++){
    #pragma unroll
    for (int r=0;r<4;r++){
      int m = m0 + wm + i*16 + quad*4 + r;
      float rm = rowmul ? rowmul[m] : 1.f;
      i64 mrow = (combine == 4) ? (i64)(((m & 255) << 8) | (m >> 8)) : (i64)m;
      #pragma unroll
      for (int j=0;j<2;j++){
        int n = n0 + wn + j*16 + mr;
        float v = acc[i][j][r] * scale;
        if (bias) v += bias[n];
        if (act == 1) v = fmaxf(v, 0.f);
        else if (act == 2) v = 1.f/(1.f + __expf(-v));
        v *= rm;
        i64 idx = mrow*ldc + n;
        if (combine == 0) C[idx] = v;
        else if (combine == 1 || combine == 4) C[idx] += v;
        else if (combine == 2) C[idx] *= v;
        else C[idx] += aux[(i64)m*ldc + n] * v;
      }
    }
  }
}

// ---------------- fused QKV projection, bf16 outputs (tri-attn) ----------------
// One A read (32MB) feeds all 3 matrices (R14: 3 separate qkvb_k each re-streamed A).
// LDS 20.5KB; grid (1024,2). The R5-R9 failure ledger exonerated this fusion shape
// (R6/R7 failed WITHOUT it); the banned config remains pt_w1-on-mgemm64 only.
__global__ __launch_bounds__(256) void qkv3b_k(
    const float* __restrict__ X, const float* __restrict__ W3,
    unsigned short* __restrict__ Oq, unsigned short* __restrict__ Ok,
    unsigned short* __restrict__ Ov, float s0)
{
  int m0 = blockIdx.x * 64, n0 = blockIdx.y * 64;
  int tid = threadIdx.x;
  int wave = tid >> 6, lane = tid & 63;
  int quad = lane >> 4, mr = lane & 15;
  int wm = (wave >> 1) * 32, wn = (wave & 1) * 32;
  __shared__ unsigned short As[64][40];
  __shared__ unsigned short Bs[3][64][40];
  f32x4 acc[3][2][2];
  #pragma unroll
  for (int t=0;t<3;t++)
    #pragma unroll
    for (int i=0;i<2;i++)
      #pragma unroll
      for (int j=0;j<2;j++) acc[t][i][j] = (f32x4){0.f,0.f,0.f,0.f};

  for (int k0 = 0; k0 < 128; k0 += 32){
    #pragma unroll
    for (int it=0; it<2; it++){
      int lin = tid + it*256;
      int r = lin >> 3, c4 = (lin & 7) * 4;
      float4 g = *(const float4*)&X[(i64)(m0+r)*128 + k0 + c4];
      As[r][c4]   = f2bf(g.x); As[r][c4+1] = f2bf(g.y);
      As[r][c4+2] = f2bf(g.z); As[r][c4+3] = f2bf(g.w);
    }
    #pragma unroll
    for (int t=0;t<3;t++){
      const float* B = W3 + t*16384;
      #pragma unroll
      for (int it=0; it<2; it++){
        int lin = tid + it*256;
        int n = lin & 63, kg = (lin >> 6) * 4;
        float v0 = B[(i64)(k0+kg  )*128 + n0 + n];
        float v1 = B[(i64)(k0+kg+1)*128 + n0 + n];
        float v2 = B[(i64)(k0+kg+2)*128 + n0 + n];
        float v3 = B[(i64)(k0+kg+3)*128 + n0 + n];
        Bs[t][n][kg] = f2bf(v0); Bs[t][n][kg+1] = f2bf(v1);
        Bs[t][n][kg+2] = f2bf(v2); Bs[t][n][kg+3] = f2bf(v3);
      }
    }
    __syncthreads();
    bf16x8 af[2];
    #pragma unroll
    for (int i=0;i<2;i++) af[i] = *(const bf16x8*)&As[wm + i*16 + mr][quad*8];
    #pragma unroll
    for (int t=0;t<3;t++){
      bf16x8 b0 = *(const bf16x8*)&Bs[t][wn + mr][quad*8];
      bf16x8 b1 = *(const bf16x8*)&Bs[t][wn + 16 + mr][quad*8];
      #pragma unroll
      for (int i=0;i<2;i++){
        acc[t][i][0] = __builtin_amdgcn_mfma_f32_16x16x32_bf16(af[i], b0, acc[t][i][0], 0, 0, 0);
        acc[t][i][1] = __builtin_amdgcn_mfma_f32_16x16x32_bf16(af[i], b1, acc[t][i][1], 0, 0, 0);
      }
    }
    __syncthreads();
  }
  unsigned short* Os[3] = {Oq, Ok, Ov};
  #pragma unroll
  for (int t=0;t<3;t++){
    float sc = (t == 0) ? s0 : 1.f;
    #pragma unroll
    for (int i=0;i<2;i++){
      #pragma unroll
      for (int r=0;r<4;r++){
        int m = m0 + wm + i*16 + quad*4 + r;
        #pragma unroll
        for (int j=0;j<2;j++){
          int n = n0 + wn + j*16 + mr;
          Os[t][(i64)m*128 + n] = f2bf(acc[t][i][j][r] * sc);
        }
      }
    }
  }
}

// ---------------- fused dual-MFMA lin*sigmoid(gate) + transpose + mask for tri-mult ------
__global__ __launch_bounds__(256) void mlrgateT_k(
    const float* __restrict__ X,
    const float* __restrict__ Wl, const float* __restrict__ bl,
    const float* __restrict__ Wg, const float* __restrict__ bg,
    const float* __restrict__ mask, float* __restrict__ Out)
{
  int m0 = blockIdx.x * 64, n0 = blockIdx.y * 64;
  int tid = threadIdx.x;
  int wave = tid >> 6, lane = tid & 63;
  int quad = lane >> 4, mr = lane & 15;
  int wm = (wave >> 1) * 32, wn = (wave & 1) * 32;
  __shared__ __align__(16) char smem[16640];   // max(3*5120 staging, 64*65*4 transpose)
  unsigned short (*As)[40]  = (unsigned short(*)[40])(smem);
  unsigned short (*B1s)[40] = (unsigned short(*)[40])(smem + 5120);
  unsigned short (*B2s)[40] = (unsigned short(*)[40])(smem + 10240);
  float (*T)[65] = (float(*)[65])(smem);
  f32x4 acc1[2][2], acc2[2][2];
  #pragma unroll
  for (int i=0;i<2;i++)
    #pragma unroll
    for (int j=0;j<2;j++){ acc1[i][j] = (f32x4){0,0,0,0}; acc2[i][j] = (f32x4){0,0,0,0}; }

  for (int k0 = 0; k0 < 128; k0 += 32){
    #pragma unroll
    for (int it=0; it<2; it++){
      int lin = tid + it*256;
      int r = lin >> 3, c4 = (lin & 7) * 4;
      float4 g = *(const float4*)&X[(i64)(m0+r)*128 + k0 + c4];
      As[r][c4]   = f2bf(g.x); As[r][c4+1] = f2bf(g.y);
      As[r][c4+2] = f2bf(g.z); As[r][c4+3] = f2bf(g.w);
    }
    #pragma unroll
    for (int it=0; it<2; it++){
      int lin = tid + it*256;
      int n = lin & 63, kg = (lin >> 6) * 4;
      float a0 = Wl[(i64)(k0+kg  )*128 + n0 + n];
      float a1 = Wl[(i64)(k0+kg+1)*128 + n0 + n];
      float a2 = Wl[(i64)(k0+kg+2)*128 + n0 + n];
      float a3 = Wl[(i64)(k0+kg+3)*128 + n0 + n];
      B1s[n][kg] = f2bf(a0); B1s[n][kg+1] = f2bf(a1);
      B1s[n][kg+2] = f2bf(a2); B1s[n][kg+3] = f2bf(a3);
      float g0 = Wg[(i64)(k0+kg  )*128 + n0 + n];
      float g1 = Wg[(i64)(k0+kg+1)*128 + n0 + n];
      float g2 = Wg[(i64)(k0+kg+2)*128 + n0 + n];
      float g3 = Wg[(i64)(k0+kg+3)*128 + n0 + n];
      B2s[n][kg] = f2bf(g0); B2s[n][kg+1] = f2bf(g1);
      B2s[n][kg+2] = f2bf(g2); B2s[n][kg+3] = f2bf(g3);
    }
    __syncthreads();
    bf16x8 af[2], b1f[2], b2f[2];
    #pragma unroll
    for (int i=0;i<2;i++) af[i]  = *(const bf16x8*)&As[wm + i*16 + mr][quad*8];
    #pragma unroll
    for (int j=0;j<2;j++){
      b1f[j] = *(const bf16x8*)&B1s[wn + j*16 + mr][quad*8];
      b2f[j] = *(const bf16x8*)&B2s[wn + j*16 + mr][quad*8];
    }
    #pragma unroll
    for (int i=0;i<2;i++)
      #pragma unroll
      for (int j=0;j<2;j++){
        acc1[i][j] = __builtin_amdgcn_mfma_f32_16x16x32_bf16(af[i], b1f[j], acc1[i][j], 0, 0, 0);
        acc2[i][j] = __builtin_amdgcn_mfma_f32_16x16x32_bf16(af[i], b2f[j], acc2[i][j], 0, 0, 0);
      }
    __syncthreads();
  }
  // epilogue: gated value -> transposed LDS tile T[n_local][m_local]
  #pragma unroll
  for (int i=0;i<2;i++){
    #pragma unroll
    for (int r=0;r<4;r++){
      int ml = wm + i*16 + quad*4 + r;
      #pragma unroll
      for (int j=0;j<2;j++){
        int nl = wn + j*16 + mr;
        float lv = acc1[i][j][r] + bl[n0 + nl];
        float gv = acc2[i][j][r] + bg[n0 + nl];
        T[nl][ml] = lv * (1.f/(1.f + __expf(-gv)));
      }
    }
  }
  __syncthreads();
  // coalesced masked write: thread -> row n = tid>>2, 16-col segment ms = (tid&3)*16
  int n = tid >> 2, ms = (tid & 3) * 16;
  const float* mk = mask + m0 + ms;
  float* op = Out + (i64)(n0 + n)*NN_ + m0 + ms;
  #pragma unroll
  for (int e=0; e<16; e+=4){
    float4 t4;
    t4.x = T[n][ms+e]   * mk[e];
    t4.y = T[n][ms+e+1] * mk[e+1];
    t4.z = T[n][ms+e+2] * mk[e+2];
    t4.w = T[n][ms+e+3] * mk[e+3];
    *(float4*)(op + e) = t4;
  }
}

// ---------------- pair transition, stage 1: H(bf16) = relu(X @ W1 + b1) ----------------
__global__ __launch_bounds__(256) void ptw1_k(
    const float* __restrict__ X, const float* __restrict__ W1,
    const float* __restrict__ b1, unsigned short* __restrict__ H)
{
  int m0 = blockIdx.x * 128, n0 = blockIdx.y * 128;
  int tid = threadIdx.x;
  int wave = tid >> 6, lane = tid & 63;
  int quad = lane >> 4, mr = lane & 15;
  int wm = (wave >> 1) * 64, wn = (wave & 1) * 64;
  __shared__ unsigned short As[128][40];
  __shared__ unsigned short Bs[128][40];
  f32x4 acc[4][4];
  #pragma unroll
  for (int i=0;i<4;i++)
    #pragma unroll
    for (int j=0;j<4;j++) acc[i][j] = (f32x4){0.f,0.f,0.f,0.f};

  for (int k0 = 0; k0 < 128; k0 += 32){
    #pragma unroll
    for (int it=0; it<4; it++){
      int lin = tid + it*256;
      int r = lin >> 3, c4 = (lin & 7) * 4;
      float4 g = *(const float4*)&X[(i64)(m0+r)*128 + k0 + c4];
      As[r][c4]   = f2bf(g.x); As[r][c4+1] = f2bf(g.y);
      As[r][c4+2] = f2bf(g.z); As[r][c4+3] = f2bf(g.w);
    }
    #pragma unroll
    for (int it=0; it<4; it++){
      int lin = tid + it*256;
      int n = lin & 127, kg = (lin >> 7) * 4;
      float v0 = W1[(i64)(k0+kg  )*512 + n0 + n];
      float v1 = W1[(i64)(k0+kg+1)*512 + n0 + n];
      float v2 = W1[(i64)(k0+kg+2)*512 + n0 + n];
      float v3 = W1[(i64)(k0+kg+3)*512 + n0 + n];
      Bs[n][kg] = f2bf(v0); Bs[n][kg+1] = f2bf(v1);
      Bs[n][kg+2] = f2bf(v2); Bs[n][kg+3] = f2bf(v3);
    }
    __syncthreads();
    bf16x8 af[4], bfr[4];
    #pragma unroll
    for (int i=0;i<4;i++) af[i]  = *(const bf16x8*)&As[wm + i*16 + mr][quad*8];
    #pragma unroll
    for (int j=0;j<4;j++) bfr[j] = *(const bf16x8*)&Bs[wn + j*16 + mr][quad*8];
    #pragma unroll
    for (int i=0;i<4;i++)
      #pragma unroll
      for (int j=0;j<4;j++)
        acc[i][j] = __builtin_amdgcn_mfma_f32_16x16x32_bf16(af[i], bfr[j], acc[i][j], 0, 0, 0);
    __syncthreads();
  }
  #pragma unroll
  for (int i=0;i<4;i++){
    #pragma unroll
    for (int r=0;r<4;r++){
      int m = m0 + wm + i*16 + quad*4 + r;
      #pragma unroll
      for (int j=0;j<4;j++){
        int n = n0 + wn + j*16 + mr;
        float v = fmaxf(acc[i][j][r] + b1[n], 0.f);
        H[(i64)m*512 + n] = f2bf(v);
      }
    }
  }
}

// ---------------- pair transition, stage 2: pa += H(bf16) @ W2 + b2 ----------------
__global__ __launch_bounds__(256) void ptw2_k(
    const unsigned short* __restrict__ H, const float* __restrict__ W2,
    const float* __restrict__ b2, float* __restrict__ pa)
{
  int m0 = blockIdx.x * 64, n0 = blockIdx.y * 64;
  int tid = threadIdx.x;
  int wave = tid >> 6, lane = tid & 63;
  int quad = lane >> 4, mr = lane & 15;
  int wm = (wave >> 1) * 32, wn = (wave & 1) * 32;
  __shared__ unsigned short As[64][40];
  __shared__ unsigned short Bs[64][40];
  f32x4 acc[2][2];
  #pragma unroll
  for (int i=0;i<2;i++)
    #pragma unroll
    for (int j=0;j<2;j++) acc[i][j] = (f32x4){0.f,0.f,0.f,0.f};

  for (int k0 = 0; k0 < 512; k0 += 32){
    #pragma unroll
    for (int it=0; it<2; it++){
      int lin = tid + it*256;
      int r = lin >> 3, c4 = (lin & 7) * 4;
      *(uint2*)&As[r][c4] = *(const uint2*)&H[(i64)(m0+r)*512 + k0 + c4];
    }
    #pragma unroll
    for (int it=0; it<2; it++){
      int lin = tid + it*256;
      int n = lin & 63, kg = (lin >> 6) * 4;
      float v0 = W2[(i64)(k0+kg  )*128 + n0 + n];
      float v1 = W2[(i64)(k0+kg+1)*128 + n0 + n];
      float v2 = W2[(i64)(k0+kg+2)*128 + n0 + n];
      float v3 = W2[(i64)(k0+kg+3)*128 + n0 + n];
      Bs[n][kg] = f2bf(v0); Bs[n][kg+1] = f2bf(v1);
      Bs[n][kg+2] = f2bf(v2); Bs[n][kg+3] = f2bf(v3);
    }
    __syncthreads();
    bf16x8 af[2], bfr[2];
    #pragma unroll
    for (int i=0;i<2;i++) af[i]  = *(const bf16x8*)&As[wm + i*16 + mr][quad*8];
    #pragma unroll
    for (int j=0;j<2;j++) bfr[j] = *(const bf16x8*)&Bs[wn + j*16 + mr][quad*8];
    #pragma unroll
    for (int i=0;i<2;i++)
      #pragma unroll
      for (int j=0;j<2;j++)
        acc[i][j] = __builtin_amdgcn_mfma_f32_16x16x32_bf16(af[i], bfr[j], acc[i][j], 0, 0, 0);
    __syncthreads();
  }
  #pragma unroll
  for (int i=0;i<2;i++){
    #pragma unroll
    for (int r=0;r<4;r++){
      int m = m0 + wm + i*16 + quad*4 + r;
      #pragma unroll
      for (int j=0;j<2;j++){
        int n = n0 + wn + j*16 + mr;
        pa[(i64)m*128 + n] += acc[i][j][r] + b2[n];
      }
    }
  }
}

// ---------------- generic batched GEMM (fp32, 64x64 tile) ----------------
template<bool TA, bool TB>
__global__ __launch_bounds__(256) void gemm_k(
    const float* __restrict__ A, int lda, i64 sA,
    const float* __restrict__ B, int ldb, i64 sB,
    float* __restrict__ C, int ldc, i64 sC,
    int M, int N, int K,
    const float* __restrict__ bias, float scale, int act,
    const float* __restrict__ rowmul, int combine)
{
  A += (i64)blockIdx.z * sA;
  B += (i64)blockIdx.z * sB;
  C += (i64)blockIdx.z * sC;
  int m0 = blockIdx.x * 64, n0 = blockIdx.y * 64;
  int tid = threadIdx.x, tx = tid & 15, ty = tid >> 4;
  __shared__ float As[16][68], Bs[16][68];
  float acc[4][4] = {};
  for (int k0 = 0; k0 < K; k0 += 16){
    if (TA){
      for (int l = tid; l < 1024; l += 256){
        int kk = l >> 6, mi = l & 63; int m = m0 + mi;
        As[kk][mi] = (m < M) ? A[(i64)(k0+kk)*lda + m] : 0.f;
      }
    } else {
      for (int l = tid; l < 1024; l += 256){
        int mi = l >> 4, kk = l & 15; int m = m0 + mi;
        As[kk][mi] = (m < M) ? A[(i64)m*lda + k0 + kk] : 0.f;
      }
    }
    if (TB){
      for (int l = tid; l < 1024; l += 256){
        int ni = l >> 4, kk = l & 15; int n = n0 + ni;
        Bs[kk][ni] = (n < N) ? B[(i64)n*ldb + k0 + kk] : 0.f;
      }
    } else {
      for (int l = tid; l < 1024; l += 256){
        int kk = l >> 6, ni = l & 63; int n = n0 + ni;
        Bs[kk][ni] = (n < N) ? B[(i64)(k0+kk)*ldb + n] : 0.f;
      }
    }
    __syncthreads();
    #pragma unroll
    for (int kk = 0; kk < 16; ++kk){
      float4 av4 = *(const float4*)&As[kk][ty*4];
      float4 bv4 = *(const float4*)&Bs[kk][tx*4];
      float av[4] = {av4.x, av4.y, av4.z, av4.w};
      float bv[4] = {bv4.x, bv4.y, bv4.z, bv4.w};
      #pragma unroll
      for (int i=0;i<4;i++)
        #pragma unroll
        for (int j=0;j<4;j++) acc[i][j] = fmaf(av[i], bv[j], acc[i][j]);
    }
    __syncthreads();
  }
  #pragma unroll
  for (int i=0;i<4;i++){
    int m = m0 + ty*4 + i;
    if (m >= M) continue;
    float rm = rowmul ? rowmul[m] : 1.f;
    #pragma unroll
    for (int j=0;j<4;j++){
      int n = n0 + tx*4 + j;
      if (n >= N) continue;
      float v = acc[i][j] * scale;
      if (bias) v += bias[n];
      if (act == 1) v = fmaxf(v, 0.f);
      else if (act == 2) v = 1.f/(1.f + expf(-v));
      v *= rm;
      i64 idx = (i64)m*ldc + n;
      if (combine == 0) C[idx] = v;
      else if (combine == 1) C[idx] += v;
      else C[idx] *= v;
    }
  }
}

// ---------------- thin GEMM (small M): split-K two-phase ----------------
__global__ __launch_bounds__(256) void gemm_part_k(
    const float* __restrict__ A, int lda,
    const float* __restrict__ B, int ldb,
    float* __restrict__ Cp, int M, int N, int K, int chunk)
{
  int m0 = blockIdx.x*16, n0 = blockIdx.y*64, z = blockIdx.z;
  int kb = z*chunk, ke = min(K, kb+chunk);
  int tid = threadIdx.x;
  int mi = tid >> 4, ni4 = (tid & 15)*4;
  __shared__ float As[16][17], Bs[16][68];
  float acc[4] = {0.f,0.f,0.f,0.f};
  for (int k0 = kb; k0 < ke; k0 += 16){
    { int r = tid>>4, c = tid&15; int m = m0+r;
      As[c][r] = (m < M) ? A[(i64)m*lda + k0 + c] : 0.f; }
    for (int l = tid; l < 1024; l += 256){
      int kk = l>>6, nn = l&63; int n = n0+nn;
      Bs[kk][nn] = (n < N) ? B[(i64)(k0+kk)*ldb + n] : 0.f;
    }
    __syncthreads();
    #pragma unroll
    for (int kk=0;kk<16;kk++){
      float a = As[kk][mi];
      float4 b = *(const float4*)&Bs[kk][ni4];
      acc[0]=fmaf(a,b.x,acc[0]); acc[1]=fmaf(a,b.y,acc[1]);
      acc[2]=fmaf(a,b.z,acc[2]); acc[3]=fmaf(a,b.w,acc[3]);
    }
    __syncthreads();
  }
  int m = m0+mi, n = n0+ni4;
  if (m < M && n < N) *(float4*)&Cp[((i64)z*M + m)*N + n] = *(float4*)acc;
}

__global__ __launch_bounds__(256) void gemm_reduce_k(
    const float* __restrict__ Cp, float* __restrict__ C, int ldc,
    int M, int N, int S,
    const float* __restrict__ bias, float scale, int act,
    const float* __restrict__ rowmul, int combine)
{
  i64 idx = (i64)blockIdx.x*256 + threadIdx.x;
  if (idx >= (i64)M*N) return;
  int m = (int)(idx / N), n = (int)(idx % N);
  float s = 0.f;
  for (int z=0; z<S; z++) s += Cp[(i64)z*M*N + idx];
  float v = s*scale;
  if (bias) v += bias[n];
  if (act == 1) v = fmaxf(v, 0.f);
  else if (act == 2) v = 1.f/(1.f + expf(-v));
  if (rowmul) v *= rowmul[m];
  i64 o = (i64)m*ldc + n;
  if (combine == 0) C[o] = v;
  else if (combine == 1) C[o] += v;
  else C[o] *= v;
}

// ---------------- OPM ----------------
__global__ __launch_bounds__(128) void opm_wd_k(const float* __restrict__ right, const float* __restrict__ W,
                                                float* __restrict__ Wd){
  int d = blockIdx.x, c = blockIdx.y, f = threadIdx.x;
  float acc = 0.f;
  #pragma unroll
  for (int e=0;e<32;e++) acc = fmaf(right[d*32+e], W[((i64)c*32+e)*128 + f], acc);
  Wd[((i64)d*32+c)*128 + f] = acc;
}

// pa[d,b,f] = pair_act[d,b,f] + (sum_c left[b,c]*Wd[d,c,f] + ob[f]) / (1e-3 + sm[d]*sm[b])
__global__ __launch_bounds__(128) void opm_final_k(const float* __restrict__ left, const float* __restrict__ Wd,
                                                   const float* __restrict__ ob, const float* __restrict__ sm,
                                                   const float* __restrict__ pair_act, float* __restrict__ pa){
  int d = blockIdx.x, b0 = blockIdx.y*16, f = threadIdx.x;
  __shared__ float wd_s[32][128];
  __shared__ float l_s[16][32];
  for (int c=0;c<32;c++) wd_s[c][f] = Wd[((i64)d*32+c)*128 + f];
  for (int l = f; l < 512; l += 128){ int bi=l>>5, c=l&31; l_s[bi][c] = left[(b0+bi)*32 + c]; }
  __syncthreads();
  float md = sm[d], obf = ob[f];
  for (int bi=0;bi<16;bi++){
    float acc = 0.f;
    #pragma unroll
    for (int c=0;c<32;c++) acc = fmaf(l_s[bi][c], wd_s[c][f], acc);
    int b = b0+bi;
    i64 idx = ((i64)d*256 + b)*128 + f;
    pa[idx] = pair_act[idx] + (acc + obf) / (1e-3f + md*sm[b]);
  }
}

// ---------------- row attention core ----------------
__global__ __launch_bounds__(256) void ra_attn_k(const float* __restrict__ q, const float* __restrict__ k,
                                                 const float* __restrict__ v, const float* __restrict__ nb,
                                                 const float* __restrict__ sm, float* __restrict__ wa){
  int qi = blockIdx.x, h = blockIdx.y, tid = threadIdx.x;
  __shared__ float qv[48];
  __shared__ float p[256];
  __shared__ float red[256];
  if (tid < 48) qv[tid] = q[(i64)qi*384 + h*48 + tid];
  __syncthreads();
  float acc = 0.f;
  const float* kr = k + (i64)tid*384 + h*48;
  #pragma unroll
  for (int c=0;c<48;c++) acc = fmaf(qv[c], kr[c], acc);
  acc += 1e9f*(sm[tid]-1.f) + nb[((i64)qi*256 + tid)*8 + h];
  red[tid] = acc; __syncthreads();
  for (int off=128;off>0;off>>=1){ if (tid<off) red[tid] = fmaxf(red[tid], red[tid+off]); __syncthreads(); }
  float mx = red[0]; __syncthreads();
  float e = expf(acc - mx);
  red[tid] = e; __syncthreads();
  for (int off=128;off>0;off>>=1){ if (tid<off) red[tid] += red[tid+off]; __syncthreads(); }
  p[tid] = e / red[0];
  __syncthreads();
  if (tid < 48){
    float a = 0.f;
    for (int kk=0;kk<256;kk++) a = fmaf(p[kk], v[(i64)kk*384 + h*48 + tid], a);
    wa[(i64)qi*384 + h*48 + tid] = a;
  }
}

// ---------------- triangle attention core v11: guarded rescale (T13 exact variant) -------
// R14: occ 68% but VALU 43% -> softmax VALU chain bound. When no lane's max grows,
// alpha == exp(0) == 1 exactly; skip the exp + 17 rescale mults (bit-identical).
__global__ __launch_bounds__(256, 8) void ta_mfma_k(
    const unsigned short* __restrict__ q, const unsigned short* __restrict__ k,
    const unsigned short* __restrict__ v,
    const float* __restrict__ nbQ, const float* __restrict__ mask, int maskT,
    float* __restrict__ wa)
{
  int d = blockIdx.x;
  int xcd = d & 7, y = d >> 3;
  int b = xcd*32 + (y >> 4);
  int w = y & 15;
  int qblk = w & 3, h = w >> 2;
  int tid = threadIdx.x;
  int wave = tid >> 6, lane = tid & 63;
  int quad = lane >> 4, mr = lane & 15;
  const i64 base = ((i64)b*256)*128 + h*32;

  __shared__ __align__(16) unsigned short Ks[64][40];    // [key][c], 64-key quarter
  __shared__ __align__(16) unsigned short Vt[32][72];    // [c][key], 64-key quarter
  __shared__ __align__(16) float mask_s[256];
  __shared__ __align__(16) unsigned short Pl[4][16][40]; // per-wave P [q][key]

  mask_s[tid] = 1e9f * ((maskT ? mask[(i64)tid*256 + b] : mask[(i64)b*256 + tid]) - 1.f);

  int q0w = qblk*64 + wave*16;
  int qg = q0w + mr;
  const float* nbq = nbQ + (i64)h*65536 + (i64)qg*256;

  bf16x8 qf = *(const bf16x8*)(q + base + (i64)qg*128 + quad*8);

  f32x4 o0 = (f32x4){0,0,0,0}, o1 = (f32x4){0,0,0,0};
  float mm = -1e30f, ll = 0.f;

  for (int qt = 0; qt < 4; qt++){
    __syncthreads();
    #pragma unroll
    for (int it=0; it<2; it++){
      int idx = it*256 + tid;
      int kl = idx >> 3, c4 = (idx & 7)*4;
      i64 roff = base + (i64)(qt*64 + kl)*128 + c4;
      *(uint2*)&Ks[kl][c4] = *(const uint2*)(k + roff);
      uint2 gv = *(const uint2*)(v + roff);
      const unsigned short* pv = (const unsigned short*)&gv;
      Vt[c4  ][kl] = pv[0];
      Vt[c4+1][kl] = pv[1];
      Vt[c4+2][kl] = pv[2];
      Vt[c4+3][kl] = pv[3];
    }
    __syncthreads();

    #pragma unroll
    for (int it=0; it<2; it++){
      int kc = it*32;
      int kg = qt*64 + kc;
      bf16x8 kf0 = *(const bf16x8*)&Ks[kc + mr][quad*8];
      bf16x8 kf1 = *(const bf16x8*)&Ks[kc + 16 + mr][quad*8];
      f32x4 s0 = __builtin_amdgcn_mfma_f32_16x16x32_bf16(kf0, qf, (f32x4){0,0,0,0}, 0, 0, 0);
      f32x4 s1 = __builtin_amdgcn_mfma_f32_16x16x32_bf16(kf1, qf, (f32x4){0,0,0,0}, 0, 0, 0);
      float4 nb0 = *(const float4*)(nbq + kg + quad*4);
      float4 nb1 = *(const float4*)(nbq + kg + 16 + quad*4);
      float4 mk0 = *(const float4*)&mask_s[kg + quad*4];
      float4 mk1 = *(const float4*)&mask_s[kg + 16 + quad*4];
      s0[0] += nb0.x + mk0.x; s0[1] += nb0.y + mk0.y; s0[2] += nb0.z + mk0.z; s0[3] += nb0.w + mk0.w;
      s1[0] += nb1.x + mk1.x; s1[1] += nb1.y + mk1.y; s1[2] += nb1.z + mk1.z; s1[3] += nb1.w + mk1.w;

      float tm = fmaxf(fmaxf(fmaxf(s0[0],s0[1]), fmaxf(s0[2],s0[3])),
                       fmaxf(fmaxf(s1[0],s1[1]), fmaxf(s1[2],s1[3])));
      tm = fmaxf(tm, __shfl_xor(tm, 16));
      tm = fmaxf(tm, __shfl_xor(tm, 32));
      // T13 exact variant: rescale only if some lane's max grew (else alpha==1 bit-exactly)
      if (__any(tm > mm)){
        float nm = fmaxf(mm, tm);
        float alpha = __expf(mm - nm);
        mm = nm;
        ll *= alpha;
        o0 *= alpha; o1 *= alpha;
      }
      float e00 = __expf(s0[0]-mm), e01 = __expf(s0[1]-mm);
      float e02 = __expf(s0[2]-mm), e03 = __expf(s0[3]-mm);
      float e10 = __expf(s1[0]-mm), e11 = __expf(s1[1]-mm);
      float e12 = __expf(s1[2]-mm), e13 = __expf(s1[3]-mm);
      float ps = ((e00+e01) + (e02+e03)) + ((e10+e11) + (e12+e13));
      ps += __shfl_xor(ps, 16);
      ps += __shfl_xor(ps, 32);
      ll += ps;
      unsigned int p0 = (unsigned int)f2bf(e00) | ((unsigned int)f2bf(e01)<<16);
      unsigned int p1 = (unsigned int)f2bf(e02) | ((unsigned int)f2bf(e03)<<16);
      unsigned int p2 = (unsigned int)f2bf(e10) | ((unsigned int)f2bf(e11)<<16);
      unsigned int p3 = (unsigned int)f2bf(e12) | ((unsigned int)f2bf(e13)<<16);
      *(uint2*)&Pl[wave][mr][quad*4]      = make_uint2(p0, p1);
      *(uint2*)&Pl[wave][mr][16 + quad*4] = make_uint2(p2, p3);
      bf16x8 pf  = *(const bf16x8*)&Pl[wave][mr][quad*8];
      bf16x8 vf0 = *(const bf16x8*)&Vt[mr     ][kc + quad*8];
      bf16x8 vf1 = *(const bf16x8*)&Vt[16 + mr][kc + quad*8];
      o0 = __builtin_amdgcn_mfma_f32_16x16x32_bf16(vf0, pf, o0, 0, 0, 0);
      o1 = __builtin_amdgcn_mfma_f32_16x16x32_bf16(vf1, pf, o1, 0, 0, 0);
    }
  }

  float inv = 1.f/ll;
  float* wp = wa + base + (i64)qg*128;
  *(float4*)(wp + quad*4)      = make_float4(o0[0]*inv, o0[1]*inv, o0[2]*inv, o0[3]*inv);
  *(float4*)(wp + 16 + quad*4) = make_float4(o1[0]*inv, o1[1]*inv, o1[2]*inv, o1[3]*inv);
}

// ---------------- host dispatch ----------------
static void gemm(hipStream_t st, bool TA, bool TB,
                 const float* A, int lda, i64 sA,
                 const float* B, int ldb, i64 sB,
                 float* C, int ldc, i64 sC,
                 int M, int N, int K, int batch,
                 const float* bias, float scale, int act,
                 const float* rowmul, int combine)
{
  dim3 g((M+63)/64, (N+63)/64, batch), bl(256);
  if (!TA && !TB)      gemm_k<false,false><<<g,bl,0,st>>>(A,lda,sA,B,ldb,sB,C,ldc,sC,M,N,K,bias,scale,act,rowmul,combine);
  else if (!TA &&  TB) gemm_k<false,true ><<<g,bl,0,st>>>(A,lda,sA,B,ldb,sB,C,ldc,sC,M,N,K,bias,scale,act,rowmul,combine);
  else                 gemm_k<true ,false><<<g,bl,0,st>>>(A,lda,sA,B,ldb,sB,C,ldc,sC,M,N,K,bias,scale,act,rowmul,combine);
}

static void mgemm(hipStream_t st, bool TA, bool TB,
                  const float* A, int lda, i64 sA,
                  const float* B, int ldb, i64 sB,
                  float* C, int ldc, i64 sC,
                  int M, int N, int K, int batch,
                  const float* bias, float scale, int act,
                  const float* rowmul, int combine, const float* aux = nullptr)
{
  dim3 bl(256);
  i64 nb128 = (i64)(M/128)*(N/128)*batch;
  if (nb128 < 1024 && (M % 64) == 0 && (N % 64) == 0){
    dim3 g(M/64, N/64, batch);
    if (!TA && !TB)      mgemm64_k<false,false><<<g,bl,0,st>>>(A,lda,sA,B,ldb,sB,C,ldc,sC,M,N,K,bias,scale,act,rowmul,combine,aux);
    else if (!TA &&  TB) mgemm64_k<false,true ><<<g,bl,0,st>>>(A,lda,sA,B,ldb,sB,C,ldc,sC,M,N,K,bias,scale,act,rowmul,combine,aux);
    else                 mgemm64_k<true ,false><<<g,bl,0,st>>>(A,lda,sA,B,ldb,sB,C,ldc,sC,M,N,K,bias,scale,act,rowmul,combine,aux);
    return;
  }
  dim3 g(M/128, N/128, batch);
  if (!TA && !TB)      mgemm_k<false,false><<<g,bl,0,st>>>(A,lda,sA,B,ldb,sB,C,ldc,sC,M,N,K,bias,scale,act,rowmul,combine,aux);
  else if (!TA &&  TB) mgemm_k<false,true ><<<g,bl,0,st>>>(A,lda,sA,B,ldb,sB,C,ldc,sC,M,N,K,bias,scale,act,rowmul,combine,aux);
  else                 mgemm_k<true ,false><<<g,bl,0,st>>>(A,lda,sA,B,ldb,sB,C,ldc,sC,M,N,K,bias,scale,act,rowmul,combine,aux);
}

static void gemm_thin(hipStream_t st,
                      const float* A, int lda, const float* B, int ldb,
                      float* C, int ldc, int M, int N, int K,
                      const float* bias, float scale, int act,
                      const float* rowmul, int combine, float* part)
{
  const int S = 8;
  int chunk = ((K/S + 15)/16)*16; if (chunk < 16) chunk = 16;
  dim3 g((M+15)/16, (N+63)/64, S);
  gemm_part_k<<<g,256,0,st>>>(A,lda,B,ldb,part,M,N,K,chunk);
  i64 t = (i64)M*N;
  gemm_reduce_k<<<(int)((t+255)/256),256,0,st>>>(part,C,ldc,M,N,S,bias,scale,act,rowmul,combine);
}

extern "C" void kernel_launch(void* const* d_in, const int* in_sizes, int n_in,
                              void* d_out, int out_size, void* d_ws, size_t ws_size,
                              hipStream_t stream)
{
  const float* IN[64];
  for (int i=0;i<n_in && i<64;i++) IN[i] = (const float*)d_in[i];

  const float* single_act = IN[0];
  const float* pair_act   = IN[1];
  const float* sm         = IN[2];
  const float* pm         = IN[3];
  const float* opm_ln     = IN[4];
  const float* opm_lr_w   = IN[5];
  const float* opm_lr_b   = IN[6];
  const float* opm_out_w  = IN[7];
  const float* opm_out_b  = IN[8];
  const float* ra_ln      = IN[9];
  const float* ra_pair_ln = IN[10];
  const float* ra_feat_w  = IN[11];
  const float* ra_qkv_w   = IN[12];
  const float* ra_gate_w  = IN[13];
  const float* ra_gate_b  = IN[14];
  const float* ra_o_w     = IN[15];
  const float* ra_o_b     = IN[16];
  const float* st_ln      = IN[17];
  const float* st_w1      = IN[18];
  const float* st_b1      = IN[19];
  const float* st_w2      = IN[20];
  const float* st_b2      = IN[21];
  const float* pt_ln      = IN[56];
  const float* pt_w1      = IN[57];
  const float* pt_b1      = IN[58];
  const float* pt_w2      = IN[59];
  const float* pt_b2      = IN[60];

  float* sa = (float*)d_out;           // [256,384]
  float* pa = (float*)d_out + 98304;   // [256,256,128]

  float* W  = (float*)d_ws;
  float* B0 = W;
  float* B1 = W + 8388608L;
  float* B2 = W + 16777216L;
  float* B3 = W + 25165824L;
  float* SMA = W + 33554432L;
  float* xs   = SMA;
  float* qb   = SMA +  98304;
  float* kb   = SMA + 196608;
  float* vb   = SMA + 294912;
  float* wab  = SMA + 393216;
  float* hst  = SMA + 491520;   // 393216
  float* nbra = SMA + 884736;   // 524288 (nb buffers: ra qkh-major / ta [h][q][k])
  float* lbuf = SMA + 1409024;  // 8192
  float* rbuf = SMA + 1417216;  // 8192
  float* Wd   = SMA + 1425408;  // 1048576

  // bf16 QKV buffers for tri-attn: q,k packed into B2, v into first half of B3.
  unsigned short* qb16 = (unsigned short*)B2;
  unsigned short* kb16 = (unsigned short*)B2 + 8388608L;
  unsigned short* vb16 = (unsigned short*)B3;

  // init sa with residual base (pa is initialized by opm_final_k's fused write)
  copy_k<<<384, 256, 0, stream>>>(sa, single_act, 98304L);

  // ---- 1) OPM -> pair residual (writes pa = pair_act + update) ----
  ln_k<<<256,128,0,stream>>>(single_act, xs, opm_ln, 384);
  gemm_thin(stream, xs,384, opm_lr_w,32,       lbuf,32, 256,32,384, opm_lr_b,    1.f,0, sm,0, B1);
  gemm_thin(stream, xs,384, opm_lr_w+12288,32, rbuf,32, 256,32,384, opm_lr_b+32, 1.f,0, sm,0, B1);
  opm_wd_k<<<dim3(256,32),128,0,stream>>>(rbuf, opm_out_w, Wd);
  opm_final_k<<<dim3(256,16),128,0,stream>>>(lbuf, Wd, opm_out_b, sm, pair_act, pa);

  // ---- 2) row attention with pair bias ----
  ln_k<<<256,128,0,stream>>>(sa, xs, ra_ln, 384);
  ln128_k<<<16384,256,0,stream>>>(pa, B0, ra_pair_ln, 0);
  feat8_k<<<256,256,0,stream>>>(B0, ra_feat_w, nbra);
  const float qs_ra = 0.14433756729740643f; // 1/sqrt(48)
  gemm_thin(stream, xs,384, ra_qkv_w,384,        qb,384, 256,384,384, nullptr,qs_ra,0,nullptr,0, B1);
  gemm_thin(stream, xs,384, ra_qkv_w+147456,384, kb,384, 256,384,384, nullptr,1.f,0,nullptr,0, B1);
  gemm_thin(stream, xs,384, ra_qkv_w+294912,384, vb,384, 256,384,384, nullptr,1.f,0,nullptr,0, B1);
  ra_attn_k<<<dim3(256,8),256,0,stream>>>(qb, kb, vb, nbra, sm, wab);
  gemm_thin(stream, xs,384,  ra_gate_w,384, wab,384, 256,384,384, ra_gate_b,1.f,2,nullptr,2, B1);
  gemm_thin(stream, wab,384, ra_o_w,384,    sa,384,  256,384,384, ra_o_b,   1.f,0,nullptr,1, B1);

  // ---- 3) single transition ----
  ln_k<<<256,128,0,stream>>>(sa, xs, st_ln, 384);
  gemm_thin(stream, xs,384,   st_w1,1536, hst,1536, 256,1536,384, st_b1,1.f,1,nullptr,0, B1);
  gemm_thin(stream, hst,1536, st_w2,384,  sa,384,   256,384,1536, st_b2,1.f,0,nullptr,1, B1);

  // ---- 4/5) triangle multiplications ----
  auto tri_mult = [&](int base, bool outgoing){
    const float* ln_w = IN[base+0];
    const float* lr_w = IN[base+1];
    const float* lr_b = IN[base+2];
    const float* gw   = IN[base+3];
    const float* gb   = IN[base+4];
    const float* cln  = IN[base+5];
    const float* ow   = IN[base+6];
    const float* ob   = IN[base+7];
    const float* ogw  = IN[base+8];
    const float* ogb  = IN[base+9];
    ln128_k<<<16384,256,0,stream>>>(pa, B0, ln_w, 0);
    // left/right = mask * (X@W+b) * sigmoid(X@Wg+bg), written DIRECTLY ch-major (fused transpose)
    mlrgateT_k<<<dim3(1024,2),256,0,stream>>>(B0, lr_w, lr_b, gw, gb, pm, B1);
    mlrgateT_k<<<dim3(1024,2),256,0,stream>>>(B0, lr_w+16384, lr_b+128, gw+16384, gb+128, pm, B2);
    if (outgoing) // out[i,j,c] = sum_k L_c[i,k] * R_c[j,k]
      mgemm(stream,false,true, B1,256,65536, B2,256,65536, B3,256,65536, 256,256,256,128, nullptr,1.f,0,nullptr,0);
    else          // out[i,j,c] = sum_k R_c[k,i] * L_c[k,j]
      mgemm(stream,true,false, B2,256,65536, B1,256,65536, B3,256,65536, 256,256,256,128, nullptr,1.f,0,nullptr,0);
    chw2hwc_k<<<dim3(2048,4),256,0,stream>>>(B3, B1);
    ln128_k<<<16384,256,0,stream>>>(B1, B3, cln, 0);
    mgemm(stream,false,false, B3,128,0, ow,128,0,  B1,128,0, 65536,128,128,1, ob,  1.f,0,nullptr,0);
    // fused: pa += B1 * sigmoid(B0@ogw + ogb)
    mgemm(stream,false,false, B0,128,0, ogw,128,0, pa,128,0, 65536,128,128,1, ogb, 1.f,2,nullptr,3, B1);
  };
  tri_mult(22, true);   // tmo
  tri_mult(32, false);  // tmi

  // ---- 6/7) triangle attentions ----
  auto tri_attn = [&](int base, bool percol){
    const float* ln_w   = IN[base+0];
    const float* feat_w = IN[base+1];
    const float* qkv_w  = IN[base+2];
    const float* gw     = IN[base+3];
    const float* gb     = IN[base+4];
    const float* ow     = IN[base+5];
    const float* ob     = IN[base+6];
    // LN with fused pair-transpose read for per-column attention
    ln128_k<<<16384,256,0,stream>>>(pa, B0, ln_w, percol?1:0);
    feat4_k<<<256,256,0,stream>>>(B0, feat_w, nbra);  // nb[h][q][k] direct
    const float qs = 0.17677669529663687f; // 1/sqrt(32)
    // fused QKV: one A read, three bf16 outputs
    qkv3b_k<<<dim3(1024,2),256,0,stream>>>(B0, qkv_w, qb16, kb16, vb16, qs);
    ta_mfma_k<<<dim3(4096),256,0,stream>>>(qb16, kb16, vb16, nbra, pm, percol?1:0, B1);
    mgemm(stream,false,false, B0,128,0, gw,128,0, B1,128,0, 65536,128,128,1, gb,1.f,2,nullptr,2); // wa *= sigmoid(gate)
    // out-projection fused with residual add (4 = transpose-pair write for per-column)
    mgemm(stream,false,false, B1,128,0, ow,128,0, pa,128,0, 65536,128,128,1, ob,1.f,0,nullptr, percol?4:1);
  };
  tri_attn(42, false);  // tas (per-row)
  tri_attn(49, true);   // tae (per-column)

  // ---- 8) pair transition: full-M, H in bf16 spanning B1+B2 ----
  ln128_k<<<16384,256,0,stream>>>(pa, B0, pt_ln, 0);
  ptw1_k<<<dim3(512,4),256,0,stream>>>(B0, pt_w1, pt_b1, (unsigned short*)B1);
  ptw2_k<<<dim3(1024,2),256,0,stream>>>((const unsigned short*)B1, pt_w2, pt_b2, pa);
}